// Round 1
// baseline (2313.769 us; speedup 1.0000x reference)
//
#include <hip/hip_runtime.h>
#include <math.h>

#define TT 2048
#define HH 16
#define DD 64
#define EE 1024
#define NN 3072

// ---------------------------------------------------------------------------
// GEMM1: qkv = x @ w_attn  (2048x1024 @ 1024x3072), epilogue splits q/k/v raw
// fp32 tiled: BM=BN=64, BK=16, 256 thr, 4x4 microtile
// ---------------------------------------------------------------------------
__global__ __launch_bounds__(256) void gemm_qkv_kernel(
    const float* __restrict__ A, const float* __restrict__ B,
    float* __restrict__ q_raw, float* __restrict__ k_raw, float* __restrict__ v_raw)
{
    const int K = EE, N = NN;
    __shared__ float As[16][68];   // [kk][row], padded
    __shared__ float Bs[16][64];   // [kk][col]
    int tid = threadIdx.x;
    int tx = tid & 15, ty = tid >> 4;
    int row0 = blockIdx.y * 64, col0 = blockIdx.x * 64;
    int arow = tid >> 2, ak4 = (tid & 3) << 2;
    int brow = tid >> 4, bc4 = (tid & 15) << 2;
    float acc[4][4] = {};
    for (int ko = 0; ko < K; ko += 16) {
        float4 av = *(const float4*)&A[(row0 + arow) * K + ko + ak4];
        float4 bv = *(const float4*)&B[(ko + brow) * N + col0 + bc4];
        __syncthreads();
        As[ak4 + 0][arow] = av.x;
        As[ak4 + 1][arow] = av.y;
        As[ak4 + 2][arow] = av.z;
        As[ak4 + 3][arow] = av.w;
        *(float4*)&Bs[brow][bc4] = bv;
        __syncthreads();
        #pragma unroll
        for (int kk = 0; kk < 16; ++kk) {
            float4 a = *(const float4*)&As[kk][ty << 2];
            float4 b = *(const float4*)&Bs[kk][tx << 2];
            float aa[4] = {a.x, a.y, a.z, a.w};
            float bb[4] = {b.x, b.y, b.z, b.w};
            #pragma unroll
            for (int i = 0; i < 4; ++i)
                #pragma unroll
                for (int j = 0; j < 4; ++j)
                    acc[i][j] = fmaf(aa[i], bb[j], acc[i][j]);
        }
    }
    #pragma unroll
    for (int i = 0; i < 4; ++i) {
        int t = row0 + (ty << 2) + i;
        #pragma unroll
        for (int j = 0; j < 4; ++j) {
            int n = col0 + (tx << 2) + j;
            int h  = n / 192;          // n = h*192 + jj*64 + d
            int rr = n % 192;
            int jj = rr >> 6;
            int d  = rr & 63;
            float* dst = (jj == 0) ? q_raw : (jj == 1) ? k_raw : v_raw;
            dst[t * EE + h * DD + d] = acc[i][j];
        }
    }
}

// ---------------------------------------------------------------------------
// GEMM2: out = y @ w_proj  (2048x1024 @ 1024x1024)
// ---------------------------------------------------------------------------
__global__ __launch_bounds__(256) void gemm_proj_kernel(
    const float* __restrict__ A, const float* __restrict__ B, float* __restrict__ C)
{
    const int K = EE, N = EE;
    __shared__ float As[16][68];
    __shared__ float Bs[16][64];
    int tid = threadIdx.x;
    int tx = tid & 15, ty = tid >> 4;
    int row0 = blockIdx.y * 64, col0 = blockIdx.x * 64;
    int arow = tid >> 2, ak4 = (tid & 3) << 2;
    int brow = tid >> 4, bc4 = (tid & 15) << 2;
    float acc[4][4] = {};
    for (int ko = 0; ko < K; ko += 16) {
        float4 av = *(const float4*)&A[(row0 + arow) * K + ko + ak4];
        float4 bv = *(const float4*)&B[(ko + brow) * N + col0 + bc4];
        __syncthreads();
        As[ak4 + 0][arow] = av.x;
        As[ak4 + 1][arow] = av.y;
        As[ak4 + 2][arow] = av.z;
        As[ak4 + 3][arow] = av.w;
        *(float4*)&Bs[brow][bc4] = bv;
        __syncthreads();
        #pragma unroll
        for (int kk = 0; kk < 16; ++kk) {
            float4 a = *(const float4*)&As[kk][ty << 2];
            float4 b = *(const float4*)&Bs[kk][tx << 2];
            float aa[4] = {a.x, a.y, a.z, a.w};
            float bb[4] = {b.x, b.y, b.z, b.w};
            #pragma unroll
            for (int i = 0; i < 4; ++i)
                #pragma unroll
                for (int j = 0; j < 4; ++j)
                    acc[i][j] = fmaf(aa[i], bb[j], acc[i][j]);
        }
    }
    #pragma unroll
    for (int i = 0; i < 4; ++i) {
        int t = row0 + (ty << 2) + i;
        #pragma unroll
        for (int j = 0; j < 4; ++j) {
            int n = col0 + (tx << 2) + j;
            C[t * N + n] = acc[i][j];
        }
    }
}

// ---------------------------------------------------------------------------
// Causal depthwise conv1d (DC=4) + SiLU, then RoPE for q,k (j=0,1); v plain.
// grid (T/4, H, 3), block (64,4)
// ---------------------------------------------------------------------------
__global__ __launch_bounds__(256) void conv_rope_kernel(
    const float* __restrict__ q_raw, const float* __restrict__ k_raw, const float* __restrict__ v_raw,
    const float* __restrict__ qw, const float* __restrict__ kw, const float* __restrict__ vw,
    const float* __restrict__ cosb, const float* __restrict__ sinb,
    float* __restrict__ qo, float* __restrict__ ko, float* __restrict__ vo)
{
    int j = blockIdx.z;
    const float* src = (j == 0) ? q_raw : (j == 1) ? k_raw : v_raw;
    const float* w   = (j == 0) ? qw   : (j == 1) ? kw   : vw;
    float* dst       = (j == 0) ? qo   : (j == 1) ? ko   : vo;
    int d  = threadIdx.x;             // 0..63
    int tl = threadIdx.y;             // 0..3
    int t  = blockIdx.x * 4 + tl;
    int h  = blockIdx.y;
    int c  = h * DD + d;
    float acc = 0.f;
    #pragma unroll
    for (int i = 0; i < 4; ++i) {
        int tt = t - 3 + i;
        if (tt >= 0) acc = fmaf(src[tt * EE + c], w[c * 4 + i], acc);
    }
    float yv = acc / (1.f + __expf(-acc));   // silu
    if (j == 2) { dst[t * EE + c] = yv; return; }
    __shared__ float sh[4][64];
    sh[tl][d] = yv;
    __syncthreads();
    int dh = d & 31;
    float cc = cosb[t * 32 + dh];
    float ss = sinb[t * 32 + dh];
    float outv;
    if (d < 32) outv = yv * cc - sh[tl][d + 32] * ss;   // x1*c - x2*s
    else        outv = yv * cc + sh[tl][d - 32] * ss;   // x2*c + x1*s
    dst[t * EE + c] = outv;
}

// ---------------------------------------------------------------------------
// Gated delta rule, sequential scan. One block per head; 256 thr = 4 waves.
// thread (w = tid>>6, vc = tid&63) owns S[w*16+i][vc], i<16.
// Global loads for step t+1 prefetched during step t.
// ---------------------------------------------------------------------------
__global__ __launch_bounds__(256) void delta_scan_kernel(
    const float* __restrict__ q, const float* __restrict__ k, const float* __restrict__ v,
    const float* __restrict__ beta, const float* __restrict__ g,
    float* __restrict__ o)
{
    int h = blockIdx.x;
    int tid = threadIdx.x;
    int vc = tid & 63;
    int w = tid >> 6;
    float S[16];
    #pragma unroll
    for (int i = 0; i < 16; ++i) S[i] = 0.f;
    __shared__ float sk[64], sq[64];
    __shared__ float pp[4][64], po[4][64];

    float kcur = (tid < 64) ? k[h * DD + tid] : 0.f;
    float qcur = (tid >= 64 && tid < 128) ? q[h * DD + (tid - 64)] : 0.f;
    float vcur = v[h * DD + vc];
    float bcur = beta[h];
    float gcur = g[h];

    for (int t = 0; t < TT; ++t) {
        float knext = 0.f, qnext = 0.f, vnext = 0.f, bnext = 0.f, gnext = 0.f;
        if (t + 1 < TT) {
            int base = (t + 1) * EE + h * DD;
            if (tid < 64) knext = k[base + tid];
            else if (tid < 128) qnext = q[base + (tid - 64)];
            vnext = v[base + vc];
            bnext = beta[(t + 1) * HH + h];
            gnext = g[(t + 1) * HH + h];
        }
        if (tid < 64) sk[tid] = kcur;
        else if (tid < 128) sq[tid - 64] = qcur;
        __syncthreads();                                    // A: staging visible
        float skr[16], sqr[16];
        #pragma unroll
        for (int i = 0; i < 16; ++i) { skr[i] = sk[w * 16 + i]; sqr[i] = sq[w * 16 + i]; }
        float p0 = 0.f, p1 = 0.f, p2 = 0.f, p3 = 0.f;
        #pragma unroll
        for (int i = 0; i < 16; i += 4) {
            p0 = fmaf(skr[i + 0], S[i + 0], p0);
            p1 = fmaf(skr[i + 1], S[i + 1], p1);
            p2 = fmaf(skr[i + 2], S[i + 2], p2);
            p3 = fmaf(skr[i + 3], S[i + 3], p3);
        }
        pp[w][vc] = (p0 + p1) + (p2 + p3);
        __syncthreads();                                    // B: pred partials
        float pred = gcur * (pp[0][vc] + pp[1][vc] + pp[2][vc] + pp[3][vc]);
        float delta = bcur * (vcur - pred);
        float o0 = 0.f, o1 = 0.f, o2 = 0.f, o3 = 0.f;
        #pragma unroll
        for (int i = 0; i < 16; i += 4) {
            S[i + 0] = fmaf(gcur, S[i + 0], skr[i + 0] * delta);
            S[i + 1] = fmaf(gcur, S[i + 1], skr[i + 1] * delta);
            S[i + 2] = fmaf(gcur, S[i + 2], skr[i + 2] * delta);
            S[i + 3] = fmaf(gcur, S[i + 3], skr[i + 3] * delta);
            o0 = fmaf(sqr[i + 0], S[i + 0], o0);
            o1 = fmaf(sqr[i + 1], S[i + 1], o1);
            o2 = fmaf(sqr[i + 2], S[i + 2], o2);
            o3 = fmaf(sqr[i + 3], S[i + 3], o3);
        }
        po[w][vc] = (o0 + o1) + (o2 + o3);
        __syncthreads();                                    // C: o partials
        if (w == 0) {
            o[t * EE + h * DD + vc] =
                (po[0][vc] + po[1][vc] + po[2][vc] + po[3][vc]) * 0.125f;
        }
        kcur = knext; qcur = qnext; vcur = vnext; bcur = bnext; gcur = gnext;
    }
}

// ---------------------------------------------------------------------------
// Causal flash attention, fp32, online softmax with lazy rescale.
// block: 256 thr = 128 rows (thread = (row, d-half)); grid (16, 16) = (rowblk, head)
// K/V tiles of 32 cols staged in LDS.
// ---------------------------------------------------------------------------
__global__ __launch_bounds__(256) void attn_kernel(
    const float* __restrict__ q, const float* __restrict__ k, const float* __restrict__ v,
    float* __restrict__ y)
{
    const int TC = 32;
    int h = blockIdx.y;
    int rb = blockIdx.x * 128;
    int tid = threadIdx.x;
    int hd = tid & 1;
    int rp = tid >> 1;
    int row = rb + rp;
    int dbase = h * DD + hd * 32;
    __shared__ float Ks[TC][64];
    __shared__ float Vs[TC][64];
    float qr[32];
    #pragma unroll
    for (int i = 0; i < 32; ++i) qr[i] = q[row * EE + dbase + i];
    float oa[32];
    #pragma unroll
    for (int i = 0; i < 32; ++i) oa[i] = 0.f;
    float m = -INFINITY, l = 0.f;
    int ncols = rb + 128;
    for (int c0 = 0; c0 < ncols; c0 += TC) {
        __syncthreads();
        #pragma unroll
        for (int u = 0; u < 2; ++u) {
            int f = tid + u * 256;          // 0..511 -> 32 cols x 16 float4
            int ci = f >> 4;
            int dq = (f & 15) << 2;
            *(float4*)&Ks[ci][dq] = *(const float4*)&k[(c0 + ci) * EE + h * DD + dq];
            *(float4*)&Vs[ci][dq] = *(const float4*)&v[(c0 + ci) * EE + h * DD + dq];
        }
        __syncthreads();
        int cend = row - c0 + 1;
        if (cend > TC) cend = TC;
        for (int cc = 0; cc < cend; ++cc) {
            const float4* kc = (const float4*)&Ks[cc][hd * 32];
            float s0 = 0.f, s1 = 0.f, s2 = 0.f, s3 = 0.f;
            #pragma unroll
            for (int i4 = 0; i4 < 8; i4 += 4) {
                float4 a = kc[i4 + 0]; float4 b = kc[i4 + 1];
                float4 c2 = kc[i4 + 2]; float4 d2 = kc[i4 + 3];
                s0 = fmaf(qr[(i4+0)*4+0], a.x, s0);  s1 = fmaf(qr[(i4+0)*4+1], a.y, s1);
                s2 = fmaf(qr[(i4+0)*4+2], a.z, s2);  s3 = fmaf(qr[(i4+0)*4+3], a.w, s3);
                s0 = fmaf(qr[(i4+1)*4+0], b.x, s0);  s1 = fmaf(qr[(i4+1)*4+1], b.y, s1);
                s2 = fmaf(qr[(i4+1)*4+2], b.z, s2);  s3 = fmaf(qr[(i4+1)*4+3], b.w, s3);
                s0 = fmaf(qr[(i4+2)*4+0], c2.x, s0); s1 = fmaf(qr[(i4+2)*4+1], c2.y, s1);
                s2 = fmaf(qr[(i4+2)*4+2], c2.z, s2); s3 = fmaf(qr[(i4+2)*4+3], c2.w, s3);
                s0 = fmaf(qr[(i4+3)*4+0], d2.x, s0); s1 = fmaf(qr[(i4+3)*4+1], d2.y, s1);
                s2 = fmaf(qr[(i4+3)*4+2], d2.z, s2); s3 = fmaf(qr[(i4+3)*4+3], d2.w, s3);
            }
            float s = (s0 + s1) + (s2 + s3);
            s += __shfl_xor(s, 1);
            s *= 0.125f;
            if (s > m) {                     // rare after warm-up: ~log(T) per row
                float corr = __expf(m - s);  // m=-inf first time -> corr=0
                #pragma unroll
                for (int i = 0; i < 32; ++i) oa[i] *= corr;
                l *= corr;
                m = s;
            }
            float p = __expf(s - m);
            l += p;
            const float4* vc = (const float4*)&Vs[cc][hd * 32];
            #pragma unroll
            for (int i4 = 0; i4 < 8; ++i4) {
                float4 vv = vc[i4];
                oa[i4*4+0] = fmaf(p, vv.x, oa[i4*4+0]);
                oa[i4*4+1] = fmaf(p, vv.y, oa[i4*4+1]);
                oa[i4*4+2] = fmaf(p, vv.z, oa[i4*4+2]);
                oa[i4*4+3] = fmaf(p, vv.w, oa[i4*4+3]);
            }
        }
    }
    float inv = 1.f / l;
    #pragma unroll
    for (int i = 0; i < 32; ++i) y[row * EE + dbase + i] = oa[i] * inv;
}

// ---------------------------------------------------------------------------
extern "C" void kernel_launch(void* const* d_in, const int* in_sizes, int n_in,
                              void* d_out, int out_size, void* d_ws, size_t ws_size,
                              hipStream_t stream)
{
    (void)in_sizes; (void)n_in; (void)out_size; (void)ws_size;
    const float* x      = (const float*)d_in[0];
    const float* w_attn = (const float*)d_in[1];
    const float* w_proj = (const float*)d_in[2];
    const float* qcw    = (const float*)d_in[3];
    const float* kcw    = (const float*)d_in[4];
    const float* vcw    = (const float*)d_in[5];
    const float* cosb   = (const float*)d_in[6];
    const float* sinb   = (const float*)d_in[7];
    const float* beta   = (const float*)d_in[8];
    const float* g      = (const float*)d_in[9];
    float* out = (float*)d_out;
    float* ws  = (float*)d_ws;

    const size_t TE = (size_t)TT * EE;
    float* q_raw = ws + 0 * TE;   // reused as o (scan output) after conv
    float* k_raw = ws + 1 * TE;   // reused as y (attn output) after conv
    float* v_raw = ws + 2 * TE;
    float* qb    = ws + 3 * TE;
    float* kb    = ws + 4 * TE;
    float* vb    = ws + 5 * TE;
    float* ob    = q_raw;
    float* yb    = k_raw;

    gemm_qkv_kernel<<<dim3(NN / 64, TT / 64), 256, 0, stream>>>(x, w_attn, q_raw, k_raw, v_raw);
    conv_rope_kernel<<<dim3(TT / 4, HH, 3), dim3(64, 4), 0, stream>>>(
        q_raw, k_raw, v_raw, qcw, kcw, vcw, cosb, sinb, qb, kb, vb);
    delta_scan_kernel<<<HH, 256, 0, stream>>>(qb, kb, vb, beta, g, ob);
    attn_kernel<<<dim3(TT / 128, HH), 256, 0, stream>>>(qb, kb, ob, yb);
    gemm_proj_kernel<<<dim3(EE / 64, TT / 64), 256, 0, stream>>>(yb, w_proj, out);
}

// Round 2
// 1143.537 us; speedup vs baseline: 2.0233x; 2.0233x over previous
//
#include <hip/hip_runtime.h>
#include <math.h>

#define TT 2048
#define HH 16
#define DD 64
#define EE 1024
#define NN 3072
#define CHUNK 64
#define NCH (TT / CHUNK)
#define SCALE 0.125f

// ---------------------------------------------------------------------------
// GEMM1: qkv = x @ w_attn  (2048x1024 @ 1024x3072), epilogue splits q/k/v raw
// ---------------------------------------------------------------------------
__global__ __launch_bounds__(256) void gemm_qkv_kernel(
    const float* __restrict__ A, const float* __restrict__ B,
    float* __restrict__ q_raw, float* __restrict__ k_raw, float* __restrict__ v_raw)
{
    const int K = EE, N = NN;
    __shared__ float As[16][68];
    __shared__ float Bs[16][64];
    int tid = threadIdx.x;
    int tx = tid & 15, ty = tid >> 4;
    int row0 = blockIdx.y * 64, col0 = blockIdx.x * 64;
    int arow = tid >> 2, ak4 = (tid & 3) << 2;
    int brow = tid >> 4, bc4 = (tid & 15) << 2;
    float acc[4][4] = {};
    for (int ko = 0; ko < K; ko += 16) {
        float4 av = *(const float4*)&A[(row0 + arow) * K + ko + ak4];
        float4 bv = *(const float4*)&B[(ko + brow) * N + col0 + bc4];
        __syncthreads();
        As[ak4 + 0][arow] = av.x;
        As[ak4 + 1][arow] = av.y;
        As[ak4 + 2][arow] = av.z;
        As[ak4 + 3][arow] = av.w;
        *(float4*)&Bs[brow][bc4] = bv;
        __syncthreads();
        #pragma unroll
        for (int kk = 0; kk < 16; ++kk) {
            float4 a = *(const float4*)&As[kk][ty << 2];
            float4 b = *(const float4*)&Bs[kk][tx << 2];
            float aa[4] = {a.x, a.y, a.z, a.w};
            float bb[4] = {b.x, b.y, b.z, b.w};
            #pragma unroll
            for (int i = 0; i < 4; ++i)
                #pragma unroll
                for (int j = 0; j < 4; ++j)
                    acc[i][j] = fmaf(aa[i], bb[j], acc[i][j]);
        }
    }
    #pragma unroll
    for (int i = 0; i < 4; ++i) {
        int t = row0 + (ty << 2) + i;
        #pragma unroll
        for (int j = 0; j < 4; ++j) {
            int n = col0 + (tx << 2) + j;
            int h  = n / 192;
            int rr = n % 192;
            int jj = rr >> 6;
            int d  = rr & 63;
            float* dst = (jj == 0) ? q_raw : (jj == 1) ? k_raw : v_raw;
            dst[t * EE + h * DD + d] = acc[i][j];
        }
    }
}

// ---------------------------------------------------------------------------
// GEMM2: out = y @ w_proj  (2048x1024 @ 1024x1024)
// ---------------------------------------------------------------------------
__global__ __launch_bounds__(256) void gemm_proj_kernel(
    const float* __restrict__ A, const float* __restrict__ B, float* __restrict__ C)
{
    const int K = EE, N = EE;
    __shared__ float As[16][68];
    __shared__ float Bs[16][64];
    int tid = threadIdx.x;
    int tx = tid & 15, ty = tid >> 4;
    int row0 = blockIdx.y * 64, col0 = blockIdx.x * 64;
    int arow = tid >> 2, ak4 = (tid & 3) << 2;
    int brow = tid >> 4, bc4 = (tid & 15) << 2;
    float acc[4][4] = {};
    for (int ko = 0; ko < K; ko += 16) {
        float4 av = *(const float4*)&A[(row0 + arow) * K + ko + ak4];
        float4 bv = *(const float4*)&B[(ko + brow) * N + col0 + bc4];
        __syncthreads();
        As[ak4 + 0][arow] = av.x;
        As[ak4 + 1][arow] = av.y;
        As[ak4 + 2][arow] = av.z;
        As[ak4 + 3][arow] = av.w;
        *(float4*)&Bs[brow][bc4] = bv;
        __syncthreads();
        #pragma unroll
        for (int kk = 0; kk < 16; ++kk) {
            float4 a = *(const float4*)&As[kk][ty << 2];
            float4 b = *(const float4*)&Bs[kk][tx << 2];
            float aa[4] = {a.x, a.y, a.z, a.w};
            float bb[4] = {b.x, b.y, b.z, b.w};
            #pragma unroll
            for (int i = 0; i < 4; ++i)
                #pragma unroll
                for (int j = 0; j < 4; ++j)
                    acc[i][j] = fmaf(aa[i], bb[j], acc[i][j]);
        }
    }
    #pragma unroll
    for (int i = 0; i < 4; ++i) {
        int t = row0 + (ty << 2) + i;
        #pragma unroll
        for (int j = 0; j < 4; ++j) {
            int n = col0 + (tx << 2) + j;
            C[t * N + n] = acc[i][j];
        }
    }
}

// ---------------------------------------------------------------------------
// Causal depthwise conv1d (DC=4) + SiLU, then RoPE for q,k; v plain.
// ---------------------------------------------------------------------------
__global__ __launch_bounds__(256) void conv_rope_kernel(
    const float* __restrict__ q_raw, const float* __restrict__ k_raw, const float* __restrict__ v_raw,
    const float* __restrict__ qw, const float* __restrict__ kw, const float* __restrict__ vw,
    const float* __restrict__ cosb, const float* __restrict__ sinb,
    float* __restrict__ qo, float* __restrict__ ko, float* __restrict__ vo)
{
    int j = blockIdx.z;
    const float* src = (j == 0) ? q_raw : (j == 1) ? k_raw : v_raw;
    const float* w   = (j == 0) ? qw   : (j == 1) ? kw   : vw;
    float* dst       = (j == 0) ? qo   : (j == 1) ? ko   : vo;
    int d  = threadIdx.x;
    int tl = threadIdx.y;
    int t  = blockIdx.x * 4 + tl;
    int h  = blockIdx.y;
    int c  = h * DD + d;
    float acc = 0.f;
    #pragma unroll
    for (int i = 0; i < 4; ++i) {
        int tt = t - 3 + i;
        if (tt >= 0) acc = fmaf(src[tt * EE + c], w[c * 4 + i], acc);
    }
    float yv = acc / (1.f + __expf(-acc));
    if (j == 2) { dst[t * EE + c] = yv; return; }
    __shared__ float sh[4][64];
    sh[tl][d] = yv;
    __syncthreads();
    int dh = d & 31;
    float cc = cosb[t * 32 + dh];
    float ss = sinb[t * 32 + dh];
    float outv;
    if (d < 32) outv = yv * cc - sh[tl][d + 32] * ss;
    else        outv = yv * cc + sh[tl][d - 32] * ss;
    dst[t * EE + c] = outv;
}

// ---------------------------------------------------------------------------
// Chunked gated delta rule, phase 1 (fully parallel over 32 chunks x 16 heads).
// Per (c,h): cumprod gates G; M[t][s]=b_t(G_t/G_s)(k_t.k_s) (s<t);
// A~^T[s][t]=scale(G_t/G_s)(q_t.k_s) (s<=t else 0);
// forward-subst X=(I+M)^-1 diag(b)[V | diag(G)K];
// then fold: B^T = X_K^T-reduce K~, C = K~^T X_V, F^T = Q~^T - (X_K^T-red A~),
// E = A~ X_V (written over vb tile in [t][EE] layout).
// ---------------------------------------------------------------------------
__global__ __launch_bounds__(256) void chunk_prep_kernel(
    const float* __restrict__ qb, const float* __restrict__ kb, float* __restrict__ vb,
    const float* __restrict__ beta, const float* __restrict__ g,
    float* __restrict__ Bt, float* __restrict__ Ct, float* __restrict__ Ft)
{
    __shared__ float Kc[64][68], Qc[64][68], Vc[64][68];
    __shared__ float Mm[64][68], At[64][68], Xv[64][68], Xk[64][68];
    __shared__ float Gs[64], bs[64];
    int c = blockIdx.x, h = blockIdx.y;
    int tid = threadIdx.x;
    int t0 = c * CHUNK;
    // stage K,Q,V chunk
    {
        int row = tid >> 4, c4 = (tid & 15) << 2;
        #pragma unroll
        for (int m = 0; m < 4; ++m) {
            int r = row + m * 16;
            size_t gidx = (size_t)(t0 + r) * EE + h * DD + c4;
            *(float4*)&Kc[r][c4] = *(const float4*)&kb[gidx];
            *(float4*)&Qc[r][c4] = *(const float4*)&qb[gidx];
            *(float4*)&Vc[r][c4] = *(const float4*)&vb[gidx];
        }
    }
    // cumprod of gates + beta (wave 0)
    if (tid < 64) {
        float x = g[(t0 + tid) * HH + h];
        #pragma unroll
        for (int off = 1; off < 64; off <<= 1) {
            float y = __shfl_up(x, off);
            if (tid >= off) x *= y;
        }
        Gs[tid] = x;
        bs[tid] = beta[(t0 + tid) * HH + h];
    }
    __syncthreads();
    // M (strict lower) and A~^T
    #pragma unroll 2
    for (int i = 0; i < 16; ++i) {
        int p = i * 256 + tid;
        int t = p >> 6, s = p & 63;      // t wave-uniform, s = lane
        float dkk = 0.f, dqk = 0.f;
        #pragma unroll
        for (int j4 = 0; j4 < 64; j4 += 4) {
            float4 ks = *(const float4*)&Kc[s][j4];
            float4 kt = *(const float4*)&Kc[t][j4];
            float4 qt = *(const float4*)&Qc[t][j4];
            dkk = fmaf(kt.x, ks.x, fmaf(kt.y, ks.y, fmaf(kt.z, ks.z, fmaf(kt.w, ks.w, dkk))));
            dqk = fmaf(qt.x, ks.x, fmaf(qt.y, ks.y, fmaf(qt.z, ks.z, fmaf(qt.w, ks.w, dqk))));
        }
        float gr = Gs[t] / Gs[s];
        if (s < t) Mm[t][s] = bs[t] * gr * dkk;
        At[s][t] = (s <= t) ? SCALE * gr * dqk : 0.f;
    }
    __syncthreads();
    // forward substitution: (I+M) X = diag(b)[V | diag(G)K]
    if (tid < 128) {
        int col = tid & 63;
        int hv = tid >> 6;
        float* Xp = hv ? &Xk[0][0] : &Xv[0][0];
        #pragma unroll 1
        for (int t = 0; t < 64; ++t) {
            float acc = hv ? (bs[t] * Gs[t] * Kc[t][col]) : (bs[t] * Vc[t][col]);
            for (int s = 0; s < t; ++s)
                acc = fmaf(-Mm[t][s], Xp[s * 68 + col], acc);
            Xp[t * 68 + col] = acc;
        }
    }
    __syncthreads();
    // Kc -> K~ in place: row s scaled by G_C/G_s
    {
        int r = tid & 63, qd = tid >> 6;
        float ratio = Gs[63] / Gs[r];
        #pragma unroll
        for (int jj = 0; jj < 4; ++jj) {
            float4 vv = *(const float4*)&Kc[r][qd * 16 + jj * 4];
            vv.x *= ratio; vv.y *= ratio; vv.z *= ratio; vv.w *= ratio;
            *(float4*)&Kc[r][qd * 16 + jj * 4] = vv;
        }
    }
    __syncthreads();
    // four fold matmuls: out[a][b] = sum_s P[s][a] * Q[s][b]
    int tx = tid & 15, ty = tid >> 4;
    int a0 = ty << 2, b0 = tx << 2;
    float aB[4][4] = {}, aC[4][4] = {}, aF[4][4] = {}, aE[4][4] = {};
    #pragma unroll 2
    for (int s = 0; s < 64; ++s) {
        float4 xkA4 = *(const float4*)&Xk[s][a0];
        float4 kcB4 = *(const float4*)&Kc[s][b0];
        float4 kcA4 = *(const float4*)&Kc[s][a0];
        float4 xvB4 = *(const float4*)&Xv[s][b0];
        float4 atA4 = *(const float4*)&At[s][a0];
        float4 atB4 = *(const float4*)&At[s][b0];
        float xkA[4] = {xkA4.x, xkA4.y, xkA4.z, xkA4.w};
        float kcB[4] = {kcB4.x, kcB4.y, kcB4.z, kcB4.w};
        float kcA[4] = {kcA4.x, kcA4.y, kcA4.z, kcA4.w};
        float xvB[4] = {xvB4.x, xvB4.y, xvB4.z, xvB4.w};
        float atA[4] = {atA4.x, atA4.y, atA4.z, atA4.w};
        float atB[4] = {atB4.x, atB4.y, atB4.z, atB4.w};
        #pragma unroll
        for (int i = 0; i < 4; ++i)
            #pragma unroll
            for (int j = 0; j < 4; ++j) {
                aB[i][j] = fmaf(xkA[i], kcB[j], aB[i][j]);   // B^T[a][b]
                aC[i][j] = fmaf(kcA[i], xvB[j], aC[i][j]);   // C[a][b]
                aF[i][j] = fmaf(xkA[i], atB[j], aF[i][j]);   // (A~X_K)^T[a][b]
                aE[i][j] = fmaf(atA[i], xvB[j], aE[i][j]);   // E[a][b]
            }
    }
    size_t tile = ((size_t)(c * HH + h)) << 12;
    #pragma unroll
    for (int i = 0; i < 4; ++i) {
        int a = a0 + i;
        float4 wB = {aB[i][0], aB[i][1], aB[i][2], aB[i][3]};
        float4 wC = {aC[i][0], aC[i][1], aC[i][2], aC[i][3]};
        float4 wF;
        wF.x = SCALE * Gs[b0 + 0] * Qc[b0 + 0][a] - aF[i][0];
        wF.y = SCALE * Gs[b0 + 1] * Qc[b0 + 1][a] - aF[i][1];
        wF.z = SCALE * Gs[b0 + 2] * Qc[b0 + 2][a] - aF[i][2];
        wF.w = SCALE * Gs[b0 + 3] * Qc[b0 + 3][a] - aF[i][3];
        float4 wE = {aE[i][0], aE[i][1], aE[i][2], aE[i][3]};
        *(float4*)&Bt[tile + a * 64 + b0] = wB;
        *(float4*)&Ct[tile + a * 64 + b0] = wC;
        *(float4*)&Ft[tile + a * 64 + b0] = wF;
        *(float4*)&vb[(size_t)(t0 + a) * EE + h * DD + b0] = wE;  // E over vb tile
    }
}

// ---------------------------------------------------------------------------
// Chunked delta rule, phase 2 (sequential over 32 chunks, parallel over heads).
// Per chunk: O = F S + E (write over vb), S <- G_C S - B S + C.
// ---------------------------------------------------------------------------
__global__ __launch_bounds__(256) void delta_scan2_kernel(
    const float* __restrict__ Bt, const float* __restrict__ Ct, const float* __restrict__ Ft,
    float* __restrict__ vb, const float* __restrict__ g)
{
    __shared__ float Ss[64][64];
    __shared__ float Bs[64][64], Fs[64][64], Cs[64][64], Es[64][64];
    __shared__ float GCs;
    int h = blockIdx.x;
    int tid = threadIdx.x;
    int tx = tid & 15, ty = tid >> 4;
    int a0 = ty << 2, b0 = tx << 2;
    {
        int row = tid >> 4, c4 = (tid & 15) << 2;
        #pragma unroll
        for (int m = 0; m < 4; ++m) {
            float4 z = {0.f, 0.f, 0.f, 0.f};
            *(float4*)&Ss[row + m * 16][c4] = z;
        }
    }
    for (int c = 0; c < NCH; ++c) {
        if (tid < 64) {
            float x = g[((c << 6) + tid) * HH + h];
            #pragma unroll
            for (int off = 32; off; off >>= 1) x *= __shfl_xor(x, off);
            if (tid == 0) GCs = x;
        }
        size_t tile = ((size_t)(c * HH + h)) << 12;
        {
            int row = tid >> 4, c4 = (tid & 15) << 2;
            #pragma unroll
            for (int m = 0; m < 4; ++m) {
                int r = row + m * 16;
                *(float4*)&Bs[r][c4] = *(const float4*)&Bt[tile + r * 64 + c4];
                *(float4*)&Fs[r][c4] = *(const float4*)&Ft[tile + r * 64 + c4];
                *(float4*)&Cs[r][c4] = *(const float4*)&Ct[tile + r * 64 + c4];
                *(float4*)&Es[r][c4] = *(const float4*)&vb[(size_t)((c << 6) + r) * EE + h * DD + c4];
            }
        }
        __syncthreads();
        float accO[4][4] = {}, accP[4][4] = {};
        #pragma unroll 4
        for (int k = 0; k < 64; ++k) {
            float4 fv = *(const float4*)&Fs[k][a0];
            float4 bv = *(const float4*)&Bs[k][a0];
            float4 sv = *(const float4*)&Ss[k][b0];
            float fa[4] = {fv.x, fv.y, fv.z, fv.w};
            float ba[4] = {bv.x, bv.y, bv.z, bv.w};
            float sa[4] = {sv.x, sv.y, sv.z, sv.w};
            #pragma unroll
            for (int i = 0; i < 4; ++i)
                #pragma unroll
                for (int j = 0; j < 4; ++j) {
                    accO[i][j] = fmaf(fa[i], sa[j], accO[i][j]);
                    accP[i][j] = fmaf(ba[i], sa[j], accP[i][j]);
                }
        }
        __syncthreads();   // all reads of S done before update
        float GC = GCs;
        #pragma unroll
        for (int i = 0; i < 4; ++i) {
            int a = a0 + i;
            float4 sv = *(const float4*)&Ss[a][b0];
            float4 cv = *(const float4*)&Cs[a][b0];
            float4 ns;
            ns.x = fmaf(GC, sv.x, cv.x - accP[i][0]);
            ns.y = fmaf(GC, sv.y, cv.y - accP[i][1]);
            ns.z = fmaf(GC, sv.z, cv.z - accP[i][2]);
            ns.w = fmaf(GC, sv.w, cv.w - accP[i][3]);
            *(float4*)&Ss[a][b0] = ns;
            float4 ev = *(const float4*)&Es[a][b0];
            float4 ov = {accO[i][0] + ev.x, accO[i][1] + ev.y,
                         accO[i][2] + ev.z, accO[i][3] + ev.w};
            *(float4*)&vb[(size_t)((c << 6) + a) * EE + h * DD + b0] = ov;
        }
        __syncthreads();
    }
}

// ---------------------------------------------------------------------------
// Causal flash attention, fp32, online softmax.
// ---------------------------------------------------------------------------
__global__ __launch_bounds__(256) void attn_kernel(
    const float* __restrict__ q, const float* __restrict__ k, const float* __restrict__ v,
    float* __restrict__ y)
{
    const int TC = 32;
    int h = blockIdx.y;
    int rb = blockIdx.x * 128;
    int tid = threadIdx.x;
    int hd = tid & 1;
    int rp = tid >> 1;
    int row = rb + rp;
    int dbase = h * DD + hd * 32;
    __shared__ float Ks[TC][64];
    __shared__ float Vs[TC][64];
    float qr[32];
    #pragma unroll
    for (int i = 0; i < 32; ++i) qr[i] = q[row * EE + dbase + i];
    float oa[32];
    #pragma unroll
    for (int i = 0; i < 32; ++i) oa[i] = 0.f;
    float m = -INFINITY, l = 0.f;
    int ncols = rb + 128;
    for (int c0 = 0; c0 < ncols; c0 += TC) {
        __syncthreads();
        #pragma unroll
        for (int u = 0; u < 2; ++u) {
            int f = tid + u * 256;
            int ci = f >> 4;
            int dq = (f & 15) << 2;
            *(float4*)&Ks[ci][dq] = *(const float4*)&k[(c0 + ci) * EE + h * DD + dq];
            *(float4*)&Vs[ci][dq] = *(const float4*)&v[(c0 + ci) * EE + h * DD + dq];
        }
        __syncthreads();
        int cend = row - c0 + 1;
        if (cend > TC) cend = TC;
        for (int cc = 0; cc < cend; ++cc) {
            const float4* kc = (const float4*)&Ks[cc][hd * 32];
            float s0 = 0.f, s1 = 0.f, s2 = 0.f, s3 = 0.f;
            #pragma unroll
            for (int i4 = 0; i4 < 8; i4 += 4) {
                float4 a = kc[i4 + 0]; float4 b = kc[i4 + 1];
                float4 c2 = kc[i4 + 2]; float4 d2 = kc[i4 + 3];
                s0 = fmaf(qr[(i4+0)*4+0], a.x, s0);  s1 = fmaf(qr[(i4+0)*4+1], a.y, s1);
                s2 = fmaf(qr[(i4+0)*4+2], a.z, s2);  s3 = fmaf(qr[(i4+0)*4+3], a.w, s3);
                s0 = fmaf(qr[(i4+1)*4+0], b.x, s0);  s1 = fmaf(qr[(i4+1)*4+1], b.y, s1);
                s2 = fmaf(qr[(i4+1)*4+2], b.z, s2);  s3 = fmaf(qr[(i4+1)*4+3], b.w, s3);
                s0 = fmaf(qr[(i4+2)*4+0], c2.x, s0); s1 = fmaf(qr[(i4+2)*4+1], c2.y, s1);
                s2 = fmaf(qr[(i4+2)*4+2], c2.z, s2); s3 = fmaf(qr[(i4+2)*4+3], c2.w, s3);
                s0 = fmaf(qr[(i4+3)*4+0], d2.x, s0); s1 = fmaf(qr[(i4+3)*4+1], d2.y, s1);
                s2 = fmaf(qr[(i4+3)*4+2], d2.z, s2); s3 = fmaf(qr[(i4+3)*4+3], d2.w, s3);
            }
            float s = (s0 + s1) + (s2 + s3);
            s += __shfl_xor(s, 1);
            s *= 0.125f;
            if (s > m) {
                float corr = __expf(m - s);
                #pragma unroll
                for (int i = 0; i < 32; ++i) oa[i] *= corr;
                l *= corr;
                m = s;
            }
            float p = __expf(s - m);
            l += p;
            const float4* vc = (const float4*)&Vs[cc][hd * 32];
            #pragma unroll
            for (int i4 = 0; i4 < 8; ++i4) {
                float4 vv = vc[i4];
                oa[i4*4+0] = fmaf(p, vv.x, oa[i4*4+0]);
                oa[i4*4+1] = fmaf(p, vv.y, oa[i4*4+1]);
                oa[i4*4+2] = fmaf(p, vv.z, oa[i4*4+2]);
                oa[i4*4+3] = fmaf(p, vv.w, oa[i4*4+3]);
            }
        }
    }
    float inv = 1.f / l;
    #pragma unroll
    for (int i = 0; i < 32; ++i) y[row * EE + dbase + i] = oa[i] * inv;
}

// ---------------------------------------------------------------------------
extern "C" void kernel_launch(void* const* d_in, const int* in_sizes, int n_in,
                              void* d_out, int out_size, void* d_ws, size_t ws_size,
                              hipStream_t stream)
{
    (void)in_sizes; (void)n_in; (void)out_size; (void)ws_size;
    const float* x      = (const float*)d_in[0];
    const float* w_attn = (const float*)d_in[1];
    const float* w_proj = (const float*)d_in[2];
    const float* qcw    = (const float*)d_in[3];
    const float* kcw    = (const float*)d_in[4];
    const float* vcw    = (const float*)d_in[5];
    const float* cosb   = (const float*)d_in[6];
    const float* sinb   = (const float*)d_in[7];
    const float* beta   = (const float*)d_in[8];
    const float* g      = (const float*)d_in[9];
    float* out = (float*)d_out;
    float* ws  = (float*)d_ws;

    const size_t TE = (size_t)TT * EE;
    float* buf0 = ws + 0 * TE;   // q_raw -> Bt tiles -> yb
    float* buf1 = ws + 1 * TE;   // k_raw -> Ct tiles
    float* buf2 = ws + 2 * TE;   // v_raw -> Ft tiles
    float* qb   = ws + 3 * TE;
    float* kb   = ws + 4 * TE;
    float* vb   = ws + 5 * TE;   // v -> E -> O (delta-rule output)

    gemm_qkv_kernel<<<dim3(NN / 64, TT / 64), 256, 0, stream>>>(x, w_attn, buf0, buf1, buf2);
    conv_rope_kernel<<<dim3(TT / 4, HH, 3), dim3(64, 4), 0, stream>>>(
        buf0, buf1, buf2, qcw, kcw, vcw, cosb, sinb, qb, kb, vb);
    chunk_prep_kernel<<<dim3(NCH, HH), 256, 0, stream>>>(qb, kb, vb, beta, g, buf0, buf1, buf2);
    delta_scan2_kernel<<<HH, 256, 0, stream>>>(buf0, buf1, buf2, vb, g);
    attn_kernel<<<dim3(TT / 128, HH), 256, 0, stream>>>(qb, kb, vb, buf0);
    gemm_proj_kernel<<<dim3(EE / 64, TT / 64), 256, 0, stream>>>(buf0, w_proj, out);
}

// Round 3
// 620.604 us; speedup vs baseline: 3.7283x; 1.8426x over previous
//
#include <hip/hip_runtime.h>
#include <math.h>

#define TT 2048
#define HH 16
#define DD 64
#define EE 1024
#define NN 3072
#define CHUNK 64
#define NCH (TT / CHUNK)
#define SCALE 0.125f
#define KS 72   // padded LDS row stride (bf16 elements): 144B rows, conflict-free b128

typedef short bf16x8 __attribute__((ext_vector_type(8)));
typedef short bf16x4 __attribute__((ext_vector_type(4)));
typedef float f32x4 __attribute__((ext_vector_type(4)));

__device__ __forceinline__ unsigned short f2bf(float x) {
    union { float f; unsigned u; } un; un.f = x;
    unsigned r = un.u + 0x7FFFu + ((un.u >> 16) & 1u);
    return (unsigned short)(r >> 16);
}

// ---------------------------------------------------------------------------
// GEMM1: qkv = x @ w_attn  (2048x1024 @ 1024x3072), epilogue splits q/k/v raw
// ---------------------------------------------------------------------------
__global__ __launch_bounds__(256) void gemm_qkv_kernel(
    const float* __restrict__ A, const float* __restrict__ B,
    float* __restrict__ q_raw, float* __restrict__ k_raw, float* __restrict__ v_raw)
{
    const int K = EE, N = NN;
    __shared__ float As[16][68];
    __shared__ float Bs[16][64];
    int tid = threadIdx.x;
    int tx = tid & 15, ty = tid >> 4;
    int row0 = blockIdx.y * 64, col0 = blockIdx.x * 64;
    int arow = tid >> 2, ak4 = (tid & 3) << 2;
    int brow = tid >> 4, bc4 = (tid & 15) << 2;
    float acc[4][4] = {};
    for (int ko = 0; ko < K; ko += 16) {
        float4 av = *(const float4*)&A[(row0 + arow) * K + ko + ak4];
        float4 bv = *(const float4*)&B[(ko + brow) * N + col0 + bc4];
        __syncthreads();
        As[ak4 + 0][arow] = av.x;
        As[ak4 + 1][arow] = av.y;
        As[ak4 + 2][arow] = av.z;
        As[ak4 + 3][arow] = av.w;
        *(float4*)&Bs[brow][bc4] = bv;
        __syncthreads();
        #pragma unroll
        for (int kk = 0; kk < 16; ++kk) {
            float4 a = *(const float4*)&As[kk][ty << 2];
            float4 b = *(const float4*)&Bs[kk][tx << 2];
            float aa[4] = {a.x, a.y, a.z, a.w};
            float bb[4] = {b.x, b.y, b.z, b.w};
            #pragma unroll
            for (int i = 0; i < 4; ++i)
                #pragma unroll
                for (int j = 0; j < 4; ++j)
                    acc[i][j] = fmaf(aa[i], bb[j], acc[i][j]);
        }
    }
    #pragma unroll
    for (int i = 0; i < 4; ++i) {
        int t = row0 + (ty << 2) + i;
        #pragma unroll
        for (int j = 0; j < 4; ++j) {
            int n = col0 + (tx << 2) + j;
            int h  = n / 192;
            int rr = n % 192;
            int jj = rr >> 6;
            int d  = rr & 63;
            float* dst = (jj == 0) ? q_raw : (jj == 1) ? k_raw : v_raw;
            dst[t * EE + h * DD + d] = acc[i][j];
        }
    }
}

// ---------------------------------------------------------------------------
// GEMM2: out = y @ w_proj  (2048x1024 @ 1024x1024)
// ---------------------------------------------------------------------------
__global__ __launch_bounds__(256) void gemm_proj_kernel(
    const float* __restrict__ A, const float* __restrict__ B, float* __restrict__ C)
{
    const int K = EE, N = EE;
    __shared__ float As[16][68];
    __shared__ float Bs[16][64];
    int tid = threadIdx.x;
    int tx = tid & 15, ty = tid >> 4;
    int row0 = blockIdx.y * 64, col0 = blockIdx.x * 64;
    int arow = tid >> 2, ak4 = (tid & 3) << 2;
    int brow = tid >> 4, bc4 = (tid & 15) << 2;
    float acc[4][4] = {};
    for (int ko = 0; ko < K; ko += 16) {
        float4 av = *(const float4*)&A[(row0 + arow) * K + ko + ak4];
        float4 bv = *(const float4*)&B[(ko + brow) * N + col0 + bc4];
        __syncthreads();
        As[ak4 + 0][arow] = av.x;
        As[ak4 + 1][arow] = av.y;
        As[ak4 + 2][arow] = av.z;
        As[ak4 + 3][arow] = av.w;
        *(float4*)&Bs[brow][bc4] = bv;
        __syncthreads();
        #pragma unroll
        for (int kk = 0; kk < 16; ++kk) {
            float4 a = *(const float4*)&As[kk][ty << 2];
            float4 b = *(const float4*)&Bs[kk][tx << 2];
            float aa[4] = {a.x, a.y, a.z, a.w};
            float bb[4] = {b.x, b.y, b.z, b.w};
            #pragma unroll
            for (int i = 0; i < 4; ++i)
                #pragma unroll
                for (int j = 0; j < 4; ++j)
                    acc[i][j] = fmaf(aa[i], bb[j], acc[i][j]);
        }
    }
    #pragma unroll
    for (int i = 0; i < 4; ++i) {
        int t = row0 + (ty << 2) + i;
        #pragma unroll
        for (int j = 0; j < 4; ++j) {
            int n = col0 + (tx << 2) + j;
            C[t * N + n] = acc[i][j];
        }
    }
}

// ---------------------------------------------------------------------------
// Causal depthwise conv1d (DC=4) + SiLU, then RoPE for q,k; v plain.
// ---------------------------------------------------------------------------
__global__ __launch_bounds__(256) void conv_rope_kernel(
    const float* __restrict__ q_raw, const float* __restrict__ k_raw, const float* __restrict__ v_raw,
    const float* __restrict__ qw, const float* __restrict__ kw, const float* __restrict__ vw,
    const float* __restrict__ cosb, const float* __restrict__ sinb,
    float* __restrict__ qo, float* __restrict__ ko, float* __restrict__ vo)
{
    int j = blockIdx.z;
    const float* src = (j == 0) ? q_raw : (j == 1) ? k_raw : v_raw;
    const float* w   = (j == 0) ? qw   : (j == 1) ? kw   : vw;
    float* dst       = (j == 0) ? qo   : (j == 1) ? ko   : vo;
    int d  = threadIdx.x;
    int tl = threadIdx.y;
    int t  = blockIdx.x * 4 + tl;
    int h  = blockIdx.y;
    int c  = h * DD + d;
    float acc = 0.f;
    #pragma unroll
    for (int i = 0; i < 4; ++i) {
        int tt = t - 3 + i;
        if (tt >= 0) acc = fmaf(src[tt * EE + c], w[c * 4 + i], acc);
    }
    float yv = acc / (1.f + __expf(-acc));
    if (j == 2) { dst[t * EE + c] = yv; return; }
    __shared__ float sh[4][64];
    sh[tl][d] = yv;
    __syncthreads();
    int dh = d & 31;
    float cc = cosb[t * 32 + dh];
    float ss = sinb[t * 32 + dh];
    float outv;
    if (d < 32) outv = yv * cc - sh[tl][d + 32] * ss;
    else        outv = yv * cc + sh[tl][d - 32] * ss;
    dst[t * EE + c] = outv;
}

// ---------------------------------------------------------------------------
// Chunked gated delta rule, phase 1 (parallel over 32 chunks x 16 heads).
// ---------------------------------------------------------------------------
__global__ __launch_bounds__(256) void chunk_prep_kernel(
    const float* __restrict__ qb, const float* __restrict__ kb, float* __restrict__ vb,
    const float* __restrict__ beta, const float* __restrict__ g,
    float* __restrict__ Bt, float* __restrict__ Ct, float* __restrict__ Ft)
{
    __shared__ float Kc[64][68], Qc[64][68], Vc[64][68];
    __shared__ float Mm[64][68], At[64][68], Xv[64][68], Xk[64][68];
    __shared__ float Gs[64], bs[64];
    int c = blockIdx.x, h = blockIdx.y;
    int tid = threadIdx.x;
    int t0 = c * CHUNK;
    {
        int row = tid >> 4, c4 = (tid & 15) << 2;
        #pragma unroll
        for (int m = 0; m < 4; ++m) {
            int r = row + m * 16;
            size_t gidx = (size_t)(t0 + r) * EE + h * DD + c4;
            *(float4*)&Kc[r][c4] = *(const float4*)&kb[gidx];
            *(float4*)&Qc[r][c4] = *(const float4*)&qb[gidx];
            *(float4*)&Vc[r][c4] = *(const float4*)&vb[gidx];
        }
    }
    if (tid < 64) {
        float x = g[(t0 + tid) * HH + h];
        #pragma unroll
        for (int off = 1; off < 64; off <<= 1) {
            float y = __shfl_up(x, off);
            if (tid >= off) x *= y;
        }
        Gs[tid] = x;
        bs[tid] = beta[(t0 + tid) * HH + h];
    }
    __syncthreads();
    #pragma unroll 2
    for (int i = 0; i < 16; ++i) {
        int p = i * 256 + tid;
        int t = p >> 6, s = p & 63;
        float dkk = 0.f, dqk = 0.f;
        #pragma unroll
        for (int j4 = 0; j4 < 64; j4 += 4) {
            float4 ks = *(const float4*)&Kc[s][j4];
            float4 kt = *(const float4*)&Kc[t][j4];
            float4 qt = *(const float4*)&Qc[t][j4];
            dkk = fmaf(kt.x, ks.x, fmaf(kt.y, ks.y, fmaf(kt.z, ks.z, fmaf(kt.w, ks.w, dkk))));
            dqk = fmaf(qt.x, ks.x, fmaf(qt.y, ks.y, fmaf(qt.z, ks.z, fmaf(qt.w, ks.w, dqk))));
        }
        float gr = Gs[t] / Gs[s];
        if (s < t) Mm[t][s] = bs[t] * gr * dkk;
        At[s][t] = (s <= t) ? SCALE * gr * dqk : 0.f;
    }
    __syncthreads();
    if (tid < 128) {
        int col = tid & 63;
        int hv = tid >> 6;
        float* Xp = hv ? &Xk[0][0] : &Xv[0][0];
        #pragma unroll 1
        for (int t = 0; t < 64; ++t) {
            float acc = hv ? (bs[t] * Gs[t] * Kc[t][col]) : (bs[t] * Vc[t][col]);
            for (int s = 0; s < t; ++s)
                acc = fmaf(-Mm[t][s], Xp[s * 68 + col], acc);
            Xp[t * 68 + col] = acc;
        }
    }
    __syncthreads();
    {
        int r = tid & 63, qd = tid >> 6;
        float ratio = Gs[63] / Gs[r];
        #pragma unroll
        for (int jj = 0; jj < 4; ++jj) {
            float4 vv = *(const float4*)&Kc[r][qd * 16 + jj * 4];
            vv.x *= ratio; vv.y *= ratio; vv.z *= ratio; vv.w *= ratio;
            *(float4*)&Kc[r][qd * 16 + jj * 4] = vv;
        }
    }
    __syncthreads();
    int tx = tid & 15, ty = tid >> 4;
    int a0 = ty << 2, b0 = tx << 2;
    float aB[4][4] = {}, aC[4][4] = {}, aF[4][4] = {}, aE[4][4] = {};
    #pragma unroll 2
    for (int s = 0; s < 64; ++s) {
        float4 xkA4 = *(const float4*)&Xk[s][a0];
        float4 kcB4 = *(const float4*)&Kc[s][b0];
        float4 kcA4 = *(const float4*)&Kc[s][a0];
        float4 xvB4 = *(const float4*)&Xv[s][b0];
        float4 atA4 = *(const float4*)&At[s][a0];
        float4 atB4 = *(const float4*)&At[s][b0];
        float xkA[4] = {xkA4.x, xkA4.y, xkA4.z, xkA4.w};
        float kcB[4] = {kcB4.x, kcB4.y, kcB4.z, kcB4.w};
        float kcA[4] = {kcA4.x, kcA4.y, kcA4.z, kcA4.w};
        float xvB[4] = {xvB4.x, xvB4.y, xvB4.z, xvB4.w};
        float atA[4] = {atA4.x, atA4.y, atA4.z, atA4.w};
        float atB[4] = {atB4.x, atB4.y, atB4.z, atB4.w};
        #pragma unroll
        for (int i = 0; i < 4; ++i)
            #pragma unroll
            for (int j = 0; j < 4; ++j) {
                aB[i][j] = fmaf(xkA[i], kcB[j], aB[i][j]);
                aC[i][j] = fmaf(kcA[i], xvB[j], aC[i][j]);
                aF[i][j] = fmaf(xkA[i], atB[j], aF[i][j]);
                aE[i][j] = fmaf(atA[i], xvB[j], aE[i][j]);
            }
    }
    size_t tile = ((size_t)(c * HH + h)) << 12;
    #pragma unroll
    for (int i = 0; i < 4; ++i) {
        int a = a0 + i;
        float4 wB = {aB[i][0], aB[i][1], aB[i][2], aB[i][3]};
        float4 wC = {aC[i][0], aC[i][1], aC[i][2], aC[i][3]};
        float4 wF;
        wF.x = SCALE * Gs[b0 + 0] * Qc[b0 + 0][a] - aF[i][0];
        wF.y = SCALE * Gs[b0 + 1] * Qc[b0 + 1][a] - aF[i][1];
        wF.z = SCALE * Gs[b0 + 2] * Qc[b0 + 2][a] - aF[i][2];
        wF.w = SCALE * Gs[b0 + 3] * Qc[b0 + 3][a] - aF[i][3];
        float4 wE = {aE[i][0], aE[i][1], aE[i][2], aE[i][3]};
        *(float4*)&Bt[tile + a * 64 + b0] = wB;
        *(float4*)&Ct[tile + a * 64 + b0] = wC;
        *(float4*)&Ft[tile + a * 64 + b0] = wF;
        *(float4*)&vb[(size_t)(t0 + a) * EE + h * DD + b0] = wE;
    }
}

// ---------------------------------------------------------------------------
// Chunked delta rule, phase 2 (sequential over 32 chunks, parallel over heads).
// ---------------------------------------------------------------------------
__global__ __launch_bounds__(256) void delta_scan2_kernel(
    const float* __restrict__ Bt, const float* __restrict__ Ct, const float* __restrict__ Ft,
    float* __restrict__ vb, const float* __restrict__ g)
{
    __shared__ float Ss[64][64];
    __shared__ float Bs[64][64], Fs[64][64], Cs[64][64], Es[64][64];
    __shared__ float GCs;
    int h = blockIdx.x;
    int tid = threadIdx.x;
    int tx = tid & 15, ty = tid >> 4;
    int a0 = ty << 2, b0 = tx << 2;
    {
        int row = tid >> 4, c4 = (tid & 15) << 2;
        #pragma unroll
        for (int m = 0; m < 4; ++m) {
            float4 z = {0.f, 0.f, 0.f, 0.f};
            *(float4*)&Ss[row + m * 16][c4] = z;
        }
    }
    for (int c = 0; c < NCH; ++c) {
        if (tid < 64) {
            float x = g[((c << 6) + tid) * HH + h];
            #pragma unroll
            for (int off = 32; off; off >>= 1) x *= __shfl_xor(x, off);
            if (tid == 0) GCs = x;
        }
        size_t tile = ((size_t)(c * HH + h)) << 12;
        {
            int row = tid >> 4, c4 = (tid & 15) << 2;
            #pragma unroll
            for (int m = 0; m < 4; ++m) {
                int r = row + m * 16;
                *(float4*)&Bs[r][c4] = *(const float4*)&Bt[tile + r * 64 + c4];
                *(float4*)&Fs[r][c4] = *(const float4*)&Ft[tile + r * 64 + c4];
                *(float4*)&Cs[r][c4] = *(const float4*)&Ct[tile + r * 64 + c4];
                *(float4*)&Es[r][c4] = *(const float4*)&vb[(size_t)((c << 6) + r) * EE + h * DD + c4];
            }
        }
        __syncthreads();
        float accO[4][4] = {}, accP[4][4] = {};
        #pragma unroll 4
        for (int k = 0; k < 64; ++k) {
            float4 fv = *(const float4*)&Fs[k][a0];
            float4 bv = *(const float4*)&Bs[k][a0];
            float4 sv = *(const float4*)&Ss[k][b0];
            float fa[4] = {fv.x, fv.y, fv.z, fv.w};
            float ba[4] = {bv.x, bv.y, bv.z, bv.w};
            float sa[4] = {sv.x, sv.y, sv.z, sv.w};
            #pragma unroll
            for (int i = 0; i < 4; ++i)
                #pragma unroll
                for (int j = 0; j < 4; ++j) {
                    accO[i][j] = fmaf(fa[i], sa[j], accO[i][j]);
                    accP[i][j] = fmaf(ba[i], sa[j], accP[i][j]);
                }
        }
        __syncthreads();
        float GC = GCs;
        #pragma unroll
        for (int i = 0; i < 4; ++i) {
            int a = a0 + i;
            float4 sv = *(const float4*)&Ss[a][b0];
            float4 cv = *(const float4*)&Cs[a][b0];
            float4 ns;
            ns.x = fmaf(GC, sv.x, cv.x - accP[i][0]);
            ns.y = fmaf(GC, sv.y, cv.y - accP[i][1]);
            ns.z = fmaf(GC, sv.z, cv.z - accP[i][2]);
            ns.w = fmaf(GC, sv.w, cv.w - accP[i][3]);
            *(float4*)&Ss[a][b0] = ns;
            float4 ev = *(const float4*)&Es[a][b0];
            float4 ov = {accO[i][0] + ev.x, accO[i][1] + ev.y,
                         accO[i][2] + ev.z, accO[i][3] + ev.w};
            *(float4*)&vb[(size_t)((c << 6) + a) * EE + h * DD + b0] = ov;
        }
        __syncthreads();
    }
}

// ---------------------------------------------------------------------------
// Causal flash attention, bf16 MFMA (16x16x32), fp32 softmax/accumulators.
// grid (T/64, H), 4 waves/block; wave w owns Q rows [rb + w*16, +16).
// K staged [s][d] bf16 pad-72; V staged transposed [d][s] pad-72.
// Per-wave P bridge buffer in LDS converts C/D layout -> A-fragment layout.
// ---------------------------------------------------------------------------
__global__ __launch_bounds__(256) void attn_mfma_kernel(
    const float* __restrict__ q, const float* __restrict__ k, const float* __restrict__ v,
    float* __restrict__ y)
{
    __shared__ __align__(16) unsigned short KsL[64 * KS];
    __shared__ __align__(16) unsigned short VtL[64 * KS];
    __shared__ __align__(16) unsigned short PsL[4][16 * KS];

    int h = blockIdx.y;
    int rb = ((int)gridDim.x - 1 - (int)blockIdx.x) * 64;   // heavy blocks first
    int tid = threadIdx.x;
    int w = tid >> 6;
    int lane = tid & 63;
    int l16 = lane & 15;
    int lq = lane >> 4;           // 0..3
    int qr0 = rb + w * 16;

    // Q A-fragments (row = l16, k = lq*8 + j within each 32-wide k window)
    bf16x8 qf[2];
    {
        const float* qrow = &q[(size_t)(qr0 + l16) * EE + h * DD];
        #pragma unroll
        for (int kk = 0; kk < 2; ++kk) {
            float4 v0 = *(const float4*)&qrow[kk * 32 + lq * 8];
            float4 v1 = *(const float4*)&qrow[kk * 32 + lq * 8 + 4];
            qf[kk][0] = (short)f2bf(v0.x); qf[kk][1] = (short)f2bf(v0.y);
            qf[kk][2] = (short)f2bf(v0.z); qf[kk][3] = (short)f2bf(v0.w);
            qf[kk][4] = (short)f2bf(v1.x); qf[kk][5] = (short)f2bf(v1.y);
            qf[kk][6] = (short)f2bf(v1.z); qf[kk][7] = (short)f2bf(v1.w);
        }
    }

    f32x4 oacc[4];
    #pragma unroll
    for (int dt = 0; dt < 4; ++dt) oacc[dt] = (f32x4){0.f, 0.f, 0.f, 0.f};
    float mrow[4] = {-3e38f, -3e38f, -3e38f, -3e38f};
    float lrow[4] = {0.f, 0.f, 0.f, 0.f};

    // staging index precompute
    int ks_s = tid >> 2, ks_d0 = (tid & 3) << 4;
    int vt_s0 = (tid & 31) * 2, vt_dq = (tid >> 5) << 3;

    for (int c0 = 0; c0 <= rb; c0 += 64) {
        __syncthreads();
        // --- stage K [s][d] ---
        {
            const float* krow = &k[(size_t)(c0 + ks_s) * EE + h * DD + ks_d0];
            #pragma unroll
            for (int u = 0; u < 4; ++u) {
                float4 kv4 = *(const float4*)&krow[u * 4];
                bf16x4 pk = { (short)f2bf(kv4.x), (short)f2bf(kv4.y),
                              (short)f2bf(kv4.z), (short)f2bf(kv4.w) };
                *(bf16x4*)&KsL[ks_s * KS + ks_d0 + u * 4] = pk;
            }
            // --- stage V transposed [d][s] ---
            const float* vr0 = &v[(size_t)(c0 + vt_s0) * EE + h * DD + vt_dq];
            const float* vr1 = vr0 + EE;
            float4 a0 = *(const float4*)&vr0[0], a1 = *(const float4*)&vr0[4];
            float4 b0 = *(const float4*)&vr1[0], b1 = *(const float4*)&vr1[4];
            float va[8] = {a0.x, a0.y, a0.z, a0.w, a1.x, a1.y, a1.z, a1.w};
            float vbv[8] = {b0.x, b0.y, b0.z, b0.w, b1.x, b1.y, b1.z, b1.w};
            #pragma unroll
            for (int u = 0; u < 8; ++u) {
                unsigned pv = (unsigned)f2bf(va[u]) | ((unsigned)f2bf(vbv[u]) << 16);
                *(unsigned*)&VtL[(vt_dq + u) * KS + vt_s0] = pv;
            }
        }
        __syncthreads();

        // --- S = Q K^T (4 col-tiles x 2 k-steps) ---
        f32x4 sacc[4];
        #pragma unroll
        for (int ct = 0; ct < 4; ++ct) {
            bf16x8 b0 = *(bf16x8*)&KsL[(ct * 16 + l16) * KS + lq * 8];
            bf16x8 b1 = *(bf16x8*)&KsL[(ct * 16 + l16) * KS + 32 + lq * 8];
            f32x4 acc = {0.f, 0.f, 0.f, 0.f};
            acc = __builtin_amdgcn_mfma_f32_16x16x32_bf16(qf[0], b0, acc, 0, 0, 0);
            acc = __builtin_amdgcn_mfma_f32_16x16x32_bf16(qf[1], b1, acc, 0, 0, 0);
            sacc[ct] = acc;
        }

        // --- scale + causal mask + online softmax ---
        float sv[4][4];
        float tmax[4] = {-3e38f, -3e38f, -3e38f, -3e38f};
        #pragma unroll
        for (int ct = 0; ct < 4; ++ct) {
            int col = c0 + ct * 16 + l16;
            #pragma unroll
            for (int r = 0; r < 4; ++r) {
                int row = qr0 + lq * 4 + r;
                float s = sacc[ct][r] * SCALE;
                if (col > row) s = -3e38f;
                sv[ct][r] = s;
                tmax[r] = fmaxf(tmax[r], s);
            }
        }
        #pragma unroll
        for (int off = 1; off < 16; off <<= 1) {
            #pragma unroll
            for (int r = 0; r < 4; ++r)
                tmax[r] = fmaxf(tmax[r], __shfl_xor(tmax[r], off));
        }
        float corr[4], psum[4];
        #pragma unroll
        for (int r = 0; r < 4; ++r) {
            float mn = fmaxf(mrow[r], tmax[r]);
            corr[r] = __expf(mrow[r] - mn);
            mrow[r] = mn;
            psum[r] = 0.f;
        }
        #pragma unroll
        for (int ct = 0; ct < 4; ++ct) {
            #pragma unroll
            for (int r = 0; r < 4; ++r) {
                float p = __expf(sv[ct][r] - mrow[r]);
                psum[r] += p;
                PsL[w][(lq * 4 + r) * KS + ct * 16 + l16] = f2bf(p);
            }
        }
        #pragma unroll
        for (int off = 1; off < 16; off <<= 1) {
            #pragma unroll
            for (int r = 0; r < 4; ++r)
                psum[r] += __shfl_xor(psum[r], off);
        }
        #pragma unroll
        for (int r = 0; r < 4; ++r)
            lrow[r] = lrow[r] * corr[r] + psum[r];
        #pragma unroll
        for (int dt = 0; dt < 4; ++dt) {
            #pragma unroll
            for (int r = 0; r < 4; ++r)
                oacc[dt][r] *= corr[r];
        }

        // --- O += P V  (A from per-wave P buffer, B from Vt) ---
        bf16x8 pa0 = *(bf16x8*)&PsL[w][l16 * KS + lq * 8];
        bf16x8 pa1 = *(bf16x8*)&PsL[w][l16 * KS + 32 + lq * 8];
        #pragma unroll
        for (int dt = 0; dt < 4; ++dt) {
            bf16x8 vb0 = *(bf16x8*)&VtL[(dt * 16 + l16) * KS + lq * 8];
            bf16x8 vb1 = *(bf16x8*)&VtL[(dt * 16 + l16) * KS + 32 + lq * 8];
            oacc[dt] = __builtin_amdgcn_mfma_f32_16x16x32_bf16(pa0, vb0, oacc[dt], 0, 0, 0);
            oacc[dt] = __builtin_amdgcn_mfma_f32_16x16x32_bf16(pa1, vb1, oacc[dt], 0, 0, 0);
        }
    }

    // --- epilogue: O /= l, store fp32 ---
    float linv[4];
    #pragma unroll
    for (int r = 0; r < 4; ++r) linv[r] = 1.f / lrow[r];
    #pragma unroll
    for (int dt = 0; dt < 4; ++dt) {
        #pragma unroll
        for (int r = 0; r < 4; ++r) {
            int row = qr0 + lq * 4 + r;
            y[(size_t)row * EE + h * DD + dt * 16 + l16] = oacc[dt][r] * linv[r];
        }
    }
}

// ---------------------------------------------------------------------------
extern "C" void kernel_launch(void* const* d_in, const int* in_sizes, int n_in,
                              void* d_out, int out_size, void* d_ws, size_t ws_size,
                              hipStream_t stream)
{
    (void)in_sizes; (void)n_in; (void)out_size; (void)ws_size;
    const float* x      = (const float*)d_in[0];
    const float* w_attn = (const float*)d_in[1];
    const float* w_proj = (const float*)d_in[2];
    const float* qcw    = (const float*)d_in[3];
    const float* kcw    = (const float*)d_in[4];
    const float* vcw    = (const float*)d_in[5];
    const float* cosb   = (const float*)d_in[6];
    const float* sinb   = (const float*)d_in[7];
    const float* beta   = (const float*)d_in[8];
    const float* g      = (const float*)d_in[9];
    float* out = (float*)d_out;
    float* ws  = (float*)d_ws;

    const size_t TE = (size_t)TT * EE;
    float* buf0 = ws + 0 * TE;   // q_raw -> Bt tiles -> yb
    float* buf1 = ws + 1 * TE;   // k_raw -> Ct tiles
    float* buf2 = ws + 2 * TE;   // v_raw -> Ft tiles
    float* qb   = ws + 3 * TE;
    float* kb   = ws + 4 * TE;
    float* vb   = ws + 5 * TE;   // v -> E -> O (delta-rule output)

    gemm_qkv_kernel<<<dim3(NN / 64, TT / 64), 256, 0, stream>>>(x, w_attn, buf0, buf1, buf2);
    conv_rope_kernel<<<dim3(TT / 4, HH, 3), dim3(64, 4), 0, stream>>>(
        buf0, buf1, buf2, qcw, kcw, vcw, cosb, sinb, qb, kb, vb);
    chunk_prep_kernel<<<dim3(NCH, HH), 256, 0, stream>>>(qb, kb, vb, beta, g, buf0, buf1, buf2);
    delta_scan2_kernel<<<HH, 256, 0, stream>>>(buf0, buf1, buf2, vb, g);
    attn_mfma_kernel<<<dim3(TT / 64, HH), 256, 0, stream>>>(qb, kb, vb, buf0);
    gemm_proj_kernel<<<dim3(EE / 64, TT / 64), 256, 0, stream>>>(buf0, w_proj, out);
}

// Round 4
// 435.895 us; speedup vs baseline: 5.3081x; 1.4237x over previous
//
#include <hip/hip_runtime.h>
#include <math.h>

#define TT 2048
#define HH 16
#define DD 64
#define EE 1024
#define NN 3072
#define CHUNK 64
#define NCH (TT / CHUNK)
#define SCALE 0.125f
#define KS 72   // attn LDS row stride (bf16): conflict-free b128

typedef short bf16x8 __attribute__((ext_vector_type(8)));
typedef short bf16x4 __attribute__((ext_vector_type(4)));
typedef float f32x4 __attribute__((ext_vector_type(4)));
typedef unsigned short ushort;
typedef const __attribute__((address_space(1))) unsigned int* gptr_t;
typedef __attribute__((address_space(3))) unsigned int* lptr_t;

__device__ __forceinline__ unsigned short f2bf(float x) {
    union { float f; unsigned u; } un; un.f = x;
    unsigned r = un.u + 0x7FFFu + ((un.u >> 16) & 1u);
    return (unsigned short)(r >> 16);
}

// ---------------------------------------------------------------------------
// fp32 -> bf16 elementwise convert (x)
// ---------------------------------------------------------------------------
__global__ __launch_bounds__(256) void cvt_bf16_kernel(
    const float* __restrict__ in, ushort* __restrict__ out)
{
    int i = ((int)blockIdx.x * 256 + (int)threadIdx.x) << 3;
    float4 a = *(const float4*)&in[i];
    float4 b = *(const float4*)&in[i + 4];
    bf16x8 o;
    o[0] = (short)f2bf(a.x); o[1] = (short)f2bf(a.y);
    o[2] = (short)f2bf(a.z); o[3] = (short)f2bf(a.w);
    o[4] = (short)f2bf(b.x); o[5] = (short)f2bf(b.y);
    o[6] = (short)f2bf(b.z); o[7] = (short)f2bf(b.w);
    *(bf16x8*)&out[i] = o;
}

// ---------------------------------------------------------------------------
// fp32 [K][N] -> bf16 [N][K] convert + transpose (weights)
// ---------------------------------------------------------------------------
__global__ __launch_bounds__(256) void cvt_transpose_kernel(
    const float* __restrict__ W, ushort* __restrict__ WT, int K, int N)
{
    __shared__ float Ls[64][65];
    int n0 = blockIdx.x * 64, k0 = blockIdx.y * 64;
    int tid = threadIdx.x;
    int lr = tid >> 4, lc4 = (tid & 15) << 2;
    #pragma unroll
    for (int m = 0; m < 4; ++m) {
        int r = lr + m * 16;
        float4 v = *(const float4*)&W[(size_t)(k0 + r) * N + n0 + lc4];
        Ls[r][lc4 + 0] = v.x; Ls[r][lc4 + 1] = v.y;
        Ls[r][lc4 + 2] = v.z; Ls[r][lc4 + 3] = v.w;
    }
    __syncthreads();
    int n = tid >> 2, kb = (tid & 3) << 4;
    bf16x8 o0, o1;
    #pragma unroll
    for (int j = 0; j < 8; ++j) o0[j] = (short)f2bf(Ls[kb + j][n]);
    #pragma unroll
    for (int j = 0; j < 8; ++j) o1[j] = (short)f2bf(Ls[kb + 8 + j][n]);
    *(bf16x8*)&WT[(size_t)(n0 + n) * K + k0 + kb] = o0;
    *(bf16x8*)&WT[(size_t)(n0 + n) * K + k0 + kb + 8] = o1;
}

// ---------------------------------------------------------------------------
// bf16 MFMA GEMM: C(fp32)[M][N] = A(bf16)[M][K] * BT(bf16)[N][K]^T
// BM x BN tile, BK=64, 4 waves (2x2), double-buffered global_load_lds staging,
// XOR slot swizzle (slot ^ row&7) pre-applied on global src + on ds_read.
// ---------------------------------------------------------------------------
template<int BM, int BN>
__global__ __launch_bounds__(256) void gemm_bf16(
    const ushort* __restrict__ A, const ushort* __restrict__ BT,
    float* __restrict__ C, int M, int N, int K)
{
    constexpr int MT = BM / 32;
    constexpr int NT = BN / 32;
    constexpr int AIT = BM * 64 / 2048;
    constexpr int BIT = BN * 64 / 2048;
    __shared__ __align__(16) ushort Asl[2][BM * 64];
    __shared__ __align__(16) ushort Bsl[2][BN * 64];
    const int tid = threadIdx.x;
    const int lane = tid & 63, w = tid >> 6;
    const int wm = w >> 1, wn = w & 1;
    const int l16 = lane & 15, lq = lane >> 4;
    const int row0 = blockIdx.y * BM, col0 = blockIdx.x * BN;
    const int wvb = w << 9;

    f32x4 acc[MT][NT];
    #pragma unroll
    for (int i = 0; i < MT; ++i)
        #pragma unroll
        for (int j = 0; j < NT; ++j)
            acc[i][j] = (f32x4){0.f, 0.f, 0.f, 0.f};

#define STAGE_TILE(buf, k0)                                                    \
    {                                                                          \
        _Pragma("unroll")                                                      \
        for (int u = 0; u < AIT; ++u) {                                        \
            int idx = u * 256 + tid;                                           \
            int r = idx >> 3, s = idx & 7;                                     \
            const ushort* srcp =                                               \
                &A[(size_t)(row0 + r) * K + (k0) + ((s ^ (r & 7)) << 3)];      \
            __builtin_amdgcn_global_load_lds((gptr_t)srcp,                     \
                (lptr_t)&Asl[buf][(u << 11) + wvb], 16, 0, 0);                 \
        }                                                                      \
        _Pragma("unroll")                                                      \
        for (int u = 0; u < BIT; ++u) {                                        \
            int idx = u * 256 + tid;                                           \
            int r = idx >> 3, s = idx & 7;                                     \
            const ushort* srcp =                                               \
                &BT[(size_t)(col0 + r) * K + (k0) + ((s ^ (r & 7)) << 3)];     \
            __builtin_amdgcn_global_load_lds((gptr_t)srcp,                     \
                (lptr_t)&Bsl[buf][(u << 11) + wvb], 16, 0, 0);                 \
        }                                                                      \
    }

    const int nK = K >> 6;
    STAGE_TILE(0, 0)
    for (int kt = 0; kt < nK; ++kt) {
        __syncthreads();                       // stage(kt) drained + visible
        if (kt + 1 < nK) STAGE_TILE((kt + 1) & 1, (kt + 1) << 6)
        const int cb = kt & 1;
        #pragma unroll
        for (int kk = 0; kk < 2; ++kk) {
            bf16x8 afr[MT], bfr[NT];
            #pragma unroll
            for (int mt = 0; mt < MT; ++mt) {
                int rr = wm * (BM / 2) + mt * 16 + l16;
                afr[mt] = *(bf16x8*)&Asl[cb][rr * 64 +
                           (((kk * 4 + lq) ^ (rr & 7)) << 3)];
            }
            #pragma unroll
            for (int nt = 0; nt < NT; ++nt) {
                int cc = wn * (BN / 2) + nt * 16 + l16;
                bfr[nt] = *(bf16x8*)&Bsl[cb][cc * 64 +
                           (((kk * 4 + lq) ^ (cc & 7)) << 3)];
            }
            #pragma unroll
            for (int mt = 0; mt < MT; ++mt)
                #pragma unroll
                for (int nt = 0; nt < NT; ++nt)
                    acc[mt][nt] = __builtin_amdgcn_mfma_f32_16x16x32_bf16(
                        afr[mt], bfr[nt], acc[mt][nt], 0, 0, 0);
        }
    }
#undef STAGE_TILE

    #pragma unroll
    for (int mt = 0; mt < MT; ++mt) {
        #pragma unroll
        for (int nt = 0; nt < NT; ++nt) {
            int col = col0 + wn * (BN / 2) + nt * 16 + l16;
            #pragma unroll
            for (int r = 0; r < 4; ++r) {
                int row = row0 + wm * (BM / 2) + mt * 16 + lq * 4 + r;
                C[(size_t)row * N + col] = acc[mt][nt][r];
            }
        }
    }
}

// ---------------------------------------------------------------------------
// Causal depthwise conv1d (DC=4) + SiLU, then RoPE for q,k; v plain.
// Reads fused qkv buffer [T][3072], channel map n = h*192 + j*64 + d.
// ---------------------------------------------------------------------------
__global__ __launch_bounds__(256) void conv_rope_kernel(
    const float* __restrict__ qkv,
    const float* __restrict__ qw, const float* __restrict__ kw, const float* __restrict__ vw,
    const float* __restrict__ cosb, const float* __restrict__ sinb,
    float* __restrict__ qo, float* __restrict__ ko, float* __restrict__ vo)
{
    int j = blockIdx.z;
    const float* w = (j == 0) ? qw : (j == 1) ? kw : vw;
    float* dst     = (j == 0) ? qo : (j == 1) ? ko : vo;
    int d  = threadIdx.x;
    int tl = threadIdx.y;
    int t  = blockIdx.x * 4 + tl;
    int h  = blockIdx.y;
    int c  = h * DD + d;
    int n  = h * 192 + j * 64 + d;
    float acc = 0.f;
    #pragma unroll
    for (int i = 0; i < 4; ++i) {
        int tt = t - 3 + i;
        if (tt >= 0) acc = fmaf(qkv[(size_t)tt * NN + n], w[c * 4 + i], acc);
    }
    float yv = acc / (1.f + __expf(-acc));
    if (j == 2) { dst[t * EE + c] = yv; return; }
    __shared__ float sh[4][64];
    sh[tl][d] = yv;
    __syncthreads();
    int dh = d & 31;
    float cc = cosb[t * 32 + dh];
    float ss = sinb[t * 32 + dh];
    float outv;
    if (d < 32) outv = yv * cc - sh[tl][d + 32] * ss;
    else        outv = yv * cc + sh[tl][d - 32] * ss;
    dst[t * EE + c] = outv;
}

// ---------------------------------------------------------------------------
// Chunked gated delta rule, phase 1 (parallel over 32 chunks x 16 heads).
// ---------------------------------------------------------------------------
__global__ __launch_bounds__(256) void chunk_prep_kernel(
    const float* __restrict__ qb, const float* __restrict__ kb, float* __restrict__ vb,
    const float* __restrict__ beta, const float* __restrict__ g,
    float* __restrict__ Bt, float* __restrict__ Ct, float* __restrict__ Ft)
{
    __shared__ float Kc[64][68], Qc[64][68], Vc[64][68];
    __shared__ float Mm[64][68], At[64][68], Xv[64][68], Xk[64][68];
    __shared__ float Gs[64], bs[64];
    int c = blockIdx.x, h = blockIdx.y;
    int tid = threadIdx.x;
    int t0 = c * CHUNK;
    {
        int row = tid >> 4, c4 = (tid & 15) << 2;
        #pragma unroll
        for (int m = 0; m < 4; ++m) {
            int r = row + m * 16;
            size_t gidx = (size_t)(t0 + r) * EE + h * DD + c4;
            *(float4*)&Kc[r][c4] = *(const float4*)&kb[gidx];
            *(float4*)&Qc[r][c4] = *(const float4*)&qb[gidx];
            *(float4*)&Vc[r][c4] = *(const float4*)&vb[gidx];
        }
    }
    if (tid < 64) {
        float x = g[(t0 + tid) * HH + h];
        #pragma unroll
        for (int off = 1; off < 64; off <<= 1) {
            float y = __shfl_up(x, off);
            if (tid >= off) x *= y;
        }
        Gs[tid] = x;
        bs[tid] = beta[(t0 + tid) * HH + h];
    }
    __syncthreads();
    #pragma unroll 2
    for (int i = 0; i < 16; ++i) {
        int p = i * 256 + tid;
        int t = p >> 6, s = p & 63;
        float dkk = 0.f, dqk = 0.f;
        #pragma unroll
        for (int j4 = 0; j4 < 64; j4 += 4) {
            float4 ks = *(const float4*)&Kc[s][j4];
            float4 kt = *(const float4*)&Kc[t][j4];
            float4 qt = *(const float4*)&Qc[t][j4];
            dkk = fmaf(kt.x, ks.x, fmaf(kt.y, ks.y, fmaf(kt.z, ks.z, fmaf(kt.w, ks.w, dkk))));
            dqk = fmaf(qt.x, ks.x, fmaf(qt.y, ks.y, fmaf(qt.z, ks.z, fmaf(qt.w, ks.w, dqk))));
        }
        float gr = Gs[t] / Gs[s];
        if (s < t) Mm[t][s] = bs[t] * gr * dkk;
        At[s][t] = (s <= t) ? SCALE * gr * dqk : 0.f;
    }
    __syncthreads();
    if (tid < 128) {
        int col = tid & 63;
        int hv = tid >> 6;
        float* Xp = hv ? &Xk[0][0] : &Xv[0][0];
        #pragma unroll 1
        for (int t = 0; t < 64; ++t) {
            float acc = hv ? (bs[t] * Gs[t] * Kc[t][col]) : (bs[t] * Vc[t][col]);
            for (int s = 0; s < t; ++s)
                acc = fmaf(-Mm[t][s], Xp[s * 68 + col], acc);
            Xp[t * 68 + col] = acc;
        }
    }
    __syncthreads();
    {
        int r = tid & 63, qd = tid >> 6;
        float ratio = Gs[63] / Gs[r];
        #pragma unroll
        for (int jj = 0; jj < 4; ++jj) {
            float4 vv = *(const float4*)&Kc[r][qd * 16 + jj * 4];
            vv.x *= ratio; vv.y *= ratio; vv.z *= ratio; vv.w *= ratio;
            *(float4*)&Kc[r][qd * 16 + jj * 4] = vv;
        }
    }
    __syncthreads();
    int tx = tid & 15, ty = tid >> 4;
    int a0 = ty << 2, b0 = tx << 2;
    float aB[4][4] = {}, aC[4][4] = {}, aF[4][4] = {}, aE[4][4] = {};
    #pragma unroll 2
    for (int s = 0; s < 64; ++s) {
        float4 xkA4 = *(const float4*)&Xk[s][a0];
        float4 kcB4 = *(const float4*)&Kc[s][b0];
        float4 kcA4 = *(const float4*)&Kc[s][a0];
        float4 xvB4 = *(const float4*)&Xv[s][b0];
        float4 atA4 = *(const float4*)&At[s][a0];
        float4 atB4 = *(const float4*)&At[s][b0];
        float xkA[4] = {xkA4.x, xkA4.y, xkA4.z, xkA4.w};
        float kcB[4] = {kcB4.x, kcB4.y, kcB4.z, kcB4.w};
        float kcA[4] = {kcA4.x, kcA4.y, kcA4.z, kcA4.w};
        float xvB[4] = {xvB4.x, xvB4.y, xvB4.z, xvB4.w};
        float atA[4] = {atA4.x, atA4.y, atA4.z, atA4.w};
        float atB[4] = {atB4.x, atB4.y, atB4.z, atB4.w};
        #pragma unroll
        for (int i = 0; i < 4; ++i)
            #pragma unroll
            for (int j = 0; j < 4; ++j) {
                aB[i][j] = fmaf(xkA[i], kcB[j], aB[i][j]);
                aC[i][j] = fmaf(kcA[i], xvB[j], aC[i][j]);
                aF[i][j] = fmaf(xkA[i], atB[j], aF[i][j]);
                aE[i][j] = fmaf(atA[i], xvB[j], aE[i][j]);
            }
    }
    size_t tile = ((size_t)(c * HH + h)) << 12;
    #pragma unroll
    for (int i = 0; i < 4; ++i) {
        int a = a0 + i;
        float4 wB = {aB[i][0], aB[i][1], aB[i][2], aB[i][3]};
        float4 wC = {aC[i][0], aC[i][1], aC[i][2], aC[i][3]};
        float4 wF;
        wF.x = SCALE * Gs[b0 + 0] * Qc[b0 + 0][a] - aF[i][0];
        wF.y = SCALE * Gs[b0 + 1] * Qc[b0 + 1][a] - aF[i][1];
        wF.z = SCALE * Gs[b0 + 2] * Qc[b0 + 2][a] - aF[i][2];
        wF.w = SCALE * Gs[b0 + 3] * Qc[b0 + 3][a] - aF[i][3];
        float4 wE = {aE[i][0], aE[i][1], aE[i][2], aE[i][3]};
        *(float4*)&Bt[tile + a * 64 + b0] = wB;
        *(float4*)&Ct[tile + a * 64 + b0] = wC;
        *(float4*)&Ft[tile + a * 64 + b0] = wF;
        *(float4*)&vb[(size_t)(t0 + a) * EE + h * DD + b0] = wE;
    }
}

// ---------------------------------------------------------------------------
// Chunked delta rule, phase 2 (sequential over 32 chunks, parallel over heads).
// ---------------------------------------------------------------------------
__global__ __launch_bounds__(256) void delta_scan2_kernel(
    const float* __restrict__ Bt, const float* __restrict__ Ct, const float* __restrict__ Ft,
    float* __restrict__ vb, const float* __restrict__ g)
{
    __shared__ float Ss[64][64];
    __shared__ float Bs[64][64], Fs[64][64], Cs[64][64], Es[64][64];
    __shared__ float GCs;
    int h = blockIdx.x;
    int tid = threadIdx.x;
    int tx = tid & 15, ty = tid >> 4;
    int a0 = ty << 2, b0 = tx << 2;
    {
        int row = tid >> 4, c4 = (tid & 15) << 2;
        #pragma unroll
        for (int m = 0; m < 4; ++m) {
            float4 z = {0.f, 0.f, 0.f, 0.f};
            *(float4*)&Ss[row + m * 16][c4] = z;
        }
    }
    for (int c = 0; c < NCH; ++c) {
        if (tid < 64) {
            float x = g[((c << 6) + tid) * HH + h];
            #pragma unroll
            for (int off = 32; off; off >>= 1) x *= __shfl_xor(x, off);
            if (tid == 0) GCs = x;
        }
        size_t tile = ((size_t)(c * HH + h)) << 12;
        {
            int row = tid >> 4, c4 = (tid & 15) << 2;
            #pragma unroll
            for (int m = 0; m < 4; ++m) {
                int r = row + m * 16;
                *(float4*)&Bs[r][c4] = *(const float4*)&Bt[tile + r * 64 + c4];
                *(float4*)&Fs[r][c4] = *(const float4*)&Ft[tile + r * 64 + c4];
                *(float4*)&Cs[r][c4] = *(const float4*)&Ct[tile + r * 64 + c4];
                *(float4*)&Es[r][c4] = *(const float4*)&vb[(size_t)((c << 6) + r) * EE + h * DD + c4];
            }
        }
        __syncthreads();
        float accO[4][4] = {}, accP[4][4] = {};
        #pragma unroll 4
        for (int k = 0; k < 64; ++k) {
            float4 fv = *(const float4*)&Fs[k][a0];
            float4 bv = *(const float4*)&Bs[k][a0];
            float4 sv = *(const float4*)&Ss[k][b0];
            float fa[4] = {fv.x, fv.y, fv.z, fv.w};
            float ba[4] = {bv.x, bv.y, bv.z, bv.w};
            float sa[4] = {sv.x, sv.y, sv.z, sv.w};
            #pragma unroll
            for (int i = 0; i < 4; ++i)
                #pragma unroll
                for (int j = 0; j < 4; ++j) {
                    accO[i][j] = fmaf(fa[i], sa[j], accO[i][j]);
                    accP[i][j] = fmaf(ba[i], sa[j], accP[i][j]);
                }
        }
        __syncthreads();
        float GC = GCs;
        #pragma unroll
        for (int i = 0; i < 4; ++i) {
            int a = a0 + i;
            float4 sv = *(const float4*)&Ss[a][b0];
            float4 cv = *(const float4*)&Cs[a][b0];
            float4 ns;
            ns.x = fmaf(GC, sv.x, cv.x - accP[i][0]);
            ns.y = fmaf(GC, sv.y, cv.y - accP[i][1]);
            ns.z = fmaf(GC, sv.z, cv.z - accP[i][2]);
            ns.w = fmaf(GC, sv.w, cv.w - accP[i][3]);
            *(float4*)&Ss[a][b0] = ns;
            float4 ev = *(const float4*)&Es[a][b0];
            float4 ov = {accO[i][0] + ev.x, accO[i][1] + ev.y,
                         accO[i][2] + ev.z, accO[i][3] + ev.w};
            *(float4*)&vb[(size_t)((c << 6) + a) * EE + h * DD + b0] = ov;
        }
        __syncthreads();
    }
}

// ---------------------------------------------------------------------------
// Causal flash attention, bf16 MFMA; output written as bf16 for proj GEMM.
// ---------------------------------------------------------------------------
__global__ __launch_bounds__(256) void attn_mfma_kernel(
    const float* __restrict__ q, const float* __restrict__ k, const float* __restrict__ v,
    ushort* __restrict__ y)
{
    __shared__ __align__(16) unsigned short KsL[64 * KS];
    __shared__ __align__(16) unsigned short VtL[64 * KS];
    __shared__ __align__(16) unsigned short PsL[4][16 * KS];

    int h = blockIdx.y;
    int rb = ((int)gridDim.x - 1 - (int)blockIdx.x) * 64;
    int tid = threadIdx.x;
    int w = tid >> 6;
    int lane = tid & 63;
    int l16 = lane & 15;
    int lq = lane >> 4;
    int qr0 = rb + w * 16;

    bf16x8 qf[2];
    {
        const float* qrow = &q[(size_t)(qr0 + l16) * EE + h * DD];
        #pragma unroll
        for (int kk = 0; kk < 2; ++kk) {
            float4 v0 = *(const float4*)&qrow[kk * 32 + lq * 8];
            float4 v1 = *(const float4*)&qrow[kk * 32 + lq * 8 + 4];
            qf[kk][0] = (short)f2bf(v0.x); qf[kk][1] = (short)f2bf(v0.y);
            qf[kk][2] = (short)f2bf(v0.z); qf[kk][3] = (short)f2bf(v0.w);
            qf[kk][4] = (short)f2bf(v1.x); qf[kk][5] = (short)f2bf(v1.y);
            qf[kk][6] = (short)f2bf(v1.z); qf[kk][7] = (short)f2bf(v1.w);
        }
    }

    f32x4 oacc[4];
    #pragma unroll
    for (int dt = 0; dt < 4; ++dt) oacc[dt] = (f32x4){0.f, 0.f, 0.f, 0.f};
    float mrow[4] = {-3e38f, -3e38f, -3e38f, -3e38f};
    float lrow[4] = {0.f, 0.f, 0.f, 0.f};

    int ks_s = tid >> 2, ks_d0 = (tid & 3) << 4;
    int vt_s0 = (tid & 31) * 2, vt_dq = (tid >> 5) << 3;

    for (int c0 = 0; c0 <= rb; c0 += 64) {
        __syncthreads();
        {
            const float* krow = &k[(size_t)(c0 + ks_s) * EE + h * DD + ks_d0];
            #pragma unroll
            for (int u = 0; u < 4; ++u) {
                float4 kv4 = *(const float4*)&krow[u * 4];
                bf16x4 pk = { (short)f2bf(kv4.x), (short)f2bf(kv4.y),
                              (short)f2bf(kv4.z), (short)f2bf(kv4.w) };
                *(bf16x4*)&KsL[ks_s * KS + ks_d0 + u * 4] = pk;
            }
            const float* vr0 = &v[(size_t)(c0 + vt_s0) * EE + h * DD + vt_dq];
            const float* vr1 = vr0 + EE;
            float4 a0 = *(const float4*)&vr0[0], a1 = *(const float4*)&vr0[4];
            float4 b0 = *(const float4*)&vr1[0], b1 = *(const float4*)&vr1[4];
            float va[8] = {a0.x, a0.y, a0.z, a0.w, a1.x, a1.y, a1.z, a1.w};
            float vbv[8] = {b0.x, b0.y, b0.z, b0.w, b1.x, b1.y, b1.z, b1.w};
            #pragma unroll
            for (int u = 0; u < 8; ++u) {
                unsigned pv = (unsigned)f2bf(va[u]) | ((unsigned)f2bf(vbv[u]) << 16);
                *(unsigned*)&VtL[(vt_dq + u) * KS + vt_s0] = pv;
            }
        }
        __syncthreads();

        f32x4 sacc[4];
        #pragma unroll
        for (int ct = 0; ct < 4; ++ct) {
            bf16x8 b0 = *(bf16x8*)&KsL[(ct * 16 + l16) * KS + lq * 8];
            bf16x8 b1 = *(bf16x8*)&KsL[(ct * 16 + l16) * KS + 32 + lq * 8];
            f32x4 acc = {0.f, 0.f, 0.f, 0.f};
            acc = __builtin_amdgcn_mfma_f32_16x16x32_bf16(qf[0], b0, acc, 0, 0, 0);
            acc = __builtin_amdgcn_mfma_f32_16x16x32_bf16(qf[1], b1, acc, 0, 0, 0);
            sacc[ct] = acc;
        }

        float sv[4][4];
        float tmax[4] = {-3e38f, -3e38f, -3e38f, -3e38f};
        #pragma unroll
        for (int ct = 0; ct < 4; ++ct) {
            int col = c0 + ct * 16 + l16;
            #pragma unroll
            for (int r = 0; r < 4; ++r) {
                int row = qr0 + lq * 4 + r;
                float s = sacc[ct][r] * SCALE;
                if (col > row) s = -3e38f;
                sv[ct][r] = s;
                tmax[r] = fmaxf(tmax[r], s);
            }
        }
        #pragma unroll
        for (int off = 1; off < 16; off <<= 1) {
            #pragma unroll
            for (int r = 0; r < 4; ++r)
                tmax[r] = fmaxf(tmax[r], __shfl_xor(tmax[r], off));
        }
        float corr[4], psum[4];
        #pragma unroll
        for (int r = 0; r < 4; ++r) {
            float mn = fmaxf(mrow[r], tmax[r]);
            corr[r] = __expf(mrow[r] - mn);
            mrow[r] = mn;
            psum[r] = 0.f;
        }
        #pragma unroll
        for (int ct = 0; ct < 4; ++ct) {
            #pragma unroll
            for (int r = 0; r < 4; ++r) {
                float p = __expf(sv[ct][r] - mrow[r]);
                psum[r] += p;
                PsL[w][(lq * 4 + r) * KS + ct * 16 + l16] = f2bf(p);
            }
        }
        #pragma unroll
        for (int off = 1; off < 16; off <<= 1) {
            #pragma unroll
            for (int r = 0; r < 4; ++r)
                psum[r] += __shfl_xor(psum[r], off);
        }
        #pragma unroll
        for (int r = 0; r < 4; ++r)
            lrow[r] = lrow[r] * corr[r] + psum[r];
        #pragma unroll
        for (int dt = 0; dt < 4; ++dt) {
            #pragma unroll
            for (int r = 0; r < 4; ++r)
                oacc[dt][r] *= corr[r];
        }

        bf16x8 pa0 = *(bf16x8*)&PsL[w][l16 * KS + lq * 8];
        bf16x8 pa1 = *(bf16x8*)&PsL[w][l16 * KS + 32 + lq * 8];
        #pragma unroll
        for (int dt = 0; dt < 4; ++dt) {
            bf16x8 vb0 = *(bf16x8*)&VtL[(dt * 16 + l16) * KS + lq * 8];
            bf16x8 vb1 = *(bf16x8*)&VtL[(dt * 16 + l16) * KS + 32 + lq * 8];
            oacc[dt] = __builtin_amdgcn_mfma_f32_16x16x32_bf16(pa0, vb0, oacc[dt], 0, 0, 0);
            oacc[dt] = __builtin_amdgcn_mfma_f32_16x16x32_bf16(pa1, vb1, oacc[dt], 0, 0, 0);
        }
    }

    float linv[4];
    #pragma unroll
    for (int r = 0; r < 4; ++r) linv[r] = 1.f / lrow[r];
    #pragma unroll
    for (int dt = 0; dt < 4; ++dt) {
        #pragma unroll
        for (int r = 0; r < 4; ++r) {
            int row = qr0 + lq * 4 + r;
            y[(size_t)row * EE + h * DD + dt * 16 + l16] = f2bf(oacc[dt][r] * linv[r]);
        }
    }
}

// ---------------------------------------------------------------------------
extern "C" void kernel_launch(void* const* d_in, const int* in_sizes, int n_in,
                              void* d_out, int out_size, void* d_ws, size_t ws_size,
                              hipStream_t stream)
{
    (void)in_sizes; (void)n_in; (void)out_size; (void)ws_size;
    const float* x      = (const float*)d_in[0];
    const float* w_attn = (const float*)d_in[1];
    const float* w_proj = (const float*)d_in[2];
    const float* qcw    = (const float*)d_in[3];
    const float* kcw    = (const float*)d_in[4];
    const float* vcw    = (const float*)d_in[5];
    const float* cosb   = (const float*)d_in[6];
    const float* sinb   = (const float*)d_in[7];
    const float* beta   = (const float*)d_in[8];
    const float* g      = (const float*)d_in[9];
    float* out = (float*)d_out;
    float* ws  = (float*)d_ws;

    const size_t TE = (size_t)TT * EE;
    float* buf0 = ws + 0 * TE;          // qkv(raw, spans buf0-2) -> Bt
    float* buf1 = ws + 1 * TE;          //                        -> Ct -> ybf
    float* buf2 = ws + 2 * TE;          //                        -> Ft -> wpT
    float* qb   = ws + 3 * TE;          // xbf -> q
    float* kb   = ws + 4 * TE;          // waT -> k
    float* vb   = ws + 5 * TE;          // v -> E -> O
    float* qkv  = buf0;                 // 2048x3072 fp32 = 24MB
    ushort* xbf = (ushort*)qb;          // 4MB  (dead before conv_rope writes q)
    ushort* waT = (ushort*)kb;          // 6MB  (dead before conv_rope writes k)
    ushort* ybf = (ushort*)buf1;        // attn out bf16 (Ct dead)
    ushort* wpT = (ushort*)buf2;        // w_proj^T bf16 (Ft dead)

    cvt_bf16_kernel<<<TT * EE / 2048, 256, 0, stream>>>(x, xbf);
    cvt_transpose_kernel<<<dim3(NN / 64, EE / 64), 256, 0, stream>>>(w_attn, waT, EE, NN);
    gemm_bf16<128, 128><<<dim3(NN / 128, TT / 128), 256, 0, stream>>>(
        xbf, waT, qkv, TT, NN, EE);
    conv_rope_kernel<<<dim3(TT / 4, HH, 3), dim3(64, 4), 0, stream>>>(
        qkv, qcw, kcw, vcw, cosb, sinb, qb, kb, vb);
    chunk_prep_kernel<<<dim3(NCH, HH), 256, 0, stream>>>(qb, kb, vb, beta, g, buf0, buf1, buf2);
    delta_scan2_kernel<<<HH, 256, 0, stream>>>(buf0, buf1, buf2, vb, g);
    cvt_transpose_kernel<<<dim3(EE / 64, EE / 64), 256, 0, stream>>>(w_proj, wpT, EE, EE);
    attn_mfma_kernel<<<dim3(TT / 64, HH), 256, 0, stream>>>(qb, kb, vb, ybf);
    gemm_bf16<64, 64><<<dim3(EE / 64, TT / 64), 256, 0, stream>>>(
        ybf, wpT, out, TT, EE, EE);
}

// Round 5
// 435.340 us; speedup vs baseline: 5.3149x; 1.0013x over previous
//
#include <hip/hip_runtime.h>
#include <math.h>

#define TT 2048
#define HH 16
#define DD 64
#define EE 1024
#define NN 3072
#define CHUNK 64
#define NCH (TT / CHUNK)
#define SCALE 0.125f
#define KS 72   // attn LDS row stride (bf16): conflict-free b128

typedef short bf16x8 __attribute__((ext_vector_type(8)));
typedef short bf16x4 __attribute__((ext_vector_type(4)));
typedef float f32x4 __attribute__((ext_vector_type(4)));
typedef unsigned short ushort;
typedef const __attribute__((address_space(1))) unsigned int* gptr_t;
typedef __attribute__((address_space(3))) unsigned int* lptr_t;

__device__ __forceinline__ unsigned short f2bf(float x) {
    union { float f; unsigned u; } un; un.f = x;
    unsigned r = un.u + 0x7FFFu + ((un.u >> 16) & 1u);
    return (unsigned short)(r >> 16);
}

// ---------------------------------------------------------------------------
// fp32 -> bf16 elementwise convert (x)
// ---------------------------------------------------------------------------
__global__ __launch_bounds__(256) void cvt_bf16_kernel(
    const float* __restrict__ in, ushort* __restrict__ out)
{
    int i = ((int)blockIdx.x * 256 + (int)threadIdx.x) << 3;
    float4 a = *(const float4*)&in[i];
    float4 b = *(const float4*)&in[i + 4];
    bf16x8 o;
    o[0] = (short)f2bf(a.x); o[1] = (short)f2bf(a.y);
    o[2] = (short)f2bf(a.z); o[3] = (short)f2bf(a.w);
    o[4] = (short)f2bf(b.x); o[5] = (short)f2bf(b.y);
    o[6] = (short)f2bf(b.z); o[7] = (short)f2bf(b.w);
    *(bf16x8*)&out[i] = o;
}

// ---------------------------------------------------------------------------
// fp32 [K][N] -> bf16 [N][K] convert + transpose (weights)
// ---------------------------------------------------------------------------
__global__ __launch_bounds__(256) void cvt_transpose_kernel(
    const float* __restrict__ W, ushort* __restrict__ WT, int K, int N)
{
    __shared__ float Ls[64][65];
    int n0 = blockIdx.x * 64, k0 = blockIdx.y * 64;
    int tid = threadIdx.x;
    int lr = tid >> 4, lc4 = (tid & 15) << 2;
    #pragma unroll
    for (int m = 0; m < 4; ++m) {
        int r = lr + m * 16;
        float4 v = *(const float4*)&W[(size_t)(k0 + r) * N + n0 + lc4];
        Ls[r][lc4 + 0] = v.x; Ls[r][lc4 + 1] = v.y;
        Ls[r][lc4 + 2] = v.z; Ls[r][lc4 + 3] = v.w;
    }
    __syncthreads();
    int n = tid >> 2, kb = (tid & 3) << 4;
    bf16x8 o0, o1;
    #pragma unroll
    for (int j = 0; j < 8; ++j) o0[j] = (short)f2bf(Ls[kb + j][n]);
    #pragma unroll
    for (int j = 0; j < 8; ++j) o1[j] = (short)f2bf(Ls[kb + 8 + j][n]);
    *(bf16x8*)&WT[(size_t)(n0 + n) * K + k0 + kb] = o0;
    *(bf16x8*)&WT[(size_t)(n0 + n) * K + k0 + kb + 8] = o1;
}

// ---------------------------------------------------------------------------
// bf16 MFMA GEMM: C(fp32)[M][N] = A(bf16)[M][K] * BT(bf16)[N][K]^T
// BM x BN tile, BK=64, 4 waves (2x2), double-buffered global_load_lds staging,
// XOR slot swizzle (slot ^ row&7) pre-applied on global src + on ds_read.
// ---------------------------------------------------------------------------
template<int BM, int BN>
__global__ __launch_bounds__(256) void gemm_bf16(
    const ushort* __restrict__ A, const ushort* __restrict__ BT,
    float* __restrict__ C, int M, int N, int K)
{
    constexpr int MT = BM / 32;
    constexpr int NT = BN / 32;
    constexpr int AIT = BM * 64 / 2048;
    constexpr int BIT = BN * 64 / 2048;
    __shared__ __align__(16) ushort Asl[2][BM * 64];
    __shared__ __align__(16) ushort Bsl[2][BN * 64];
    const int tid = threadIdx.x;
    const int lane = tid & 63, w = tid >> 6;
    const int wm = w >> 1, wn = w & 1;
    const int l16 = lane & 15, lq = lane >> 4;
    const int row0 = blockIdx.y * BM, col0 = blockIdx.x * BN;
    const int wvb = w << 9;

    f32x4 acc[MT][NT];
    #pragma unroll
    for (int i = 0; i < MT; ++i)
        #pragma unroll
        for (int j = 0; j < NT; ++j)
            acc[i][j] = (f32x4){0.f, 0.f, 0.f, 0.f};

#define STAGE_TILE(buf, k0)                                                    \
    {                                                                          \
        _Pragma("unroll")                                                      \
        for (int u = 0; u < AIT; ++u) {                                        \
            int idx = u * 256 + tid;                                           \
            int r = idx >> 3, s = idx & 7;                                     \
            const ushort* srcp =                                               \
                &A[(size_t)(row0 + r) * K + (k0) + ((s ^ (r & 7)) << 3)];      \
            __builtin_amdgcn_global_load_lds((gptr_t)srcp,                     \
                (lptr_t)&Asl[buf][(u << 11) + wvb], 16, 0, 0);                 \
        }                                                                      \
        _Pragma("unroll")                                                      \
        for (int u = 0; u < BIT; ++u) {                                        \
            int idx = u * 256 + tid;                                           \
            int r = idx >> 3, s = idx & 7;                                     \
            const ushort* srcp =                                               \
                &BT[(size_t)(col0 + r) * K + (k0) + ((s ^ (r & 7)) << 3)];     \
            __builtin_amdgcn_global_load_lds((gptr_t)srcp,                     \
                (lptr_t)&Bsl[buf][(u << 11) + wvb], 16, 0, 0);                 \
        }                                                                      \
    }

    const int nK = K >> 6;
    STAGE_TILE(0, 0)
    for (int kt = 0; kt < nK; ++kt) {
        __syncthreads();                       // stage(kt) drained + visible
        if (kt + 1 < nK) STAGE_TILE((kt + 1) & 1, (kt + 1) << 6)
        const int cb = kt & 1;
        #pragma unroll
        for (int kk = 0; kk < 2; ++kk) {
            bf16x8 afr[MT], bfr[NT];
            #pragma unroll
            for (int mt = 0; mt < MT; ++mt) {
                int rr = wm * (BM / 2) + mt * 16 + l16;
                afr[mt] = *(bf16x8*)&Asl[cb][rr * 64 +
                           (((kk * 4 + lq) ^ (rr & 7)) << 3)];
            }
            #pragma unroll
            for (int nt = 0; nt < NT; ++nt) {
                int cc = wn * (BN / 2) + nt * 16 + l16;
                bfr[nt] = *(bf16x8*)&Bsl[cb][cc * 64 +
                           (((kk * 4 + lq) ^ (cc & 7)) << 3)];
            }
            #pragma unroll
            for (int mt = 0; mt < MT; ++mt)
                #pragma unroll
                for (int nt = 0; nt < NT; ++nt)
                    acc[mt][nt] = __builtin_amdgcn_mfma_f32_16x16x32_bf16(
                        afr[mt], bfr[nt], acc[mt][nt], 0, 0, 0);
        }
    }
#undef STAGE_TILE

    #pragma unroll
    for (int mt = 0; mt < MT; ++mt) {
        #pragma unroll
        for (int nt = 0; nt < NT; ++nt) {
            int col = col0 + wn * (BN / 2) + nt * 16 + l16;
            #pragma unroll
            for (int r = 0; r < 4; ++r) {
                int row = row0 + wm * (BM / 2) + mt * 16 + lq * 4 + r;
                C[(size_t)row * N + col] = acc[mt][nt][r];
            }
        }
    }
}

// ---------------------------------------------------------------------------
// Causal depthwise conv1d (DC=4) + SiLU, then RoPE for q,k; v plain.
// Reads fused qkv buffer [T][3072], channel map n = h*192 + j*64 + d.
// ---------------------------------------------------------------------------
__global__ __launch_bounds__(256) void conv_rope_kernel(
    const float* __restrict__ qkv,
    const float* __restrict__ qw, const float* __restrict__ kw, const float* __restrict__ vw,
    const float* __restrict__ cosb, const float* __restrict__ sinb,
    float* __restrict__ qo, float* __restrict__ ko, float* __restrict__ vo)
{
    int j = blockIdx.z;
    const float* w = (j == 0) ? qw : (j == 1) ? kw : vw;
    float* dst     = (j == 0) ? qo : (j == 1) ? ko : vo;
    int d  = threadIdx.x;
    int tl = threadIdx.y;
    int t  = blockIdx.x * 4 + tl;
    int h  = blockIdx.y;
    int c  = h * DD + d;
    int n  = h * 192 + j * 64 + d;
    float acc = 0.f;
    #pragma unroll
    for (int i = 0; i < 4; ++i) {
        int tt = t - 3 + i;
        if (tt >= 0) acc = fmaf(qkv[(size_t)tt * NN + n], w[c * 4 + i], acc);
    }
    float yv = acc / (1.f + __expf(-acc));
    if (j == 2) { dst[t * EE + c] = yv; return; }
    __shared__ float sh[4][64];
    sh[tl][d] = yv;
    __syncthreads();
    int dh = d & 31;
    float cc = cosb[t * 32 + dh];
    float ss = sinb[t * 32 + dh];
    float outv;
    if (d < 32) outv = yv * cc - sh[tl][d + 32] * ss;
    else        outv = yv * cc + sh[tl][d - 32] * ss;
    dst[t * EE + c] = outv;
}

// ---------------------------------------------------------------------------
// Chunked gated delta rule, phase 1 (parallel over 32 chunks x 16 heads).
// ---------------------------------------------------------------------------
__global__ __launch_bounds__(256) void chunk_prep_kernel(
    const float* __restrict__ qb, const float* __restrict__ kb, float* __restrict__ vb,
    const float* __restrict__ beta, const float* __restrict__ g,
    float* __restrict__ Bt, float* __restrict__ Ct, float* __restrict__ Ft)
{
    __shared__ float Kc[64][68], Qc[64][68], Vc[64][68];
    __shared__ float Mm[64][68], At[64][68], Xv[64][68], Xk[64][68];
    __shared__ float Gs[64], bs[64];
    int c = blockIdx.x, h = blockIdx.y;
    int tid = threadIdx.x;
    int t0 = c * CHUNK;
    {
        int row = tid >> 4, c4 = (tid & 15) << 2;
        #pragma unroll
        for (int m = 0; m < 4; ++m) {
            int r = row + m * 16;
            size_t gidx = (size_t)(t0 + r) * EE + h * DD + c4;
            *(float4*)&Kc[r][c4] = *(const float4*)&kb[gidx];
            *(float4*)&Qc[r][c4] = *(const float4*)&qb[gidx];
            *(float4*)&Vc[r][c4] = *(const float4*)&vb[gidx];
        }
    }
    if (tid < 64) {
        float x = g[(t0 + tid) * HH + h];
        #pragma unroll
        for (int off = 1; off < 64; off <<= 1) {
            float y = __shfl_up(x, off);
            if (tid >= off) x *= y;
        }
        Gs[tid] = x;
        bs[tid] = beta[(t0 + tid) * HH + h];
    }
    __syncthreads();
    #pragma unroll 2
    for (int i = 0; i < 16; ++i) {
        int p = i * 256 + tid;
        int t = p >> 6, s = p & 63;
        float dkk = 0.f, dqk = 0.f;
        #pragma unroll
        for (int j4 = 0; j4 < 64; j4 += 4) {
            float4 ks = *(const float4*)&Kc[s][j4];
            float4 kt = *(const float4*)&Kc[t][j4];
            float4 qt = *(const float4*)&Qc[t][j4];
            dkk = fmaf(kt.x, ks.x, fmaf(kt.y, ks.y, fmaf(kt.z, ks.z, fmaf(kt.w, ks.w, dkk))));
            dqk = fmaf(qt.x, ks.x, fmaf(qt.y, ks.y, fmaf(qt.z, ks.z, fmaf(qt.w, ks.w, dqk))));
        }
        float gr = Gs[t] / Gs[s];
        if (s < t) Mm[t][s] = bs[t] * gr * dkk;
        At[s][t] = (s <= t) ? SCALE * gr * dqk : 0.f;
    }
    __syncthreads();
    if (tid < 128) {
        int col = tid & 63;
        int hv = tid >> 6;
        float* Xp = hv ? &Xk[0][0] : &Xv[0][0];
        #pragma unroll 1
        for (int t = 0; t < 64; ++t) {
            float acc = hv ? (bs[t] * Gs[t] * Kc[t][col]) : (bs[t] * Vc[t][col]);
            for (int s = 0; s < t; ++s)
                acc = fmaf(-Mm[t][s], Xp[s * 68 + col], acc);
            Xp[t * 68 + col] = acc;
        }
    }
    __syncthreads();
    {
        int r = tid & 63, qd = tid >> 6;
        float ratio = Gs[63] / Gs[r];
        #pragma unroll
        for (int jj = 0; jj < 4; ++jj) {
            float4 vv = *(const float4*)&Kc[r][qd * 16 + jj * 4];
            vv.x *= ratio; vv.y *= ratio; vv.z *= ratio; vv.w *= ratio;
            *(float4*)&Kc[r][qd * 16 + jj * 4] = vv;
        }
    }
    __syncthreads();
    int tx = tid & 15, ty = tid >> 4;
    int a0 = ty << 2, b0 = tx << 2;
    float aB[4][4] = {}, aC[4][4] = {}, aF[4][4] = {}, aE[4][4] = {};
    #pragma unroll 2
    for (int s = 0; s < 64; ++s) {
        float4 xkA4 = *(const float4*)&Xk[s][a0];
        float4 kcB4 = *(const float4*)&Kc[s][b0];
        float4 kcA4 = *(const float4*)&Kc[s][a0];
        float4 xvB4 = *(const float4*)&Xv[s][b0];
        float4 atA4 = *(const float4*)&At[s][a0];
        float4 atB4 = *(const float4*)&At[s][b0];
        float xkA[4] = {xkA4.x, xkA4.y, xkA4.z, xkA4.w};
        float kcB[4] = {kcB4.x, kcB4.y, kcB4.z, kcB4.w};
        float kcA[4] = {kcA4.x, kcA4.y, kcA4.z, kcA4.w};
        float xvB[4] = {xvB4.x, xvB4.y, xvB4.z, xvB4.w};
        float atA[4] = {atA4.x, atA4.y, atA4.z, atA4.w};
        float atB[4] = {atB4.x, atB4.y, atB4.z, atB4.w};
        #pragma unroll
        for (int i = 0; i < 4; ++i)
            #pragma unroll
            for (int j = 0; j < 4; ++j) {
                aB[i][j] = fmaf(xkA[i], kcB[j], aB[i][j]);
                aC[i][j] = fmaf(kcA[i], xvB[j], aC[i][j]);
                aF[i][j] = fmaf(xkA[i], atB[j], aF[i][j]);
                aE[i][j] = fmaf(atA[i], xvB[j], aE[i][j]);
            }
    }
    size_t tile = ((size_t)(c * HH + h)) << 12;
    #pragma unroll
    for (int i = 0; i < 4; ++i) {
        int a = a0 + i;
        float4 wB = {aB[i][0], aB[i][1], aB[i][2], aB[i][3]};
        float4 wC = {aC[i][0], aC[i][1], aC[i][2], aC[i][3]};
        float4 wF;
        wF.x = SCALE * Gs[b0 + 0] * Qc[b0 + 0][a] - aF[i][0];
        wF.y = SCALE * Gs[b0 + 1] * Qc[b0 + 1][a] - aF[i][1];
        wF.z = SCALE * Gs[b0 + 2] * Qc[b0 + 2][a] - aF[i][2];
        wF.w = SCALE * Gs[b0 + 3] * Qc[b0 + 3][a] - aF[i][3];
        float4 wE = {aE[i][0], aE[i][1], aE[i][2], aE[i][3]};
        *(float4*)&Bt[tile + a * 64 + b0] = wB;
        *(float4*)&Ct[tile + a * 64 + b0] = wC;
        *(float4*)&Ft[tile + a * 64 + b0] = wF;
        *(float4*)&vb[(size_t)(t0 + a) * EE + h * DD + b0] = wE;
    }
}

// ---------------------------------------------------------------------------
// Chunked delta rule, phase 2 (sequential over 32 chunks, parallel over heads).
// ---------------------------------------------------------------------------
__global__ __launch_bounds__(256) void delta_scan2_kernel(
    const float* __restrict__ Bt, const float* __restrict__ Ct, const float* __restrict__ Ft,
    float* __restrict__ vb, const float* __restrict__ g)
{
    __shared__ float Ss[64][64];
    __shared__ float Bs[64][64], Fs[64][64], Cs[64][64], Es[64][64];
    __shared__ float GCs;
    int h = blockIdx.x;
    int tid = threadIdx.x;
    int tx = tid & 15, ty = tid >> 4;
    int a0 = ty << 2, b0 = tx << 2;
    {
        int row = tid >> 4, c4 = (tid & 15) << 2;
        #pragma unroll
        for (int m = 0; m < 4; ++m) {
            float4 z = {0.f, 0.f, 0.f, 0.f};
            *(float4*)&Ss[row + m * 16][c4] = z;
        }
    }
    for (int c = 0; c < NCH; ++c) {
        if (tid < 64) {
            float x = g[((c << 6) + tid) * HH + h];
            #pragma unroll
            for (int off = 32; off; off >>= 1) x *= __shfl_xor(x, off);
            if (tid == 0) GCs = x;
        }
        size_t tile = ((size_t)(c * HH + h)) << 12;
        {
            int row = tid >> 4, c4 = (tid & 15) << 2;
            #pragma unroll
            for (int m = 0; m < 4; ++m) {
                int r = row + m * 16;
                *(float4*)&Bs[r][c4] = *(const float4*)&Bt[tile + r * 64 + c4];
                *(float4*)&Fs[r][c4] = *(const float4*)&Ft[tile + r * 64 + c4];
                *(float4*)&Cs[r][c4] = *(const float4*)&Ct[tile + r * 64 + c4];
                *(float4*)&Es[r][c4] = *(const float4*)&vb[(size_t)((c << 6) + r) * EE + h * DD + c4];
            }
        }
        __syncthreads();
        float accO[4][4] = {}, accP[4][4] = {};
        #pragma unroll 4
        for (int k = 0; k < 64; ++k) {
            float4 fv = *(const float4*)&Fs[k][a0];
            float4 bv = *(const float4*)&Bs[k][a0];
            float4 sv = *(const float4*)&Ss[k][b0];
            float fa[4] = {fv.x, fv.y, fv.z, fv.w};
            float ba[4] = {bv.x, bv.y, bv.z, bv.w};
            float sa[4] = {sv.x, sv.y, sv.z, sv.w};
            #pragma unroll
            for (int i = 0; i < 4; ++i)
                #pragma unroll
                for (int j = 0; j < 4; ++j) {
                    accO[i][j] = fmaf(fa[i], sa[j], accO[i][j]);
                    accP[i][j] = fmaf(ba[i], sa[j], accP[i][j]);
                }
        }
        __syncthreads();
        float GC = GCs;
        #pragma unroll
        for (int i = 0; i < 4; ++i) {
            int a = a0 + i;
            float4 sv = *(const float4*)&Ss[a][b0];
            float4 cv = *(const float4*)&Cs[a][b0];
            float4 ns;
            ns.x = fmaf(GC, sv.x, cv.x - accP[i][0]);
            ns.y = fmaf(GC, sv.y, cv.y - accP[i][1]);
            ns.z = fmaf(GC, sv.z, cv.z - accP[i][2]);
            ns.w = fmaf(GC, sv.w, cv.w - accP[i][3]);
            *(float4*)&Ss[a][b0] = ns;
            float4 ev = *(const float4*)&Es[a][b0];
            float4 ov = {accO[i][0] + ev.x, accO[i][1] + ev.y,
                         accO[i][2] + ev.z, accO[i][3] + ev.w};
            *(float4*)&vb[(size_t)((c << 6) + a) * EE + h * DD + b0] = ov;
        }
        __syncthreads();
    }
}

// ---------------------------------------------------------------------------
// Causal flash attention, bf16 MFMA; output written as bf16 for proj GEMM.
// ---------------------------------------------------------------------------
__global__ __launch_bounds__(256) void attn_mfma_kernel(
    const float* __restrict__ q, const float* __restrict__ k, const float* __restrict__ v,
    ushort* __restrict__ y)
{
    __shared__ __align__(16) unsigned short KsL[64 * KS];
    __shared__ __align__(16) unsigned short VtL[64 * KS];
    __shared__ __align__(16) unsigned short PsL[4][16 * KS];

    int h = blockIdx.y;
    int rb = ((int)gridDim.x - 1 - (int)blockIdx.x) * 64;
    int tid = threadIdx.x;
    int w = tid >> 6;
    int lane = tid & 63;
    int l16 = lane & 15;
    int lq = lane >> 4;
    int qr0 = rb + w * 16;

    bf16x8 qf[2];
    {
        const float* qrow = &q[(size_t)(qr0 + l16) * EE + h * DD];
        #pragma unroll
        for (int kk = 0; kk < 2; ++kk) {
            float4 v0 = *(const float4*)&qrow[kk * 32 + lq * 8];
            float4 v1 = *(const float4*)&qrow[kk * 32 + lq * 8 + 4];
            qf[kk][0] = (short)f2bf(v0.x); qf[kk][1] = (short)f2bf(v0.y);
            qf[kk][2] = (short)f2bf(v0.z); qf[kk][3] = (short)f2bf(v0.w);
            qf[kk][4] = (short)f2bf(v1.x); qf[kk][5] = (short)f2bf(v1.y);
            qf[kk][6] = (short)f2bf(v1.z); qf[kk][7] = (short)f2bf(v1.w);
        }
    }

    f32x4 oacc[4];
    #pragma unroll
    for (int dt = 0; dt < 4; ++dt) oacc[dt] = (f32x4){0.f, 0.f, 0.f, 0.f};
    float mrow[4] = {-3e38f, -3e38f, -3e38f, -3e38f};
    float lrow[4] = {0.f, 0.f, 0.f, 0.f};

    int ks_s = tid >> 2, ks_d0 = (tid & 3) << 4;
    int vt_s0 = (tid & 31) * 2, vt_dq = (tid >> 5) << 3;

    for (int c0 = 0; c0 <= rb; c0 += 64) {
        __syncthreads();
        {
            const float* krow = &k[(size_t)(c0 + ks_s) * EE + h * DD + ks_d0];
            #pragma unroll
            for (int u = 0; u < 4; ++u) {
                float4 kv4 = *(const float4*)&krow[u * 4];
                bf16x4 pk = { (short)f2bf(kv4.x), (short)f2bf(kv4.y),
                              (short)f2bf(kv4.z), (short)f2bf(kv4.w) };
                *(bf16x4*)&KsL[ks_s * KS + ks_d0 + u * 4] = pk;
            }
            const float* vr0 = &v[(size_t)(c0 + vt_s0) * EE + h * DD + vt_dq];
            const float* vr1 = vr0 + EE;
            float4 a0 = *(const float4*)&vr0[0], a1 = *(const float4*)&vr0[4];
            float4 b0 = *(const float4*)&vr1[0], b1 = *(const float4*)&vr1[4];
            float va[8] = {a0.x, a0.y, a0.z, a0.w, a1.x, a1.y, a1.z, a1.w};
            float vbv[8] = {b0.x, b0.y, b0.z, b0.w, b1.x, b1.y, b1.z, b1.w};
            #pragma unroll
            for (int u = 0; u < 8; ++u) {
                unsigned pv = (unsigned)f2bf(va[u]) | ((unsigned)f2bf(vbv[u]) << 16);
                *(unsigned*)&VtL[(vt_dq + u) * KS + vt_s0] = pv;
            }
        }
        __syncthreads();

        f32x4 sacc[4];
        #pragma unroll
        for (int ct = 0; ct < 4; ++ct) {
            bf16x8 b0 = *(bf16x8*)&KsL[(ct * 16 + l16) * KS + lq * 8];
            bf16x8 b1 = *(bf16x8*)&KsL[(ct * 16 + l16) * KS + 32 + lq * 8];
            f32x4 acc = {0.f, 0.f, 0.f, 0.f};
            acc = __builtin_amdgcn_mfma_f32_16x16x32_bf16(qf[0], b0, acc, 0, 0, 0);
            acc = __builtin_amdgcn_mfma_f32_16x16x32_bf16(qf[1], b1, acc, 0, 0, 0);
            sacc[ct] = acc;
        }

        float sv[4][4];
        float tmax[4] = {-3e38f, -3e38f, -3e38f, -3e38f};
        #pragma unroll
        for (int ct = 0; ct < 4; ++ct) {
            int col = c0 + ct * 16 + l16;
            #pragma unroll
            for (int r = 0; r < 4; ++r) {
                int row = qr0 + lq * 4 + r;
                float s = sacc[ct][r] * SCALE;
                if (col > row) s = -3e38f;
                sv[ct][r] = s;
                tmax[r] = fmaxf(tmax[r], s);
            }
        }
        #pragma unroll
        for (int off = 1; off < 16; off <<= 1) {
            #pragma unroll
            for (int r = 0; r < 4; ++r)
                tmax[r] = fmaxf(tmax[r], __shfl_xor(tmax[r], off));
        }
        float corr[4], psum[4];
        #pragma unroll
        for (int r = 0; r < 4; ++r) {
            float mn = fmaxf(mrow[r], tmax[r]);
            corr[r] = __expf(mrow[r] - mn);
            mrow[r] = mn;
            psum[r] = 0.f;
        }
        #pragma unroll
        for (int ct = 0; ct < 4; ++ct) {
            #pragma unroll
            for (int r = 0; r < 4; ++r) {
                float p = __expf(sv[ct][r] - mrow[r]);
                psum[r] += p;
                PsL[w][(lq * 4 + r) * KS + ct * 16 + l16] = f2bf(p);
            }
        }
        #pragma unroll
        for (int off = 1; off < 16; off <<= 1) {
            #pragma unroll
            for (int r = 0; r < 4; ++r)
                psum[r] += __shfl_xor(psum[r], off);
        }
        #pragma unroll
        for (int r = 0; r < 4; ++r)
            lrow[r] = lrow[r] * corr[r] + psum[r];
        #pragma unroll
        for (int dt = 0; dt < 4; ++dt) {
            #pragma unroll
            for (int r = 0; r < 4; ++r)
                oacc[dt][r] *= corr[r];
        }

        bf16x8 pa0 = *(bf16x8*)&PsL[w][l16 * KS + lq * 8];
        bf16x8 pa1 = *(bf16x8*)&PsL[w][l16 * KS + 32 + lq * 8];
        #pragma unroll
        for (int dt = 0; dt < 4; ++dt) {
            bf16x8 vb0 = *(bf16x8*)&VtL[(dt * 16 + l16) * KS + lq * 8];
            bf16x8 vb1 = *(bf16x8*)&VtL[(dt * 16 + l16) * KS + 32 + lq * 8];
            oacc[dt] = __builtin_amdgcn_mfma_f32_16x16x32_bf16(pa0, vb0, oacc[dt], 0, 0, 0);
            oacc[dt] = __builtin_amdgcn_mfma_f32_16x16x32_bf16(pa1, vb1, oacc[dt], 0, 0, 0);
        }
    }

    float linv[4];
    #pragma unroll
    for (int r = 0; r < 4; ++r) linv[r] = 1.f / lrow[r];
    #pragma unroll
    for (int dt = 0; dt < 4; ++dt) {
        #pragma unroll
        for (int r = 0; r < 4; ++r) {
            int row = qr0 + lq * 4 + r;
            y[(size_t)row * EE + h * DD + dt * 16 + l16] = f2bf(oacc[dt][r] * linv[r]);
        }
    }
}

// ---------------------------------------------------------------------------
extern "C" void kernel_launch(void* const* d_in, const int* in_sizes, int n_in,
                              void* d_out, int out_size, void* d_ws, size_t ws_size,
                              hipStream_t stream)
{
    (void)in_sizes; (void)n_in; (void)out_size; (void)ws_size;
    const float* x      = (const float*)d_in[0];
    const float* w_attn = (const float*)d_in[1];
    const float* w_proj = (const float*)d_in[2];
    const float* qcw    = (const float*)d_in[3];
    const float* kcw    = (const float*)d_in[4];
    const float* vcw    = (const float*)d_in[5];
    const float* cosb   = (const float*)d_in[6];
    const float* sinb   = (const float*)d_in[7];
    const float* beta   = (const float*)d_in[8];
    const float* g      = (const float*)d_in[9];
    float* out = (float*)d_out;
    float* ws  = (float*)d_ws;

    const size_t TE = (size_t)TT * EE;
    float* buf0 = ws + 0 * TE;          // qkv(raw, spans buf0-2) -> Bt
    float* buf1 = ws + 1 * TE;          //                        -> Ct -> ybf
    float* buf2 = ws + 2 * TE;          //                        -> Ft -> wpT
    float* qb   = ws + 3 * TE;          // xbf -> q
    float* kb   = ws + 4 * TE;          // waT -> k
    float* vb   = ws + 5 * TE;          // v -> E -> O
    float* qkv  = buf0;                 // 2048x3072 fp32 = 24MB
    ushort* xbf = (ushort*)qb;          // 4MB  (dead before conv_rope writes q)
    ushort* waT = (ushort*)kb;          // 6MB  (dead before conv_rope writes k)
    ushort* ybf = (ushort*)buf1;        // attn out bf16 (Ct dead)
    ushort* wpT = (ushort*)buf2;        // w_proj^T bf16 (Ft dead)

    cvt_bf16_kernel<<<TT * EE / 2048, 256, 0, stream>>>(x, xbf);
    cvt_transpose_kernel<<<dim3(NN / 64, EE / 64), 256, 0, stream>>>(w_attn, waT, EE, NN);
    gemm_bf16<128, 128><<<dim3(NN / 128, TT / 128), 256, 0, stream>>>(
        xbf, waT, qkv, TT, NN, EE);
    conv_rope_kernel<<<dim3(TT / 4, HH, 3), dim3(64, 4), 0, stream>>>(
        qkv, qcw, kcw, vcw, cosb, sinb, qb, kb, vb);
    chunk_prep_kernel<<<dim3(NCH, HH), 256, 0, stream>>>(qb, kb, vb, beta, g, buf0, buf1, buf2);
    delta_scan2_kernel<<<HH, 256, 0, stream>>>(buf0, buf1, buf2, vb, g);
    cvt_transpose_kernel<<<dim3(EE / 64, EE / 64), 256, 0, stream>>>(w_proj, wpT, EE, EE);
    attn_mfma_kernel<<<dim3(TT / 64, HH), 256, 0, stream>>>(qb, kb, vb, ybf);
    gemm_bf16<64, 64><<<dim3(EE / 64, TT / 64), 256, 0, stream>>>(
        ybf, wpT, out, TT, EE, EE);
}

// Round 6
// 406.705 us; speedup vs baseline: 5.6891x; 1.0704x over previous
//
#include <hip/hip_runtime.h>
#include <math.h>

#define TT 2048
#define HH 16
#define DD 64
#define EE 1024
#define NN 3072
#define CHUNK 64
#define NCH (TT / CHUNK)
#define SCALE 0.125f
#define KS 72   // attn LDS row stride (bf16): conflict-free b128

typedef short bf16x8 __attribute__((ext_vector_type(8)));
typedef short bf16x4 __attribute__((ext_vector_type(4)));
typedef float f32x4 __attribute__((ext_vector_type(4)));
typedef unsigned short ushort;
typedef const __attribute__((address_space(1))) unsigned int* gptr_t;
typedef __attribute__((address_space(3))) unsigned int* lptr_t;

__device__ __forceinline__ unsigned short f2bf(float x) {
    union { float f; unsigned u; } un; un.f = x;
    unsigned r = un.u + 0x7FFFu + ((un.u >> 16) & 1u);
    return (unsigned short)(r >> 16);
}

// ---------------------------------------------------------------------------
// fp32 -> bf16 elementwise convert (x)
// ---------------------------------------------------------------------------
__global__ __launch_bounds__(256) void cvt_bf16_kernel(
    const float* __restrict__ in, ushort* __restrict__ out)
{
    int i = ((int)blockIdx.x * 256 + (int)threadIdx.x) << 3;
    float4 a = *(const float4*)&in[i];
    float4 b = *(const float4*)&in[i + 4];
    bf16x8 o;
    o[0] = (short)f2bf(a.x); o[1] = (short)f2bf(a.y);
    o[2] = (short)f2bf(a.z); o[3] = (short)f2bf(a.w);
    o[4] = (short)f2bf(b.x); o[5] = (short)f2bf(b.y);
    o[6] = (short)f2bf(b.z); o[7] = (short)f2bf(b.w);
    *(bf16x8*)&out[i] = o;
}

// ---------------------------------------------------------------------------
// fp32 [K][N] -> bf16 [N][K] convert + transpose (weights)
// ---------------------------------------------------------------------------
__global__ __launch_bounds__(256) void cvt_transpose_kernel(
    const float* __restrict__ W, ushort* __restrict__ WT, int K, int N)
{
    __shared__ float Ls[64][65];
    int n0 = blockIdx.x * 64, k0 = blockIdx.y * 64;
    int tid = threadIdx.x;
    int lr = tid >> 4, lc4 = (tid & 15) << 2;
    #pragma unroll
    for (int m = 0; m < 4; ++m) {
        int r = lr + m * 16;
        float4 v = *(const float4*)&W[(size_t)(k0 + r) * N + n0 + lc4];
        Ls[r][lc4 + 0] = v.x; Ls[r][lc4 + 1] = v.y;
        Ls[r][lc4 + 2] = v.z; Ls[r][lc4 + 3] = v.w;
    }
    __syncthreads();
    int n = tid >> 2, kb = (tid & 3) << 4;
    bf16x8 o0, o1;
    #pragma unroll
    for (int j = 0; j < 8; ++j) o0[j] = (short)f2bf(Ls[kb + j][n]);
    #pragma unroll
    for (int j = 0; j < 8; ++j) o1[j] = (short)f2bf(Ls[kb + 8 + j][n]);
    *(bf16x8*)&WT[(size_t)(n0 + n) * K + k0 + kb] = o0;
    *(bf16x8*)&WT[(size_t)(n0 + n) * K + k0 + kb + 8] = o1;
}

// ---------------------------------------------------------------------------
// bf16 MFMA GEMM: C(fp32)[M][N] = A(bf16)[M][K] * BT(bf16)[N][K]^T
// ---------------------------------------------------------------------------
template<int BM, int BN>
__global__ __launch_bounds__(256) void gemm_bf16(
    const ushort* __restrict__ A, const ushort* __restrict__ BT,
    float* __restrict__ C, int M, int N, int K)
{
    constexpr int MT = BM / 32;
    constexpr int NT = BN / 32;
    constexpr int AIT = BM * 64 / 2048;
    constexpr int BIT = BN * 64 / 2048;
    __shared__ __align__(16) ushort Asl[2][BM * 64];
    __shared__ __align__(16) ushort Bsl[2][BN * 64];
    const int tid = threadIdx.x;
    const int lane = tid & 63, w = tid >> 6;
    const int wm = w >> 1, wn = w & 1;
    const int l16 = lane & 15, lq = lane >> 4;
    const int row0 = blockIdx.y * BM, col0 = blockIdx.x * BN;
    const int wvb = w << 9;

    f32x4 acc[MT][NT];
    #pragma unroll
    for (int i = 0; i < MT; ++i)
        #pragma unroll
        for (int j = 0; j < NT; ++j)
            acc[i][j] = (f32x4){0.f, 0.f, 0.f, 0.f};

#define STAGE_TILE(buf, k0)                                                    \
    {                                                                          \
        _Pragma("unroll")                                                      \
        for (int u = 0; u < AIT; ++u) {                                        \
            int idx = u * 256 + tid;                                           \
            int r = idx >> 3, s = idx & 7;                                     \
            const ushort* srcp =                                               \
                &A[(size_t)(row0 + r) * K + (k0) + ((s ^ (r & 7)) << 3)];      \
            __builtin_amdgcn_global_load_lds((gptr_t)srcp,                     \
                (lptr_t)&Asl[buf][(u << 11) + wvb], 16, 0, 0);                 \
        }                                                                      \
        _Pragma("unroll")                                                      \
        for (int u = 0; u < BIT; ++u) {                                        \
            int idx = u * 256 + tid;                                           \
            int r = idx >> 3, s = idx & 7;                                     \
            const ushort* srcp =                                               \
                &BT[(size_t)(col0 + r) * K + (k0) + ((s ^ (r & 7)) << 3)];     \
            __builtin_amdgcn_global_load_lds((gptr_t)srcp,                     \
                (lptr_t)&Bsl[buf][(u << 11) + wvb], 16, 0, 0);                 \
        }                                                                      \
    }

    const int nK = K >> 6;
    STAGE_TILE(0, 0)
    for (int kt = 0; kt < nK; ++kt) {
        __syncthreads();                       // stage(kt) drained + visible
        if (kt + 1 < nK) STAGE_TILE((kt + 1) & 1, (kt + 1) << 6)
        const int cb = kt & 1;
        #pragma unroll
        for (int kk = 0; kk < 2; ++kk) {
            bf16x8 afr[MT], bfr[NT];
            #pragma unroll
            for (int mt = 0; mt < MT; ++mt) {
                int rr = wm * (BM / 2) + mt * 16 + l16;
                afr[mt] = *(bf16x8*)&Asl[cb][rr * 64 +
                           (((kk * 4 + lq) ^ (rr & 7)) << 3)];
            }
            #pragma unroll
            for (int nt = 0; nt < NT; ++nt) {
                int cc = wn * (BN / 2) + nt * 16 + l16;
                bfr[nt] = *(bf16x8*)&Bsl[cb][cc * 64 +
                           (((kk * 4 + lq) ^ (cc & 7)) << 3)];
            }
            #pragma unroll
            for (int mt = 0; mt < MT; ++mt)
                #pragma unroll
                for (int nt = 0; nt < NT; ++nt)
                    acc[mt][nt] = __builtin_amdgcn_mfma_f32_16x16x32_bf16(
                        afr[mt], bfr[nt], acc[mt][nt], 0, 0, 0);
        }
    }
#undef STAGE_TILE

    #pragma unroll
    for (int mt = 0; mt < MT; ++mt) {
        #pragma unroll
        for (int nt = 0; nt < NT; ++nt) {
            int col = col0 + wn * (BN / 2) + nt * 16 + l16;
            #pragma unroll
            for (int r = 0; r < 4; ++r) {
                int row = row0 + wm * (BM / 2) + mt * 16 + lq * 4 + r;
                C[(size_t)row * N + col] = acc[mt][nt][r];
            }
        }
    }
}

// ---------------------------------------------------------------------------
// Causal depthwise conv1d (DC=4) + SiLU, then RoPE for q,k; v plain.
// ---------------------------------------------------------------------------
__global__ __launch_bounds__(256) void conv_rope_kernel(
    const float* __restrict__ qkv,
    const float* __restrict__ qw, const float* __restrict__ kw, const float* __restrict__ vw,
    const float* __restrict__ cosb, const float* __restrict__ sinb,
    float* __restrict__ qo, float* __restrict__ ko, float* __restrict__ vo)
{
    int j = blockIdx.z;
    const float* w = (j == 0) ? qw : (j == 1) ? kw : vw;
    float* dst     = (j == 0) ? qo : (j == 1) ? ko : vo;
    int d  = threadIdx.x;
    int tl = threadIdx.y;
    int t  = blockIdx.x * 4 + tl;
    int h  = blockIdx.y;
    int c  = h * DD + d;
    int n  = h * 192 + j * 64 + d;
    float acc = 0.f;
    #pragma unroll
    for (int i = 0; i < 4; ++i) {
        int tt = t - 3 + i;
        if (tt >= 0) acc = fmaf(qkv[(size_t)tt * NN + n], w[c * 4 + i], acc);
    }
    float yv = acc / (1.f + __expf(-acc));
    if (j == 2) { dst[t * EE + c] = yv; return; }
    __shared__ float sh[4][64];
    sh[tl][d] = yv;
    __syncthreads();
    int dh = d & 31;
    float cc = cosb[t * 32 + dh];
    float ss = sinb[t * 32 + dh];
    float outv;
    if (d < 32) outv = yv * cc - sh[tl][d + 32] * ss;
    else        outv = yv * cc + sh[tl][d - 32] * ss;
    dst[t * EE + c] = outv;
}

// ---------------------------------------------------------------------------
// Chunked gated delta rule, phase 1 (parallel over 32 chunks x 16 heads).
// ---------------------------------------------------------------------------
__global__ __launch_bounds__(256) void chunk_prep_kernel(
    const float* __restrict__ qb, const float* __restrict__ kb, float* __restrict__ vb,
    const float* __restrict__ beta, const float* __restrict__ g,
    float* __restrict__ Bt, float* __restrict__ Ct, float* __restrict__ Ft)
{
    __shared__ float Kc[64][68], Qc[64][68], Vc[64][68];
    __shared__ float Mm[64][68], At[64][68], Xv[64][68], Xk[64][68];
    __shared__ float Gs[64], bs[64];
    int c = blockIdx.x, h = blockIdx.y;
    int tid = threadIdx.x;
    int t0 = c * CHUNK;
    {
        int row = tid >> 4, c4 = (tid & 15) << 2;
        #pragma unroll
        for (int m = 0; m < 4; ++m) {
            int r = row + m * 16;
            size_t gidx = (size_t)(t0 + r) * EE + h * DD + c4;
            *(float4*)&Kc[r][c4] = *(const float4*)&kb[gidx];
            *(float4*)&Qc[r][c4] = *(const float4*)&qb[gidx];
            *(float4*)&Vc[r][c4] = *(const float4*)&vb[gidx];
        }
    }
    if (tid < 64) {
        float x = g[(t0 + tid) * HH + h];
        #pragma unroll
        for (int off = 1; off < 64; off <<= 1) {
            float y = __shfl_up(x, off);
            if (tid >= off) x *= y;
        }
        Gs[tid] = x;
        bs[tid] = beta[(t0 + tid) * HH + h];
    }
    __syncthreads();
    #pragma unroll 2
    for (int i = 0; i < 16; ++i) {
        int p = i * 256 + tid;
        int t = p >> 6, s = p & 63;
        float dkk = 0.f, dqk = 0.f;
        #pragma unroll
        for (int j4 = 0; j4 < 64; j4 += 4) {
            float4 ks = *(const float4*)&Kc[s][j4];
            float4 kt = *(const float4*)&Kc[t][j4];
            float4 qt = *(const float4*)&Qc[t][j4];
            dkk = fmaf(kt.x, ks.x, fmaf(kt.y, ks.y, fmaf(kt.z, ks.z, fmaf(kt.w, ks.w, dkk))));
            dqk = fmaf(qt.x, ks.x, fmaf(qt.y, ks.y, fmaf(qt.z, ks.z, fmaf(qt.w, ks.w, dqk))));
        }
        float gr = Gs[t] / Gs[s];
        if (s < t) Mm[t][s] = bs[t] * gr * dkk;
        At[s][t] = (s <= t) ? SCALE * gr * dqk : 0.f;
    }
    __syncthreads();
    if (tid < 128) {
        int col = tid & 63;
        int hv = tid >> 6;
        float* Xp = hv ? &Xk[0][0] : &Xv[0][0];
        #pragma unroll 1
        for (int t = 0; t < 64; ++t) {
            float acc = hv ? (bs[t] * Gs[t] * Kc[t][col]) : (bs[t] * Vc[t][col]);
            for (int s = 0; s < t; ++s)
                acc = fmaf(-Mm[t][s], Xp[s * 68 + col], acc);
            Xp[t * 68 + col] = acc;
        }
    }
    __syncthreads();
    {
        int r = tid & 63, qd = tid >> 6;
        float ratio = Gs[63] / Gs[r];
        #pragma unroll
        for (int jj = 0; jj < 4; ++jj) {
            float4 vv = *(const float4*)&Kc[r][qd * 16 + jj * 4];
            vv.x *= ratio; vv.y *= ratio; vv.z *= ratio; vv.w *= ratio;
            *(float4*)&Kc[r][qd * 16 + jj * 4] = vv;
        }
    }
    __syncthreads();
    int tx = tid & 15, ty = tid >> 4;
    int a0 = ty << 2, b0 = tx << 2;
    float aB[4][4] = {}, aC[4][4] = {}, aF[4][4] = {}, aE[4][4] = {};
    #pragma unroll 2
    for (int s = 0; s < 64; ++s) {
        float4 xkA4 = *(const float4*)&Xk[s][a0];
        float4 kcB4 = *(const float4*)&Kc[s][b0];
        float4 kcA4 = *(const float4*)&Kc[s][a0];
        float4 xvB4 = *(const float4*)&Xv[s][b0];
        float4 atA4 = *(const float4*)&At[s][a0];
        float4 atB4 = *(const float4*)&At[s][b0];
        float xkA[4] = {xkA4.x, xkA4.y, xkA4.z, xkA4.w};
        float kcB[4] = {kcB4.x, kcB4.y, kcB4.z, kcB4.w};
        float kcA[4] = {kcA4.x, kcA4.y, kcA4.z, kcA4.w};
        float xvB[4] = {xvB4.x, xvB4.y, xvB4.z, xvB4.w};
        float atA[4] = {atA4.x, atA4.y, atA4.z, atA4.w};
        float atB[4] = {atB4.x, atB4.y, atB4.z, atB4.w};
        #pragma unroll
        for (int i = 0; i < 4; ++i)
            #pragma unroll
            for (int j = 0; j < 4; ++j) {
                aB[i][j] = fmaf(xkA[i], kcB[j], aB[i][j]);
                aC[i][j] = fmaf(kcA[i], xvB[j], aC[i][j]);
                aF[i][j] = fmaf(xkA[i], atB[j], aF[i][j]);
                aE[i][j] = fmaf(atA[i], xvB[j], aE[i][j]);
            }
    }
    size_t tile = ((size_t)(c * HH + h)) << 12;
    #pragma unroll
    for (int i = 0; i < 4; ++i) {
        int a = a0 + i;
        float4 wB = {aB[i][0], aB[i][1], aB[i][2], aB[i][3]};
        float4 wC = {aC[i][0], aC[i][1], aC[i][2], aC[i][3]};
        float4 wF;
        wF.x = SCALE * Gs[b0 + 0] * Qc[b0 + 0][a] - aF[i][0];
        wF.y = SCALE * Gs[b0 + 1] * Qc[b0 + 1][a] - aF[i][1];
        wF.z = SCALE * Gs[b0 + 2] * Qc[b0 + 2][a] - aF[i][2];
        wF.w = SCALE * Gs[b0 + 3] * Qc[b0 + 3][a] - aF[i][3];
        float4 wE = {aE[i][0], aE[i][1], aE[i][2], aE[i][3]};
        *(float4*)&Bt[tile + a * 64 + b0] = wB;
        *(float4*)&Ct[tile + a * 64 + b0] = wC;
        *(float4*)&Ft[tile + a * 64 + b0] = wF;
        *(float4*)&vb[(size_t)(t0 + a) * EE + h * DD + b0] = wE;
    }
}

// ---------------------------------------------------------------------------
// Delta rule serial S-chain: per chunk, save S_c (pre-update, overwrites Bt
// tile) then S <- GC*S - B.S + C. Double-buffered global_load_lds prefetch.
// One block per head.
// ---------------------------------------------------------------------------
__global__ __launch_bounds__(256) void delta_scan3_kernel(
    float* __restrict__ BtS, const float* __restrict__ Ct,
    const float* __restrict__ g)
{
    __shared__ float Ss[64][64];
    __shared__ __align__(16) float Bsb[2][4096];
    __shared__ __align__(16) float Csb[2][4096];
    int h = blockIdx.x;
    int tid = threadIdx.x;
    int lane = tid & 63;
    int tx = tid & 15, ty = tid >> 4;
    int a0 = ty << 2, b0 = tx << 2;
    {
        int row = tid >> 4, c4 = (tid & 15) << 2;
        #pragma unroll
        for (int m = 0; m < 4; ++m)
            *(float4*)&Ss[row + m * 16][c4] = (float4){0.f, 0.f, 0.f, 0.f};
    }

#define STG3(buf, cc)                                                          \
    {                                                                          \
        size_t tb = ((size_t)((cc) * HH + h)) << 12;                           \
        _Pragma("unroll")                                                      \
        for (int u = 0; u < 4; ++u) {                                          \
            int fi = ((u << 8) + tid) << 2;          /* per-lane float idx */  \
            int fb = ((u << 8) + (tid & 192)) << 2;  /* wave-uniform base */   \
            __builtin_amdgcn_global_load_lds((gptr_t)&BtS[tb + fi],            \
                (lptr_t)&Bsb[buf][fb], 16, 0, 0);                              \
            __builtin_amdgcn_global_load_lds((gptr_t)&Ct[tb + fi],             \
                (lptr_t)&Csb[buf][fb], 16, 0, 0);                              \
        }                                                                      \
    }

    STG3(0, 0)
    for (int c = 0; c < NCH; ++c) {
        float gc = g[((c << 6) + lane) * HH + h];
        #pragma unroll
        for (int off = 32; off; off >>= 1) gc *= __shfl_xor(gc, off);
        __syncthreads();            // drains gload_lds(c); S writes visible
        if (c + 1 < NCH) STG3((c + 1) & 1, c + 1)
        const float* Bsp = Bsb[c & 1];
        const float* Csp = Csb[c & 1];
        // save pre-update S_c over the (consumed) Bt tile
        size_t tile = ((size_t)(c * HH + h)) << 12;
        #pragma unroll
        for (int i = 0; i < 4; ++i)
            *(float4*)&BtS[tile + (a0 + i) * 64 + b0] =
                *(const float4*)&Ss[a0 + i][b0];
        // P = B.S
        float accP[4][4] = {};
        #pragma unroll 4
        for (int k = 0; k < 64; ++k) {
            float4 bv = *(const float4*)&Bsp[k * 64 + a0];
            float4 sv = *(const float4*)&Ss[k][b0];
            float ba[4] = {bv.x, bv.y, bv.z, bv.w};
            float sa[4] = {sv.x, sv.y, sv.z, sv.w};
            #pragma unroll
            for (int i = 0; i < 4; ++i)
                #pragma unroll
                for (int j = 0; j < 4; ++j)
                    accP[i][j] = fmaf(ba[i], sa[j], accP[i][j]);
        }
        __syncthreads();            // all reads of Ss done
        #pragma unroll
        for (int i = 0; i < 4; ++i) {
            float4 sv = *(const float4*)&Ss[a0 + i][b0];
            float4 cv = *(const float4*)&Csp[(a0 + i) * 64 + b0];
            float4 ns;
            ns.x = fmaf(gc, sv.x, cv.x - accP[i][0]);
            ns.y = fmaf(gc, sv.y, cv.y - accP[i][1]);
            ns.z = fmaf(gc, sv.z, cv.z - accP[i][2]);
            ns.w = fmaf(gc, sv.w, cv.w - accP[i][3]);
            *(float4*)&Ss[a0 + i][b0] = ns;
        }
    }
#undef STG3
}

// ---------------------------------------------------------------------------
// Delta rule parallel output map: O_c = F_c.S_c + E_c (E in vb, O over vb).
// grid (NCH, HH).
// ---------------------------------------------------------------------------
__global__ __launch_bounds__(256) void delta_apply_kernel(
    const float* __restrict__ Sb, const float* __restrict__ Ft,
    float* __restrict__ vb)
{
    __shared__ float Fs[64][64], S2[64][64];
    int c = blockIdx.x, h = blockIdx.y;
    int tid = threadIdx.x;
    int tx = tid & 15, ty = tid >> 4;
    int a0 = ty << 2, b0 = tx << 2;
    size_t tile = ((size_t)(c * HH + h)) << 12;
    {
        int row = tid >> 4, c4 = (tid & 15) << 2;
        #pragma unroll
        for (int m = 0; m < 4; ++m) {
            int r = row + m * 16;
            *(float4*)&Fs[r][c4] = *(const float4*)&Ft[tile + r * 64 + c4];
            *(float4*)&S2[r][c4] = *(const float4*)&Sb[tile + r * 64 + c4];
        }
    }
    __syncthreads();
    float accO[4][4] = {};
    #pragma unroll 4
    for (int k = 0; k < 64; ++k) {
        float4 fv = *(const float4*)&Fs[k][a0];
        float4 sv = *(const float4*)&S2[k][b0];
        float fa[4] = {fv.x, fv.y, fv.z, fv.w};
        float sa[4] = {sv.x, sv.y, sv.z, sv.w};
        #pragma unroll
        for (int i = 0; i < 4; ++i)
            #pragma unroll
            for (int j = 0; j < 4; ++j)
                accO[i][j] = fmaf(fa[i], sa[j], accO[i][j]);
    }
    #pragma unroll
    for (int i = 0; i < 4; ++i) {
        size_t gi = (size_t)((c << 6) + a0 + i) * EE + h * DD + b0;
        float4 ev = *(const float4*)&vb[gi];
        float4 ov = {accO[i][0] + ev.x, accO[i][1] + ev.y,
                     accO[i][2] + ev.z, accO[i][3] + ev.w};
        *(float4*)&vb[gi] = ov;
    }
}

// ---------------------------------------------------------------------------
// Causal flash attention, bf16 MFMA; output written as bf16 for proj GEMM.
// ---------------------------------------------------------------------------
__global__ __launch_bounds__(256) void attn_mfma_kernel(
    const float* __restrict__ q, const float* __restrict__ k, const float* __restrict__ v,
    ushort* __restrict__ y)
{
    __shared__ __align__(16) unsigned short KsL[64 * KS];
    __shared__ __align__(16) unsigned short VtL[64 * KS];
    __shared__ __align__(16) unsigned short PsL[4][16 * KS];

    int h = blockIdx.y;
    int rb = ((int)gridDim.x - 1 - (int)blockIdx.x) * 64;
    int tid = threadIdx.x;
    int w = tid >> 6;
    int lane = tid & 63;
    int l16 = lane & 15;
    int lq = lane >> 4;
    int qr0 = rb + w * 16;

    bf16x8 qf[2];
    {
        const float* qrow = &q[(size_t)(qr0 + l16) * EE + h * DD];
        #pragma unroll
        for (int kk = 0; kk < 2; ++kk) {
            float4 v0 = *(const float4*)&qrow[kk * 32 + lq * 8];
            float4 v1 = *(const float4*)&qrow[kk * 32 + lq * 8 + 4];
            qf[kk][0] = (short)f2bf(v0.x); qf[kk][1] = (short)f2bf(v0.y);
            qf[kk][2] = (short)f2bf(v0.z); qf[kk][3] = (short)f2bf(v0.w);
            qf[kk][4] = (short)f2bf(v1.x); qf[kk][5] = (short)f2bf(v1.y);
            qf[kk][6] = (short)f2bf(v1.z); qf[kk][7] = (short)f2bf(v1.w);
        }
    }

    f32x4 oacc[4];
    #pragma unroll
    for (int dt = 0; dt < 4; ++dt) oacc[dt] = (f32x4){0.f, 0.f, 0.f, 0.f};
    float mrow[4] = {-3e38f, -3e38f, -3e38f, -3e38f};
    float lrow[4] = {0.f, 0.f, 0.f, 0.f};

    int ks_s = tid >> 2, ks_d0 = (tid & 3) << 4;
    int vt_s0 = (tid & 31) * 2, vt_dq = (tid >> 5) << 3;

    for (int c0 = 0; c0 <= rb; c0 += 64) {
        __syncthreads();
        {
            const float* krow = &k[(size_t)(c0 + ks_s) * EE + h * DD + ks_d0];
            #pragma unroll
            for (int u = 0; u < 4; ++u) {
                float4 kv4 = *(const float4*)&krow[u * 4];
                bf16x4 pk = { (short)f2bf(kv4.x), (short)f2bf(kv4.y),
                              (short)f2bf(kv4.z), (short)f2bf(kv4.w) };
                *(bf16x4*)&KsL[ks_s * KS + ks_d0 + u * 4] = pk;
            }
            const float* vr0 = &v[(size_t)(c0 + vt_s0) * EE + h * DD + vt_dq];
            const float* vr1 = vr0 + EE;
            float4 a0 = *(const float4*)&vr0[0], a1 = *(const float4*)&vr0[4];
            float4 b0 = *(const float4*)&vr1[0], b1 = *(const float4*)&vr1[4];
            float va[8] = {a0.x, a0.y, a0.z, a0.w, a1.x, a1.y, a1.z, a1.w};
            float vbv[8] = {b0.x, b0.y, b0.z, b0.w, b1.x, b1.y, b1.z, b1.w};
            #pragma unroll
            for (int u = 0; u < 8; ++u) {
                unsigned pv = (unsigned)f2bf(va[u]) | ((unsigned)f2bf(vbv[u]) << 16);
                *(unsigned*)&VtL[(vt_dq + u) * KS + vt_s0] = pv;
            }
        }
        __syncthreads();

        f32x4 sacc[4];
        #pragma unroll
        for (int ct = 0; ct < 4; ++ct) {
            bf16x8 b0 = *(bf16x8*)&KsL[(ct * 16 + l16) * KS + lq * 8];
            bf16x8 b1 = *(bf16x8*)&KsL[(ct * 16 + l16) * KS + 32 + lq * 8];
            f32x4 acc = {0.f, 0.f, 0.f, 0.f};
            acc = __builtin_amdgcn_mfma_f32_16x16x32_bf16(qf[0], b0, acc, 0, 0, 0);
            acc = __builtin_amdgcn_mfma_f32_16x16x32_bf16(qf[1], b1, acc, 0, 0, 0);
            sacc[ct] = acc;
        }

        float sv[4][4];
        float tmax[4] = {-3e38f, -3e38f, -3e38f, -3e38f};
        #pragma unroll
        for (int ct = 0; ct < 4; ++ct) {
            int col = c0 + ct * 16 + l16;
            #pragma unroll
            for (int r = 0; r < 4; ++r) {
                int row = qr0 + lq * 4 + r;
                float s = sacc[ct][r] * SCALE;
                if (col > row) s = -3e38f;
                sv[ct][r] = s;
                tmax[r] = fmaxf(tmax[r], s);
            }
        }
        #pragma unroll
        for (int off = 1; off < 16; off <<= 1) {
            #pragma unroll
            for (int r = 0; r < 4; ++r)
                tmax[r] = fmaxf(tmax[r], __shfl_xor(tmax[r], off));
        }
        float corr[4], psum[4];
        #pragma unroll
        for (int r = 0; r < 4; ++r) {
            float mn = fmaxf(mrow[r], tmax[r]);
            corr[r] = __expf(mrow[r] - mn);
            mrow[r] = mn;
            psum[r] = 0.f;
        }
        #pragma unroll
        for (int ct = 0; ct < 4; ++ct) {
            #pragma unroll
            for (int r = 0; r < 4; ++r) {
                float p = __expf(sv[ct][r] - mrow[r]);
                psum[r] += p;
                PsL[w][(lq * 4 + r) * KS + ct * 16 + l16] = f2bf(p);
            }
        }
        #pragma unroll
        for (int off = 1; off < 16; off <<= 1) {
            #pragma unroll
            for (int r = 0; r < 4; ++r)
                psum[r] += __shfl_xor(psum[r], off);
        }
        #pragma unroll
        for (int r = 0; r < 4; ++r)
            lrow[r] = lrow[r] * corr[r] + psum[r];
        #pragma unroll
        for (int dt = 0; dt < 4; ++dt) {
            #pragma unroll
            for (int r = 0; r < 4; ++r)
                oacc[dt][r] *= corr[r];
        }

        bf16x8 pa0 = *(bf16x8*)&PsL[w][l16 * KS + lq * 8];
        bf16x8 pa1 = *(bf16x8*)&PsL[w][l16 * KS + 32 + lq * 8];
        #pragma unroll
        for (int dt = 0; dt < 4; ++dt) {
            bf16x8 vb0 = *(bf16x8*)&VtL[(dt * 16 + l16) * KS + lq * 8];
            bf16x8 vb1 = *(bf16x8*)&VtL[(dt * 16 + l16) * KS + 32 + lq * 8];
            oacc[dt] = __builtin_amdgcn_mfma_f32_16x16x32_bf16(pa0, vb0, oacc[dt], 0, 0, 0);
            oacc[dt] = __builtin_amdgcn_mfma_f32_16x16x32_bf16(pa1, vb1, oacc[dt], 0, 0, 0);
        }
    }

    float linv[4];
    #pragma unroll
    for (int r = 0; r < 4; ++r) linv[r] = 1.f / lrow[r];
    #pragma unroll
    for (int dt = 0; dt < 4; ++dt) {
        #pragma unroll
        for (int r = 0; r < 4; ++r) {
            int row = qr0 + lq * 4 + r;
            y[(size_t)row * EE + h * DD + dt * 16 + l16] = f2bf(oacc[dt][r] * linv[r]);
        }
    }
}

// ---------------------------------------------------------------------------
extern "C" void kernel_launch(void* const* d_in, const int* in_sizes, int n_in,
                              void* d_out, int out_size, void* d_ws, size_t ws_size,
                              hipStream_t stream)
{
    (void)in_sizes; (void)n_in; (void)out_size; (void)ws_size;
    const float* x      = (const float*)d_in[0];
    const float* w_attn = (const float*)d_in[1];
    const float* w_proj = (const float*)d_in[2];
    const float* qcw    = (const float*)d_in[3];
    const float* kcw    = (const float*)d_in[4];
    const float* vcw    = (const float*)d_in[5];
    const float* cosb   = (const float*)d_in[6];
    const float* sinb   = (const float*)d_in[7];
    const float* beta   = (const float*)d_in[8];
    const float* g      = (const float*)d_in[9];
    float* out = (float*)d_out;
    float* ws  = (float*)d_ws;

    const size_t TE = (size_t)TT * EE;
    float* buf0 = ws + 0 * TE;          // qkv -> Bt -> S tiles
    float* buf1 = ws + 1 * TE;          // qkv -> Ct -> ybf
    float* buf2 = ws + 2 * TE;          // qkv -> Ft -> wpT
    float* qb   = ws + 3 * TE;          // xbf -> q
    float* kb   = ws + 4 * TE;          // waT -> k
    float* vb   = ws + 5 * TE;          // v -> E -> O
    float* qkv  = buf0;
    ushort* xbf = (ushort*)qb;
    ushort* waT = (ushort*)kb;
    ushort* ybf = (ushort*)buf1;
    ushort* wpT = (ushort*)buf2;

    cvt_bf16_kernel<<<TT * EE / 2048, 256, 0, stream>>>(x, xbf);
    cvt_transpose_kernel<<<dim3(NN / 64, EE / 64), 256, 0, stream>>>(w_attn, waT, EE, NN);
    gemm_bf16<128, 128><<<dim3(NN / 128, TT / 128), 256, 0, stream>>>(
        xbf, waT, qkv, TT, NN, EE);
    conv_rope_kernel<<<dim3(TT / 4, HH, 3), dim3(64, 4), 0, stream>>>(
        qkv, qcw, kcw, vcw, cosb, sinb, qb, kb, vb);
    chunk_prep_kernel<<<dim3(NCH, HH), 256, 0, stream>>>(qb, kb, vb, beta, g, buf0, buf1, buf2);
    delta_scan3_kernel<<<HH, 256, 0, stream>>>(buf0, buf1, g);
    delta_apply_kernel<<<dim3(NCH, HH), 256, 0, stream>>>(buf0, buf2, vb);
    cvt_transpose_kernel<<<dim3(EE / 64, EE / 64), 256, 0, stream>>>(w_proj, wpT, EE, EE);
    attn_mfma_kernel<<<dim3(TT / 64, HH), 256, 0, stream>>>(qb, kb, vb, ybf);
    gemm_bf16<64, 64><<<dim3(EE / 64, TT / 64), 256, 0, stream>>>(
        ybf, wpT, out, TT, EE, EE);
}

// Round 7
// 350.968 us; speedup vs baseline: 6.5925x; 1.1588x over previous
//
#include <hip/hip_runtime.h>
#include <math.h>

#define TT 2048
#define HH 16
#define DD 64
#define EE 1024
#define NN 3072
#define CHUNK 64
#define NCH (TT / CHUNK)
#define SCALE 0.125f
#define KS 72   // attn LDS row stride (bf16): conflict-free b128
#define CPH 8   // column-split blocks per head in delta scan

typedef short bf16x8 __attribute__((ext_vector_type(8)));
typedef short bf16x4 __attribute__((ext_vector_type(4)));
typedef float f32x4 __attribute__((ext_vector_type(4)));
typedef unsigned short ushort;
typedef const __attribute__((address_space(1))) unsigned int* gptr_t;
typedef __attribute__((address_space(3))) unsigned int* lptr_t;

__device__ __forceinline__ unsigned short f2bf(float x) {
    union { float f; unsigned u; } un; un.f = x;
    unsigned r = un.u + 0x7FFFu + ((un.u >> 16) & 1u);
    return (unsigned short)(r >> 16);
}

// ---------------------------------------------------------------------------
// fp32 -> bf16 elementwise convert (x)
// ---------------------------------------------------------------------------
__global__ __launch_bounds__(256) void cvt_bf16_kernel(
    const float* __restrict__ in, ushort* __restrict__ out)
{
    int i = ((int)blockIdx.x * 256 + (int)threadIdx.x) << 3;
    float4 a = *(const float4*)&in[i];
    float4 b = *(const float4*)&in[i + 4];
    bf16x8 o;
    o[0] = (short)f2bf(a.x); o[1] = (short)f2bf(a.y);
    o[2] = (short)f2bf(a.z); o[3] = (short)f2bf(a.w);
    o[4] = (short)f2bf(b.x); o[5] = (short)f2bf(b.y);
    o[6] = (short)f2bf(b.z); o[7] = (short)f2bf(b.w);
    *(bf16x8*)&out[i] = o;
}

// ---------------------------------------------------------------------------
// fp32 [K][N] -> bf16 [N][K] convert + transpose (weights)
// ---------------------------------------------------------------------------
__global__ __launch_bounds__(256) void cvt_transpose_kernel(
    const float* __restrict__ W, ushort* __restrict__ WT, int K, int N)
{
    __shared__ float Ls[64][65];
    int n0 = blockIdx.x * 64, k0 = blockIdx.y * 64;
    int tid = threadIdx.x;
    int lr = tid >> 4, lc4 = (tid & 15) << 2;
    #pragma unroll
    for (int m = 0; m < 4; ++m) {
        int r = lr + m * 16;
        float4 v = *(const float4*)&W[(size_t)(k0 + r) * N + n0 + lc4];
        Ls[r][lc4 + 0] = v.x; Ls[r][lc4 + 1] = v.y;
        Ls[r][lc4 + 2] = v.z; Ls[r][lc4 + 3] = v.w;
    }
    __syncthreads();
    int n = tid >> 2, kb = (tid & 3) << 4;
    bf16x8 o0, o1;
    #pragma unroll
    for (int j = 0; j < 8; ++j) o0[j] = (short)f2bf(Ls[kb + j][n]);
    #pragma unroll
    for (int j = 0; j < 8; ++j) o1[j] = (short)f2bf(Ls[kb + 8 + j][n]);
    *(bf16x8*)&WT[(size_t)(n0 + n) * K + k0 + kb] = o0;
    *(bf16x8*)&WT[(size_t)(n0 + n) * K + k0 + kb + 8] = o1;
}

// ---------------------------------------------------------------------------
// bf16 MFMA GEMM: C(fp32)[M][N] = A(bf16)[M][K] * BT(bf16)[N][K]^T
// ---------------------------------------------------------------------------
template<int BM, int BN>
__global__ __launch_bounds__(256) void gemm_bf16(
    const ushort* __restrict__ A, const ushort* __restrict__ BT,
    float* __restrict__ C, int M, int N, int K)
{
    constexpr int MT = BM / 32;
    constexpr int NT = BN / 32;
    constexpr int AIT = BM * 64 / 2048;
    constexpr int BIT = BN * 64 / 2048;
    __shared__ __align__(16) ushort Asl[2][BM * 64];
    __shared__ __align__(16) ushort Bsl[2][BN * 64];
    const int tid = threadIdx.x;
    const int lane = tid & 63, w = tid >> 6;
    const int wm = w >> 1, wn = w & 1;
    const int l16 = lane & 15, lq = lane >> 4;
    const int row0 = blockIdx.y * BM, col0 = blockIdx.x * BN;
    const int wvb = w << 9;

    f32x4 acc[MT][NT];
    #pragma unroll
    for (int i = 0; i < MT; ++i)
        #pragma unroll
        for (int j = 0; j < NT; ++j)
            acc[i][j] = (f32x4){0.f, 0.f, 0.f, 0.f};

#define STAGE_TILE(buf, k0)                                                    \
    {                                                                          \
        _Pragma("unroll")                                                      \
        for (int u = 0; u < AIT; ++u) {                                        \
            int idx = u * 256 + tid;                                           \
            int r = idx >> 3, s = idx & 7;                                     \
            const ushort* srcp =                                               \
                &A[(size_t)(row0 + r) * K + (k0) + ((s ^ (r & 7)) << 3)];      \
            __builtin_amdgcn_global_load_lds((gptr_t)srcp,                     \
                (lptr_t)&Asl[buf][(u << 11) + wvb], 16, 0, 0);                 \
        }                                                                      \
        _Pragma("unroll")                                                      \
        for (int u = 0; u < BIT; ++u) {                                        \
            int idx = u * 256 + tid;                                           \
            int r = idx >> 3, s = idx & 7;                                     \
            const ushort* srcp =                                               \
                &BT[(size_t)(col0 + r) * K + (k0) + ((s ^ (r & 7)) << 3)];     \
            __builtin_amdgcn_global_load_lds((gptr_t)srcp,                     \
                (lptr_t)&Bsl[buf][(u << 11) + wvb], 16, 0, 0);                 \
        }                                                                      \
    }

    const int nK = K >> 6;
    STAGE_TILE(0, 0)
    for (int kt = 0; kt < nK; ++kt) {
        __syncthreads();                       // stage(kt) drained + visible
        if (kt + 1 < nK) STAGE_TILE((kt + 1) & 1, (kt + 1) << 6)
        const int cb = kt & 1;
        #pragma unroll
        for (int kk = 0; kk < 2; ++kk) {
            bf16x8 afr[MT], bfr[NT];
            #pragma unroll
            for (int mt = 0; mt < MT; ++mt) {
                int rr = wm * (BM / 2) + mt * 16 + l16;
                afr[mt] = *(bf16x8*)&Asl[cb][rr * 64 +
                           (((kk * 4 + lq) ^ (rr & 7)) << 3)];
            }
            #pragma unroll
            for (int nt = 0; nt < NT; ++nt) {
                int cc = wn * (BN / 2) + nt * 16 + l16;
                bfr[nt] = *(bf16x8*)&Bsl[cb][cc * 64 +
                           (((kk * 4 + lq) ^ (cc & 7)) << 3)];
            }
            #pragma unroll
            for (int mt = 0; mt < MT; ++mt)
                #pragma unroll
                for (int nt = 0; nt < NT; ++nt)
                    acc[mt][nt] = __builtin_amdgcn_mfma_f32_16x16x32_bf16(
                        afr[mt], bfr[nt], acc[mt][nt], 0, 0, 0);
        }
    }
#undef STAGE_TILE

    #pragma unroll
    for (int mt = 0; mt < MT; ++mt) {
        #pragma unroll
        for (int nt = 0; nt < NT; ++nt) {
            int col = col0 + wn * (BN / 2) + nt * 16 + l16;
            #pragma unroll
            for (int r = 0; r < 4; ++r) {
                int row = row0 + wm * (BM / 2) + mt * 16 + lq * 4 + r;
                C[(size_t)row * N + col] = acc[mt][nt][r];
            }
        }
    }
}

// ---------------------------------------------------------------------------
// Causal depthwise conv1d (DC=4) + SiLU, then RoPE for q,k; v plain.
// ---------------------------------------------------------------------------
__global__ __launch_bounds__(256) void conv_rope_kernel(
    const float* __restrict__ qkv,
    const float* __restrict__ qw, const float* __restrict__ kw, const float* __restrict__ vw,
    const float* __restrict__ cosb, const float* __restrict__ sinb,
    float* __restrict__ qo, float* __restrict__ ko, float* __restrict__ vo)
{
    int j = blockIdx.z;
    const float* w = (j == 0) ? qw : (j == 1) ? kw : vw;
    float* dst     = (j == 0) ? qo : (j == 1) ? ko : vo;
    int d  = threadIdx.x;
    int tl = threadIdx.y;
    int t  = blockIdx.x * 4 + tl;
    int h  = blockIdx.y;
    int c  = h * DD + d;
    int n  = h * 192 + j * 64 + d;
    float acc = 0.f;
    #pragma unroll
    for (int i = 0; i < 4; ++i) {
        int tt = t - 3 + i;
        if (tt >= 0) acc = fmaf(qkv[(size_t)tt * NN + n], w[c * 4 + i], acc);
    }
    float yv = acc / (1.f + __expf(-acc));
    if (j == 2) { dst[t * EE + c] = yv; return; }
    __shared__ float sh[4][64];
    sh[tl][d] = yv;
    __syncthreads();
    int dh = d & 31;
    float cc = cosb[t * 32 + dh];
    float ss = sinb[t * 32 + dh];
    float outv;
    if (d < 32) outv = yv * cc - sh[tl][d + 32] * ss;
    else        outv = yv * cc + sh[tl][d - 32] * ss;
    dst[t * EE + c] = outv;
}

// ---------------------------------------------------------------------------
// Chunked gated delta rule, phase 1 (parallel over 32 chunks x 16 heads).
// ---------------------------------------------------------------------------
__global__ __launch_bounds__(256) void chunk_prep_kernel(
    const float* __restrict__ qb, const float* __restrict__ kb, float* __restrict__ vb,
    const float* __restrict__ beta, const float* __restrict__ g,
    float* __restrict__ Bt, float* __restrict__ Ct, float* __restrict__ Ft)
{
    __shared__ float Kc[64][68], Qc[64][68], Vc[64][68];
    __shared__ float Mm[64][68], At[64][68], Xv[64][68], Xk[64][68];
    __shared__ float Gs[64], bs[64];
    int c = blockIdx.x, h = blockIdx.y;
    int tid = threadIdx.x;
    int t0 = c * CHUNK;
    {
        int row = tid >> 4, c4 = (tid & 15) << 2;
        #pragma unroll
        for (int m = 0; m < 4; ++m) {
            int r = row + m * 16;
            size_t gidx = (size_t)(t0 + r) * EE + h * DD + c4;
            *(float4*)&Kc[r][c4] = *(const float4*)&kb[gidx];
            *(float4*)&Qc[r][c4] = *(const float4*)&qb[gidx];
            *(float4*)&Vc[r][c4] = *(const float4*)&vb[gidx];
        }
    }
    if (tid < 64) {
        float x = g[(t0 + tid) * HH + h];
        #pragma unroll
        for (int off = 1; off < 64; off <<= 1) {
            float y = __shfl_up(x, off);
            if (tid >= off) x *= y;
        }
        Gs[tid] = x;
        bs[tid] = beta[(t0 + tid) * HH + h];
    }
    __syncthreads();
    #pragma unroll 2
    for (int i = 0; i < 16; ++i) {
        int p = i * 256 + tid;
        int t = p >> 6, s = p & 63;
        float dkk = 0.f, dqk = 0.f;
        #pragma unroll
        for (int j4 = 0; j4 < 64; j4 += 4) {
            float4 ks = *(const float4*)&Kc[s][j4];
            float4 kt = *(const float4*)&Kc[t][j4];
            float4 qt = *(const float4*)&Qc[t][j4];
            dkk = fmaf(kt.x, ks.x, fmaf(kt.y, ks.y, fmaf(kt.z, ks.z, fmaf(kt.w, ks.w, dkk))));
            dqk = fmaf(qt.x, ks.x, fmaf(qt.y, ks.y, fmaf(qt.z, ks.z, fmaf(qt.w, ks.w, dqk))));
        }
        float gr = Gs[t] / Gs[s];
        if (s < t) Mm[t][s] = bs[t] * gr * dkk;
        At[s][t] = (s <= t) ? SCALE * gr * dqk : 0.f;
    }
    __syncthreads();
    if (tid < 128) {
        int col = tid & 63;
        int hv = tid >> 6;
        float* Xp = hv ? &Xk[0][0] : &Xv[0][0];
        #pragma unroll 1
        for (int t = 0; t < 64; ++t) {
            float acc = hv ? (bs[t] * Gs[t] * Kc[t][col]) : (bs[t] * Vc[t][col]);
            for (int s = 0; s < t; ++s)
                acc = fmaf(-Mm[t][s], Xp[s * 68 + col], acc);
            Xp[t * 68 + col] = acc;
        }
    }
    __syncthreads();
    {
        int r = tid & 63, qd = tid >> 6;
        float ratio = Gs[63] / Gs[r];
        #pragma unroll
        for (int jj = 0; jj < 4; ++jj) {
            float4 vv = *(const float4*)&Kc[r][qd * 16 + jj * 4];
            vv.x *= ratio; vv.y *= ratio; vv.z *= ratio; vv.w *= ratio;
            *(float4*)&Kc[r][qd * 16 + jj * 4] = vv;
        }
    }
    __syncthreads();
    int tx = tid & 15, ty = tid >> 4;
    int a0 = ty << 2, b0 = tx << 2;
    float aB[4][4] = {}, aC[4][4] = {}, aF[4][4] = {}, aE[4][4] = {};
    #pragma unroll 2
    for (int s = 0; s < 64; ++s) {
        float4 xkA4 = *(const float4*)&Xk[s][a0];
        float4 kcB4 = *(const float4*)&Kc[s][b0];
        float4 kcA4 = *(const float4*)&Kc[s][a0];
        float4 xvB4 = *(const float4*)&Xv[s][b0];
        float4 atA4 = *(const float4*)&At[s][a0];
        float4 atB4 = *(const float4*)&At[s][b0];
        float xkA[4] = {xkA4.x, xkA4.y, xkA4.z, xkA4.w};
        float kcB[4] = {kcB4.x, kcB4.y, kcB4.z, kcB4.w};
        float kcA[4] = {kcA4.x, kcA4.y, kcA4.z, kcA4.w};
        float xvB[4] = {xvB4.x, xvB4.y, xvB4.z, xvB4.w};
        float atA[4] = {atA4.x, atA4.y, atA4.z, atA4.w};
        float atB[4] = {atB4.x, atB4.y, atB4.z, atB4.w};
        #pragma unroll
        for (int i = 0; i < 4; ++i)
            #pragma unroll
            for (int j = 0; j < 4; ++j) {
                aB[i][j] = fmaf(xkA[i], kcB[j], aB[i][j]);
                aC[i][j] = fmaf(kcA[i], xvB[j], aC[i][j]);
                aF[i][j] = fmaf(xkA[i], atB[j], aF[i][j]);
                aE[i][j] = fmaf(atA[i], xvB[j], aE[i][j]);
            }
    }
    size_t tile = ((size_t)(c * HH + h)) << 12;
    #pragma unroll
    for (int i = 0; i < 4; ++i) {
        int a = a0 + i;
        float4 wB = {aB[i][0], aB[i][1], aB[i][2], aB[i][3]};
        float4 wC = {aC[i][0], aC[i][1], aC[i][2], aC[i][3]};
        float4 wF;
        wF.x = SCALE * Gs[b0 + 0] * Qc[b0 + 0][a] - aF[i][0];
        wF.y = SCALE * Gs[b0 + 1] * Qc[b0 + 1][a] - aF[i][1];
        wF.z = SCALE * Gs[b0 + 2] * Qc[b0 + 2][a] - aF[i][2];
        wF.w = SCALE * Gs[b0 + 3] * Qc[b0 + 3][a] - aF[i][3];
        float4 wE = {aE[i][0], aE[i][1], aE[i][2], aE[i][3]};
        *(float4*)&Bt[tile + a * 64 + b0] = wB;
        *(float4*)&Ct[tile + a * 64 + b0] = wC;
        *(float4*)&Ft[tile + a * 64 + b0] = wF;
        *(float4*)&vb[(size_t)(t0 + a) * EE + h * DD + b0] = wE;
    }
}

// ---------------------------------------------------------------------------
// Delta rule serial S-chain, column-split: grid (CPH, HH); block (p,h) owns
// state columns [p*8, p*8+8). Per chunk: save S_c slice (column-major, into
// Sout), P = B^T-tile . S_cols, S <- gc*S - P + C_cols.
// Per-chunk gate products precomputed in prologue (no serial g loads).
// ---------------------------------------------------------------------------
__global__ __launch_bounds__(256) void delta_scan4_kernel(
    const float* __restrict__ Bt, const float* __restrict__ Ct,
    const float* __restrict__ g, float* __restrict__ Sout)
{
    __shared__ __align__(16) float Bsb[2][4096];
    __shared__ __align__(16) float Csb[2][512];
    __shared__ float Ss[64][10];
    __shared__ float GCs[NCH];
    int p = blockIdx.x, h = blockIdx.y;
    int bo = p * 8;
    int tid = threadIdx.x;
    int a = tid & 63;
    int w = tid >> 6;
    int j0 = w * 2;

    // prologue: per-chunk gate products (8 t's per thread, tree over 8 threads)
    {
        float pr = 1.f;
        int t0 = tid * 8;
        #pragma unroll
        for (int j = 0; j < 8; ++j) pr *= g[(t0 + j) * HH + h];
        pr *= __shfl_xor(pr, 1);
        pr *= __shfl_xor(pr, 2);
        pr *= __shfl_xor(pr, 4);
        GCs[tid >> 3] = pr;
        Ss[a][j0] = 0.f;
        Ss[a][j0 + 1] = 0.f;
    }

#define STG4(buf, cc)                                                          \
    {                                                                          \
        size_t tb = ((size_t)((cc) * HH + h)) << 12;                           \
        _Pragma("unroll")                                                      \
        for (int u = 0; u < 4; ++u) {                                          \
            int fi = ((u << 8) + tid) << 2;                                    \
            int fb = ((u << 8) + (tid & 192)) << 2;                            \
            __builtin_amdgcn_global_load_lds((gptr_t)&Bt[tb + fi],             \
                (lptr_t)&Bsb[buf][fb], 16, 0, 0);                              \
        }                                                                      \
        if (tid < 128) {                                                       \
            size_t cfi = tb + ((size_t)(tid >> 1) << 6) + bo + ((tid & 1) << 2); \
            __builtin_amdgcn_global_load_lds((gptr_t)&Ct[cfi],                 \
                (lptr_t)&Csb[buf][(tid & 64) << 2], 16, 0, 0);                 \
        }                                                                      \
    }

    STG4(0, 0)
    for (int c = 0; c < NCH; ++c) {
        __syncthreads();            // stage(c) drained + S/GCs writes visible
        if (c + 1 < NCH) STG4((c + 1) & 1, c + 1)
        const float* Bsp = Bsb[c & 1];
        const float* Csp = Csb[c & 1];
        float gc = GCs[c];
        // save pre-update S_c (column-major compact: [b][a], coalesced)
        size_t tile = ((size_t)(c * HH + h)) << 12;
        float s0 = Ss[a][j0], s1 = Ss[a][j0 + 1];
        Sout[tile + (size_t)(bo + j0) * 64 + a] = s0;
        Sout[tile + (size_t)(bo + j0 + 1) * 64 + a] = s1;
        // P[a][j] = sum_k B[k][a] * S[k][j]  (B-read conflict-free, S broadcast)
        float p0 = 0.f, p1 = 0.f;
        #pragma unroll 4
        for (int k = 0; k < 64; ++k) {
            float bk = Bsp[k * 64 + a];
            float2 sv = *(const float2*)&Ss[k][j0];
            p0 = fmaf(bk, sv.x, p0);
            p1 = fmaf(bk, sv.y, p1);
        }
        __syncthreads();            // all reads of Ss done before update
        float c0v = Csp[a * 8 + j0], c1v = Csp[a * 8 + j0 + 1];
        Ss[a][j0]     = fmaf(gc, s0, c0v - p0);
        Ss[a][j0 + 1] = fmaf(gc, s1, c1v - p1);
    }
#undef STG4
}

// ---------------------------------------------------------------------------
// Delta rule parallel output map: O_c = F_c.S_c + E_c (E in vb, O over vb).
// S_c read from column-major Sout via padded LDS transpose. grid (NCH, HH).
// ---------------------------------------------------------------------------
__global__ __launch_bounds__(256) void delta_apply_kernel(
    const float* __restrict__ Sb, const float* __restrict__ Ft,
    float* __restrict__ vb)
{
    __shared__ float Fs[64][64];
    __shared__ float S2[64][68];
    int c = blockIdx.x, h = blockIdx.y;
    int tid = threadIdx.x;
    int tx = tid & 15, ty = tid >> 4;
    int a0 = ty << 2, b0 = tx << 2;
    size_t tile = ((size_t)(c * HH + h)) << 12;
    {
        int row = tid >> 4, c4 = (tid & 15) << 2;
        #pragma unroll
        for (int m = 0; m < 4; ++m) {
            int r = row + m * 16;
            *(float4*)&Fs[r][c4] = *(const float4*)&Ft[tile + r * 64 + c4];
            float4 sv = *(const float4*)&Sb[tile + r * 64 + c4]; // [b=r][k=c4..]
            S2[c4 + 0][r] = sv.x;
            S2[c4 + 1][r] = sv.y;
            S2[c4 + 2][r] = sv.z;
            S2[c4 + 3][r] = sv.w;
        }
    }
    __syncthreads();
    float accO[4][4] = {};
    #pragma unroll 4
    for (int k = 0; k < 64; ++k) {
        float4 fv = *(const float4*)&Fs[k][a0];
        float4 sv = *(const float4*)&S2[k][b0];
        float fa[4] = {fv.x, fv.y, fv.z, fv.w};
        float sa[4] = {sv.x, sv.y, sv.z, sv.w};
        #pragma unroll
        for (int i = 0; i < 4; ++i)
            #pragma unroll
            for (int j = 0; j < 4; ++j)
                accO[i][j] = fmaf(fa[i], sa[j], accO[i][j]);
    }
    #pragma unroll
    for (int i = 0; i < 4; ++i) {
        size_t gi = (size_t)((c << 6) + a0 + i) * EE + h * DD + b0;
        float4 ev = *(const float4*)&vb[gi];
        float4 ov = {accO[i][0] + ev.x, accO[i][1] + ev.y,
                     accO[i][2] + ev.z, accO[i][3] + ev.w};
        *(float4*)&vb[gi] = ov;
    }
}

// ---------------------------------------------------------------------------
// Causal flash attention, bf16 MFMA; output written as bf16 for proj GEMM.
// ---------------------------------------------------------------------------
__global__ __launch_bounds__(256) void attn_mfma_kernel(
    const float* __restrict__ q, const float* __restrict__ k, const float* __restrict__ v,
    ushort* __restrict__ y)
{
    __shared__ __align__(16) unsigned short KsL[64 * KS];
    __shared__ __align__(16) unsigned short VtL[64 * KS];
    __shared__ __align__(16) unsigned short PsL[4][16 * KS];

    int h = blockIdx.y;
    int rb = ((int)gridDim.x - 1 - (int)blockIdx.x) * 64;
    int tid = threadIdx.x;
    int w = tid >> 6;
    int lane = tid & 63;
    int l16 = lane & 15;
    int lq = lane >> 4;
    int qr0 = rb + w * 16;

    bf16x8 qf[2];
    {
        const float* qrow = &q[(size_t)(qr0 + l16) * EE + h * DD];
        #pragma unroll
        for (int kk = 0; kk < 2; ++kk) {
            float4 v0 = *(const float4*)&qrow[kk * 32 + lq * 8];
            float4 v1 = *(const float4*)&qrow[kk * 32 + lq * 8 + 4];
            qf[kk][0] = (short)f2bf(v0.x); qf[kk][1] = (short)f2bf(v0.y);
            qf[kk][2] = (short)f2bf(v0.z); qf[kk][3] = (short)f2bf(v0.w);
            qf[kk][4] = (short)f2bf(v1.x); qf[kk][5] = (short)f2bf(v1.y);
            qf[kk][6] = (short)f2bf(v1.z); qf[kk][7] = (short)f2bf(v1.w);
        }
    }

    f32x4 oacc[4];
    #pragma unroll
    for (int dt = 0; dt < 4; ++dt) oacc[dt] = (f32x4){0.f, 0.f, 0.f, 0.f};
    float mrow[4] = {-3e38f, -3e38f, -3e38f, -3e38f};
    float lrow[4] = {0.f, 0.f, 0.f, 0.f};

    int ks_s = tid >> 2, ks_d0 = (tid & 3) << 4;
    int vt_s0 = (tid & 31) * 2, vt_dq = (tid >> 5) << 3;

    for (int c0 = 0; c0 <= rb; c0 += 64) {
        __syncthreads();
        {
            const float* krow = &k[(size_t)(c0 + ks_s) * EE + h * DD + ks_d0];
            #pragma unroll
            for (int u = 0; u < 4; ++u) {
                float4 kv4 = *(const float4*)&krow[u * 4];
                bf16x4 pk = { (short)f2bf(kv4.x), (short)f2bf(kv4.y),
                              (short)f2bf(kv4.z), (short)f2bf(kv4.w) };
                *(bf16x4*)&KsL[ks_s * KS + ks_d0 + u * 4] = pk;
            }
            const float* vr0 = &v[(size_t)(c0 + vt_s0) * EE + h * DD + vt_dq];
            const float* vr1 = vr0 + EE;
            float4 a0 = *(const float4*)&vr0[0], a1 = *(const float4*)&vr0[4];
            float4 b0 = *(const float4*)&vr1[0], b1 = *(const float4*)&vr1[4];
            float va[8] = {a0.x, a0.y, a0.z, a0.w, a1.x, a1.y, a1.z, a1.w};
            float vbv[8] = {b0.x, b0.y, b0.z, b0.w, b1.x, b1.y, b1.z, b1.w};
            #pragma unroll
            for (int u = 0; u < 8; ++u) {
                unsigned pv = (unsigned)f2bf(va[u]) | ((unsigned)f2bf(vbv[u]) << 16);
                *(unsigned*)&VtL[(vt_dq + u) * KS + vt_s0] = pv;
            }
        }
        __syncthreads();

        f32x4 sacc[4];
        #pragma unroll
        for (int ct = 0; ct < 4; ++ct) {
            bf16x8 b0 = *(bf16x8*)&KsL[(ct * 16 + l16) * KS + lq * 8];
            bf16x8 b1 = *(bf16x8*)&KsL[(ct * 16 + l16) * KS + 32 + lq * 8];
            f32x4 acc = {0.f, 0.f, 0.f, 0.f};
            acc = __builtin_amdgcn_mfma_f32_16x16x32_bf16(qf[0], b0, acc, 0, 0, 0);
            acc = __builtin_amdgcn_mfma_f32_16x16x32_bf16(qf[1], b1, acc, 0, 0, 0);
            sacc[ct] = acc;
        }

        float sv[4][4];
        float tmax[4] = {-3e38f, -3e38f, -3e38f, -3e38f};
        #pragma unroll
        for (int ct = 0; ct < 4; ++ct) {
            int col = c0 + ct * 16 + l16;
            #pragma unroll
            for (int r = 0; r < 4; ++r) {
                int row = qr0 + lq * 4 + r;
                float s = sacc[ct][r] * SCALE;
                if (col > row) s = -3e38f;
                sv[ct][r] = s;
                tmax[r] = fmaxf(tmax[r], s);
            }
        }
        #pragma unroll
        for (int off = 1; off < 16; off <<= 1) {
            #pragma unroll
            for (int r = 0; r < 4; ++r)
                tmax[r] = fmaxf(tmax[r], __shfl_xor(tmax[r], off));
        }
        float corr[4], psum[4];
        #pragma unroll
        for (int r = 0; r < 4; ++r) {
            float mn = fmaxf(mrow[r], tmax[r]);
            corr[r] = __expf(mrow[r] - mn);
            mrow[r] = mn;
            psum[r] = 0.f;
        }
        #pragma unroll
        for (int ct = 0; ct < 4; ++ct) {
            #pragma unroll
            for (int r = 0; r < 4; ++r) {
                float p = __expf(sv[ct][r] - mrow[r]);
                psum[r] += p;
                PsL[w][(lq * 4 + r) * KS + ct * 16 + l16] = f2bf(p);
            }
        }
        #pragma unroll
        for (int off = 1; off < 16; off <<= 1) {
            #pragma unroll
            for (int r = 0; r < 4; ++r)
                psum[r] += __shfl_xor(psum[r], off);
        }
        #pragma unroll
        for (int r = 0; r < 4; ++r)
            lrow[r] = lrow[r] * corr[r] + psum[r];
        #pragma unroll
        for (int dt = 0; dt < 4; ++dt) {
            #pragma unroll
            for (int r = 0; r < 4; ++r)
                oacc[dt][r] *= corr[r];
        }

        bf16x8 pa0 = *(bf16x8*)&PsL[w][l16 * KS + lq * 8];
        bf16x8 pa1 = *(bf16x8*)&PsL[w][l16 * KS + 32 + lq * 8];
        #pragma unroll
        for (int dt = 0; dt < 4; ++dt) {
            bf16x8 vb0 = *(bf16x8*)&VtL[(dt * 16 + l16) * KS + lq * 8];
            bf16x8 vb1 = *(bf16x8*)&VtL[(dt * 16 + l16) * KS + 32 + lq * 8];
            oacc[dt] = __builtin_amdgcn_mfma_f32_16x16x32_bf16(pa0, vb0, oacc[dt], 0, 0, 0);
            oacc[dt] = __builtin_amdgcn_mfma_f32_16x16x32_bf16(pa1, vb1, oacc[dt], 0, 0, 0);
        }
    }

    float linv[4];
    #pragma unroll
    for (int r = 0; r < 4; ++r) linv[r] = 1.f / lrow[r];
    #pragma unroll
    for (int dt = 0; dt < 4; ++dt) {
        #pragma unroll
        for (int r = 0; r < 4; ++r) {
            int row = qr0 + lq * 4 + r;
            y[(size_t)row * EE + h * DD + dt * 16 + l16] = f2bf(oacc[dt][r] * linv[r]);
        }
    }
}

// ---------------------------------------------------------------------------
extern "C" void kernel_launch(void* const* d_in, const int* in_sizes, int n_in,
                              void* d_out, int out_size, void* d_ws, size_t ws_size,
                              hipStream_t stream)
{
    (void)in_sizes; (void)n_in; (void)out_size; (void)ws_size;
    const float* x      = (const float*)d_in[0];
    const float* w_attn = (const float*)d_in[1];
    const float* w_proj = (const float*)d_in[2];
    const float* qcw    = (const float*)d_in[3];
    const float* kcw    = (const float*)d_in[4];
    const float* vcw    = (const float*)d_in[5];
    const float* cosb   = (const float*)d_in[6];
    const float* sinb   = (const float*)d_in[7];
    const float* beta   = (const float*)d_in[8];
    const float* g      = (const float*)d_in[9];
    float* out = (float*)d_out;
    float* ws  = (float*)d_ws;

    const size_t TE = (size_t)TT * EE;
    float* buf0 = ws + 0 * TE;          // qkv -> Bt
    float* buf1 = ws + 1 * TE;          // qkv -> Ct -> ybf
    float* buf2 = ws + 2 * TE;          // qkv -> Ft -> wpT
    float* qb   = ws + 3 * TE;          // xbf -> q
    float* kb   = ws + 4 * TE;          // waT -> k
    float* vb   = ws + 5 * TE;          // v -> E -> O
    float* qkv  = buf0;
    ushort* xbf = (ushort*)qb;
    ushort* waT = (ushort*)kb;
    ushort* ybf = (ushort*)buf1;
    ushort* wpT = (ushort*)buf2;
    float* Sbuf = out;                  // d_out as S-tile scratch (overwritten
                                        // by final GEMM after apply consumes it)

    cvt_bf16_kernel<<<TT * EE / 2048, 256, 0, stream>>>(x, xbf);
    cvt_transpose_kernel<<<dim3(NN / 64, EE / 64), 256, 0, stream>>>(w_attn, waT, EE, NN);
    gemm_bf16<128, 128><<<dim3(NN / 128, TT / 128), 256, 0, stream>>>(
        xbf, waT, qkv, TT, NN, EE);
    conv_rope_kernel<<<dim3(TT / 4, HH, 3), dim3(64, 4), 0, stream>>>(
        qkv, qcw, kcw, vcw, cosb, sinb, qb, kb, vb);
    chunk_prep_kernel<<<dim3(NCH, HH), 256, 0, stream>>>(qb, kb, vb, beta, g, buf0, buf1, buf2);
    delta_scan4_kernel<<<dim3(CPH, HH), 256, 0, stream>>>(buf0, buf1, g, Sbuf);
    delta_apply_kernel<<<dim3(NCH, HH), 256, 0, stream>>>(Sbuf, buf2, vb);
    cvt_transpose_kernel<<<dim3(EE / 64, EE / 64), 256, 0, stream>>>(w_proj, wpT, EE, EE);
    attn_mfma_kernel<<<dim3(TT / 64, HH), 256, 0, stream>>>(qb, kb, vb, ybf);
    gemm_bf16<64, 64><<<dim3(EE / 64, TT / 64), 256, 0, stream>>>(
        ybf, wpT, out, TT, EE, EE);
}

// Round 8
// 313.904 us; speedup vs baseline: 7.3709x; 1.1181x over previous
//
#include <hip/hip_runtime.h>
#include <math.h>

#define TT 2048
#define HH 16
#define DD 64
#define EE 1024
#define NN 3072
#define CHUNK 64
#define NCH (TT / CHUNK)
#define SCALE 0.125f
#define KS 72   // attn LDS row stride (bf16): conflict-free b128
#define CPH 8   // column-split blocks per head in delta scan

typedef short bf16x8 __attribute__((ext_vector_type(8)));
typedef short bf16x4 __attribute__((ext_vector_type(4)));
typedef float f32x4 __attribute__((ext_vector_type(4)));
typedef unsigned short ushort;
typedef const __attribute__((address_space(1))) unsigned int* gptr_t;
typedef __attribute__((address_space(3))) unsigned int* lptr_t;

__device__ __forceinline__ unsigned short f2bf(float x) {
    union { float f; unsigned u; } un; un.f = x;
    unsigned r = un.u + 0x7FFFu + ((un.u >> 16) & 1u);
    return (unsigned short)(r >> 16);
}

// XOR slot swizzle for 64-float rows (4-float slots, key = row bits 2..4)
__device__ __forceinline__ int swz(int r, int c) {
    return (r << 6) + ((((c >> 2) ^ ((r >> 2) & 7)) << 2) | (c & 3));
}
__device__ __forceinline__ int swz4(int r, int c4) {
    return (r << 6) + (((c4 >> 2) ^ ((r >> 2) & 7)) << 2);
}

// ---------------------------------------------------------------------------
// fp32 -> bf16 elementwise convert (x)
// ---------------------------------------------------------------------------
__global__ __launch_bounds__(256) void cvt_bf16_kernel(
    const float* __restrict__ in, ushort* __restrict__ out)
{
    int i = ((int)blockIdx.x * 256 + (int)threadIdx.x) << 3;
    float4 a = *(const float4*)&in[i];
    float4 b = *(const float4*)&in[i + 4];
    bf16x8 o;
    o[0] = (short)f2bf(a.x); o[1] = (short)f2bf(a.y);
    o[2] = (short)f2bf(a.z); o[3] = (short)f2bf(a.w);
    o[4] = (short)f2bf(b.x); o[5] = (short)f2bf(b.y);
    o[6] = (short)f2bf(b.z); o[7] = (short)f2bf(b.w);
    *(bf16x8*)&out[i] = o;
}

// ---------------------------------------------------------------------------
// fp32 [K][N] -> bf16 [N][K] convert + transpose (weights)
// ---------------------------------------------------------------------------
__global__ __launch_bounds__(256) void cvt_transpose_kernel(
    const float* __restrict__ W, ushort* __restrict__ WT, int K, int N)
{
    __shared__ float Ls[64][65];
    int n0 = blockIdx.x * 64, k0 = blockIdx.y * 64;
    int tid = threadIdx.x;
    int lr = tid >> 4, lc4 = (tid & 15) << 2;
    #pragma unroll
    for (int m = 0; m < 4; ++m) {
        int r = lr + m * 16;
        float4 v = *(const float4*)&W[(size_t)(k0 + r) * N + n0 + lc4];
        Ls[r][lc4 + 0] = v.x; Ls[r][lc4 + 1] = v.y;
        Ls[r][lc4 + 2] = v.z; Ls[r][lc4 + 3] = v.w;
    }
    __syncthreads();
    int n = tid >> 2, kb = (tid & 3) << 4;
    bf16x8 o0, o1;
    #pragma unroll
    for (int j = 0; j < 8; ++j) o0[j] = (short)f2bf(Ls[kb + j][n]);
    #pragma unroll
    for (int j = 0; j < 8; ++j) o1[j] = (short)f2bf(Ls[kb + 8 + j][n]);
    *(bf16x8*)&WT[(size_t)(n0 + n) * K + k0 + kb] = o0;
    *(bf16x8*)&WT[(size_t)(n0 + n) * K + k0 + kb + 8] = o1;
}

// ---------------------------------------------------------------------------
// bf16 MFMA GEMM: C(fp32)[M][N] = A(bf16)[M][K] * BT(bf16)[N][K]^T
// ---------------------------------------------------------------------------
template<int BM, int BN>
__global__ __launch_bounds__(256) void gemm_bf16(
    const ushort* __restrict__ A, const ushort* __restrict__ BT,
    float* __restrict__ C, int M, int N, int K)
{
    constexpr int MT = BM / 32;
    constexpr int NT = BN / 32;
    constexpr int AIT = BM * 64 / 2048;
    constexpr int BIT = BN * 64 / 2048;
    __shared__ __align__(16) ushort Asl[2][BM * 64];
    __shared__ __align__(16) ushort Bsl[2][BN * 64];
    const int tid = threadIdx.x;
    const int lane = tid & 63, w = tid >> 6;
    const int wm = w >> 1, wn = w & 1;
    const int l16 = lane & 15, lq = lane >> 4;
    const int row0 = blockIdx.y * BM, col0 = blockIdx.x * BN;
    const int wvb = w << 9;

    f32x4 acc[MT][NT];
    #pragma unroll
    for (int i = 0; i < MT; ++i)
        #pragma unroll
        for (int j = 0; j < NT; ++j)
            acc[i][j] = (f32x4){0.f, 0.f, 0.f, 0.f};

#define STAGE_TILE(buf, k0)                                                    \
    {                                                                          \
        _Pragma("unroll")                                                      \
        for (int u = 0; u < AIT; ++u) {                                        \
            int idx = u * 256 + tid;                                           \
            int r = idx >> 3, s = idx & 7;                                     \
            const ushort* srcp =                                               \
                &A[(size_t)(row0 + r) * K + (k0) + ((s ^ (r & 7)) << 3)];      \
            __builtin_amdgcn_global_load_lds((gptr_t)srcp,                     \
                (lptr_t)&Asl[buf][(u << 11) + wvb], 16, 0, 0);                 \
        }                                                                      \
        _Pragma("unroll")                                                      \
        for (int u = 0; u < BIT; ++u) {                                        \
            int idx = u * 256 + tid;                                           \
            int r = idx >> 3, s = idx & 7;                                     \
            const ushort* srcp =                                               \
                &BT[(size_t)(col0 + r) * K + (k0) + ((s ^ (r & 7)) << 3)];     \
            __builtin_amdgcn_global_load_lds((gptr_t)srcp,                     \
                (lptr_t)&Bsl[buf][(u << 11) + wvb], 16, 0, 0);                 \
        }                                                                      \
    }

    const int nK = K >> 6;
    STAGE_TILE(0, 0)
    for (int kt = 0; kt < nK; ++kt) {
        __syncthreads();                       // stage(kt) drained + visible
        if (kt + 1 < nK) STAGE_TILE((kt + 1) & 1, (kt + 1) << 6)
        const int cb = kt & 1;
        #pragma unroll
        for (int kk = 0; kk < 2; ++kk) {
            bf16x8 afr[MT], bfr[NT];
            #pragma unroll
            for (int mt = 0; mt < MT; ++mt) {
                int rr = wm * (BM / 2) + mt * 16 + l16;
                afr[mt] = *(bf16x8*)&Asl[cb][rr * 64 +
                           (((kk * 4 + lq) ^ (rr & 7)) << 3)];
            }
            #pragma unroll
            for (int nt = 0; nt < NT; ++nt) {
                int cc = wn * (BN / 2) + nt * 16 + l16;
                bfr[nt] = *(bf16x8*)&Bsl[cb][cc * 64 +
                           (((kk * 4 + lq) ^ (cc & 7)) << 3)];
            }
            #pragma unroll
            for (int mt = 0; mt < MT; ++mt)
                #pragma unroll
                for (int nt = 0; nt < NT; ++nt)
                    acc[mt][nt] = __builtin_amdgcn_mfma_f32_16x16x32_bf16(
                        afr[mt], bfr[nt], acc[mt][nt], 0, 0, 0);
        }
    }
#undef STAGE_TILE

    #pragma unroll
    for (int mt = 0; mt < MT; ++mt) {
        #pragma unroll
        for (int nt = 0; nt < NT; ++nt) {
            int col = col0 + wn * (BN / 2) + nt * 16 + l16;
            #pragma unroll
            for (int r = 0; r < 4; ++r) {
                int row = row0 + wm * (BM / 2) + mt * 16 + lq * 4 + r;
                C[(size_t)row * N + col] = acc[mt][nt][r];
            }
        }
    }
}

// ---------------------------------------------------------------------------
// Causal depthwise conv1d (DC=4) + SiLU, then RoPE for q,k; v plain.
// ---------------------------------------------------------------------------
__global__ __launch_bounds__(256) void conv_rope_kernel(
    const float* __restrict__ qkv,
    const float* __restrict__ qw, const float* __restrict__ kw, const float* __restrict__ vw,
    const float* __restrict__ cosb, const float* __restrict__ sinb,
    float* __restrict__ qo, float* __restrict__ ko, float* __restrict__ vo)
{
    int j = blockIdx.z;
    const float* w = (j == 0) ? qw : (j == 1) ? kw : vw;
    float* dst     = (j == 0) ? qo : (j == 1) ? ko : vo;
    int d  = threadIdx.x;
    int tl = threadIdx.y;
    int t  = blockIdx.x * 4 + tl;
    int h  = blockIdx.y;
    int c  = h * DD + d;
    int n  = h * 192 + j * 64 + d;
    float acc = 0.f;
    #pragma unroll
    for (int i = 0; i < 4; ++i) {
        int tt = t - 3 + i;
        if (tt >= 0) acc = fmaf(qkv[(size_t)tt * NN + n], w[c * 4 + i], acc);
    }
    float yv = acc / (1.f + __expf(-acc));
    if (j == 2) { dst[t * EE + c] = yv; return; }
    __shared__ float sh[4][64];
    sh[tl][d] = yv;
    __syncthreads();
    int dh = d & 31;
    float cc = cosb[t * 32 + dh];
    float ss = sinb[t * 32 + dh];
    float outv;
    if (d < 32) outv = yv * cc - sh[tl][d + 32] * ss;
    else        outv = yv * cc + sh[tl][d - 32] * ss;
    dst[t * EE + c] = outv;
}

// ---------------------------------------------------------------------------
// Chunked gated delta rule, phase 1 (parallel over 32 chunks x 16 heads). v2:
// 64.5KB LDS (2 blocks/CU): Tm packs M (strict lower) + A~ (upper incl diag);
// Xk overwrites Qx after phase B; Xv overwrites Vx in place (column-owned
// substitution); XOR slot swizzle kills bank conflicts. FMA order identical
// to v1 -> bit-identical output.
// ---------------------------------------------------------------------------
__global__ __launch_bounds__(256) void chunk_prep_kernel(
    const float* __restrict__ qb, const float* __restrict__ kb, float* __restrict__ vb,
    const float* __restrict__ beta, const float* __restrict__ g,
    float* __restrict__ Bt, float* __restrict__ Ct, float* __restrict__ Ft)
{
    __shared__ __align__(16) float Kc[4096];   // K -> K~
    __shared__ __align__(16) float Qx[4096];   // Q -> Xk
    __shared__ __align__(16) float Vx[4096];   // V -> Xv
    __shared__ __align__(16) float Tm[4096];   // M (lower) + A~ (upper+diag)
    __shared__ float Gs[64], bs[64];
    int c = blockIdx.x, h = blockIdx.y;
    int tid = threadIdx.x;
    int t0 = c * CHUNK;

    // --- stage K, Q, V (swizzled) ---
    {
        int row = tid >> 4, c4 = (tid & 15) << 2;
        #pragma unroll
        for (int m = 0; m < 4; ++m) {
            int r = row + m * 16;
            size_t gidx = (size_t)(t0 + r) * EE + h * DD + c4;
            *(float4*)&Kc[swz4(r, c4)] = *(const float4*)&kb[gidx];
            *(float4*)&Qx[swz4(r, c4)] = *(const float4*)&qb[gidx];
            *(float4*)&Vx[swz4(r, c4)] = *(const float4*)&vb[gidx];
        }
    }
    if (tid < 64) {
        float x = g[(t0 + tid) * HH + h];
        #pragma unroll
        for (int off = 1; off < 64; off <<= 1) {
            float y = __shfl_up(x, off);
            if (tid >= off) x *= y;
        }
        Gs[tid] = x;
        bs[tid] = beta[(t0 + tid) * HH + h];
    }
    __syncthreads();

    // --- phase B: dkk/dqk 4x4 register tiles (t rows = a0.., s cols = b0..) ---
    int ty = tid >> 4, tx = tid & 15;
    int a0 = ty << 2, b0 = tx << 2;
    float dkk[4][4] = {}, dqk[4][4] = {};
    #pragma unroll 4
    for (int j4 = 0; j4 < 64; j4 += 4) {
        float4 kt[4], ks[4], qt[4];
        #pragma unroll
        for (int i = 0; i < 4; ++i) kt[i] = *(const float4*)&Kc[swz4(a0 + i, j4)];
        #pragma unroll
        for (int j = 0; j < 4; ++j) ks[j] = *(const float4*)&Kc[swz4(b0 + j, j4)];
        #pragma unroll
        for (int i = 0; i < 4; ++i) qt[i] = *(const float4*)&Qx[swz4(a0 + i, j4)];
        #pragma unroll
        for (int i = 0; i < 4; ++i)
            #pragma unroll
            for (int j = 0; j < 4; ++j) {
                float d1 = dkk[i][j];
                d1 = fmaf(kt[i].w, ks[j].w, d1);
                d1 = fmaf(kt[i].z, ks[j].z, d1);
                d1 = fmaf(kt[i].y, ks[j].y, d1);
                d1 = fmaf(kt[i].x, ks[j].x, d1);
                dkk[i][j] = d1;
                float d2 = dqk[i][j];
                d2 = fmaf(qt[i].w, ks[j].w, d2);
                d2 = fmaf(qt[i].z, ks[j].z, d2);
                d2 = fmaf(qt[i].y, ks[j].y, d2);
                d2 = fmaf(qt[i].x, ks[j].x, d2);
                dqk[i][j] = d2;
            }
    }
    __syncthreads();   // all Qx/Kc reads done before Tm writes (Tm fresh) / later Qx reuse
    #pragma unroll
    for (int i = 0; i < 4; ++i) {
        int t = a0 + i;
        #pragma unroll
        for (int j = 0; j < 4; ++j) {
            int s = b0 + j;
            float gr = Gs[t] / Gs[s];
            if (s < t)  Tm[swz(t, s)] = bs[t] * gr * dkk[i][j];
            if (s <= t) Tm[swz(s, t)] = SCALE * gr * dqk[i][j];
        }
    }
    __syncthreads();

    // --- substitution: thread owns one X column; X into Vx (V) / Qx (K) ---
    if (tid < 128) {
        int col = tid & 63;
        int wK = tid >> 6;
        float* Xp = wK ? Qx : Vx;
        #pragma unroll 1
        for (int t = 0; t < 64; ++t) {
            float acc = wK ? (bs[t] * Gs[t] * Kc[swz(t, col)])
                           : (bs[t] * Vx[swz(t, col)]);
            int t4 = t & ~3;
            for (int s4 = 0; s4 < t4; s4 += 4) {
                float4 mp = *(const float4*)&Tm[swz4(t, s4)];
                acc = fmaf(-mp.x, Xp[swz(s4 + 0, col)], acc);
                acc = fmaf(-mp.y, Xp[swz(s4 + 1, col)], acc);
                acc = fmaf(-mp.z, Xp[swz(s4 + 2, col)], acc);
                acc = fmaf(-mp.w, Xp[swz(s4 + 3, col)], acc);
            }
            for (int s = t4; s < t; ++s)
                acc = fmaf(-Tm[swz(t, s)], Xp[swz(s, col)], acc);
            Xp[swz(t, col)] = acc;
        }
    }
    __syncthreads();

    // --- Kc -> K~ in place ---
    {
        int r = tid & 63, qd = tid >> 6;
        float ratio = Gs[63] / Gs[r];
        #pragma unroll
        for (int jj = 0; jj < 4; ++jj) {
            int c4 = qd * 16 + jj * 4;
            float4 vv = *(const float4*)&Kc[swz4(r, c4)];
            vv.x *= ratio; vv.y *= ratio; vv.z *= ratio; vv.w *= ratio;
            *(float4*)&Kc[swz4(r, c4)] = vv;
        }
    }
    __syncthreads();

    // --- prefetch epilogue Q term from global (L2-hot) ---
    float4 qe[4];
    #pragma unroll
    for (int j = 0; j < 4; ++j)
        qe[j] = *(const float4*)&qb[(size_t)(t0 + b0 + j) * EE + h * DD + a0];

    // --- fold: aB=Xk.K~, aC=K~.Xv, aF=Xk.A~, aE=A~.Xv (A~ masked from Tm) ---
    float aB[4][4] = {}, aC[4][4] = {}, aF[4][4] = {}, aE[4][4] = {};
    #pragma unroll 2
    for (int s = 0; s < 64; ++s) {
        float4 xkA4 = *(const float4*)&Qx[swz4(s, a0)];
        float4 kcB4 = *(const float4*)&Kc[swz4(s, b0)];
        float4 kcA4 = *(const float4*)&Kc[swz4(s, a0)];
        float4 xvB4 = *(const float4*)&Vx[swz4(s, b0)];
        float4 taA4 = *(const float4*)&Tm[swz4(s, a0)];
        float4 taB4 = *(const float4*)&Tm[swz4(s, b0)];
        float xkA[4] = {xkA4.x, xkA4.y, xkA4.z, xkA4.w};
        float kcB[4] = {kcB4.x, kcB4.y, kcB4.z, kcB4.w};
        float kcA[4] = {kcA4.x, kcA4.y, kcA4.z, kcA4.w};
        float xvB[4] = {xvB4.x, xvB4.y, xvB4.z, xvB4.w};
        float atA[4], atB[4];
        atA[0] = (s <= a0 + 0) ? taA4.x : 0.f;
        atA[1] = (s <= a0 + 1) ? taA4.y : 0.f;
        atA[2] = (s <= a0 + 2) ? taA4.z : 0.f;
        atA[3] = (s <= a0 + 3) ? taA4.w : 0.f;
        atB[0] = (s <= b0 + 0) ? taB4.x : 0.f;
        atB[1] = (s <= b0 + 1) ? taB4.y : 0.f;
        atB[2] = (s <= b0 + 2) ? taB4.z : 0.f;
        atB[3] = (s <= b0 + 3) ? taB4.w : 0.f;
        #pragma unroll
        for (int i = 0; i < 4; ++i)
            #pragma unroll
            for (int j = 0; j < 4; ++j) {
                aB[i][j] = fmaf(xkA[i], kcB[j], aB[i][j]);
                aC[i][j] = fmaf(kcA[i], xvB[j], aC[i][j]);
                aF[i][j] = fmaf(xkA[i], atB[j], aF[i][j]);
                aE[i][j] = fmaf(atA[i], xvB[j], aE[i][j]);
            }
    }
    size_t tile = ((size_t)(c * HH + h)) << 12;
    #pragma unroll
    for (int i = 0; i < 4; ++i) {
        int a = a0 + i;
        float4 wB = {aB[i][0], aB[i][1], aB[i][2], aB[i][3]};
        float4 wC = {aC[i][0], aC[i][1], aC[i][2], aC[i][3]};
        float4 wF;
        wF.x = SCALE * Gs[b0 + 0] * qe[0][i] - aF[i][0];
        wF.y = SCALE * Gs[b0 + 1] * qe[1][i] - aF[i][1];
        wF.z = SCALE * Gs[b0 + 2] * qe[2][i] - aF[i][2];
        wF.w = SCALE * Gs[b0 + 3] * qe[3][i] - aF[i][3];
        float4 wE = {aE[i][0], aE[i][1], aE[i][2], aE[i][3]};
        *(float4*)&Bt[tile + a * 64 + b0] = wB;
        *(float4*)&Ct[tile + a * 64 + b0] = wC;
        *(float4*)&Ft[tile + a * 64 + b0] = wF;
        *(float4*)&vb[(size_t)(t0 + a) * EE + h * DD + b0] = wE;
    }
}

// ---------------------------------------------------------------------------
// Delta rule serial S-chain, column-split: grid (CPH, HH).
// ---------------------------------------------------------------------------
__global__ __launch_bounds__(256) void delta_scan4_kernel(
    const float* __restrict__ Bt, const float* __restrict__ Ct,
    const float* __restrict__ g, float* __restrict__ Sout)
{
    __shared__ __align__(16) float Bsb[2][4096];
    __shared__ __align__(16) float Csb[2][512];
    __shared__ float Ss[64][10];
    __shared__ float GCs[NCH];
    int p = blockIdx.x, h = blockIdx.y;
    int bo = p * 8;
    int tid = threadIdx.x;
    int a = tid & 63;
    int w = tid >> 6;
    int j0 = w * 2;

    {
        float pr = 1.f;
        int t0 = tid * 8;
        #pragma unroll
        for (int j = 0; j < 8; ++j) pr *= g[(t0 + j) * HH + h];
        pr *= __shfl_xor(pr, 1);
        pr *= __shfl_xor(pr, 2);
        pr *= __shfl_xor(pr, 4);
        GCs[tid >> 3] = pr;
        Ss[a][j0] = 0.f;
        Ss[a][j0 + 1] = 0.f;
    }

#define STG4(buf, cc)                                                          \
    {                                                                          \
        size_t tb = ((size_t)((cc) * HH + h)) << 12;                           \
        _Pragma("unroll")                                                      \
        for (int u = 0; u < 4; ++u) {                                          \
            int fi = ((u << 8) + tid) << 2;                                    \
            int fb = ((u << 8) + (tid & 192)) << 2;                            \
            __builtin_amdgcn_global_load_lds((gptr_t)&Bt[tb + fi],             \
                (lptr_t)&Bsb[buf][fb], 16, 0, 0);                              \
        }                                                                      \
        if (tid < 128) {                                                       \
            size_t cfi = tb + ((size_t)(tid >> 1) << 6) + bo + ((tid & 1) << 2); \
            __builtin_amdgcn_global_load_lds((gptr_t)&Ct[cfi],                 \
                (lptr_t)&Csb[buf][(tid & 64) << 2], 16, 0, 0);                 \
        }                                                                      \
    }

    STG4(0, 0)
    for (int c = 0; c < NCH; ++c) {
        __syncthreads();
        if (c + 1 < NCH) STG4((c + 1) & 1, c + 1)
        const float* Bsp = Bsb[c & 1];
        const float* Csp = Csb[c & 1];
        float gc = GCs[c];
        size_t tile = ((size_t)(c * HH + h)) << 12;
        float s0 = Ss[a][j0], s1 = Ss[a][j0 + 1];
        Sout[tile + (size_t)(bo + j0) * 64 + a] = s0;
        Sout[tile + (size_t)(bo + j0 + 1) * 64 + a] = s1;
        float p0 = 0.f, p1 = 0.f;
        #pragma unroll 4
        for (int k = 0; k < 64; ++k) {
            float bk = Bsp[k * 64 + a];
            float2 sv = *(const float2*)&Ss[k][j0];
            p0 = fmaf(bk, sv.x, p0);
            p1 = fmaf(bk, sv.y, p1);
        }
        __syncthreads();
        float c0v = Csp[a * 8 + j0], c1v = Csp[a * 8 + j0 + 1];
        Ss[a][j0]     = fmaf(gc, s0, c0v - p0);
        Ss[a][j0 + 1] = fmaf(gc, s1, c1v - p1);
    }
#undef STG4
}

// ---------------------------------------------------------------------------
// Delta rule parallel output map: O_c = F_c.S_c + E_c. grid (NCH, HH).
// ---------------------------------------------------------------------------
__global__ __launch_bounds__(256) void delta_apply_kernel(
    const float* __restrict__ Sb, const float* __restrict__ Ft,
    float* __restrict__ vb)
{
    __shared__ float Fs[64][64];
    __shared__ float S2[64][68];
    int c = blockIdx.x, h = blockIdx.y;
    int tid = threadIdx.x;
    int tx = tid & 15, ty = tid >> 4;
    int a0 = ty << 2, b0 = tx << 2;
    size_t tile = ((size_t)(c * HH + h)) << 12;
    {
        int row = tid >> 4, c4 = (tid & 15) << 2;
        #pragma unroll
        for (int m = 0; m < 4; ++m) {
            int r = row + m * 16;
            *(float4*)&Fs[r][c4] = *(const float4*)&Ft[tile + r * 64 + c4];
            float4 sv = *(const float4*)&Sb[tile + r * 64 + c4];
            S2[c4 + 0][r] = sv.x;
            S2[c4 + 1][r] = sv.y;
            S2[c4 + 2][r] = sv.z;
            S2[c4 + 3][r] = sv.w;
        }
    }
    __syncthreads();
    float accO[4][4] = {};
    #pragma unroll 4
    for (int k = 0; k < 64; ++k) {
        float4 fv = *(const float4*)&Fs[k][a0];
        float4 sv = *(const float4*)&S2[k][b0];
        float fa[4] = {fv.x, fv.y, fv.z, fv.w};
        float sa[4] = {sv.x, sv.y, sv.z, sv.w};
        #pragma unroll
        for (int i = 0; i < 4; ++i)
            #pragma unroll
            for (int j = 0; j < 4; ++j)
                accO[i][j] = fmaf(fa[i], sa[j], accO[i][j]);
    }
    #pragma unroll
    for (int i = 0; i < 4; ++i) {
        size_t gi = (size_t)((c << 6) + a0 + i) * EE + h * DD + b0;
        float4 ev = *(const float4*)&vb[gi];
        float4 ov = {accO[i][0] + ev.x, accO[i][1] + ev.y,
                     accO[i][2] + ev.z, accO[i][3] + ev.w};
        *(float4*)&vb[gi] = ov;
    }
}

// ---------------------------------------------------------------------------
// Causal flash attention, bf16 MFMA; output written as bf16 for proj GEMM.
// ---------------------------------------------------------------------------
__global__ __launch_bounds__(256) void attn_mfma_kernel(
    const float* __restrict__ q, const float* __restrict__ k, const float* __restrict__ v,
    ushort* __restrict__ y)
{
    __shared__ __align__(16) unsigned short KsL[64 * KS];
    __shared__ __align__(16) unsigned short VtL[64 * KS];
    __shared__ __align__(16) unsigned short PsL[4][16 * KS];

    int h = blockIdx.y;
    int rb = ((int)gridDim.x - 1 - (int)blockIdx.x) * 64;
    int tid = threadIdx.x;
    int w = tid >> 6;
    int lane = tid & 63;
    int l16 = lane & 15;
    int lq = lane >> 4;
    int qr0 = rb + w * 16;

    bf16x8 qf[2];
    {
        const float* qrow = &q[(size_t)(qr0 + l16) * EE + h * DD];
        #pragma unroll
        for (int kk = 0; kk < 2; ++kk) {
            float4 v0 = *(const float4*)&qrow[kk * 32 + lq * 8];
            float4 v1 = *(const float4*)&qrow[kk * 32 + lq * 8 + 4];
            qf[kk][0] = (short)f2bf(v0.x); qf[kk][1] = (short)f2bf(v0.y);
            qf[kk][2] = (short)f2bf(v0.z); qf[kk][3] = (short)f2bf(v0.w);
            qf[kk][4] = (short)f2bf(v1.x); qf[kk][5] = (short)f2bf(v1.y);
            qf[kk][6] = (short)f2bf(v1.z); qf[kk][7] = (short)f2bf(v1.w);
        }
    }

    f32x4 oacc[4];
    #pragma unroll
    for (int dt = 0; dt < 4; ++dt) oacc[dt] = (f32x4){0.f, 0.f, 0.f, 0.f};
    float mrow[4] = {-3e38f, -3e38f, -3e38f, -3e38f};
    float lrow[4] = {0.f, 0.f, 0.f, 0.f};

    int ks_s = tid >> 2, ks_d0 = (tid & 3) << 4;
    int vt_s0 = (tid & 31) * 2, vt_dq = (tid >> 5) << 3;

    for (int c0 = 0; c0 <= rb; c0 += 64) {
        __syncthreads();
        {
            const float* krow = &k[(size_t)(c0 + ks_s) * EE + h * DD + ks_d0];
            #pragma unroll
            for (int u = 0; u < 4; ++u) {
                float4 kv4 = *(const float4*)&krow[u * 4];
                bf16x4 pk = { (short)f2bf(kv4.x), (short)f2bf(kv4.y),
                              (short)f2bf(kv4.z), (short)f2bf(kv4.w) };
                *(bf16x4*)&KsL[ks_s * KS + ks_d0 + u * 4] = pk;
            }
            const float* vr0 = &v[(size_t)(c0 + vt_s0) * EE + h * DD + vt_dq];
            const float* vr1 = vr0 + EE;
            float4 a0 = *(const float4*)&vr0[0], a1 = *(const float4*)&vr0[4];
            float4 b0 = *(const float4*)&vr1[0], b1 = *(const float4*)&vr1[4];
            float va[8] = {a0.x, a0.y, a0.z, a0.w, a1.x, a1.y, a1.z, a1.w};
            float vbv[8] = {b0.x, b0.y, b0.z, b0.w, b1.x, b1.y, b1.z, b1.w};
            #pragma unroll
            for (int u = 0; u < 8; ++u) {
                unsigned pv = (unsigned)f2bf(va[u]) | ((unsigned)f2bf(vbv[u]) << 16);
                *(unsigned*)&VtL[(vt_dq + u) * KS + vt_s0] = pv;
            }
        }
        __syncthreads();

        f32x4 sacc[4];
        #pragma unroll
        for (int ct = 0; ct < 4; ++ct) {
            bf16x8 b0 = *(bf16x8*)&KsL[(ct * 16 + l16) * KS + lq * 8];
            bf16x8 b1 = *(bf16x8*)&KsL[(ct * 16 + l16) * KS + 32 + lq * 8];
            f32x4 acc = {0.f, 0.f, 0.f, 0.f};
            acc = __builtin_amdgcn_mfma_f32_16x16x32_bf16(qf[0], b0, acc, 0, 0, 0);
            acc = __builtin_amdgcn_mfma_f32_16x16x32_bf16(qf[1], b1, acc, 0, 0, 0);
            sacc[ct] = acc;
        }

        float sv[4][4];
        float tmax[4] = {-3e38f, -3e38f, -3e38f, -3e38f};
        #pragma unroll
        for (int ct = 0; ct < 4; ++ct) {
            int col = c0 + ct * 16 + l16;
            #pragma unroll
            for (int r = 0; r < 4; ++r) {
                int row = qr0 + lq * 4 + r;
                float s = sacc[ct][r] * SCALE;
                if (col > row) s = -3e38f;
                sv[ct][r] = s;
                tmax[r] = fmaxf(tmax[r], s);
            }
        }
        #pragma unroll
        for (int off = 1; off < 16; off <<= 1) {
            #pragma unroll
            for (int r = 0; r < 4; ++r)
                tmax[r] = fmaxf(tmax[r], __shfl_xor(tmax[r], off));
        }
        float corr[4], psum[4];
        #pragma unroll
        for (int r = 0; r < 4; ++r) {
            float mn = fmaxf(mrow[r], tmax[r]);
            corr[r] = __expf(mrow[r] - mn);
            mrow[r] = mn;
            psum[r] = 0.f;
        }
        #pragma unroll
        for (int ct = 0; ct < 4; ++ct) {
            #pragma unroll
            for (int r = 0; r < 4; ++r) {
                float p = __expf(sv[ct][r] - mrow[r]);
                psum[r] += p;
                PsL[w][(lq * 4 + r) * KS + ct * 16 + l16] = f2bf(p);
            }
        }
        #pragma unroll
        for (int off = 1; off < 16; off <<= 1) {
            #pragma unroll
            for (int r = 0; r < 4; ++r)
                psum[r] += __shfl_xor(psum[r], off);
        }
        #pragma unroll
        for (int r = 0; r < 4; ++r)
            lrow[r] = lrow[r] * corr[r] + psum[r];
        #pragma unroll
        for (int dt = 0; dt < 4; ++dt) {
            #pragma unroll
            for (int r = 0; r < 4; ++r)
                oacc[dt][r] *= corr[r];
        }

        bf16x8 pa0 = *(bf16x8*)&PsL[w][l16 * KS + lq * 8];
        bf16x8 pa1 = *(bf16x8*)&PsL[w][l16 * KS + 32 + lq * 8];
        #pragma unroll
        for (int dt = 0; dt < 4; ++dt) {
            bf16x8 vb0 = *(bf16x8*)&VtL[(dt * 16 + l16) * KS + lq * 8];
            bf16x8 vb1 = *(bf16x8*)&VtL[(dt * 16 + l16) * KS + 32 + lq * 8];
            oacc[dt] = __builtin_amdgcn_mfma_f32_16x16x32_bf16(pa0, vb0, oacc[dt], 0, 0, 0);
            oacc[dt] = __builtin_amdgcn_mfma_f32_16x16x32_bf16(pa1, vb1, oacc[dt], 0, 0, 0);
        }
    }

    float linv[4];
    #pragma unroll
    for (int r = 0; r < 4; ++r) linv[r] = 1.f / lrow[r];
    #pragma unroll
    for (int dt = 0; dt < 4; ++dt) {
        #pragma unroll
        for (int r = 0; r < 4; ++r) {
            int row = qr0 + lq * 4 + r;
            y[(size_t)row * EE + h * DD + dt * 16 + l16] = f2bf(oacc[dt][r] * linv[r]);
        }
    }
}

// ---------------------------------------------------------------------------
extern "C" void kernel_launch(void* const* d_in, const int* in_sizes, int n_in,
                              void* d_out, int out_size, void* d_ws, size_t ws_size,
                              hipStream_t stream)
{
    (void)in_sizes; (void)n_in; (void)out_size; (void)ws_size;
    const float* x      = (const float*)d_in[0];
    const float* w_attn = (const float*)d_in[1];
    const float* w_proj = (const float*)d_in[2];
    const float* qcw    = (const float*)d_in[3];
    const float* kcw    = (const float*)d_in[4];
    const float* vcw    = (const float*)d_in[5];
    const float* cosb   = (const float*)d_in[6];
    const float* sinb   = (const float*)d_in[7];
    const float* beta   = (const float*)d_in[8];
    const float* g      = (const float*)d_in[9];
    float* out = (float*)d_out;
    float* ws  = (float*)d_ws;

    const size_t TE = (size_t)TT * EE;
    float* buf0 = ws + 0 * TE;          // qkv -> Bt
    float* buf1 = ws + 1 * TE;          // qkv -> Ct -> ybf
    float* buf2 = ws + 2 * TE;          // qkv -> Ft -> wpT
    float* qb   = ws + 3 * TE;          // xbf -> q
    float* kb   = ws + 4 * TE;          // waT -> k
    float* vb   = ws + 5 * TE;          // v -> E -> O
    float* qkv  = buf0;
    ushort* xbf = (ushort*)qb;
    ushort* waT = (ushort*)kb;
    ushort* ybf = (ushort*)buf1;
    ushort* wpT = (ushort*)buf2;
    float* Sbuf = out;                  // d_out as S-tile scratch

    cvt_bf16_kernel<<<TT * EE / 2048, 256, 0, stream>>>(x, xbf);
    cvt_transpose_kernel<<<dim3(NN / 64, EE / 64), 256, 0, stream>>>(w_attn, waT, EE, NN);
    gemm_bf16<128, 128><<<dim3(NN / 128, TT / 128), 256, 0, stream>>>(
        xbf, waT, qkv, TT, NN, EE);
    conv_rope_kernel<<<dim3(TT / 4, HH, 3), dim3(64, 4), 0, stream>>>(
        qkv, qcw, kcw, vcw, cosb, sinb, qb, kb, vb);
    chunk_prep_kernel<<<dim3(NCH, HH), 256, 0, stream>>>(qb, kb, vb, beta, g, buf0, buf1, buf2);
    delta_scan4_kernel<<<dim3(CPH, HH), 256, 0, stream>>>(buf0, buf1, g, Sbuf);
    delta_apply_kernel<<<dim3(NCH, HH), 256, 0, stream>>>(Sbuf, buf2, vb);
    cvt_transpose_kernel<<<dim3(EE / 64, EE / 64), 256, 0, stream>>>(w_proj, wpT, EE, EE);
    attn_mfma_kernel<<<dim3(TT / 64, HH), 256, 0, stream>>>(qb, kb, vb, ybf);
    gemm_bf16<64, 64><<<dim3(EE / 64, TT / 64), 256, 0, stream>>>(
        ybf, wpT, out, TT, EE, EE);
}

// Round 9
// 292.251 us; speedup vs baseline: 7.9170x; 1.0741x over previous
//
#include <hip/hip_runtime.h>
#include <math.h>

#define TT 2048
#define HH 16
#define DD 64
#define EE 1024
#define NN 3072
#define CHUNK 64
#define NCH (TT / CHUNK)
#define SCALE 0.125f
#define KS 72   // attn LDS row stride (bf16): conflict-free b128
#define CPH 8   // column-split blocks per head in delta scan

typedef short bf16x8 __attribute__((ext_vector_type(8)));
typedef short bf16x4 __attribute__((ext_vector_type(4)));
typedef float f32x4 __attribute__((ext_vector_type(4)));
typedef unsigned short ushort;
typedef const __attribute__((address_space(1))) unsigned int* gptr_t;
typedef __attribute__((address_space(3))) unsigned int* lptr_t;

__device__ __forceinline__ unsigned short f2bf(float x) {
    union { float f; unsigned u; } un; un.f = x;
    unsigned r = un.u + 0x7FFFu + ((un.u >> 16) & 1u);
    return (unsigned short)(r >> 16);
}

// XOR slot swizzle for 64-float rows (4-float slots, key = row bits 2..4)
__device__ __forceinline__ int swz(int r, int c) {
    return (r << 6) + ((((c >> 2) ^ ((r >> 2) & 7)) << 2) | (c & 3));
}
__device__ __forceinline__ int swz4(int r, int c4) {
    return (r << 6) + (((c4 >> 2) ^ ((r >> 2) & 7)) << 2);
}

// ---------------------------------------------------------------------------
// fp32 -> bf16 elementwise convert (x)
// ---------------------------------------------------------------------------
__global__ __launch_bounds__(256) void cvt_bf16_kernel(
    const float* __restrict__ in, ushort* __restrict__ out)
{
    int i = ((int)blockIdx.x * 256 + (int)threadIdx.x) << 3;
    float4 a = *(const float4*)&in[i];
    float4 b = *(const float4*)&in[i + 4];
    bf16x8 o;
    o[0] = (short)f2bf(a.x); o[1] = (short)f2bf(a.y);
    o[2] = (short)f2bf(a.z); o[3] = (short)f2bf(a.w);
    o[4] = (short)f2bf(b.x); o[5] = (short)f2bf(b.y);
    o[6] = (short)f2bf(b.z); o[7] = (short)f2bf(b.w);
    *(bf16x8*)&out[i] = o;
}

// ---------------------------------------------------------------------------
// fp32 [K][N] -> bf16 [N][K] convert + transpose (weights)
// ---------------------------------------------------------------------------
__global__ __launch_bounds__(256) void cvt_transpose_kernel(
    const float* __restrict__ W, ushort* __restrict__ WT, int K, int N)
{
    __shared__ float Ls[64][65];
    int n0 = blockIdx.x * 64, k0 = blockIdx.y * 64;
    int tid = threadIdx.x;
    int lr = tid >> 4, lc4 = (tid & 15) << 2;
    #pragma unroll
    for (int m = 0; m < 4; ++m) {
        int r = lr + m * 16;
        float4 v = *(const float4*)&W[(size_t)(k0 + r) * N + n0 + lc4];
        Ls[r][lc4 + 0] = v.x; Ls[r][lc4 + 1] = v.y;
        Ls[r][lc4 + 2] = v.z; Ls[r][lc4 + 3] = v.w;
    }
    __syncthreads();
    int n = tid >> 2, kb = (tid & 3) << 4;
    bf16x8 o0, o1;
    #pragma unroll
    for (int j = 0; j < 8; ++j) o0[j] = (short)f2bf(Ls[kb + j][n]);
    #pragma unroll
    for (int j = 0; j < 8; ++j) o1[j] = (short)f2bf(Ls[kb + 8 + j][n]);
    *(bf16x8*)&WT[(size_t)(n0 + n) * K + k0 + kb] = o0;
    *(bf16x8*)&WT[(size_t)(n0 + n) * K + k0 + kb + 8] = o1;
}

// ---------------------------------------------------------------------------
// bf16 MFMA GEMM: C(fp32)[M][N] = A(bf16)[M][K] * BT(bf16)[N][K]^T
// ---------------------------------------------------------------------------
template<int BM, int BN>
__global__ __launch_bounds__(256) void gemm_bf16(
    const ushort* __restrict__ A, const ushort* __restrict__ BT,
    float* __restrict__ C, int M, int N, int K)
{
    constexpr int MT = BM / 32;
    constexpr int NT = BN / 32;
    constexpr int AIT = BM * 64 / 2048;
    constexpr int BIT = BN * 64 / 2048;
    __shared__ __align__(16) ushort Asl[2][BM * 64];
    __shared__ __align__(16) ushort Bsl[2][BN * 64];
    const int tid = threadIdx.x;
    const int lane = tid & 63, w = tid >> 6;
    const int wm = w >> 1, wn = w & 1;
    const int l16 = lane & 15, lq = lane >> 4;
    const int row0 = blockIdx.y * BM, col0 = blockIdx.x * BN;
    const int wvb = w << 9;

    f32x4 acc[MT][NT];
    #pragma unroll
    for (int i = 0; i < MT; ++i)
        #pragma unroll
        for (int j = 0; j < NT; ++j)
            acc[i][j] = (f32x4){0.f, 0.f, 0.f, 0.f};

#define STAGE_TILE(buf, k0)                                                    \
    {                                                                          \
        _Pragma("unroll")                                                      \
        for (int u = 0; u < AIT; ++u) {                                        \
            int idx = u * 256 + tid;                                           \
            int r = idx >> 3, s = idx & 7;                                     \
            const ushort* srcp =                                               \
                &A[(size_t)(row0 + r) * K + (k0) + ((s ^ (r & 7)) << 3)];      \
            __builtin_amdgcn_global_load_lds((gptr_t)srcp,                     \
                (lptr_t)&Asl[buf][(u << 11) + wvb], 16, 0, 0);                 \
        }                                                                      \
        _Pragma("unroll")                                                      \
        for (int u = 0; u < BIT; ++u) {                                        \
            int idx = u * 256 + tid;                                           \
            int r = idx >> 3, s = idx & 7;                                     \
            const ushort* srcp =                                               \
                &BT[(size_t)(col0 + r) * K + (k0) + ((s ^ (r & 7)) << 3)];     \
            __builtin_amdgcn_global_load_lds((gptr_t)srcp,                     \
                (lptr_t)&Bsl[buf][(u << 11) + wvb], 16, 0, 0);                 \
        }                                                                      \
    }

    const int nK = K >> 6;
    STAGE_TILE(0, 0)
    for (int kt = 0; kt < nK; ++kt) {
        __syncthreads();                       // stage(kt) drained + visible
        if (kt + 1 < nK) STAGE_TILE((kt + 1) & 1, (kt + 1) << 6)
        const int cb = kt & 1;
        #pragma unroll
        for (int kk = 0; kk < 2; ++kk) {
            bf16x8 afr[MT], bfr[NT];
            #pragma unroll
            for (int mt = 0; mt < MT; ++mt) {
                int rr = wm * (BM / 2) + mt * 16 + l16;
                afr[mt] = *(bf16x8*)&Asl[cb][rr * 64 +
                           (((kk * 4 + lq) ^ (rr & 7)) << 3)];
            }
            #pragma unroll
            for (int nt = 0; nt < NT; ++nt) {
                int cc = wn * (BN / 2) + nt * 16 + l16;
                bfr[nt] = *(bf16x8*)&Bsl[cb][cc * 64 +
                           (((kk * 4 + lq) ^ (cc & 7)) << 3)];
            }
            #pragma unroll
            for (int mt = 0; mt < MT; ++mt)
                #pragma unroll
                for (int nt = 0; nt < NT; ++nt)
                    acc[mt][nt] = __builtin_amdgcn_mfma_f32_16x16x32_bf16(
                        afr[mt], bfr[nt], acc[mt][nt], 0, 0, 0);
        }
    }
#undef STAGE_TILE

    #pragma unroll
    for (int mt = 0; mt < MT; ++mt) {
        #pragma unroll
        for (int nt = 0; nt < NT; ++nt) {
            int col = col0 + wn * (BN / 2) + nt * 16 + l16;
            #pragma unroll
            for (int r = 0; r < 4; ++r) {
                int row = row0 + wm * (BM / 2) + mt * 16 + lq * 4 + r;
                C[(size_t)row * N + col] = acc[mt][nt][r];
            }
        }
    }
}

// ---------------------------------------------------------------------------
// Causal depthwise conv1d (DC=4) + SiLU, then RoPE for q,k; v plain.
// ---------------------------------------------------------------------------
__global__ __launch_bounds__(256) void conv_rope_kernel(
    const float* __restrict__ qkv,
    const float* __restrict__ qw, const float* __restrict__ kw, const float* __restrict__ vw,
    const float* __restrict__ cosb, const float* __restrict__ sinb,
    float* __restrict__ qo, float* __restrict__ ko, float* __restrict__ vo)
{
    int j = blockIdx.z;
    const float* w = (j == 0) ? qw : (j == 1) ? kw : vw;
    float* dst     = (j == 0) ? qo : (j == 1) ? ko : vo;
    int d  = threadIdx.x;
    int tl = threadIdx.y;
    int t  = blockIdx.x * 4 + tl;
    int h  = blockIdx.y;
    int c  = h * DD + d;
    int n  = h * 192 + j * 64 + d;
    float acc = 0.f;
    #pragma unroll
    for (int i = 0; i < 4; ++i) {
        int tt = t - 3 + i;
        if (tt >= 0) acc = fmaf(qkv[(size_t)tt * NN + n], w[c * 4 + i], acc);
    }
    float yv = acc / (1.f + __expf(-acc));
    if (j == 2) { dst[t * EE + c] = yv; return; }
    __shared__ float sh[4][64];
    sh[tl][d] = yv;
    __syncthreads();
    int dh = d & 31;
    float cc = cosb[t * 32 + dh];
    float ss = sinb[t * 32 + dh];
    float outv;
    if (d < 32) outv = yv * cc - sh[tl][d + 32] * ss;
    else        outv = yv * cc + sh[tl][d - 32] * ss;
    dst[t * EE + c] = outv;
}

// ---------------------------------------------------------------------------
// Chunked gated delta rule, phase 1 (parallel over 32 chunks x 16 heads).
// ---------------------------------------------------------------------------
__global__ __launch_bounds__(256) void chunk_prep_kernel(
    const float* __restrict__ qb, const float* __restrict__ kb, float* __restrict__ vb,
    const float* __restrict__ beta, const float* __restrict__ g,
    float* __restrict__ Bt, float* __restrict__ Ct, float* __restrict__ Ft)
{
    __shared__ __align__(16) float Kc[4096];   // K -> K~
    __shared__ __align__(16) float Qx[4096];   // Q -> Xk
    __shared__ __align__(16) float Vx[4096];   // V -> Xv
    __shared__ __align__(16) float Tm[4096];   // M (lower) + A~ (upper+diag)
    __shared__ float Gs[64], bs[64];
    int c = blockIdx.x, h = blockIdx.y;
    int tid = threadIdx.x;
    int t0 = c * CHUNK;

    {
        int row = tid >> 4, c4 = (tid & 15) << 2;
        #pragma unroll
        for (int m = 0; m < 4; ++m) {
            int r = row + m * 16;
            size_t gidx = (size_t)(t0 + r) * EE + h * DD + c4;
            *(float4*)&Kc[swz4(r, c4)] = *(const float4*)&kb[gidx];
            *(float4*)&Qx[swz4(r, c4)] = *(const float4*)&qb[gidx];
            *(float4*)&Vx[swz4(r, c4)] = *(const float4*)&vb[gidx];
        }
    }
    if (tid < 64) {
        float x = g[(t0 + tid) * HH + h];
        #pragma unroll
        for (int off = 1; off < 64; off <<= 1) {
            float y = __shfl_up(x, off);
            if (tid >= off) x *= y;
        }
        Gs[tid] = x;
        bs[tid] = beta[(t0 + tid) * HH + h];
    }
    __syncthreads();

    int ty = tid >> 4, tx = tid & 15;
    int a0 = ty << 2, b0 = tx << 2;
    float dkk[4][4] = {}, dqk[4][4] = {};
    #pragma unroll 4
    for (int j4 = 0; j4 < 64; j4 += 4) {
        float4 kt[4], ks[4], qt[4];
        #pragma unroll
        for (int i = 0; i < 4; ++i) kt[i] = *(const float4*)&Kc[swz4(a0 + i, j4)];
        #pragma unroll
        for (int j = 0; j < 4; ++j) ks[j] = *(const float4*)&Kc[swz4(b0 + j, j4)];
        #pragma unroll
        for (int i = 0; i < 4; ++i) qt[i] = *(const float4*)&Qx[swz4(a0 + i, j4)];
        #pragma unroll
        for (int i = 0; i < 4; ++i)
            #pragma unroll
            for (int j = 0; j < 4; ++j) {
                float d1 = dkk[i][j];
                d1 = fmaf(kt[i].w, ks[j].w, d1);
                d1 = fmaf(kt[i].z, ks[j].z, d1);
                d1 = fmaf(kt[i].y, ks[j].y, d1);
                d1 = fmaf(kt[i].x, ks[j].x, d1);
                dkk[i][j] = d1;
                float d2 = dqk[i][j];
                d2 = fmaf(qt[i].w, ks[j].w, d2);
                d2 = fmaf(qt[i].z, ks[j].z, d2);
                d2 = fmaf(qt[i].y, ks[j].y, d2);
                d2 = fmaf(qt[i].x, ks[j].x, d2);
                dqk[i][j] = d2;
            }
    }
    __syncthreads();
    #pragma unroll
    for (int i = 0; i < 4; ++i) {
        int t = a0 + i;
        #pragma unroll
        for (int j = 0; j < 4; ++j) {
            int s = b0 + j;
            float gr = Gs[t] / Gs[s];
            if (s < t)  Tm[swz(t, s)] = bs[t] * gr * dkk[i][j];
            if (s <= t) Tm[swz(s, t)] = SCALE * gr * dqk[i][j];
        }
    }
    __syncthreads();

    if (tid < 128) {
        int col = tid & 63;
        int wK = tid >> 6;
        float* Xp = wK ? Qx : Vx;
        #pragma unroll 1
        for (int t = 0; t < 64; ++t) {
            float acc = wK ? (bs[t] * Gs[t] * Kc[swz(t, col)])
                           : (bs[t] * Vx[swz(t, col)]);
            int t4 = t & ~3;
            for (int s4 = 0; s4 < t4; s4 += 4) {
                float4 mp = *(const float4*)&Tm[swz4(t, s4)];
                acc = fmaf(-mp.x, Xp[swz(s4 + 0, col)], acc);
                acc = fmaf(-mp.y, Xp[swz(s4 + 1, col)], acc);
                acc = fmaf(-mp.z, Xp[swz(s4 + 2, col)], acc);
                acc = fmaf(-mp.w, Xp[swz(s4 + 3, col)], acc);
            }
            for (int s = t4; s < t; ++s)
                acc = fmaf(-Tm[swz(t, s)], Xp[swz(s, col)], acc);
            Xp[swz(t, col)] = acc;
        }
    }
    __syncthreads();

    {
        int r = tid & 63, qd = tid >> 6;
        float ratio = Gs[63] / Gs[r];
        #pragma unroll
        for (int jj = 0; jj < 4; ++jj) {
            int c4 = qd * 16 + jj * 4;
            float4 vv = *(const float4*)&Kc[swz4(r, c4)];
            vv.x *= ratio; vv.y *= ratio; vv.z *= ratio; vv.w *= ratio;
            *(float4*)&Kc[swz4(r, c4)] = vv;
        }
    }
    __syncthreads();

    float4 qe[4];
    #pragma unroll
    for (int j = 0; j < 4; ++j)
        qe[j] = *(const float4*)&qb[(size_t)(t0 + b0 + j) * EE + h * DD + a0];

    float aB[4][4] = {}, aC[4][4] = {}, aF[4][4] = {}, aE[4][4] = {};
    #pragma unroll 2
    for (int s = 0; s < 64; ++s) {
        float4 xkA4 = *(const float4*)&Qx[swz4(s, a0)];
        float4 kcB4 = *(const float4*)&Kc[swz4(s, b0)];
        float4 kcA4 = *(const float4*)&Kc[swz4(s, a0)];
        float4 xvB4 = *(const float4*)&Vx[swz4(s, b0)];
        float4 taA4 = *(const float4*)&Tm[swz4(s, a0)];
        float4 taB4 = *(const float4*)&Tm[swz4(s, b0)];
        float xkA[4] = {xkA4.x, xkA4.y, xkA4.z, xkA4.w};
        float kcB[4] = {kcB4.x, kcB4.y, kcB4.z, kcB4.w};
        float kcA[4] = {kcA4.x, kcA4.y, kcA4.z, kcA4.w};
        float xvB[4] = {xvB4.x, xvB4.y, xvB4.z, xvB4.w};
        float atA[4], atB[4];
        atA[0] = (s <= a0 + 0) ? taA4.x : 0.f;
        atA[1] = (s <= a0 + 1) ? taA4.y : 0.f;
        atA[2] = (s <= a0 + 2) ? taA4.z : 0.f;
        atA[3] = (s <= a0 + 3) ? taA4.w : 0.f;
        atB[0] = (s <= b0 + 0) ? taB4.x : 0.f;
        atB[1] = (s <= b0 + 1) ? taB4.y : 0.f;
        atB[2] = (s <= b0 + 2) ? taB4.z : 0.f;
        atB[3] = (s <= b0 + 3) ? taB4.w : 0.f;
        #pragma unroll
        for (int i = 0; i < 4; ++i)
            #pragma unroll
            for (int j = 0; j < 4; ++j) {
                aB[i][j] = fmaf(xkA[i], kcB[j], aB[i][j]);
                aC[i][j] = fmaf(kcA[i], xvB[j], aC[i][j]);
                aF[i][j] = fmaf(xkA[i], atB[j], aF[i][j]);
                aE[i][j] = fmaf(atA[i], xvB[j], aE[i][j]);
            }
    }
    size_t tile = ((size_t)(c * HH + h)) << 12;
    #pragma unroll
    for (int i = 0; i < 4; ++i) {
        int a = a0 + i;
        float4 wB = {aB[i][0], aB[i][1], aB[i][2], aB[i][3]};
        float4 wC = {aC[i][0], aC[i][1], aC[i][2], aC[i][3]};
        float4 wF;
        wF.x = SCALE * Gs[b0 + 0] * qe[0][i] - aF[i][0];
        wF.y = SCALE * Gs[b0 + 1] * qe[1][i] - aF[i][1];
        wF.z = SCALE * Gs[b0 + 2] * qe[2][i] - aF[i][2];
        wF.w = SCALE * Gs[b0 + 3] * qe[3][i] - aF[i][3];
        float4 wE = {aE[i][0], aE[i][1], aE[i][2], aE[i][3]};
        *(float4*)&Bt[tile + a * 64 + b0] = wB;
        *(float4*)&Ct[tile + a * 64 + b0] = wC;
        *(float4*)&Ft[tile + a * 64 + b0] = wF;
        *(float4*)&vb[(size_t)(t0 + a) * EE + h * DD + b0] = wE;
    }
}

// ---------------------------------------------------------------------------
// Delta rule serial S-chain, column-split: grid (CPH, HH).
// ---------------------------------------------------------------------------
__global__ __launch_bounds__(256) void delta_scan4_kernel(
    const float* __restrict__ Bt, const float* __restrict__ Ct,
    const float* __restrict__ g, float* __restrict__ Sout)
{
    __shared__ __align__(16) float Bsb[2][4096];
    __shared__ __align__(16) float Csb[2][512];
    __shared__ float Ss[64][10];
    __shared__ float GCs[NCH];
    int p = blockIdx.x, h = blockIdx.y;
    int bo = p * 8;
    int tid = threadIdx.x;
    int a = tid & 63;
    int w = tid >> 6;
    int j0 = w * 2;

    {
        float pr = 1.f;
        int t0 = tid * 8;
        #pragma unroll
        for (int j = 0; j < 8; ++j) pr *= g[(t0 + j) * HH + h];
        pr *= __shfl_xor(pr, 1);
        pr *= __shfl_xor(pr, 2);
        pr *= __shfl_xor(pr, 4);
        GCs[tid >> 3] = pr;
        Ss[a][j0] = 0.f;
        Ss[a][j0 + 1] = 0.f;
    }

#define STG4(buf, cc)                                                          \
    {                                                                          \
        size_t tb = ((size_t)((cc) * HH + h)) << 12;                           \
        _Pragma("unroll")                                                      \
        for (int u = 0; u < 4; ++u) {                                          \
            int fi = ((u << 8) + tid) << 2;                                    \
            int fb = ((u << 8) + (tid & 192)) << 2;                            \
            __builtin_amdgcn_global_load_lds((gptr_t)&Bt[tb + fi],             \
                (lptr_t)&Bsb[buf][fb], 16, 0, 0);                              \
        }                                                                      \
        if (tid < 128) {                                                       \
            size_t cfi = tb + ((size_t)(tid >> 1) << 6) + bo + ((tid & 1) << 2); \
            __builtin_amdgcn_global_load_lds((gptr_t)&Ct[cfi],                 \
                (lptr_t)&Csb[buf][(tid & 64) << 2], 16, 0, 0);                 \
        }                                                                      \
    }

    STG4(0, 0)
    for (int c = 0; c < NCH; ++c) {
        __syncthreads();
        if (c + 1 < NCH) STG4((c + 1) & 1, c + 1)
        const float* Bsp = Bsb[c & 1];
        const float* Csp = Csb[c & 1];
        float gc = GCs[c];
        size_t tile = ((size_t)(c * HH + h)) << 12;
        float s0 = Ss[a][j0], s1 = Ss[a][j0 + 1];
        Sout[tile + (size_t)(bo + j0) * 64 + a] = s0;
        Sout[tile + (size_t)(bo + j0 + 1) * 64 + a] = s1;
        float p0 = 0.f, p1 = 0.f;
        #pragma unroll 4
        for (int k = 0; k < 64; ++k) {
            float bk = Bsp[k * 64 + a];
            float2 sv = *(const float2*)&Ss[k][j0];
            p0 = fmaf(bk, sv.x, p0);
            p1 = fmaf(bk, sv.y, p1);
        }
        __syncthreads();
        float c0v = Csp[a * 8 + j0], c1v = Csp[a * 8 + j0 + 1];
        Ss[a][j0]     = fmaf(gc, s0, c0v - p0);
        Ss[a][j0 + 1] = fmaf(gc, s1, c1v - p1);
    }
#undef STG4
}

// ---------------------------------------------------------------------------
// Delta rule parallel output map: O_c = F_c.S_c + E_c. grid (NCH, HH).
// ---------------------------------------------------------------------------
__global__ __launch_bounds__(256) void delta_apply_kernel(
    const float* __restrict__ Sb, const float* __restrict__ Ft,
    float* __restrict__ vb)
{
    __shared__ float Fs[64][64];
    __shared__ float S2[64][68];
    int c = blockIdx.x, h = blockIdx.y;
    int tid = threadIdx.x;
    int tx = tid & 15, ty = tid >> 4;
    int a0 = ty << 2, b0 = tx << 2;
    size_t tile = ((size_t)(c * HH + h)) << 12;
    {
        int row = tid >> 4, c4 = (tid & 15) << 2;
        #pragma unroll
        for (int m = 0; m < 4; ++m) {
            int r = row + m * 16;
            *(float4*)&Fs[r][c4] = *(const float4*)&Ft[tile + r * 64 + c4];
            float4 sv = *(const float4*)&Sb[tile + r * 64 + c4];
            S2[c4 + 0][r] = sv.x;
            S2[c4 + 1][r] = sv.y;
            S2[c4 + 2][r] = sv.z;
            S2[c4 + 3][r] = sv.w;
        }
    }
    __syncthreads();
    float accO[4][4] = {};
    #pragma unroll 4
    for (int k = 0; k < 64; ++k) {
        float4 fv = *(const float4*)&Fs[k][a0];
        float4 sv = *(const float4*)&S2[k][b0];
        float fa[4] = {fv.x, fv.y, fv.z, fv.w};
        float sa[4] = {sv.x, sv.y, sv.z, sv.w};
        #pragma unroll
        for (int i = 0; i < 4; ++i)
            #pragma unroll
            for (int j = 0; j < 4; ++j)
                accO[i][j] = fmaf(fa[i], sa[j], accO[i][j]);
    }
    #pragma unroll
    for (int i = 0; i < 4; ++i) {
        size_t gi = (size_t)((c << 6) + a0 + i) * EE + h * DD + b0;
        float4 ev = *(const float4*)&vb[gi];
        float4 ov = {accO[i][0] + ev.x, accO[i][1] + ev.y,
                     accO[i][2] + ev.z, accO[i][3] + ev.w};
        *(float4*)&vb[gi] = ov;
    }
}

// ---------------------------------------------------------------------------
// Causal flash attention, bf16 MFMA; async reg-staged K/V prefetch (T14):
// issue tile c+1 global loads during tile c compute; regs -> LDS after
// barrier. Output bf16 for proj GEMM. Math order identical to round 8.
// ---------------------------------------------------------------------------
__global__ __launch_bounds__(256) void attn_mfma_kernel(
    const float* __restrict__ q, const float* __restrict__ k, const float* __restrict__ v,
    ushort* __restrict__ y)
{
    __shared__ __align__(16) unsigned short KsL[64 * KS];
    __shared__ __align__(16) unsigned short VtL[64 * KS];
    __shared__ __align__(16) unsigned short PsL[4][16 * KS];

    int h = blockIdx.y;
    int rb = ((int)gridDim.x - 1 - (int)blockIdx.x) * 64;
    int tid = threadIdx.x;
    int w = tid >> 6;
    int lane = tid & 63;
    int l16 = lane & 15;
    int lq = lane >> 4;
    int qr0 = rb + w * 16;

    bf16x8 qf[2];
    {
        const float* qrow = &q[(size_t)(qr0 + l16) * EE + h * DD];
        #pragma unroll
        for (int kk = 0; kk < 2; ++kk) {
            float4 v0 = *(const float4*)&qrow[kk * 32 + lq * 8];
            float4 v1 = *(const float4*)&qrow[kk * 32 + lq * 8 + 4];
            qf[kk][0] = (short)f2bf(v0.x); qf[kk][1] = (short)f2bf(v0.y);
            qf[kk][2] = (short)f2bf(v0.z); qf[kk][3] = (short)f2bf(v0.w);
            qf[kk][4] = (short)f2bf(v1.x); qf[kk][5] = (short)f2bf(v1.y);
            qf[kk][6] = (short)f2bf(v1.z); qf[kk][7] = (short)f2bf(v1.w);
        }
    }

    f32x4 oacc[4];
    #pragma unroll
    for (int dt = 0; dt < 4; ++dt) oacc[dt] = (f32x4){0.f, 0.f, 0.f, 0.f};
    float mrow[4] = {-3e38f, -3e38f, -3e38f, -3e38f};
    float lrow[4] = {0.f, 0.f, 0.f, 0.f};

    int ks_s = tid >> 2, ks_d0 = (tid & 3) << 4;
    int vt_s0 = (tid & 31) * 2, vt_dq = (tid >> 5) << 3;

    // prefetch registers: K 4xfloat4, V 2 rows x 2xfloat4
    float4 kreg[4], va0, va1, vb0r, vb1r;

#define ATT_ISSUE(c0)                                                          \
    {                                                                          \
        const float* krow = &k[(size_t)((c0) + ks_s) * EE + h * DD + ks_d0];   \
        kreg[0] = *(const float4*)&krow[0];                                    \
        kreg[1] = *(const float4*)&krow[4];                                    \
        kreg[2] = *(const float4*)&krow[8];                                    \
        kreg[3] = *(const float4*)&krow[12];                                   \
        const float* vr0 = &v[(size_t)((c0) + vt_s0) * EE + h * DD + vt_dq];   \
        const float* vr1 = vr0 + EE;                                           \
        va0 = *(const float4*)&vr0[0]; va1 = *(const float4*)&vr0[4];          \
        vb0r = *(const float4*)&vr1[0]; vb1r = *(const float4*)&vr1[4];        \
    }

    ATT_ISSUE(0)
    for (int c0 = 0; c0 <= rb; c0 += 64) {
        __syncthreads();          // prior tile's LDS reads complete
        // --- write staged regs to LDS (vmcnt wait lands here) ---
        {
            #pragma unroll
            for (int u = 0; u < 4; ++u) {
                bf16x4 pk = { (short)f2bf(kreg[u].x), (short)f2bf(kreg[u].y),
                              (short)f2bf(kreg[u].z), (short)f2bf(kreg[u].w) };
                *(bf16x4*)&KsL[ks_s * KS + ks_d0 + u * 4] = pk;
            }
            float va[8] = {va0.x, va0.y, va0.z, va0.w, va1.x, va1.y, va1.z, va1.w};
            float vbv[8] = {vb0r.x, vb0r.y, vb0r.z, vb0r.w, vb1r.x, vb1r.y, vb1r.z, vb1r.w};
            #pragma unroll
            for (int u = 0; u < 8; ++u) {
                unsigned pv = (unsigned)f2bf(va[u]) | ((unsigned)f2bf(vbv[u]) << 16);
                *(unsigned*)&VtL[(vt_dq + u) * KS + vt_s0] = pv;
            }
        }
        __syncthreads();          // tile visible to all waves
        if (c0 + 64 <= rb) ATT_ISSUE(c0 + 64)   // prefetch next (lands during compute)

        f32x4 sacc[4];
        #pragma unroll
        for (int ct = 0; ct < 4; ++ct) {
            bf16x8 b0 = *(bf16x8*)&KsL[(ct * 16 + l16) * KS + lq * 8];
            bf16x8 b1 = *(bf16x8*)&KsL[(ct * 16 + l16) * KS + 32 + lq * 8];
            f32x4 acc = {0.f, 0.f, 0.f, 0.f};
            acc = __builtin_amdgcn_mfma_f32_16x16x32_bf16(qf[0], b0, acc, 0, 0, 0);
            acc = __builtin_amdgcn_mfma_f32_16x16x32_bf16(qf[1], b1, acc, 0, 0, 0);
            sacc[ct] = acc;
        }

        float sv[4][4];
        float tmax[4] = {-3e38f, -3e38f, -3e38f, -3e38f};
        #pragma unroll
        for (int ct = 0; ct < 4; ++ct) {
            int col = c0 + ct * 16 + l16;
            #pragma unroll
            for (int r = 0; r < 4; ++r) {
                int row = qr0 + lq * 4 + r;
                float s = sacc[ct][r] * SCALE;
                if (col > row) s = -3e38f;
                sv[ct][r] = s;
                tmax[r] = fmaxf(tmax[r], s);
            }
        }
        #pragma unroll
        for (int off = 1; off < 16; off <<= 1) {
            #pragma unroll
            for (int r = 0; r < 4; ++r)
                tmax[r] = fmaxf(tmax[r], __shfl_xor(tmax[r], off));
        }
        float corr[4], psum[4];
        #pragma unroll
        for (int r = 0; r < 4; ++r) {
            float mn = fmaxf(mrow[r], tmax[r]);
            corr[r] = __expf(mrow[r] - mn);
            mrow[r] = mn;
            psum[r] = 0.f;
        }
        #pragma unroll
        for (int ct = 0; ct < 4; ++ct) {
            #pragma unroll
            for (int r = 0; r < 4; ++r) {
                float p = __expf(sv[ct][r] - mrow[r]);
                psum[r] += p;
                PsL[w][(lq * 4 + r) * KS + ct * 16 + l16] = f2bf(p);
            }
        }
        #pragma unroll
        for (int off = 1; off < 16; off <<= 1) {
            #pragma unroll
            for (int r = 0; r < 4; ++r)
                psum[r] += __shfl_xor(psum[r], off);
        }
        #pragma unroll
        for (int r = 0; r < 4; ++r)
            lrow[r] = lrow[r] * corr[r] + psum[r];
        #pragma unroll
        for (int dt = 0; dt < 4; ++dt) {
            #pragma unroll
            for (int r = 0; r < 4; ++r)
                oacc[dt][r] *= corr[r];
        }

        bf16x8 pa0 = *(bf16x8*)&PsL[w][l16 * KS + lq * 8];
        bf16x8 pa1 = *(bf16x8*)&PsL[w][l16 * KS + 32 + lq * 8];
        #pragma unroll
        for (int dt = 0; dt < 4; ++dt) {
            bf16x8 vv0 = *(bf16x8*)&VtL[(dt * 16 + l16) * KS + lq * 8];
            bf16x8 vv1 = *(bf16x8*)&VtL[(dt * 16 + l16) * KS + 32 + lq * 8];
            oacc[dt] = __builtin_amdgcn_mfma_f32_16x16x32_bf16(pa0, vv0, oacc[dt], 0, 0, 0);
            oacc[dt] = __builtin_amdgcn_mfma_f32_16x16x32_bf16(pa1, vv1, oacc[dt], 0, 0, 0);
        }
    }
#undef ATT_ISSUE

    float linv[4];
    #pragma unroll
    for (int r = 0; r < 4; ++r) linv[r] = 1.f / lrow[r];
    #pragma unroll
    for (int dt = 0; dt < 4; ++dt) {
        #pragma unroll
        for (int r = 0; r < 4; ++r) {
            int row = qr0 + lq * 4 + r;
            y[(size_t)row * EE + h * DD + dt * 16 + l16] = f2bf(oacc[dt][r] * linv[r]);
        }
    }
}

// ---------------------------------------------------------------------------
extern "C" void kernel_launch(void* const* d_in, const int* in_sizes, int n_in,
                              void* d_out, int out_size, void* d_ws, size_t ws_size,
                              hipStream_t stream)
{
    (void)in_sizes; (void)n_in; (void)out_size; (void)ws_size;
    const float* x      = (const float*)d_in[0];
    const float* w_attn = (const float*)d_in[1];
    const float* w_proj = (const float*)d_in[2];
    const float* qcw    = (const float*)d_in[3];
    const float* kcw    = (const float*)d_in[4];
    const float* vcw    = (const float*)d_in[5];
    const float* cosb   = (const float*)d_in[6];
    const float* sinb   = (const float*)d_in[7];
    const float* beta   = (const float*)d_in[8];
    const float* g      = (const float*)d_in[9];
    float* out = (float*)d_out;
    float* ws  = (float*)d_ws;

    const size_t TE = (size_t)TT * EE;
    float* buf0 = ws + 0 * TE;          // qkv -> Bt
    float* buf1 = ws + 1 * TE;          // qkv -> Ct -> ybf
    float* buf2 = ws + 2 * TE;          // qkv -> Ft -> wpT
    float* qb   = ws + 3 * TE;          // xbf -> q
    float* kb   = ws + 4 * TE;          // waT -> k
    float* vb   = ws + 5 * TE;          // v -> E -> O
    float* qkv  = buf0;
    ushort* xbf = (ushort*)qb;
    ushort* waT = (ushort*)kb;
    ushort* ybf = (ushort*)buf1;
    ushort* wpT = (ushort*)buf2;
    float* Sbuf = out;                  // d_out as S-tile scratch

    cvt_bf16_kernel<<<TT * EE / 2048, 256, 0, stream>>>(x, xbf);
    cvt_transpose_kernel<<<dim3(NN / 64, EE / 64), 256, 0, stream>>>(w_attn, waT, EE, NN);
    gemm_bf16<128, 128><<<dim3(NN / 128, TT / 128), 256, 0, stream>>>(
        xbf, waT, qkv, TT, NN, EE);
    conv_rope_kernel<<<dim3(TT / 4, HH, 3), dim3(64, 4), 0, stream>>>(
        qkv, qcw, kcw, vcw, cosb, sinb, qb, kb, vb);
    chunk_prep_kernel<<<dim3(NCH, HH), 256, 0, stream>>>(qb, kb, vb, beta, g, buf0, buf1, buf2);
    delta_scan4_kernel<<<dim3(CPH, HH), 256, 0, stream>>>(buf0, buf1, g, Sbuf);
    delta_apply_kernel<<<dim3(NCH, HH), 256, 0, stream>>>(Sbuf, buf2, vb);
    cvt_transpose_kernel<<<dim3(EE / 64, EE / 64), 256, 0, stream>>>(w_proj, wpT, EE, EE);
    attn_mfma_kernel<<<dim3(TT / 64, HH), 256, 0, stream>>>(qb, kb, vb, ybf);
    gemm_bf16<64, 64><<<dim3(EE / 64, TT / 64), 256, 0, stream>>>(
        ybf, wpT, out, TT, EE, EE);
}

// Round 10
// 282.917 us; speedup vs baseline: 8.1783x; 1.0330x over previous
//
#include <hip/hip_runtime.h>
#include <math.h>

#define TT 2048
#define HH 16
#define DD 64
#define EE 1024
#define NN 3072
#define CHUNK 64
#define NCH (TT / CHUNK)
#define SCALE 0.125f
#define KS 72   // attn LDS row stride (bf16): conflict-free b128
#define CPH 8   // column-split blocks per head in delta scan

typedef short bf16x8 __attribute__((ext_vector_type(8)));
typedef short bf16x4 __attribute__((ext_vector_type(4)));
typedef float f32x4 __attribute__((ext_vector_type(4)));
typedef unsigned short ushort;
typedef const __attribute__((address_space(1))) unsigned int* gptr_t;
typedef __attribute__((address_space(3))) unsigned int* lptr_t;

__device__ __forceinline__ unsigned short f2bf(float x) {
    union { float f; unsigned u; } un; un.f = x;
    unsigned r = un.u + 0x7FFFu + ((un.u >> 16) & 1u);
    return (unsigned short)(r >> 16);
}

// XOR slot swizzle for 64-float rows (4-float slots, key = row bits 2..4)
__device__ __forceinline__ int swz(int r, int c) {
    return (r << 6) + ((((c >> 2) ^ ((r >> 2) & 7)) << 2) | (c & 3));
}
__device__ __forceinline__ int swz4(int r, int c4) {
    return (r << 6) + (((c4 >> 2) ^ ((r >> 2) & 7)) << 2);
}

// ---------------------------------------------------------------------------
// fp32 -> bf16 elementwise convert (x)
// ---------------------------------------------------------------------------
__global__ __launch_bounds__(256) void cvt_bf16_kernel(
    const float* __restrict__ in, ushort* __restrict__ out)
{
    int i = ((int)blockIdx.x * 256 + (int)threadIdx.x) << 3;
    float4 a = *(const float4*)&in[i];
    float4 b = *(const float4*)&in[i + 4];
    bf16x8 o;
    o[0] = (short)f2bf(a.x); o[1] = (short)f2bf(a.y);
    o[2] = (short)f2bf(a.z); o[3] = (short)f2bf(a.w);
    o[4] = (short)f2bf(b.x); o[5] = (short)f2bf(b.y);
    o[6] = (short)f2bf(b.z); o[7] = (short)f2bf(b.w);
    *(bf16x8*)&out[i] = o;
}

// ---------------------------------------------------------------------------
// fp32 [K][N] -> bf16 [N][K] convert + transpose (weights)
// ---------------------------------------------------------------------------
__global__ __launch_bounds__(256) void cvt_transpose_kernel(
    const float* __restrict__ W, ushort* __restrict__ WT, int K, int N)
{
    __shared__ float Ls[64][65];
    int n0 = blockIdx.x * 64, k0 = blockIdx.y * 64;
    int tid = threadIdx.x;
    int lr = tid >> 4, lc4 = (tid & 15) << 2;
    #pragma unroll
    for (int m = 0; m < 4; ++m) {
        int r = lr + m * 16;
        float4 v = *(const float4*)&W[(size_t)(k0 + r) * N + n0 + lc4];
        Ls[r][lc4 + 0] = v.x; Ls[r][lc4 + 1] = v.y;
        Ls[r][lc4 + 2] = v.z; Ls[r][lc4 + 3] = v.w;
    }
    __syncthreads();
    int n = tid >> 2, kb = (tid & 3) << 4;
    bf16x8 o0, o1;
    #pragma unroll
    for (int j = 0; j < 8; ++j) o0[j] = (short)f2bf(Ls[kb + j][n]);
    #pragma unroll
    for (int j = 0; j < 8; ++j) o1[j] = (short)f2bf(Ls[kb + 8 + j][n]);
    *(bf16x8*)&WT[(size_t)(n0 + n) * K + k0 + kb] = o0;
    *(bf16x8*)&WT[(size_t)(n0 + n) * K + k0 + kb + 8] = o1;
}

// ---------------------------------------------------------------------------
// bf16 MFMA GEMM: C(fp32)[M][N] = A(bf16)[M][K] * BT(bf16)[N][K]^T
// ---------------------------------------------------------------------------
template<int BM, int BN>
__global__ __launch_bounds__(256) void gemm_bf16(
    const ushort* __restrict__ A, const ushort* __restrict__ BT,
    float* __restrict__ C, int M, int N, int K)
{
    constexpr int MT = BM / 32;
    constexpr int NT = BN / 32;
    constexpr int AIT = BM * 64 / 2048;
    constexpr int BIT = BN * 64 / 2048;
    __shared__ __align__(16) ushort Asl[2][BM * 64];
    __shared__ __align__(16) ushort Bsl[2][BN * 64];
    const int tid = threadIdx.x;
    const int lane = tid & 63, w = tid >> 6;
    const int wm = w >> 1, wn = w & 1;
    const int l16 = lane & 15, lq = lane >> 4;
    const int row0 = blockIdx.y * BM, col0 = blockIdx.x * BN;
    const int wvb = w << 9;

    f32x4 acc[MT][NT];
    #pragma unroll
    for (int i = 0; i < MT; ++i)
        #pragma unroll
        for (int j = 0; j < NT; ++j)
            acc[i][j] = (f32x4){0.f, 0.f, 0.f, 0.f};

#define STAGE_TILE(buf, k0)                                                    \
    {                                                                          \
        _Pragma("unroll")                                                      \
        for (int u = 0; u < AIT; ++u) {                                        \
            int idx = u * 256 + tid;                                           \
            int r = idx >> 3, s = idx & 7;                                     \
            const ushort* srcp =                                               \
                &A[(size_t)(row0 + r) * K + (k0) + ((s ^ (r & 7)) << 3)];      \
            __builtin_amdgcn_global_load_lds((gptr_t)srcp,                     \
                (lptr_t)&Asl[buf][(u << 11) + wvb], 16, 0, 0);                 \
        }                                                                      \
        _Pragma("unroll")                                                      \
        for (int u = 0; u < BIT; ++u) {                                        \
            int idx = u * 256 + tid;                                           \
            int r = idx >> 3, s = idx & 7;                                     \
            const ushort* srcp =                                               \
                &BT[(size_t)(col0 + r) * K + (k0) + ((s ^ (r & 7)) << 3)];     \
            __builtin_amdgcn_global_load_lds((gptr_t)srcp,                     \
                (lptr_t)&Bsl[buf][(u << 11) + wvb], 16, 0, 0);                 \
        }                                                                      \
    }

    const int nK = K >> 6;
    STAGE_TILE(0, 0)
    for (int kt = 0; kt < nK; ++kt) {
        __syncthreads();                       // stage(kt) drained + visible
        if (kt + 1 < nK) STAGE_TILE((kt + 1) & 1, (kt + 1) << 6)
        const int cb = kt & 1;
        #pragma unroll
        for (int kk = 0; kk < 2; ++kk) {
            bf16x8 afr[MT], bfr[NT];
            #pragma unroll
            for (int mt = 0; mt < MT; ++mt) {
                int rr = wm * (BM / 2) + mt * 16 + l16;
                afr[mt] = *(bf16x8*)&Asl[cb][rr * 64 +
                           (((kk * 4 + lq) ^ (rr & 7)) << 3)];
            }
            #pragma unroll
            for (int nt = 0; nt < NT; ++nt) {
                int cc = wn * (BN / 2) + nt * 16 + l16;
                bfr[nt] = *(bf16x8*)&Bsl[cb][cc * 64 +
                           (((kk * 4 + lq) ^ (cc & 7)) << 3)];
            }
            #pragma unroll
            for (int mt = 0; mt < MT; ++mt)
                #pragma unroll
                for (int nt = 0; nt < NT; ++nt)
                    acc[mt][nt] = __builtin_amdgcn_mfma_f32_16x16x32_bf16(
                        afr[mt], bfr[nt], acc[mt][nt], 0, 0, 0);
        }
    }
#undef STAGE_TILE

    #pragma unroll
    for (int mt = 0; mt < MT; ++mt) {
        #pragma unroll
        for (int nt = 0; nt < NT; ++nt) {
            int col = col0 + wn * (BN / 2) + nt * 16 + l16;
            #pragma unroll
            for (int r = 0; r < 4; ++r) {
                int row = row0 + wm * (BM / 2) + mt * 16 + lq * 4 + r;
                C[(size_t)row * N + col] = acc[mt][nt][r];
            }
        }
    }
}

// ---------------------------------------------------------------------------
// Causal depthwise conv1d (DC=4) + SiLU, then RoPE for q,k; v plain.
// ---------------------------------------------------------------------------
__global__ __launch_bounds__(256) void conv_rope_kernel(
    const float* __restrict__ qkv,
    const float* __restrict__ qw, const float* __restrict__ kw, const float* __restrict__ vw,
    const float* __restrict__ cosb, const float* __restrict__ sinb,
    float* __restrict__ qo, float* __restrict__ ko, float* __restrict__ vo)
{
    int j = blockIdx.z;
    const float* w = (j == 0) ? qw : (j == 1) ? kw : vw;
    float* dst     = (j == 0) ? qo : (j == 1) ? ko : vo;
    int d  = threadIdx.x;
    int tl = threadIdx.y;
    int t  = blockIdx.x * 4 + tl;
    int h  = blockIdx.y;
    int c  = h * DD + d;
    int n  = h * 192 + j * 64 + d;
    float acc = 0.f;
    #pragma unroll
    for (int i = 0; i < 4; ++i) {
        int tt = t - 3 + i;
        if (tt >= 0) acc = fmaf(qkv[(size_t)tt * NN + n], w[c * 4 + i], acc);
    }
    float yv = acc / (1.f + __expf(-acc));
    if (j == 2) { dst[t * EE + c] = yv; return; }
    __shared__ float sh[4][64];
    sh[tl][d] = yv;
    __syncthreads();
    int dh = d & 31;
    float cc = cosb[t * 32 + dh];
    float ss = sinb[t * 32 + dh];
    float outv;
    if (d < 32) outv = yv * cc - sh[tl][d + 32] * ss;
    else        outv = yv * cc + sh[tl][d - 32] * ss;
    dst[t * EE + c] = outv;
}

// ---------------------------------------------------------------------------
// Chunked gated delta rule, phase 1 (parallel over 32 chunks x 16 heads).
// ---------------------------------------------------------------------------
__global__ __launch_bounds__(256) void chunk_prep_kernel(
    const float* __restrict__ qb, const float* __restrict__ kb, float* __restrict__ vb,
    const float* __restrict__ beta, const float* __restrict__ g,
    float* __restrict__ Bt, float* __restrict__ Ct, float* __restrict__ Ft)
{
    __shared__ __align__(16) float Kc[4096];   // K -> K~
    __shared__ __align__(16) float Qx[4096];   // Q -> Xk
    __shared__ __align__(16) float Vx[4096];   // V -> Xv
    __shared__ __align__(16) float Tm[4096];   // M (lower) + A~ (upper+diag)
    __shared__ float Gs[64], bs[64];
    int c = blockIdx.x, h = blockIdx.y;
    int tid = threadIdx.x;
    int t0 = c * CHUNK;

    {
        int row = tid >> 4, c4 = (tid & 15) << 2;
        #pragma unroll
        for (int m = 0; m < 4; ++m) {
            int r = row + m * 16;
            size_t gidx = (size_t)(t0 + r) * EE + h * DD + c4;
            *(float4*)&Kc[swz4(r, c4)] = *(const float4*)&kb[gidx];
            *(float4*)&Qx[swz4(r, c4)] = *(const float4*)&qb[gidx];
            *(float4*)&Vx[swz4(r, c4)] = *(const float4*)&vb[gidx];
        }
    }
    if (tid < 64) {
        float x = g[(t0 + tid) * HH + h];
        #pragma unroll
        for (int off = 1; off < 64; off <<= 1) {
            float y = __shfl_up(x, off);
            if (tid >= off) x *= y;
        }
        Gs[tid] = x;
        bs[tid] = beta[(t0 + tid) * HH + h];
    }
    __syncthreads();

    int ty = tid >> 4, tx = tid & 15;
    int a0 = ty << 2, b0 = tx << 2;
    float dkk[4][4] = {}, dqk[4][4] = {};
    #pragma unroll 4
    for (int j4 = 0; j4 < 64; j4 += 4) {
        float4 kt[4], ks[4], qt[4];
        #pragma unroll
        for (int i = 0; i < 4; ++i) kt[i] = *(const float4*)&Kc[swz4(a0 + i, j4)];
        #pragma unroll
        for (int j = 0; j < 4; ++j) ks[j] = *(const float4*)&Kc[swz4(b0 + j, j4)];
        #pragma unroll
        for (int i = 0; i < 4; ++i) qt[i] = *(const float4*)&Qx[swz4(a0 + i, j4)];
        #pragma unroll
        for (int i = 0; i < 4; ++i)
            #pragma unroll
            for (int j = 0; j < 4; ++j) {
                float d1 = dkk[i][j];
                d1 = fmaf(kt[i].w, ks[j].w, d1);
                d1 = fmaf(kt[i].z, ks[j].z, d1);
                d1 = fmaf(kt[i].y, ks[j].y, d1);
                d1 = fmaf(kt[i].x, ks[j].x, d1);
                dkk[i][j] = d1;
                float d2 = dqk[i][j];
                d2 = fmaf(qt[i].w, ks[j].w, d2);
                d2 = fmaf(qt[i].z, ks[j].z, d2);
                d2 = fmaf(qt[i].y, ks[j].y, d2);
                d2 = fmaf(qt[i].x, ks[j].x, d2);
                dqk[i][j] = d2;
            }
    }
    __syncthreads();
    #pragma unroll
    for (int i = 0; i < 4; ++i) {
        int t = a0 + i;
        #pragma unroll
        for (int j = 0; j < 4; ++j) {
            int s = b0 + j;
            float gr = Gs[t] / Gs[s];
            if (s < t)  Tm[swz(t, s)] = bs[t] * gr * dkk[i][j];
            if (s <= t) Tm[swz(s, t)] = SCALE * gr * dqk[i][j];
        }
    }
    __syncthreads();

    if (tid < 128) {
        int col = tid & 63;
        int wK = tid >> 6;
        float* Xp = wK ? Qx : Vx;
        #pragma unroll 1
        for (int t = 0; t < 64; ++t) {
            float acc = wK ? (bs[t] * Gs[t] * Kc[swz(t, col)])
                           : (bs[t] * Vx[swz(t, col)]);
            int t4 = t & ~3;
            for (int s4 = 0; s4 < t4; s4 += 4) {
                float4 mp = *(const float4*)&Tm[swz4(t, s4)];
                acc = fmaf(-mp.x, Xp[swz(s4 + 0, col)], acc);
                acc = fmaf(-mp.y, Xp[swz(s4 + 1, col)], acc);
                acc = fmaf(-mp.z, Xp[swz(s4 + 2, col)], acc);
                acc = fmaf(-mp.w, Xp[swz(s4 + 3, col)], acc);
            }
            for (int s = t4; s < t; ++s)
                acc = fmaf(-Tm[swz(t, s)], Xp[swz(s, col)], acc);
            Xp[swz(t, col)] = acc;
        }
    }
    __syncthreads();

    {
        int r = tid & 63, qd = tid >> 6;
        float ratio = Gs[63] / Gs[r];
        #pragma unroll
        for (int jj = 0; jj < 4; ++jj) {
            int c4 = qd * 16 + jj * 4;
            float4 vv = *(const float4*)&Kc[swz4(r, c4)];
            vv.x *= ratio; vv.y *= ratio; vv.z *= ratio; vv.w *= ratio;
            *(float4*)&Kc[swz4(r, c4)] = vv;
        }
    }
    __syncthreads();

    float4 qe[4];
    #pragma unroll
    for (int j = 0; j < 4; ++j)
        qe[j] = *(const float4*)&qb[(size_t)(t0 + b0 + j) * EE + h * DD + a0];

    float aB[4][4] = {}, aC[4][4] = {}, aF[4][4] = {}, aE[4][4] = {};
    #pragma unroll 2
    for (int s = 0; s < 64; ++s) {
        float4 xkA4 = *(const float4*)&Qx[swz4(s, a0)];
        float4 kcB4 = *(const float4*)&Kc[swz4(s, b0)];
        float4 kcA4 = *(const float4*)&Kc[swz4(s, a0)];
        float4 xvB4 = *(const float4*)&Vx[swz4(s, b0)];
        float4 taA4 = *(const float4*)&Tm[swz4(s, a0)];
        float4 taB4 = *(const float4*)&Tm[swz4(s, b0)];
        float xkA[4] = {xkA4.x, xkA4.y, xkA4.z, xkA4.w};
        float kcB[4] = {kcB4.x, kcB4.y, kcB4.z, kcB4.w};
        float kcA[4] = {kcA4.x, kcA4.y, kcA4.z, kcA4.w};
        float xvB[4] = {xvB4.x, xvB4.y, xvB4.z, xvB4.w};
        float atA[4], atB[4];
        atA[0] = (s <= a0 + 0) ? taA4.x : 0.f;
        atA[1] = (s <= a0 + 1) ? taA4.y : 0.f;
        atA[2] = (s <= a0 + 2) ? taA4.z : 0.f;
        atA[3] = (s <= a0 + 3) ? taA4.w : 0.f;
        atB[0] = (s <= b0 + 0) ? taB4.x : 0.f;
        atB[1] = (s <= b0 + 1) ? taB4.y : 0.f;
        atB[2] = (s <= b0 + 2) ? taB4.z : 0.f;
        atB[3] = (s <= b0 + 3) ? taB4.w : 0.f;
        #pragma unroll
        for (int i = 0; i < 4; ++i)
            #pragma unroll
            for (int j = 0; j < 4; ++j) {
                aB[i][j] = fmaf(xkA[i], kcB[j], aB[i][j]);
                aC[i][j] = fmaf(kcA[i], xvB[j], aC[i][j]);
                aF[i][j] = fmaf(xkA[i], atB[j], aF[i][j]);
                aE[i][j] = fmaf(atA[i], xvB[j], aE[i][j]);
            }
    }
    size_t tile = ((size_t)(c * HH + h)) << 12;
    #pragma unroll
    for (int i = 0; i < 4; ++i) {
        int a = a0 + i;
        float4 wB = {aB[i][0], aB[i][1], aB[i][2], aB[i][3]};
        float4 wC = {aC[i][0], aC[i][1], aC[i][2], aC[i][3]};
        float4 wF;
        wF.x = SCALE * Gs[b0 + 0] * qe[0][i] - aF[i][0];
        wF.y = SCALE * Gs[b0 + 1] * qe[1][i] - aF[i][1];
        wF.z = SCALE * Gs[b0 + 2] * qe[2][i] - aF[i][2];
        wF.w = SCALE * Gs[b0 + 3] * qe[3][i] - aF[i][3];
        float4 wE = {aE[i][0], aE[i][1], aE[i][2], aE[i][3]};
        *(float4*)&Bt[tile + a * 64 + b0] = wB;
        *(float4*)&Ct[tile + a * 64 + b0] = wC;
        *(float4*)&Ft[tile + a * 64 + b0] = wF;
        *(float4*)&vb[(size_t)(t0 + a) * EE + h * DD + b0] = wE;
    }
}

// ---------------------------------------------------------------------------
// Delta rule serial S-chain, column-split: grid (CPH, HH).
// ---------------------------------------------------------------------------
__global__ __launch_bounds__(256) void delta_scan4_kernel(
    const float* __restrict__ Bt, const float* __restrict__ Ct,
    const float* __restrict__ g, float* __restrict__ Sout)
{
    __shared__ __align__(16) float Bsb[2][4096];
    __shared__ __align__(16) float Csb[2][512];
    __shared__ float Ss[64][10];
    __shared__ float GCs[NCH];
    int p = blockIdx.x, h = blockIdx.y;
    int bo = p * 8;
    int tid = threadIdx.x;
    int a = tid & 63;
    int w = tid >> 6;
    int j0 = w * 2;

    {
        float pr = 1.f;
        int t0 = tid * 8;
        #pragma unroll
        for (int j = 0; j < 8; ++j) pr *= g[(t0 + j) * HH + h];
        pr *= __shfl_xor(pr, 1);
        pr *= __shfl_xor(pr, 2);
        pr *= __shfl_xor(pr, 4);
        GCs[tid >> 3] = pr;
        Ss[a][j0] = 0.f;
        Ss[a][j0 + 1] = 0.f;
    }

#define STG4(buf, cc)                                                          \
    {                                                                          \
        size_t tb = ((size_t)((cc) * HH + h)) << 12;                           \
        _Pragma("unroll")                                                      \
        for (int u = 0; u < 4; ++u) {                                          \
            int fi = ((u << 8) + tid) << 2;                                    \
            int fb = ((u << 8) + (tid & 192)) << 2;                            \
            __builtin_amdgcn_global_load_lds((gptr_t)&Bt[tb + fi],             \
                (lptr_t)&Bsb[buf][fb], 16, 0, 0);                              \
        }                                                                      \
        if (tid < 128) {                                                       \
            size_t cfi = tb + ((size_t)(tid >> 1) << 6) + bo + ((tid & 1) << 2); \
            __builtin_amdgcn_global_load_lds((gptr_t)&Ct[cfi],                 \
                (lptr_t)&Csb[buf][(tid & 64) << 2], 16, 0, 0);                 \
        }                                                                      \
    }

    STG4(0, 0)
    for (int c = 0; c < NCH; ++c) {
        __syncthreads();
        if (c + 1 < NCH) STG4((c + 1) & 1, c + 1)
        const float* Bsp = Bsb[c & 1];
        const float* Csp = Csb[c & 1];
        float gc = GCs[c];
        size_t tile = ((size_t)(c * HH + h)) << 12;
        float s0 = Ss[a][j0], s1 = Ss[a][j0 + 1];
        Sout[tile + (size_t)(bo + j0) * 64 + a] = s0;
        Sout[tile + (size_t)(bo + j0 + 1) * 64 + a] = s1;
        float p0 = 0.f, p1 = 0.f;
        #pragma unroll 4
        for (int k = 0; k < 64; ++k) {
            float bk = Bsp[k * 64 + a];
            float2 sv = *(const float2*)&Ss[k][j0];
            p0 = fmaf(bk, sv.x, p0);
            p1 = fmaf(bk, sv.y, p1);
        }
        __syncthreads();
        float c0v = Csp[a * 8 + j0], c1v = Csp[a * 8 + j0 + 1];
        Ss[a][j0]     = fmaf(gc, s0, c0v - p0);
        Ss[a][j0 + 1] = fmaf(gc, s1, c1v - p1);
    }
#undef STG4
}

// ---------------------------------------------------------------------------
// Delta rule parallel output map: O_c = F_c.S_c + E_c. grid (NCH, HH).
// ---------------------------------------------------------------------------
__global__ __launch_bounds__(256) void delta_apply_kernel(
    const float* __restrict__ Sb, const float* __restrict__ Ft,
    float* __restrict__ vb)
{
    __shared__ float Fs[64][64];
    __shared__ float S2[64][68];
    int c = blockIdx.x, h = blockIdx.y;
    int tid = threadIdx.x;
    int tx = tid & 15, ty = tid >> 4;
    int a0 = ty << 2, b0 = tx << 2;
    size_t tile = ((size_t)(c * HH + h)) << 12;
    {
        int row = tid >> 4, c4 = (tid & 15) << 2;
        #pragma unroll
        for (int m = 0; m < 4; ++m) {
            int r = row + m * 16;
            *(float4*)&Fs[r][c4] = *(const float4*)&Ft[tile + r * 64 + c4];
            float4 sv = *(const float4*)&Sb[tile + r * 64 + c4];
            S2[c4 + 0][r] = sv.x;
            S2[c4 + 1][r] = sv.y;
            S2[c4 + 2][r] = sv.z;
            S2[c4 + 3][r] = sv.w;
        }
    }
    __syncthreads();
    float accO[4][4] = {};
    #pragma unroll 4
    for (int k = 0; k < 64; ++k) {
        float4 fv = *(const float4*)&Fs[k][a0];
        float4 sv = *(const float4*)&S2[k][b0];
        float fa[4] = {fv.x, fv.y, fv.z, fv.w};
        float sa[4] = {sv.x, sv.y, sv.z, sv.w};
        #pragma unroll
        for (int i = 0; i < 4; ++i)
            #pragma unroll
            for (int j = 0; j < 4; ++j)
                accO[i][j] = fmaf(fa[i], sa[j], accO[i][j]);
    }
    #pragma unroll
    for (int i = 0; i < 4; ++i) {
        size_t gi = (size_t)((c << 6) + a0 + i) * EE + h * DD + b0;
        float4 ev = *(const float4*)&vb[gi];
        float4 ov = {accO[i][0] + ev.x, accO[i][1] + ev.y,
                     accO[i][2] + ev.z, accO[i][3] + ev.w};
        *(float4*)&vb[gi] = ov;
    }
}

// ---------------------------------------------------------------------------
// Causal flash attention, bf16 MFMA, swapped-operand QK^T (S^T layout):
// lane owns one q-row (q = qr0+l16) -> scalar m/l, 2-shuffle row reduce,
// in-lane P packing (4 ds_write_b64 + 2 ds_read_b128 bridge).
// Async reg-staged K/V prefetch (T14). Output bf16 for proj GEMM.
// ---------------------------------------------------------------------------
__global__ __launch_bounds__(256) void attn_mfma_kernel(
    const float* __restrict__ q, const float* __restrict__ k, const float* __restrict__ v,
    ushort* __restrict__ y)
{
    __shared__ __align__(16) unsigned short KsL[64 * KS];
    __shared__ __align__(16) unsigned short VtL[64 * KS];
    __shared__ __align__(16) unsigned int PL[4][16 * 36];  // packed P, stride 36 u32

    int h = blockIdx.y;
    int rb = ((int)gridDim.x - 1 - (int)blockIdx.x) * 64;
    int tid = threadIdx.x;
    int w = tid >> 6;
    int lane = tid & 63;
    int l16 = lane & 15;
    int lq = lane >> 4;
    int qr0 = rb + w * 16;
    unsigned* PLw = PL[w];

    bf16x8 qf[2];
    {
        const float* qrow = &q[(size_t)(qr0 + l16) * EE + h * DD];
        #pragma unroll
        for (int kk = 0; kk < 2; ++kk) {
            float4 v0 = *(const float4*)&qrow[kk * 32 + lq * 8];
            float4 v1 = *(const float4*)&qrow[kk * 32 + lq * 8 + 4];
            qf[kk][0] = (short)f2bf(v0.x); qf[kk][1] = (short)f2bf(v0.y);
            qf[kk][2] = (short)f2bf(v0.z); qf[kk][3] = (short)f2bf(v0.w);
            qf[kk][4] = (short)f2bf(v1.x); qf[kk][5] = (short)f2bf(v1.y);
            qf[kk][6] = (short)f2bf(v1.z); qf[kk][7] = (short)f2bf(v1.w);
        }
    }

    f32x4 oacc[4];
    #pragma unroll
    for (int dt = 0; dt < 4; ++dt) oacc[dt] = (f32x4){0.f, 0.f, 0.f, 0.f};
    float mrow = -3e38f, lrow = 0.f;
    const int qrow_i = qr0 + l16;

    int ks_s = tid >> 2, ks_d0 = (tid & 3) << 4;
    int vt_s0 = (tid & 31) * 2, vt_dq = (tid >> 5) << 3;

    float4 kreg[4], va0, va1, vb0r, vb1r;

#define ATT_ISSUE(c0)                                                          \
    {                                                                          \
        const float* krow = &k[(size_t)((c0) + ks_s) * EE + h * DD + ks_d0];   \
        kreg[0] = *(const float4*)&krow[0];                                    \
        kreg[1] = *(const float4*)&krow[4];                                    \
        kreg[2] = *(const float4*)&krow[8];                                    \
        kreg[3] = *(const float4*)&krow[12];                                   \
        const float* vr0 = &v[(size_t)((c0) + vt_s0) * EE + h * DD + vt_dq];   \
        const float* vr1 = vr0 + EE;                                           \
        va0 = *(const float4*)&vr0[0]; va1 = *(const float4*)&vr0[4];          \
        vb0r = *(const float4*)&vr1[0]; vb1r = *(const float4*)&vr1[4];        \
    }

    ATT_ISSUE(0)
    for (int c0 = 0; c0 <= rb; c0 += 64) {
        __syncthreads();          // prior tile's LDS reads complete
        {
            #pragma unroll
            for (int u = 0; u < 4; ++u) {
                bf16x4 pk4 = { (short)f2bf(kreg[u].x), (short)f2bf(kreg[u].y),
                               (short)f2bf(kreg[u].z), (short)f2bf(kreg[u].w) };
                *(bf16x4*)&KsL[ks_s * KS + ks_d0 + u * 4] = pk4;
            }
            float va[8] = {va0.x, va0.y, va0.z, va0.w, va1.x, va1.y, va1.z, va1.w};
            float vbv[8] = {vb0r.x, vb0r.y, vb0r.z, vb0r.w, vb1r.x, vb1r.y, vb1r.z, vb1r.w};
            #pragma unroll
            for (int u = 0; u < 8; ++u) {
                unsigned pv = (unsigned)f2bf(va[u]) | ((unsigned)f2bf(vbv[u]) << 16);
                *(unsigned*)&VtL[(vt_dq + u) * KS + vt_s0] = pv;
            }
        }
        __syncthreads();          // tile visible to all waves
        if (c0 + 64 <= rb) ATT_ISSUE(c0 + 64)

        // --- S^T = K Q^T (A = K-frag, B = Q-frag; same LDS reads as before) ---
        f32x4 sacc[4];
        #pragma unroll
        for (int ct = 0; ct < 4; ++ct) {
            bf16x8 ka0 = *(bf16x8*)&KsL[(ct * 16 + l16) * KS + lq * 8];
            bf16x8 ka1 = *(bf16x8*)&KsL[(ct * 16 + l16) * KS + 32 + lq * 8];
            f32x4 acc = {0.f, 0.f, 0.f, 0.f};
            acc = __builtin_amdgcn_mfma_f32_16x16x32_bf16(ka0, qf[0], acc, 0, 0, 0);
            acc = __builtin_amdgcn_mfma_f32_16x16x32_bf16(ka1, qf[1], acc, 0, 0, 0);
            sacc[ct] = acc;
        }

        // --- scale + causal (q = qr0+l16 per lane; s = c0+ct*16+lq*4+r) ---
        float sv[4][4];
        float tm = -3e38f;
        #pragma unroll
        for (int ct = 0; ct < 4; ++ct) {
            int sbase = c0 + ct * 16 + lq * 4;
            #pragma unroll
            for (int r = 0; r < 4; ++r) {
                float s = sacc[ct][r] * SCALE;
                if (sbase + r > qrow_i) s = -3e38f;
                sv[ct][r] = s;
                tm = fmaxf(tm, s);
            }
        }
        tm = fmaxf(tm, __shfl_xor(tm, 16));
        tm = fmaxf(tm, __shfl_xor(tm, 32));
        float mn = fmaxf(mrow, tm);
        float corr = __expf(mrow - mn);
        mrow = mn;

        float ps = 0.f;
        #pragma unroll
        for (int ct = 0; ct < 4; ++ct) {
            float p0 = __expf(sv[ct][0] - mn);
            float p1 = __expf(sv[ct][1] - mn);
            float p2 = __expf(sv[ct][2] - mn);
            float p3 = __expf(sv[ct][3] - mn);
            ps += (p0 + p1) + (p2 + p3);
            uint2 wv;
            wv.x = (unsigned)f2bf(p0) | ((unsigned)f2bf(p1) << 16);
            wv.y = (unsigned)f2bf(p2) | ((unsigned)f2bf(p3) << 16);
            *(uint2*)&PLw[l16 * 36 + ct * 8 + lq * 2] = wv;   // ds_write_b64
        }
        ps += __shfl_xor(ps, 16);
        ps += __shfl_xor(ps, 32);
        lrow = lrow * corr + ps;

        // --- rescale O (O rows are q' = qr0 + lq*4 + r; broadcast corr) ---
        float corr_o[4];
        #pragma unroll
        for (int r = 0; r < 4; ++r)
            corr_o[r] = __shfl(corr, (lane & 48) + lq * 4 + r);
        #pragma unroll
        for (int dt = 0; dt < 4; ++dt) {
            #pragma unroll
            for (int r = 0; r < 4; ++r)
                oacc[dt][r] *= corr_o[r];
        }

        // --- O += P V (A = packed P from LDS, B = V^T) ---
        bf16x8 pa0 = *(bf16x8*)&PLw[l16 * 36 + lq * 4];        // ds_read_b128
        bf16x8 pa1 = *(bf16x8*)&PLw[l16 * 36 + 16 + lq * 4];
        #pragma unroll
        for (int dt = 0; dt < 4; ++dt) {
            bf16x8 vv0 = *(bf16x8*)&VtL[(dt * 16 + l16) * KS + lq * 8];
            bf16x8 vv1 = *(bf16x8*)&VtL[(dt * 16 + l16) * KS + 32 + lq * 8];
            oacc[dt] = __builtin_amdgcn_mfma_f32_16x16x32_bf16(pa0, vv0, oacc[dt], 0, 0, 0);
            oacc[dt] = __builtin_amdgcn_mfma_f32_16x16x32_bf16(pa1, vv1, oacc[dt], 0, 0, 0);
        }
    }
#undef ATT_ISSUE

    float li = 1.f / lrow;
    float linv_o[4];
    #pragma unroll
    for (int r = 0; r < 4; ++r)
        linv_o[r] = __shfl(li, (lane & 48) + lq * 4 + r);
    #pragma unroll
    for (int dt = 0; dt < 4; ++dt) {
        #pragma unroll
        for (int r = 0; r < 4; ++r) {
            int row = qr0 + lq * 4 + r;
            y[(size_t)row * EE + h * DD + dt * 16 + l16] = f2bf(oacc[dt][r] * linv_o[r]);
        }
    }
}

// ---------------------------------------------------------------------------
extern "C" void kernel_launch(void* const* d_in, const int* in_sizes, int n_in,
                              void* d_out, int out_size, void* d_ws, size_t ws_size,
                              hipStream_t stream)
{
    (void)in_sizes; (void)n_in; (void)out_size; (void)ws_size;
    const float* x      = (const float*)d_in[0];
    const float* w_attn = (const float*)d_in[1];
    const float* w_proj = (const float*)d_in[2];
    const float* qcw    = (const float*)d_in[3];
    const float* kcw    = (const float*)d_in[4];
    const float* vcw    = (const float*)d_in[5];
    const float* cosb   = (const float*)d_in[6];
    const float* sinb   = (const float*)d_in[7];
    const float* beta   = (const float*)d_in[8];
    const float* g      = (const float*)d_in[9];
    float* out = (float*)d_out;
    float* ws  = (float*)d_ws;

    const size_t TE = (size_t)TT * EE;
    float* buf0 = ws + 0 * TE;          // qkv -> Bt
    float* buf1 = ws + 1 * TE;          // qkv -> Ct -> ybf
    float* buf2 = ws + 2 * TE;          // qkv -> Ft -> wpT
    float* qb   = ws + 3 * TE;          // xbf -> q
    float* kb   = ws + 4 * TE;          // waT -> k
    float* vb   = ws + 5 * TE;          // v -> E -> O
    float* qkv  = buf0;
    ushort* xbf = (ushort*)qb;
    ushort* waT = (ushort*)kb;
    ushort* ybf = (ushort*)buf1;
    ushort* wpT = (ushort*)buf2;
    float* Sbuf = out;                  // d_out as S-tile scratch

    cvt_bf16_kernel<<<TT * EE / 2048, 256, 0, stream>>>(x, xbf);
    cvt_transpose_kernel<<<dim3(NN / 64, EE / 64), 256, 0, stream>>>(w_attn, waT, EE, NN);
    gemm_bf16<128, 128><<<dim3(NN / 128, TT / 128), 256, 0, stream>>>(
        xbf, waT, qkv, TT, NN, EE);
    conv_rope_kernel<<<dim3(TT / 4, HH, 3), dim3(64, 4), 0, stream>>>(
        qkv, qcw, kcw, vcw, cosb, sinb, qb, kb, vb);
    chunk_prep_kernel<<<dim3(NCH, HH), 256, 0, stream>>>(qb, kb, vb, beta, g, buf0, buf1, buf2);
    delta_scan4_kernel<<<dim3(CPH, HH), 256, 0, stream>>>(buf0, buf1, g, Sbuf);
    delta_apply_kernel<<<dim3(NCH, HH), 256, 0, stream>>>(Sbuf, buf2, vb);
    cvt_transpose_kernel<<<dim3(EE / 64, EE / 64), 256, 0, stream>>>(w_proj, wpT, EE, EE);
    attn_mfma_kernel<<<dim3(TT / 64, HH), 256, 0, stream>>>(qb, kb, vb, ybf);
    gemm_bf16<64, 64><<<dim3(EE / 64, TT / 64), 256, 0, stream>>>(
        ybf, wpT, out, TT, EE, EE);
}

// Round 11
// 258.508 us; speedup vs baseline: 8.9505x; 1.0944x over previous
//
#include <hip/hip_runtime.h>
#include <math.h>

#define TT 2048
#define HH 16
#define DD 64
#define EE 1024
#define NN 3072
#define CHUNK 64
#define NCH (TT / CHUNK)
#define SCALE 0.125f
#define KS 72   // attn LDS row stride (bf16): conflict-free b128
#define CPH 8   // column-split blocks per head in delta scan

typedef short bf16x8 __attribute__((ext_vector_type(8)));
typedef short bf16x4 __attribute__((ext_vector_type(4)));
typedef float f32x4 __attribute__((ext_vector_type(4)));
typedef unsigned short ushort;
typedef const __attribute__((address_space(1))) unsigned int* gptr_t;
typedef __attribute__((address_space(3))) unsigned int* lptr_t;

__device__ __forceinline__ unsigned short f2bf(float x) {
    union { float f; unsigned u; } un; un.f = x;
    unsigned r = un.u + 0x7FFFu + ((un.u >> 16) & 1u);
    return (unsigned short)(r >> 16);
}

// XOR slot swizzle for 64-float rows (4-float slots, key = row bits 2..4)
__device__ __forceinline__ int swz(int r, int c) {
    return (r << 6) + ((((c >> 2) ^ ((r >> 2) & 7)) << 2) | (c & 3));
}
__device__ __forceinline__ int swz4(int r, int c4) {
    return (r << 6) + (((c4 >> 2) ^ ((r >> 2) & 7)) << 2);
}
// XOR slot swizzle for 64-bf16 rows (8-elem 16B slots, key = row bits 0..2)
__device__ __forceinline__ int bswz(int r, int c) {
    return (r << 6) + ((((c >> 3) ^ (r & 7)) << 3) | (c & 7));
}

// ---------------------------------------------------------------------------
// fp32 -> bf16 elementwise convert (x)
// ---------------------------------------------------------------------------
__global__ __launch_bounds__(256) void cvt_bf16_kernel(
    const float* __restrict__ in, ushort* __restrict__ out)
{
    int i = ((int)blockIdx.x * 256 + (int)threadIdx.x) << 3;
    float4 a = *(const float4*)&in[i];
    float4 b = *(const float4*)&in[i + 4];
    bf16x8 o;
    o[0] = (short)f2bf(a.x); o[1] = (short)f2bf(a.y);
    o[2] = (short)f2bf(a.z); o[3] = (short)f2bf(a.w);
    o[4] = (short)f2bf(b.x); o[5] = (short)f2bf(b.y);
    o[6] = (short)f2bf(b.z); o[7] = (short)f2bf(b.w);
    *(bf16x8*)&out[i] = o;
}

// ---------------------------------------------------------------------------
// fp32 [K][N] -> bf16 [N][K] convert + transpose (weights)
// ---------------------------------------------------------------------------
__global__ __launch_bounds__(256) void cvt_transpose_kernel(
    const float* __restrict__ W, ushort* __restrict__ WT, int K, int N)
{
    __shared__ float Ls[64][65];
    int n0 = blockIdx.x * 64, k0 = blockIdx.y * 64;
    int tid = threadIdx.x;
    int lr = tid >> 4, lc4 = (tid & 15) << 2;
    #pragma unroll
    for (int m = 0; m < 4; ++m) {
        int r = lr + m * 16;
        float4 v = *(const float4*)&W[(size_t)(k0 + r) * N + n0 + lc4];
        Ls[r][lc4 + 0] = v.x; Ls[r][lc4 + 1] = v.y;
        Ls[r][lc4 + 2] = v.z; Ls[r][lc4 + 3] = v.w;
    }
    __syncthreads();
    int n = tid >> 2, kb = (tid & 3) << 4;
    bf16x8 o0, o1;
    #pragma unroll
    for (int j = 0; j < 8; ++j) o0[j] = (short)f2bf(Ls[kb + j][n]);
    #pragma unroll
    for (int j = 0; j < 8; ++j) o1[j] = (short)f2bf(Ls[kb + 8 + j][n]);
    *(bf16x8*)&WT[(size_t)(n0 + n) * K + k0 + kb] = o0;
    *(bf16x8*)&WT[(size_t)(n0 + n) * K + k0 + kb + 8] = o1;
}

// ---------------------------------------------------------------------------
// bf16 MFMA GEMM: C(fp32)[M][N] = A(bf16)[M][K] * BT(bf16)[N][K]^T
// ---------------------------------------------------------------------------
template<int BM, int BN>
__global__ __launch_bounds__(256) void gemm_bf16(
    const ushort* __restrict__ A, const ushort* __restrict__ BT,
    float* __restrict__ C, int M, int N, int K)
{
    constexpr int MT = BM / 32;
    constexpr int NT = BN / 32;
    constexpr int AIT = BM * 64 / 2048;
    constexpr int BIT = BN * 64 / 2048;
    __shared__ __align__(16) ushort Asl[2][BM * 64];
    __shared__ __align__(16) ushort Bsl[2][BN * 64];
    const int tid = threadIdx.x;
    const int lane = tid & 63, w = tid >> 6;
    const int wm = w >> 1, wn = w & 1;
    const int l16 = lane & 15, lq = lane >> 4;
    const int row0 = blockIdx.y * BM, col0 = blockIdx.x * BN;
    const int wvb = w << 9;

    f32x4 acc[MT][NT];
    #pragma unroll
    for (int i = 0; i < MT; ++i)
        #pragma unroll
        for (int j = 0; j < NT; ++j)
            acc[i][j] = (f32x4){0.f, 0.f, 0.f, 0.f};

#define STAGE_TILE(buf, k0)                                                    \
    {                                                                          \
        _Pragma("unroll")                                                      \
        for (int u = 0; u < AIT; ++u) {                                        \
            int idx = u * 256 + tid;                                           \
            int r = idx >> 3, s = idx & 7;                                     \
            const ushort* srcp =                                               \
                &A[(size_t)(row0 + r) * K + (k0) + ((s ^ (r & 7)) << 3)];      \
            __builtin_amdgcn_global_load_lds((gptr_t)srcp,                     \
                (lptr_t)&Asl[buf][(u << 11) + wvb], 16, 0, 0);                 \
        }                                                                      \
        _Pragma("unroll")                                                      \
        for (int u = 0; u < BIT; ++u) {                                        \
            int idx = u * 256 + tid;                                           \
            int r = idx >> 3, s = idx & 7;                                     \
            const ushort* srcp =                                               \
                &BT[(size_t)(col0 + r) * K + (k0) + ((s ^ (r & 7)) << 3)];     \
            __builtin_amdgcn_global_load_lds((gptr_t)srcp,                     \
                (lptr_t)&Bsl[buf][(u << 11) + wvb], 16, 0, 0);                 \
        }                                                                      \
    }

    const int nK = K >> 6;
    STAGE_TILE(0, 0)
    for (int kt = 0; kt < nK; ++kt) {
        __syncthreads();                       // stage(kt) drained + visible
        if (kt + 1 < nK) STAGE_TILE((kt + 1) & 1, (kt + 1) << 6)
        const int cb = kt & 1;
        #pragma unroll
        for (int kk = 0; kk < 2; ++kk) {
            bf16x8 afr[MT], bfr[NT];
            #pragma unroll
            for (int mt = 0; mt < MT; ++mt) {
                int rr = wm * (BM / 2) + mt * 16 + l16;
                afr[mt] = *(bf16x8*)&Asl[cb][rr * 64 +
                           (((kk * 4 + lq) ^ (rr & 7)) << 3)];
            }
            #pragma unroll
            for (int nt = 0; nt < NT; ++nt) {
                int cc = wn * (BN / 2) + nt * 16 + l16;
                bfr[nt] = *(bf16x8*)&Bsl[cb][cc * 64 +
                           (((kk * 4 + lq) ^ (cc & 7)) << 3)];
            }
            #pragma unroll
            for (int mt = 0; mt < MT; ++mt)
                #pragma unroll
                for (int nt = 0; nt < NT; ++nt)
                    acc[mt][nt] = __builtin_amdgcn_mfma_f32_16x16x32_bf16(
                        afr[mt], bfr[nt], acc[mt][nt], 0, 0, 0);
        }
    }
#undef STAGE_TILE

    #pragma unroll
    for (int mt = 0; mt < MT; ++mt) {
        #pragma unroll
        for (int nt = 0; nt < NT; ++nt) {
            int col = col0 + wn * (BN / 2) + nt * 16 + l16;
            #pragma unroll
            for (int r = 0; r < 4; ++r) {
                int row = row0 + wm * (BM / 2) + mt * 16 + lq * 4 + r;
                C[(size_t)row * N + col] = acc[mt][nt][r];
            }
        }
    }
}

// ---------------------------------------------------------------------------
// Causal depthwise conv1d (DC=4) + SiLU, then RoPE for q,k; v plain.
// ---------------------------------------------------------------------------
__global__ __launch_bounds__(256) void conv_rope_kernel(
    const float* __restrict__ qkv,
    const float* __restrict__ qw, const float* __restrict__ kw, const float* __restrict__ vw,
    const float* __restrict__ cosb, const float* __restrict__ sinb,
    float* __restrict__ qo, float* __restrict__ ko, float* __restrict__ vo)
{
    int j = blockIdx.z;
    const float* w = (j == 0) ? qw : (j == 1) ? kw : vw;
    float* dst     = (j == 0) ? qo : (j == 1) ? ko : vo;
    int d  = threadIdx.x;
    int tl = threadIdx.y;
    int t  = blockIdx.x * 4 + tl;
    int h  = blockIdx.y;
    int c  = h * DD + d;
    int n  = h * 192 + j * 64 + d;
    float acc = 0.f;
    #pragma unroll
    for (int i = 0; i < 4; ++i) {
        int tt = t - 3 + i;
        if (tt >= 0) acc = fmaf(qkv[(size_t)tt * NN + n], w[c * 4 + i], acc);
    }
    float yv = acc / (1.f + __expf(-acc));
    if (j == 2) { dst[t * EE + c] = yv; return; }
    __shared__ float sh[4][64];
    sh[tl][d] = yv;
    __syncthreads();
    int dh = d & 31;
    float cc = cosb[t * 32 + dh];
    float ss = sinb[t * 32 + dh];
    float outv;
    if (d < 32) outv = yv * cc - sh[tl][d + 32] * ss;
    else        outv = yv * cc + sh[tl][d - 32] * ss;
    dst[t * EE + c] = outv;
}

// ---------------------------------------------------------------------------
// Chunked gated delta rule, phase 1 — v3: MFMA for phase B (dkk/dqk) and the
// four fold matmuls; fp32 forward substitution unchanged.
// LDS pool = 80KB exactly (2 blocks/CU): Kc(fp32,->Xk) 16K, Vx(fp32,->Xv) 16K,
// Mpool 16K (Kbf+Qbf bf16 -> M fp32), Abf/KTb/XkT/XvT bf16 8K each.
// Gs/bs live in registers (per-wave cumprod + __shfl).
// Outputs keep round-10 layouts -> scan4/apply untouched.
// ---------------------------------------------------------------------------
__global__ __launch_bounds__(256) void chunk_prep_kernel(
    const float* __restrict__ qb, const float* __restrict__ kb, float* __restrict__ vb,
    const float* __restrict__ beta, const float* __restrict__ g,
    float* __restrict__ Bt, float* __restrict__ Ct, float* __restrict__ Ft)
{
    __shared__ __align__(16) float Kc[4096];     // K fp32 swz -> Xk in place
    __shared__ __align__(16) float Vx[4096];     // V fp32 swz -> Xv in place
    __shared__ __align__(16) float Mpool[4096];  // Kbf+Qbf bf16 -> M fp32 swz
    __shared__ __align__(16) ushort Abf[4096];   // A~ bf16 [t][s] bswz (0 for s>t)
    __shared__ __align__(16) ushort KTb[4096];   // K~^T bf16 [b][s] bswz
    __shared__ __align__(16) ushort XkT[4096];   // Xk^T bf16 [a][s] bswz
    __shared__ __align__(16) ushort XvT[4096];   // Xv^T bf16 [a][s] bswz
    ushort* Kbf = (ushort*)Mpool;
    ushort* Qbf = (ushort*)Mpool + 4096;
    float*  Mm  = Mpool;

    int c = blockIdx.x, h = blockIdx.y;
    int tid = threadIdx.x;
    int lane = tid & 63;
    int w = tid >> 6;
    int l16 = lane & 15, lq = lane >> 4;
    int t0 = c * CHUNK;

    // --- gates/beta in registers (each wave computes the full 64-cumprod) ---
    float gsreg, bsreg;
    {
        float x = g[(t0 + lane) * HH + h];
        #pragma unroll
        for (int off = 1; off < 64; off <<= 1) {
            float y = __shfl_up(x, off);
            if (lane >= off) x *= y;
        }
        gsreg = x;
        bsreg = beta[(t0 + lane) * HH + h];
    }

    // --- stage K,V fp32 (swz) + K,Q bf16 (bswz) ---
    {
        int row = tid >> 4, c4 = (tid & 15) << 2;
        #pragma unroll
        for (int m = 0; m < 4; ++m) {
            int r = row + m * 16;
            size_t gidx = (size_t)(t0 + r) * EE + h * DD + c4;
            float4 kv = *(const float4*)&kb[gidx];
            float4 qv = *(const float4*)&qb[gidx];
            float4 vv = *(const float4*)&vb[gidx];
            *(float4*)&Kc[swz4(r, c4)] = kv;
            *(float4*)&Vx[swz4(r, c4)] = vv;
            int ba = bswz(r, c4);
            bf16x4 kb4 = { (short)f2bf(kv.x), (short)f2bf(kv.y),
                           (short)f2bf(kv.z), (short)f2bf(kv.w) };
            bf16x4 qb4 = { (short)f2bf(qv.x), (short)f2bf(qv.y),
                           (short)f2bf(qv.z), (short)f2bf(qv.w) };
            *(bf16x4*)&Kbf[ba] = kb4;
            *(bf16x4*)&Qbf[ba] = qb4;
        }
    }
    __syncthreads();

    // --- phase B (MFMA): dkkT[s][t]=k_s.k_t, dqkT[s][t]=k_s.q_t; wave owns s-tile ---
    f32x4 akk[4], aqk[4];
    {
        bf16x8 kaf[2];
        int rr = w * 16 + l16;
        #pragma unroll
        for (int kk = 0; kk < 2; ++kk)
            kaf[kk] = *(bf16x8*)&Kbf[rr * 64 + (((kk * 4 + lq) ^ (rr & 7)) << 3)];
        #pragma unroll
        for (int ct = 0; ct < 4; ++ct) {
            int tt = ct * 16 + l16;
            f32x4 a1 = {0.f, 0.f, 0.f, 0.f}, a2 = {0.f, 0.f, 0.f, 0.f};
            #pragma unroll
            for (int kk = 0; kk < 2; ++kk) {
                int sl = ((kk * 4 + lq) ^ (tt & 7)) << 3;
                bf16x8 kbfr = *(bf16x8*)&Kbf[tt * 64 + sl];
                bf16x8 qbfr = *(bf16x8*)&Qbf[tt * 64 + sl];
                a1 = __builtin_amdgcn_mfma_f32_16x16x32_bf16(kaf[kk], kbfr, a1, 0, 0, 0);
                a2 = __builtin_amdgcn_mfma_f32_16x16x32_bf16(kaf[kk], qbfr, a2, 0, 0, 0);
            }
            akk[ct] = a1; aqk[ct] = a2;
        }
    }
    __syncthreads();   // all Kbf/Qbf reads done -> Mpool reusable as M

    // --- write M fp32 (swz, garbage at s>=t never read) and Abf bf16 (0 for s>t) ---
    {
        int s0 = w * 16 + lq * 4;
        float gS[4];
        #pragma unroll
        for (int r = 0; r < 4; ++r) gS[r] = __shfl(gsreg, s0 + r);
        #pragma unroll
        for (int ct = 0; ct < 4; ++ct) {
            int t = ct * 16 + l16;
            float gT = __shfl(gsreg, t);
            float bT = __shfl(bsreg, t);
            float mw[4];
            bf16x4 ab4;
            #pragma unroll
            for (int r = 0; r < 4; ++r) {
                int s = s0 + r;
                float gr = gT / gS[r];
                mw[r] = bT * gr * akk[ct][r];
                float av = (s <= t) ? SCALE * gr * aqk[ct][r] : 0.f;
                ab4[r] = (short)f2bf(av);
            }
            float4 mw4 = {mw[0], mw[1], mw[2], mw[3]};
            *(float4*)&Mm[swz4(t, s0)] = mw4;
            *(bf16x4*)&Abf[bswz(t, s0)] = ab4;
        }
    }

    // --- K~^T pass: KTb[b][s] = (G63/Gs)*K[s][b] (reads raw Kc; before subst) ---
    {
        float g63 = __shfl(gsreg, 63);
        int s = tid >> 2;
        int cb = (tid & 3) << 4;
        float ratio = g63 / __shfl(gsreg, s);
        #pragma unroll
        for (int u = 0; u < 4; ++u) {
            int b4 = cb + u * 4;
            float4 kv = *(const float4*)&Kc[swz4(s, b4)];
            float kvr[4] = {kv.x, kv.y, kv.z, kv.w};
            #pragma unroll
            for (int j = 0; j < 4; ++j)
                KTb[bswz(b4 + j, s)] = f2bf(ratio * kvr[j]);
        }
    }
    __syncthreads();

    // --- fp32 forward substitution: (I+M)X = rhs; Xv->Vx, Xk->Kc in place.
    //     bf16 transposed tails into XkT/XvT (b128 every 8 steps, static idx) ---
    if (tid < 128) {
        int col = tid & 63;
        int wK = tid >> 6;
        float* Xp = wK ? Kc : Vx;
        ushort* XT = wK ? XkT : XvT;
        #pragma unroll 1
        for (int tb = 0; tb < 64; tb += 8) {
            unsigned pk0 = 0, pk1 = 0, pk2 = 0, pk3 = 0;
            #pragma unroll
            for (int u = 0; u < 8; ++u) {
                int t = tb + u;
                float bsv = __shfl(bsreg, t);
                float acc = wK ? (bsv * __shfl(gsreg, t) * Kc[swz(t, col)])
                               : (bsv * Vx[swz(t, col)]);
                int t4 = t & ~3;
                for (int s4 = 0; s4 < t4; s4 += 4) {
                    float4 mp = *(const float4*)&Mm[swz4(t, s4)];
                    acc = fmaf(-mp.x, Xp[swz(s4 + 0, col)], acc);
                    acc = fmaf(-mp.y, Xp[swz(s4 + 1, col)], acc);
                    acc = fmaf(-mp.z, Xp[swz(s4 + 2, col)], acc);
                    acc = fmaf(-mp.w, Xp[swz(s4 + 3, col)], acc);
                }
                for (int s = t4; s < t; ++s)
                    acc = fmaf(-Mm[swz(t, s)], Xp[swz(s, col)], acc);
                Xp[swz(t, col)] = acc;
                unsigned hb = (unsigned)f2bf(acc) << ((u & 1) * 16);
                if (u == 0) pk0 = hb; else if (u == 1) pk0 |= hb;
                else if (u == 2) pk1 = hb; else if (u == 3) pk1 |= hb;
                else if (u == 4) pk2 = hb; else if (u == 5) pk2 |= hb;
                else if (u == 6) pk3 = hb; else pk3 |= hb;
            }
            int slot = (((tb >> 3) ^ (col & 7)) << 3);
            uint4 pkv = {pk0, pk1, pk2, pk3};
            *(uint4*)&XT[col * 64 + slot] = pkv;
        }
    }
    __syncthreads();

    // --- fold (MFMA): aB=Xk^T.K~ , aC=K~^T.Xv , aF=Xk^T.A~^T , aE=A~.Xv ---
    {
        int a_r = w * 16 + l16;          // A-frag row (fold a-dim)
        bf16x8 xkA[2], ktA[2], abA[2];
        #pragma unroll
        for (int kk = 0; kk < 2; ++kk) {
            int sl = ((kk * 4 + lq) ^ (a_r & 7)) << 3;
            xkA[kk] = *(bf16x8*)&XkT[a_r * 64 + sl];
            ktA[kk] = *(bf16x8*)&KTb[a_r * 64 + sl];
            abA[kk] = *(bf16x8*)&Abf[a_r * 64 + sl];
        }
        size_t tile = ((size_t)(c * HH + h)) << 12;
        int a0f = w * 16 + lq * 4;
        #pragma unroll
        for (int ct = 0; ct < 4; ++ct) {
            int b_r = ct * 16 + l16;
            f32x4 accB = {0.f,0.f,0.f,0.f}, accC = {0.f,0.f,0.f,0.f};
            f32x4 accF = {0.f,0.f,0.f,0.f}, accE = {0.f,0.f,0.f,0.f};
            #pragma unroll
            for (int kk = 0; kk < 2; ++kk) {
                int sl = ((kk * 4 + lq) ^ (b_r & 7)) << 3;
                bf16x8 ktB = *(bf16x8*)&KTb[b_r * 64 + sl];
                bf16x8 xvB = *(bf16x8*)&XvT[b_r * 64 + sl];
                bf16x8 abB = *(bf16x8*)&Abf[b_r * 64 + sl];
                accB = __builtin_amdgcn_mfma_f32_16x16x32_bf16(xkA[kk], ktB, accB, 0, 0, 0);
                accC = __builtin_amdgcn_mfma_f32_16x16x32_bf16(ktA[kk], xvB, accC, 0, 0, 0);
                accF = __builtin_amdgcn_mfma_f32_16x16x32_bf16(xkA[kk], abB, accF, 0, 0, 0);
                accE = __builtin_amdgcn_mfma_f32_16x16x32_bf16(abA[kk], xvB, accE, 0, 0, 0);
            }
            float gB = __shfl(gsreg, b_r);
            float4 qv = *(const float4*)&qb[(size_t)(t0 + b_r) * EE + h * DD + a0f];
            float qvr[4] = {qv.x, qv.y, qv.z, qv.w};
            #pragma unroll
            for (int i = 0; i < 4; ++i) {
                int a = a0f + i;
                Bt[tile + (size_t)a * 64 + b_r] = accB[i];
                Ct[tile + (size_t)a * 64 + b_r] = accC[i];
                Ft[tile + (size_t)a * 64 + b_r] = SCALE * gB * qvr[i] - accF[i];
                vb[(size_t)(t0 + a) * EE + h * DD + b_r] = accE[i];
            }
        }
    }
}

// ---------------------------------------------------------------------------
// Delta rule serial S-chain, column-split: grid (CPH, HH).
// ---------------------------------------------------------------------------
__global__ __launch_bounds__(256) void delta_scan4_kernel(
    const float* __restrict__ Bt, const float* __restrict__ Ct,
    const float* __restrict__ g, float* __restrict__ Sout)
{
    __shared__ __align__(16) float Bsb[2][4096];
    __shared__ __align__(16) float Csb[2][512];
    __shared__ float Ss[64][10];
    __shared__ float GCs[NCH];
    int p = blockIdx.x, h = blockIdx.y;
    int bo = p * 8;
    int tid = threadIdx.x;
    int a = tid & 63;
    int w = tid >> 6;
    int j0 = w * 2;

    {
        float pr = 1.f;
        int t0 = tid * 8;
        #pragma unroll
        for (int j = 0; j < 8; ++j) pr *= g[(t0 + j) * HH + h];
        pr *= __shfl_xor(pr, 1);
        pr *= __shfl_xor(pr, 2);
        pr *= __shfl_xor(pr, 4);
        GCs[tid >> 3] = pr;
        Ss[a][j0] = 0.f;
        Ss[a][j0 + 1] = 0.f;
    }

#define STG4(buf, cc)                                                          \
    {                                                                          \
        size_t tb = ((size_t)((cc) * HH + h)) << 12;                           \
        _Pragma("unroll")                                                      \
        for (int u = 0; u < 4; ++u) {                                          \
            int fi = ((u << 8) + tid) << 2;                                    \
            int fb = ((u << 8) + (tid & 192)) << 2;                            \
            __builtin_amdgcn_global_load_lds((gptr_t)&Bt[tb + fi],             \
                (lptr_t)&Bsb[buf][fb], 16, 0, 0);                              \
        }                                                                      \
        if (tid < 128) {                                                       \
            size_t cfi = tb + ((size_t)(tid >> 1) << 6) + bo + ((tid & 1) << 2); \
            __builtin_amdgcn_global_load_lds((gptr_t)&Ct[cfi],                 \
                (lptr_t)&Csb[buf][(tid & 64) << 2], 16, 0, 0);                 \
        }                                                                      \
    }

    STG4(0, 0)
    for (int c = 0; c < NCH; ++c) {
        __syncthreads();
        if (c + 1 < NCH) STG4((c + 1) & 1, c + 1)
        const float* Bsp = Bsb[c & 1];
        const float* Csp = Csb[c & 1];
        float gc = GCs[c];
        size_t tile = ((size_t)(c * HH + h)) << 12;
        float s0 = Ss[a][j0], s1 = Ss[a][j0 + 1];
        Sout[tile + (size_t)(bo + j0) * 64 + a] = s0;
        Sout[tile + (size_t)(bo + j0 + 1) * 64 + a] = s1;
        float p0 = 0.f, p1 = 0.f;
        #pragma unroll 4
        for (int k = 0; k < 64; ++k) {
            float bk = Bsp[k * 64 + a];
            float2 sv = *(const float2*)&Ss[k][j0];
            p0 = fmaf(bk, sv.x, p0);
            p1 = fmaf(bk, sv.y, p1);
        }
        __syncthreads();
        float c0v = Csp[a * 8 + j0], c1v = Csp[a * 8 + j0 + 1];
        Ss[a][j0]     = fmaf(gc, s0, c0v - p0);
        Ss[a][j0 + 1] = fmaf(gc, s1, c1v - p1);
    }
#undef STG4
}

// ---------------------------------------------------------------------------
// Delta rule parallel output map: O_c = F_c.S_c + E_c. grid (NCH, HH).
// ---------------------------------------------------------------------------
__global__ __launch_bounds__(256) void delta_apply_kernel(
    const float* __restrict__ Sb, const float* __restrict__ Ft,
    float* __restrict__ vb)
{
    __shared__ float Fs[64][64];
    __shared__ float S2[64][68];
    int c = blockIdx.x, h = blockIdx.y;
    int tid = threadIdx.x;
    int tx = tid & 15, ty = tid >> 4;
    int a0 = ty << 2, b0 = tx << 2;
    size_t tile = ((size_t)(c * HH + h)) << 12;
    {
        int row = tid >> 4, c4 = (tid & 15) << 2;
        #pragma unroll
        for (int m = 0; m < 4; ++m) {
            int r = row + m * 16;
            *(float4*)&Fs[r][c4] = *(const float4*)&Ft[tile + r * 64 + c4];
            float4 sv = *(const float4*)&Sb[tile + r * 64 + c4];
            S2[c4 + 0][r] = sv.x;
            S2[c4 + 1][r] = sv.y;
            S2[c4 + 2][r] = sv.z;
            S2[c4 + 3][r] = sv.w;
        }
    }
    __syncthreads();
    float accO[4][4] = {};
    #pragma unroll 4
    for (int k = 0; k < 64; ++k) {
        float4 fv = *(const float4*)&Fs[k][a0];
        float4 sv = *(const float4*)&S2[k][b0];
        float fa[4] = {fv.x, fv.y, fv.z, fv.w};
        float sa[4] = {sv.x, sv.y, sv.z, sv.w};
        #pragma unroll
        for (int i = 0; i < 4; ++i)
            #pragma unroll
            for (int j = 0; j < 4; ++j)
                accO[i][j] = fmaf(fa[i], sa[j], accO[i][j]);
    }
    #pragma unroll
    for (int i = 0; i < 4; ++i) {
        size_t gi = (size_t)((c << 6) + a0 + i) * EE + h * DD + b0;
        float4 ev = *(const float4*)&vb[gi];
        float4 ov = {accO[i][0] + ev.x, accO[i][1] + ev.y,
                     accO[i][2] + ev.z, accO[i][3] + ev.w};
        *(float4*)&vb[gi] = ov;
    }
}

// ---------------------------------------------------------------------------
// Causal flash attention, bf16 MFMA, swapped-operand QK^T (S^T layout).
// ---------------------------------------------------------------------------
__global__ __launch_bounds__(256) void attn_mfma_kernel(
    const float* __restrict__ q, const float* __restrict__ k, const float* __restrict__ v,
    ushort* __restrict__ y)
{
    __shared__ __align__(16) unsigned short KsL[64 * KS];
    __shared__ __align__(16) unsigned short VtL[64 * KS];
    __shared__ __align__(16) unsigned int PL[4][16 * 36];  // packed P, stride 36 u32

    int h = blockIdx.y;
    int rb = ((int)gridDim.x - 1 - (int)blockIdx.x) * 64;
    int tid = threadIdx.x;
    int w = tid >> 6;
    int lane = tid & 63;
    int l16 = lane & 15;
    int lq = lane >> 4;
    int qr0 = rb + w * 16;
    unsigned* PLw = PL[w];

    bf16x8 qf[2];
    {
        const float* qrow = &q[(size_t)(qr0 + l16) * EE + h * DD];
        #pragma unroll
        for (int kk = 0; kk < 2; ++kk) {
            float4 v0 = *(const float4*)&qrow[kk * 32 + lq * 8];
            float4 v1 = *(const float4*)&qrow[kk * 32 + lq * 8 + 4];
            qf[kk][0] = (short)f2bf(v0.x); qf[kk][1] = (short)f2bf(v0.y);
            qf[kk][2] = (short)f2bf(v0.z); qf[kk][3] = (short)f2bf(v0.w);
            qf[kk][4] = (short)f2bf(v1.x); qf[kk][5] = (short)f2bf(v1.y);
            qf[kk][6] = (short)f2bf(v1.z); qf[kk][7] = (short)f2bf(v1.w);
        }
    }

    f32x4 oacc[4];
    #pragma unroll
    for (int dt = 0; dt < 4; ++dt) oacc[dt] = (f32x4){0.f, 0.f, 0.f, 0.f};
    float mrow = -3e38f, lrow = 0.f;
    const int qrow_i = qr0 + l16;

    int ks_s = tid >> 2, ks_d0 = (tid & 3) << 4;
    int vt_s0 = (tid & 31) * 2, vt_dq = (tid >> 5) << 3;

    float4 kreg[4], va0, va1, vb0r, vb1r;

#define ATT_ISSUE(c0)                                                          \
    {                                                                          \
        const float* krow = &k[(size_t)((c0) + ks_s) * EE + h * DD + ks_d0];   \
        kreg[0] = *(const float4*)&krow[0];                                    \
        kreg[1] = *(const float4*)&krow[4];                                    \
        kreg[2] = *(const float4*)&krow[8];                                    \
        kreg[3] = *(const float4*)&krow[12];                                   \
        const float* vr0 = &v[(size_t)((c0) + vt_s0) * EE + h * DD + vt_dq];   \
        const float* vr1 = vr0 + EE;                                           \
        va0 = *(const float4*)&vr0[0]; va1 = *(const float4*)&vr0[4];          \
        vb0r = *(const float4*)&vr1[0]; vb1r = *(const float4*)&vr1[4];        \
    }

    ATT_ISSUE(0)
    for (int c0 = 0; c0 <= rb; c0 += 64) {
        __syncthreads();
        {
            #pragma unroll
            for (int u = 0; u < 4; ++u) {
                bf16x4 pk4 = { (short)f2bf(kreg[u].x), (short)f2bf(kreg[u].y),
                               (short)f2bf(kreg[u].z), (short)f2bf(kreg[u].w) };
                *(bf16x4*)&KsL[ks_s * KS + ks_d0 + u * 4] = pk4;
            }
            float va[8] = {va0.x, va0.y, va0.z, va0.w, va1.x, va1.y, va1.z, va1.w};
            float vbv[8] = {vb0r.x, vb0r.y, vb0r.z, vb0r.w, vb1r.x, vb1r.y, vb1r.z, vb1r.w};
            #pragma unroll
            for (int u = 0; u < 8; ++u) {
                unsigned pv = (unsigned)f2bf(va[u]) | ((unsigned)f2bf(vbv[u]) << 16);
                *(unsigned*)&VtL[(vt_dq + u) * KS + vt_s0] = pv;
            }
        }
        __syncthreads();
        if (c0 + 64 <= rb) ATT_ISSUE(c0 + 64)

        f32x4 sacc[4];
        #pragma unroll
        for (int ct = 0; ct < 4; ++ct) {
            bf16x8 ka0 = *(bf16x8*)&KsL[(ct * 16 + l16) * KS + lq * 8];
            bf16x8 ka1 = *(bf16x8*)&KsL[(ct * 16 + l16) * KS + 32 + lq * 8];
            f32x4 acc = {0.f, 0.f, 0.f, 0.f};
            acc = __builtin_amdgcn_mfma_f32_16x16x32_bf16(ka0, qf[0], acc, 0, 0, 0);
            acc = __builtin_amdgcn_mfma_f32_16x16x32_bf16(ka1, qf[1], acc, 0, 0, 0);
            sacc[ct] = acc;
        }

        float sv[4][4];
        float tm = -3e38f;
        #pragma unroll
        for (int ct = 0; ct < 4; ++ct) {
            int sbase = c0 + ct * 16 + lq * 4;
            #pragma unroll
            for (int r = 0; r < 4; ++r) {
                float s = sacc[ct][r] * SCALE;
                if (sbase + r > qrow_i) s = -3e38f;
                sv[ct][r] = s;
                tm = fmaxf(tm, s);
            }
        }
        tm = fmaxf(tm, __shfl_xor(tm, 16));
        tm = fmaxf(tm, __shfl_xor(tm, 32));
        float mn = fmaxf(mrow, tm);
        float corr = __expf(mrow - mn);
        mrow = mn;

        float ps = 0.f;
        #pragma unroll
        for (int ct = 0; ct < 4; ++ct) {
            float p0 = __expf(sv[ct][0] - mn);
            float p1 = __expf(sv[ct][1] - mn);
            float p2 = __expf(sv[ct][2] - mn);
            float p3 = __expf(sv[ct][3] - mn);
            ps += (p0 + p1) + (p2 + p3);
            uint2 wv;
            wv.x = (unsigned)f2bf(p0) | ((unsigned)f2bf(p1) << 16);
            wv.y = (unsigned)f2bf(p2) | ((unsigned)f2bf(p3) << 16);
            *(uint2*)&PLw[l16 * 36 + ct * 8 + lq * 2] = wv;
        }
        ps += __shfl_xor(ps, 16);
        ps += __shfl_xor(ps, 32);
        lrow = lrow * corr + ps;

        float corr_o[4];
        #pragma unroll
        for (int r = 0; r < 4; ++r)
            corr_o[r] = __shfl(corr, (lane & 48) + lq * 4 + r);
        #pragma unroll
        for (int dt = 0; dt < 4; ++dt) {
            #pragma unroll
            for (int r = 0; r < 4; ++r)
                oacc[dt][r] *= corr_o[r];
        }

        bf16x8 pa0 = *(bf16x8*)&PLw[l16 * 36 + lq * 4];
        bf16x8 pa1 = *(bf16x8*)&PLw[l16 * 36 + 16 + lq * 4];
        #pragma unroll
        for (int dt = 0; dt < 4; ++dt) {
            bf16x8 vv0 = *(bf16x8*)&VtL[(dt * 16 + l16) * KS + lq * 8];
            bf16x8 vv1 = *(bf16x8*)&VtL[(dt * 16 + l16) * KS + 32 + lq * 8];
            oacc[dt] = __builtin_amdgcn_mfma_f32_16x16x32_bf16(pa0, vv0, oacc[dt], 0, 0, 0);
            oacc[dt] = __builtin_amdgcn_mfma_f32_16x16x32_bf16(pa1, vv1, oacc[dt], 0, 0, 0);
        }
    }
#undef ATT_ISSUE

    float li = 1.f / lrow;
    float linv_o[4];
    #pragma unroll
    for (int r = 0; r < 4; ++r)
        linv_o[r] = __shfl(li, (lane & 48) + lq * 4 + r);
    #pragma unroll
    for (int dt = 0; dt < 4; ++dt) {
        #pragma unroll
        for (int r = 0; r < 4; ++r) {
            int row = qr0 + lq * 4 + r;
            y[(size_t)row * EE + h * DD + dt * 16 + l16] = f2bf(oacc[dt][r] * linv_o[r]);
        }
    }
}

// ---------------------------------------------------------------------------
extern "C" void kernel_launch(void* const* d_in, const int* in_sizes, int n_in,
                              void* d_out, int out_size, void* d_ws, size_t ws_size,
                              hipStream_t stream)
{
    (void)in_sizes; (void)n_in; (void)out_size; (void)ws_size;
    const float* x      = (const float*)d_in[0];
    const float* w_attn = (const float*)d_in[1];
    const float* w_proj = (const float*)d_in[2];
    const float* qcw    = (const float*)d_in[3];
    const float* kcw    = (const float*)d_in[4];
    const float* vcw    = (const float*)d_in[5];
    const float* cosb   = (const float*)d_in[6];
    const float* sinb   = (const float*)d_in[7];
    const float* beta   = (const float*)d_in[8];
    const float* g      = (const float*)d_in[9];
    float* out = (float*)d_out;
    float* ws  = (float*)d_ws;

    const size_t TE = (size_t)TT * EE;
    float* buf0 = ws + 0 * TE;          // qkv -> Bt
    float* buf1 = ws + 1 * TE;          // qkv -> Ct -> ybf
    float* buf2 = ws + 2 * TE;          // qkv -> Ft -> wpT
    float* qb   = ws + 3 * TE;          // xbf -> q
    float* kb   = ws + 4 * TE;          // waT -> k
    float* vb   = ws + 5 * TE;          // v -> E -> O
    float* qkv  = buf0;
    ushort* xbf = (ushort*)qb;
    ushort* waT = (ushort*)kb;
    ushort* ybf = (ushort*)buf1;
    ushort* wpT = (ushort*)buf2;
    float* Sbuf = out;                  // d_out as S-tile scratch

    cvt_bf16_kernel<<<TT * EE / 2048, 256, 0, stream>>>(x, xbf);
    cvt_transpose_kernel<<<dim3(NN / 64, EE / 64), 256, 0, stream>>>(w_attn, waT, EE, NN);
    gemm_bf16<128, 128><<<dim3(NN / 128, TT / 128), 256, 0, stream>>>(
        xbf, waT, qkv, TT, NN, EE);
    conv_rope_kernel<<<dim3(TT / 4, HH, 3), dim3(64, 4), 0, stream>>>(
        qkv, qcw, kcw, vcw, cosb, sinb, qb, kb, vb);
    chunk_prep_kernel<<<dim3(NCH, HH), 256, 0, stream>>>(qb, kb, vb, beta, g, buf0, buf1, buf2);
    delta_scan4_kernel<<<dim3(CPH, HH), 256, 0, stream>>>(buf0, buf1, g, Sbuf);
    delta_apply_kernel<<<dim3(NCH, HH), 256, 0, stream>>>(Sbuf, buf2, vb);
    cvt_transpose_kernel<<<dim3(EE / 64, EE / 64), 256, 0, stream>>>(w_proj, wpT, EE, EE);
    attn_mfma_kernel<<<dim3(TT / 64, HH), 256, 0, stream>>>(qb, kb, vb, ybf);
    gemm_bf16<64, 64><<<dim3(EE / 64, TT / 64), 256, 0, stream>>>(
        ybf, wpT, out, TT, EE, EE);
}

// Round 12
// 242.095 us; speedup vs baseline: 9.5573x; 1.0678x over previous
//
#include <hip/hip_runtime.h>
#include <math.h>

#define TT 2048
#define HH 16
#define DD 64
#define EE 1024
#define NN 3072
#define CHUNK 64
#define NCH (TT / CHUNK)
#define SCALE 0.125f
#define KS 72   // attn LDS row stride (bf16): conflict-free b128
#define CPH 8   // column-split blocks per head in delta scan

typedef short bf16x8 __attribute__((ext_vector_type(8)));
typedef short bf16x4 __attribute__((ext_vector_type(4)));
typedef float f32x4 __attribute__((ext_vector_type(4)));
typedef unsigned short ushort;
typedef const __attribute__((address_space(1))) unsigned int* gptr_t;
typedef __attribute__((address_space(3))) unsigned int* lptr_t;

__device__ __forceinline__ unsigned short f2bf(float x) {
    union { float f; unsigned u; } un; un.f = x;
    unsigned r = un.u + 0x7FFFu + ((un.u >> 16) & 1u);
    return (unsigned short)(r >> 16);
}

// XOR slot swizzle for 64-float rows (4-float slots, key = row bits 2..4)
__device__ __forceinline__ int swz(int r, int c) {
    return (r << 6) + ((((c >> 2) ^ ((r >> 2) & 7)) << 2) | (c & 3));
}
__device__ __forceinline__ int swz4(int r, int c4) {
    return (r << 6) + (((c4 >> 2) ^ ((r >> 2) & 7)) << 2);
}
// XOR slot swizzle for 64-bf16 rows (8-elem 16B slots, key = row bits 0..2)
__device__ __forceinline__ int bswz(int r, int c) {
    return (r << 6) + ((((c >> 3) ^ (r & 7)) << 3) | (c & 7));
}

// ---------------------------------------------------------------------------
// fp32 -> bf16 elementwise convert (x)
// ---------------------------------------------------------------------------
__global__ __launch_bounds__(256) void cvt_bf16_kernel(
    const float* __restrict__ in, ushort* __restrict__ out)
{
    int i = ((int)blockIdx.x * 256 + (int)threadIdx.x) << 3;
    float4 a = *(const float4*)&in[i];
    float4 b = *(const float4*)&in[i + 4];
    bf16x8 o;
    o[0] = (short)f2bf(a.x); o[1] = (short)f2bf(a.y);
    o[2] = (short)f2bf(a.z); o[3] = (short)f2bf(a.w);
    o[4] = (short)f2bf(b.x); o[5] = (short)f2bf(b.y);
    o[6] = (short)f2bf(b.z); o[7] = (short)f2bf(b.w);
    *(bf16x8*)&out[i] = o;
}

// ---------------------------------------------------------------------------
// fp32 [K][N] -> bf16 [N][K] convert + transpose (weights)
// ---------------------------------------------------------------------------
__global__ __launch_bounds__(256) void cvt_transpose_kernel(
    const float* __restrict__ W, ushort* __restrict__ WT, int K, int N)
{
    __shared__ float Ls[64][65];
    int n0 = blockIdx.x * 64, k0 = blockIdx.y * 64;
    int tid = threadIdx.x;
    int lr = tid >> 4, lc4 = (tid & 15) << 2;
    #pragma unroll
    for (int m = 0; m < 4; ++m) {
        int r = lr + m * 16;
        float4 v = *(const float4*)&W[(size_t)(k0 + r) * N + n0 + lc4];
        Ls[r][lc4 + 0] = v.x; Ls[r][lc4 + 1] = v.y;
        Ls[r][lc4 + 2] = v.z; Ls[r][lc4 + 3] = v.w;
    }
    __syncthreads();
    int n = tid >> 2, kb = (tid & 3) << 4;
    bf16x8 o0, o1;
    #pragma unroll
    for (int j = 0; j < 8; ++j) o0[j] = (short)f2bf(Ls[kb + j][n]);
    #pragma unroll
    for (int j = 0; j < 8; ++j) o1[j] = (short)f2bf(Ls[kb + 8 + j][n]);
    *(bf16x8*)&WT[(size_t)(n0 + n) * K + k0 + kb] = o0;
    *(bf16x8*)&WT[(size_t)(n0 + n) * K + k0 + kb + 8] = o1;
}

// ---------------------------------------------------------------------------
// bf16 MFMA GEMM: C(fp32)[M][N] = A(bf16)[M][K] * BT(bf16)[N][K]^T
// ---------------------------------------------------------------------------
template<int BM, int BN>
__global__ __launch_bounds__(256) void gemm_bf16(
    const ushort* __restrict__ A, const ushort* __restrict__ BT,
    float* __restrict__ C, int M, int N, int K)
{
    constexpr int MT = BM / 32;
    constexpr int NT = BN / 32;
    constexpr int AIT = BM * 64 / 2048;
    constexpr int BIT = BN * 64 / 2048;
    __shared__ __align__(16) ushort Asl[2][BM * 64];
    __shared__ __align__(16) ushort Bsl[2][BN * 64];
    const int tid = threadIdx.x;
    const int lane = tid & 63, w = tid >> 6;
    const int wm = w >> 1, wn = w & 1;
    const int l16 = lane & 15, lq = lane >> 4;
    const int row0 = blockIdx.y * BM, col0 = blockIdx.x * BN;
    const int wvb = w << 9;

    f32x4 acc[MT][NT];
    #pragma unroll
    for (int i = 0; i < MT; ++i)
        #pragma unroll
        for (int j = 0; j < NT; ++j)
            acc[i][j] = (f32x4){0.f, 0.f, 0.f, 0.f};

#define STAGE_TILE(buf, k0)                                                    \
    {                                                                          \
        _Pragma("unroll")                                                      \
        for (int u = 0; u < AIT; ++u) {                                        \
            int idx = u * 256 + tid;                                           \
            int r = idx >> 3, s = idx & 7;                                     \
            const ushort* srcp =                                               \
                &A[(size_t)(row0 + r) * K + (k0) + ((s ^ (r & 7)) << 3)];      \
            __builtin_amdgcn_global_load_lds((gptr_t)srcp,                     \
                (lptr_t)&Asl[buf][(u << 11) + wvb], 16, 0, 0);                 \
        }                                                                      \
        _Pragma("unroll")                                                      \
        for (int u = 0; u < BIT; ++u) {                                        \
            int idx = u * 256 + tid;                                           \
            int r = idx >> 3, s = idx & 7;                                     \
            const ushort* srcp =                                               \
                &BT[(size_t)(col0 + r) * K + (k0) + ((s ^ (r & 7)) << 3)];     \
            __builtin_amdgcn_global_load_lds((gptr_t)srcp,                     \
                (lptr_t)&Bsl[buf][(u << 11) + wvb], 16, 0, 0);                 \
        }                                                                      \
    }

    const int nK = K >> 6;
    STAGE_TILE(0, 0)
    for (int kt = 0; kt < nK; ++kt) {
        __syncthreads();                       // stage(kt) drained + visible
        if (kt + 1 < nK) STAGE_TILE((kt + 1) & 1, (kt + 1) << 6)
        const int cb = kt & 1;
        #pragma unroll
        for (int kk = 0; kk < 2; ++kk) {
            bf16x8 afr[MT], bfr[NT];
            #pragma unroll
            for (int mt = 0; mt < MT; ++mt) {
                int rr = wm * (BM / 2) + mt * 16 + l16;
                afr[mt] = *(bf16x8*)&Asl[cb][rr * 64 +
                           (((kk * 4 + lq) ^ (rr & 7)) << 3)];
            }
            #pragma unroll
            for (int nt = 0; nt < NT; ++nt) {
                int cc = wn * (BN / 2) + nt * 16 + l16;
                bfr[nt] = *(bf16x8*)&Bsl[cb][cc * 64 +
                           (((kk * 4 + lq) ^ (cc & 7)) << 3)];
            }
            #pragma unroll
            for (int mt = 0; mt < MT; ++mt)
                #pragma unroll
                for (int nt = 0; nt < NT; ++nt)
                    acc[mt][nt] = __builtin_amdgcn_mfma_f32_16x16x32_bf16(
                        afr[mt], bfr[nt], acc[mt][nt], 0, 0, 0);
        }
    }
#undef STAGE_TILE

    #pragma unroll
    for (int mt = 0; mt < MT; ++mt) {
        #pragma unroll
        for (int nt = 0; nt < NT; ++nt) {
            int col = col0 + wn * (BN / 2) + nt * 16 + l16;
            #pragma unroll
            for (int r = 0; r < 4; ++r) {
                int row = row0 + wm * (BM / 2) + mt * 16 + lq * 4 + r;
                C[(size_t)row * N + col] = acc[mt][nt][r];
            }
        }
    }
}

// ---------------------------------------------------------------------------
// Causal depthwise conv1d (DC=4) + SiLU, then RoPE for q,k; v plain.
// ---------------------------------------------------------------------------
__global__ __launch_bounds__(256) void conv_rope_kernel(
    const float* __restrict__ qkv,
    const float* __restrict__ qw, const float* __restrict__ kw, const float* __restrict__ vw,
    const float* __restrict__ cosb, const float* __restrict__ sinb,
    float* __restrict__ qo, float* __restrict__ ko, float* __restrict__ vo)
{
    int j = blockIdx.z;
    const float* w = (j == 0) ? qw : (j == 1) ? kw : vw;
    float* dst     = (j == 0) ? qo : (j == 1) ? ko : vo;
    int d  = threadIdx.x;
    int tl = threadIdx.y;
    int t  = blockIdx.x * 4 + tl;
    int h  = blockIdx.y;
    int c  = h * DD + d;
    int n  = h * 192 + j * 64 + d;
    float acc = 0.f;
    #pragma unroll
    for (int i = 0; i < 4; ++i) {
        int tt = t - 3 + i;
        if (tt >= 0) acc = fmaf(qkv[(size_t)tt * NN + n], w[c * 4 + i], acc);
    }
    float yv = acc / (1.f + __expf(-acc));
    if (j == 2) { dst[t * EE + c] = yv; return; }
    __shared__ float sh[4][64];
    sh[tl][d] = yv;
    __syncthreads();
    int dh = d & 31;
    float cc = cosb[t * 32 + dh];
    float ss = sinb[t * 32 + dh];
    float outv;
    if (d < 32) outv = yv * cc - sh[tl][d + 32] * ss;
    else        outv = yv * cc + sh[tl][d - 32] * ss;
    dst[t * EE + c] = outv;
}

// ---------------------------------------------------------------------------
// Chunked gated delta rule, phase 1 — v3 (MFMA phase B + fold, fp32 subst).
// ---------------------------------------------------------------------------
__global__ __launch_bounds__(256) void chunk_prep_kernel(
    const float* __restrict__ qb, const float* __restrict__ kb, float* __restrict__ vb,
    const float* __restrict__ beta, const float* __restrict__ g,
    float* __restrict__ Bt, float* __restrict__ Ct, float* __restrict__ Ft)
{
    __shared__ __align__(16) float Kc[4096];     // K fp32 swz -> Xk in place
    __shared__ __align__(16) float Vx[4096];     // V fp32 swz -> Xv in place
    __shared__ __align__(16) float Mpool[4096];  // Kbf+Qbf bf16 -> M fp32 swz
    __shared__ __align__(16) ushort Abf[4096];   // A~ bf16 [t][s] bswz (0 for s>t)
    __shared__ __align__(16) ushort KTb[4096];   // K~^T bf16 [b][s] bswz
    __shared__ __align__(16) ushort XkT[4096];   // Xk^T bf16 [a][s] bswz
    __shared__ __align__(16) ushort XvT[4096];   // Xv^T bf16 [a][s] bswz
    ushort* Kbf = (ushort*)Mpool;
    ushort* Qbf = (ushort*)Mpool + 4096;
    float*  Mm  = Mpool;

    int c = blockIdx.x, h = blockIdx.y;
    int tid = threadIdx.x;
    int lane = tid & 63;
    int w = tid >> 6;
    int l16 = lane & 15, lq = lane >> 4;
    int t0 = c * CHUNK;

    float gsreg, bsreg;
    {
        float x = g[(t0 + lane) * HH + h];
        #pragma unroll
        for (int off = 1; off < 64; off <<= 1) {
            float y = __shfl_up(x, off);
            if (lane >= off) x *= y;
        }
        gsreg = x;
        bsreg = beta[(t0 + lane) * HH + h];
    }

    {
        int row = tid >> 4, c4 = (tid & 15) << 2;
        #pragma unroll
        for (int m = 0; m < 4; ++m) {
            int r = row + m * 16;
            size_t gidx = (size_t)(t0 + r) * EE + h * DD + c4;
            float4 kv = *(const float4*)&kb[gidx];
            float4 qv = *(const float4*)&qb[gidx];
            float4 vv = *(const float4*)&vb[gidx];
            *(float4*)&Kc[swz4(r, c4)] = kv;
            *(float4*)&Vx[swz4(r, c4)] = vv;
            int ba = bswz(r, c4);
            bf16x4 kb4 = { (short)f2bf(kv.x), (short)f2bf(kv.y),
                           (short)f2bf(kv.z), (short)f2bf(kv.w) };
            bf16x4 qb4 = { (short)f2bf(qv.x), (short)f2bf(qv.y),
                           (short)f2bf(qv.z), (short)f2bf(qv.w) };
            *(bf16x4*)&Kbf[ba] = kb4;
            *(bf16x4*)&Qbf[ba] = qb4;
        }
    }
    __syncthreads();

    f32x4 akk[4], aqk[4];
    {
        bf16x8 kaf[2];
        int rr = w * 16 + l16;
        #pragma unroll
        for (int kk = 0; kk < 2; ++kk)
            kaf[kk] = *(bf16x8*)&Kbf[rr * 64 + (((kk * 4 + lq) ^ (rr & 7)) << 3)];
        #pragma unroll
        for (int ct = 0; ct < 4; ++ct) {
            int tt = ct * 16 + l16;
            f32x4 a1 = {0.f, 0.f, 0.f, 0.f}, a2 = {0.f, 0.f, 0.f, 0.f};
            #pragma unroll
            for (int kk = 0; kk < 2; ++kk) {
                int sl = ((kk * 4 + lq) ^ (tt & 7)) << 3;
                bf16x8 kbfr = *(bf16x8*)&Kbf[tt * 64 + sl];
                bf16x8 qbfr = *(bf16x8*)&Qbf[tt * 64 + sl];
                a1 = __builtin_amdgcn_mfma_f32_16x16x32_bf16(kaf[kk], kbfr, a1, 0, 0, 0);
                a2 = __builtin_amdgcn_mfma_f32_16x16x32_bf16(kaf[kk], qbfr, a2, 0, 0, 0);
            }
            akk[ct] = a1; aqk[ct] = a2;
        }
    }
    __syncthreads();

    {
        int s0 = w * 16 + lq * 4;
        float gS[4];
        #pragma unroll
        for (int r = 0; r < 4; ++r) gS[r] = __shfl(gsreg, s0 + r);
        #pragma unroll
        for (int ct = 0; ct < 4; ++ct) {
            int t = ct * 16 + l16;
            float gT = __shfl(gsreg, t);
            float bT = __shfl(bsreg, t);
            float mw[4];
            bf16x4 ab4;
            #pragma unroll
            for (int r = 0; r < 4; ++r) {
                int s = s0 + r;
                float gr = gT / gS[r];
                mw[r] = bT * gr * akk[ct][r];
                float av = (s <= t) ? SCALE * gr * aqk[ct][r] : 0.f;
                ab4[r] = (short)f2bf(av);
            }
            float4 mw4 = {mw[0], mw[1], mw[2], mw[3]};
            *(float4*)&Mm[swz4(t, s0)] = mw4;
            *(bf16x4*)&Abf[bswz(t, s0)] = ab4;
        }
    }

    {
        float g63 = __shfl(gsreg, 63);
        int s = tid >> 2;
        int cb = (tid & 3) << 4;
        float ratio = g63 / __shfl(gsreg, s);
        #pragma unroll
        for (int u = 0; u < 4; ++u) {
            int b4 = cb + u * 4;
            float4 kv = *(const float4*)&Kc[swz4(s, b4)];
            float kvr[4] = {kv.x, kv.y, kv.z, kv.w};
            #pragma unroll
            for (int j = 0; j < 4; ++j)
                KTb[bswz(b4 + j, s)] = f2bf(ratio * kvr[j]);
        }
    }
    __syncthreads();

    if (tid < 128) {
        int col = tid & 63;
        int wK = tid >> 6;
        float* Xp = wK ? Kc : Vx;
        ushort* XT = wK ? XkT : XvT;
        #pragma unroll 1
        for (int tb = 0; tb < 64; tb += 8) {
            unsigned pk0 = 0, pk1 = 0, pk2 = 0, pk3 = 0;
            #pragma unroll
            for (int u = 0; u < 8; ++u) {
                int t = tb + u;
                float bsv = __shfl(bsreg, t);
                float acc = wK ? (bsv * __shfl(gsreg, t) * Kc[swz(t, col)])
                               : (bsv * Vx[swz(t, col)]);
                int t4 = t & ~3;
                for (int s4 = 0; s4 < t4; s4 += 4) {
                    float4 mp = *(const float4*)&Mm[swz4(t, s4)];
                    acc = fmaf(-mp.x, Xp[swz(s4 + 0, col)], acc);
                    acc = fmaf(-mp.y, Xp[swz(s4 + 1, col)], acc);
                    acc = fmaf(-mp.z, Xp[swz(s4 + 2, col)], acc);
                    acc = fmaf(-mp.w, Xp[swz(s4 + 3, col)], acc);
                }
                for (int s = t4; s < t; ++s)
                    acc = fmaf(-Mm[swz(t, s)], Xp[swz(s, col)], acc);
                Xp[swz(t, col)] = acc;
                unsigned hb = (unsigned)f2bf(acc) << ((u & 1) * 16);
                if (u == 0) pk0 = hb; else if (u == 1) pk0 |= hb;
                else if (u == 2) pk1 = hb; else if (u == 3) pk1 |= hb;
                else if (u == 4) pk2 = hb; else if (u == 5) pk2 |= hb;
                else if (u == 6) pk3 = hb; else pk3 |= hb;
            }
            int slot = (((tb >> 3) ^ (col & 7)) << 3);
            uint4 pkv = {pk0, pk1, pk2, pk3};
            *(uint4*)&XT[col * 64 + slot] = pkv;
        }
    }
    __syncthreads();

    {
        int a_r = w * 16 + l16;
        bf16x8 xkA[2], ktA[2], abA[2];
        #pragma unroll
        for (int kk = 0; kk < 2; ++kk) {
            int sl = ((kk * 4 + lq) ^ (a_r & 7)) << 3;
            xkA[kk] = *(bf16x8*)&XkT[a_r * 64 + sl];
            ktA[kk] = *(bf16x8*)&KTb[a_r * 64 + sl];
            abA[kk] = *(bf16x8*)&Abf[a_r * 64 + sl];
        }
        size_t tile = ((size_t)(c * HH + h)) << 12;
        int a0f = w * 16 + lq * 4;
        #pragma unroll
        for (int ct = 0; ct < 4; ++ct) {
            int b_r = ct * 16 + l16;
            f32x4 accB = {0.f,0.f,0.f,0.f}, accC = {0.f,0.f,0.f,0.f};
            f32x4 accF = {0.f,0.f,0.f,0.f}, accE = {0.f,0.f,0.f,0.f};
            #pragma unroll
            for (int kk = 0; kk < 2; ++kk) {
                int sl = ((kk * 4 + lq) ^ (b_r & 7)) << 3;
                bf16x8 ktB = *(bf16x8*)&KTb[b_r * 64 + sl];
                bf16x8 xvB = *(bf16x8*)&XvT[b_r * 64 + sl];
                bf16x8 abB = *(bf16x8*)&Abf[b_r * 64 + sl];
                accB = __builtin_amdgcn_mfma_f32_16x16x32_bf16(xkA[kk], ktB, accB, 0, 0, 0);
                accC = __builtin_amdgcn_mfma_f32_16x16x32_bf16(ktA[kk], xvB, accC, 0, 0, 0);
                accF = __builtin_amdgcn_mfma_f32_16x16x32_bf16(xkA[kk], abB, accF, 0, 0, 0);
                accE = __builtin_amdgcn_mfma_f32_16x16x32_bf16(abA[kk], xvB, accE, 0, 0, 0);
            }
            float gB = __shfl(gsreg, b_r);
            float4 qv = *(const float4*)&qb[(size_t)(t0 + b_r) * EE + h * DD + a0f];
            float qvr[4] = {qv.x, qv.y, qv.z, qv.w};
            #pragma unroll
            for (int i = 0; i < 4; ++i) {
                int a = a0f + i;
                Bt[tile + (size_t)a * 64 + b_r] = accB[i];
                Ct[tile + (size_t)a * 64 + b_r] = accC[i];
                Ft[tile + (size_t)a * 64 + b_r] = SCALE * gB * qvr[i] - accF[i];
                vb[(size_t)(t0 + a) * EE + h * DD + b_r] = accE[i];
            }
        }
    }
}

// ---------------------------------------------------------------------------
// Delta rule serial S-chain, column-split: grid (CPH, HH).
// ---------------------------------------------------------------------------
__global__ __launch_bounds__(256) void delta_scan4_kernel(
    const float* __restrict__ Bt, const float* __restrict__ Ct,
    const float* __restrict__ g, float* __restrict__ Sout)
{
    __shared__ __align__(16) float Bsb[2][4096];
    __shared__ __align__(16) float Csb[2][512];
    __shared__ float Ss[64][10];
    __shared__ float GCs[NCH];
    int p = blockIdx.x, h = blockIdx.y;
    int bo = p * 8;
    int tid = threadIdx.x;
    int a = tid & 63;
    int w = tid >> 6;
    int j0 = w * 2;

    {
        float pr = 1.f;
        int t0 = tid * 8;
        #pragma unroll
        for (int j = 0; j < 8; ++j) pr *= g[(t0 + j) * HH + h];
        pr *= __shfl_xor(pr, 1);
        pr *= __shfl_xor(pr, 2);
        pr *= __shfl_xor(pr, 4);
        GCs[tid >> 3] = pr;
        Ss[a][j0] = 0.f;
        Ss[a][j0 + 1] = 0.f;
    }

#define STG4(buf, cc)                                                          \
    {                                                                          \
        size_t tb = ((size_t)((cc) * HH + h)) << 12;                           \
        _Pragma("unroll")                                                      \
        for (int u = 0; u < 4; ++u) {                                          \
            int fi = ((u << 8) + tid) << 2;                                    \
            int fb = ((u << 8) + (tid & 192)) << 2;                            \
            __builtin_amdgcn_global_load_lds((gptr_t)&Bt[tb + fi],             \
                (lptr_t)&Bsb[buf][fb], 16, 0, 0);                              \
        }                                                                      \
        if (tid < 128) {                                                       \
            size_t cfi = tb + ((size_t)(tid >> 1) << 6) + bo + ((tid & 1) << 2); \
            __builtin_amdgcn_global_load_lds((gptr_t)&Ct[cfi],                 \
                (lptr_t)&Csb[buf][(tid & 64) << 2], 16, 0, 0);                 \
        }                                                                      \
    }

    STG4(0, 0)
    for (int c = 0; c < NCH; ++c) {
        __syncthreads();
        if (c + 1 < NCH) STG4((c + 1) & 1, c + 1)
        const float* Bsp = Bsb[c & 1];
        const float* Csp = Csb[c & 1];
        float gc = GCs[c];
        size_t tile = ((size_t)(c * HH + h)) << 12;
        float s0 = Ss[a][j0], s1 = Ss[a][j0 + 1];
        Sout[tile + (size_t)(bo + j0) * 64 + a] = s0;
        Sout[tile + (size_t)(bo + j0 + 1) * 64 + a] = s1;
        float p0 = 0.f, p1 = 0.f;
        #pragma unroll 4
        for (int k = 0; k < 64; ++k) {
            float bk = Bsp[k * 64 + a];
            float2 sv = *(const float2*)&Ss[k][j0];
            p0 = fmaf(bk, sv.x, p0);
            p1 = fmaf(bk, sv.y, p1);
        }
        __syncthreads();
        float c0v = Csp[a * 8 + j0], c1v = Csp[a * 8 + j0 + 1];
        Ss[a][j0]     = fmaf(gc, s0, c0v - p0);
        Ss[a][j0 + 1] = fmaf(gc, s1, c1v - p1);
    }
#undef STG4
}

// ---------------------------------------------------------------------------
// Delta rule parallel output map: O_c = F_c.S_c + E_c. grid (NCH, HH).
// ---------------------------------------------------------------------------
__global__ __launch_bounds__(256) void delta_apply_kernel(
    const float* __restrict__ Sb, const float* __restrict__ Ft,
    float* __restrict__ vb)
{
    __shared__ float Fs[64][64];
    __shared__ float S2[64][68];
    int c = blockIdx.x, h = blockIdx.y;
    int tid = threadIdx.x;
    int tx = tid & 15, ty = tid >> 4;
    int a0 = ty << 2, b0 = tx << 2;
    size_t tile = ((size_t)(c * HH + h)) << 12;
    {
        int row = tid >> 4, c4 = (tid & 15) << 2;
        #pragma unroll
        for (int m = 0; m < 4; ++m) {
            int r = row + m * 16;
            *(float4*)&Fs[r][c4] = *(const float4*)&Ft[tile + r * 64 + c4];
            float4 sv = *(const float4*)&Sb[tile + r * 64 + c4];
            S2[c4 + 0][r] = sv.x;
            S2[c4 + 1][r] = sv.y;
            S2[c4 + 2][r] = sv.z;
            S2[c4 + 3][r] = sv.w;
        }
    }
    __syncthreads();
    float accO[4][4] = {};
    #pragma unroll 4
    for (int k = 0; k < 64; ++k) {
        float4 fv = *(const float4*)&Fs[k][a0];
        float4 sv = *(const float4*)&S2[k][b0];
        float fa[4] = {fv.x, fv.y, fv.z, fv.w};
        float sa[4] = {sv.x, sv.y, sv.z, sv.w};
        #pragma unroll
        for (int i = 0; i < 4; ++i)
            #pragma unroll
            for (int j = 0; j < 4; ++j)
                accO[i][j] = fmaf(fa[i], sa[j], accO[i][j]);
    }
    #pragma unroll
    for (int i = 0; i < 4; ++i) {
        size_t gi = (size_t)((c << 6) + a0 + i) * EE + h * DD + b0;
        float4 ev = *(const float4*)&vb[gi];
        float4 ov = {accO[i][0] + ev.x, accO[i][1] + ev.y,
                     accO[i][2] + ev.z, accO[i][3] + ev.w};
        *(float4*)&vb[gi] = ov;
    }
}

// ---------------------------------------------------------------------------
// Causal flash attention, bf16 MFMA, swapped-operand QK^T (S^T layout).
// v2: XCD-pinned head swizzle (all 32 blocks of head h on XCD h%8 -> K/V
// L2-resident), V staged via 4x ds_write_b64 (s-quad x d-quad per thread).
// Math identical to round 11.
// ---------------------------------------------------------------------------
__global__ __launch_bounds__(256) void attn_mfma_kernel(
    const float* __restrict__ q, const float* __restrict__ k, const float* __restrict__ v,
    ushort* __restrict__ y)
{
    __shared__ __align__(16) unsigned short KsL[64 * KS];
    __shared__ __align__(16) unsigned short VtL[64 * KS];
    __shared__ __align__(16) unsigned int PL[4][16 * 36];  // packed P, stride 36 u32

    // XCD-pinned decode: xcd = bid&7 hosts heads {xcd, xcd+8}; heavy rows first
    int bid = (int)blockIdx.x;
    int xcd = bid & 7;
    int idx = bid >> 3;                 // 0..63 within XCD
    int h = xcd + ((idx & 1) << 3);
    int rb = (31 - (idx >> 1)) * 64;

    int tid = threadIdx.x;
    int w = tid >> 6;
    int lane = tid & 63;
    int l16 = lane & 15;
    int lq = lane >> 4;
    int qr0 = rb + w * 16;
    unsigned* PLw = PL[w];

    bf16x8 qf[2];
    {
        const float* qrow = &q[(size_t)(qr0 + l16) * EE + h * DD];
        #pragma unroll
        for (int kk = 0; kk < 2; ++kk) {
            float4 v0 = *(const float4*)&qrow[kk * 32 + lq * 8];
            float4 v1 = *(const float4*)&qrow[kk * 32 + lq * 8 + 4];
            qf[kk][0] = (short)f2bf(v0.x); qf[kk][1] = (short)f2bf(v0.y);
            qf[kk][2] = (short)f2bf(v0.z); qf[kk][3] = (short)f2bf(v0.w);
            qf[kk][4] = (short)f2bf(v1.x); qf[kk][5] = (short)f2bf(v1.y);
            qf[kk][6] = (short)f2bf(v1.z); qf[kk][7] = (short)f2bf(v1.w);
        }
    }

    f32x4 oacc[4];
    #pragma unroll
    for (int dt = 0; dt < 4; ++dt) oacc[dt] = (f32x4){0.f, 0.f, 0.f, 0.f};
    float mrow = -3e38f, lrow = 0.f;
    const int qrow_i = qr0 + l16;

    int ks_s = tid >> 2, ks_d0 = (tid & 3) << 4;
    int vt_s0 = (tid & 15) << 2;        // s-quad
    int vt_d0 = (tid >> 4) << 2;        // d-quad

    float4 kreg[4];
    f32x4 vreg0, vreg1, vreg2, vreg3;

#define ATT_ISSUE(c0)                                                          \
    {                                                                          \
        const float* krow = &k[(size_t)((c0) + ks_s) * EE + h * DD + ks_d0];   \
        kreg[0] = *(const float4*)&krow[0];                                    \
        kreg[1] = *(const float4*)&krow[4];                                    \
        kreg[2] = *(const float4*)&krow[8];                                    \
        kreg[3] = *(const float4*)&krow[12];                                   \
        const float* vrow = &v[(size_t)((c0) + vt_s0) * EE + h * DD + vt_d0];  \
        vreg0 = *(const f32x4*)&vrow[0];                                       \
        vreg1 = *(const f32x4*)&vrow[EE];                                      \
        vreg2 = *(const f32x4*)&vrow[2 * EE];                                  \
        vreg3 = *(const f32x4*)&vrow[3 * EE];                                  \
    }

    ATT_ISSUE(0)
    for (int c0 = 0; c0 <= rb; c0 += 64) {
        __syncthreads();          // prior tile's LDS reads complete
        {
            #pragma unroll
            for (int u = 0; u < 4; ++u) {
                bf16x4 pk4 = { (short)f2bf(kreg[u].x), (short)f2bf(kreg[u].y),
                               (short)f2bf(kreg[u].z), (short)f2bf(kreg[u].w) };
                *(bf16x4*)&KsL[ks_s * KS + ks_d0 + u * 4] = pk4;
            }
            #pragma unroll
            for (int dd = 0; dd < 4; ++dd) {
                uint2 pv;
                pv.x = (unsigned)f2bf(vreg0[dd]) | ((unsigned)f2bf(vreg1[dd]) << 16);
                pv.y = (unsigned)f2bf(vreg2[dd]) | ((unsigned)f2bf(vreg3[dd]) << 16);
                *(uint2*)&VtL[(vt_d0 + dd) * KS + vt_s0] = pv;   // ds_write_b64
            }
        }
        __syncthreads();          // tile visible to all waves
        if (c0 + 64 <= rb) ATT_ISSUE(c0 + 64)

        f32x4 sacc[4];
        #pragma unroll
        for (int ct = 0; ct < 4; ++ct) {
            bf16x8 ka0 = *(bf16x8*)&KsL[(ct * 16 + l16) * KS + lq * 8];
            bf16x8 ka1 = *(bf16x8*)&KsL[(ct * 16 + l16) * KS + 32 + lq * 8];
            f32x4 acc = {0.f, 0.f, 0.f, 0.f};
            acc = __builtin_amdgcn_mfma_f32_16x16x32_bf16(ka0, qf[0], acc, 0, 0, 0);
            acc = __builtin_amdgcn_mfma_f32_16x16x32_bf16(ka1, qf[1], acc, 0, 0, 0);
            sacc[ct] = acc;
        }

        float sv[4][4];
        float tm = -3e38f;
        #pragma unroll
        for (int ct = 0; ct < 4; ++ct) {
            int sbase = c0 + ct * 16 + lq * 4;
            #pragma unroll
            for (int r = 0; r < 4; ++r) {
                float s = sacc[ct][r] * SCALE;
                if (sbase + r > qrow_i) s = -3e38f;
                sv[ct][r] = s;
                tm = fmaxf(tm, s);
            }
        }
        tm = fmaxf(tm, __shfl_xor(tm, 16));
        tm = fmaxf(tm, __shfl_xor(tm, 32));
        float mn = fmaxf(mrow, tm);
        float corr = __expf(mrow - mn);
        mrow = mn;

        float ps = 0.f;
        #pragma unroll
        for (int ct = 0; ct < 4; ++ct) {
            float p0 = __expf(sv[ct][0] - mn);
            float p1 = __expf(sv[ct][1] - mn);
            float p2 = __expf(sv[ct][2] - mn);
            float p3 = __expf(sv[ct][3] - mn);
            ps += (p0 + p1) + (p2 + p3);
            uint2 wv;
            wv.x = (unsigned)f2bf(p0) | ((unsigned)f2bf(p1) << 16);
            wv.y = (unsigned)f2bf(p2) | ((unsigned)f2bf(p3) << 16);
            *(uint2*)&PLw[l16 * 36 + ct * 8 + lq * 2] = wv;
        }
        ps += __shfl_xor(ps, 16);
        ps += __shfl_xor(ps, 32);
        lrow = lrow * corr + ps;

        float corr_o[4];
        #pragma unroll
        for (int r = 0; r < 4; ++r)
            corr_o[r] = __shfl(corr, (lane & 48) + lq * 4 + r);
        #pragma unroll
        for (int dt = 0; dt < 4; ++dt) {
            #pragma unroll
            for (int r = 0; r < 4; ++r)
                oacc[dt][r] *= corr_o[r];
        }

        bf16x8 pa0 = *(bf16x8*)&PLw[l16 * 36 + lq * 4];
        bf16x8 pa1 = *(bf16x8*)&PLw[l16 * 36 + 16 + lq * 4];
        #pragma unroll
        for (int dt = 0; dt < 4; ++dt) {
            bf16x8 vv0 = *(bf16x8*)&VtL[(dt * 16 + l16) * KS + lq * 8];
            bf16x8 vv1 = *(bf16x8*)&VtL[(dt * 16 + l16) * KS + 32 + lq * 8];
            oacc[dt] = __builtin_amdgcn_mfma_f32_16x16x32_bf16(pa0, vv0, oacc[dt], 0, 0, 0);
            oacc[dt] = __builtin_amdgcn_mfma_f32_16x16x32_bf16(pa1, vv1, oacc[dt], 0, 0, 0);
        }
    }
#undef ATT_ISSUE

    float li = 1.f / lrow;
    float linv_o[4];
    #pragma unroll
    for (int r = 0; r < 4; ++r)
        linv_o[r] = __shfl(li, (lane & 48) + lq * 4 + r);
    #pragma unroll
    for (int dt = 0; dt < 4; ++dt) {
        #pragma unroll
        for (int r = 0; r < 4; ++r) {
            int row = qr0 + lq * 4 + r;
            y[(size_t)row * EE + h * DD + dt * 16 + l16] = f2bf(oacc[dt][r] * linv_o[r]);
        }
    }
}

// ---------------------------------------------------------------------------
extern "C" void kernel_launch(void* const* d_in, const int* in_sizes, int n_in,
                              void* d_out, int out_size, void* d_ws, size_t ws_size,
                              hipStream_t stream)
{
    (void)in_sizes; (void)n_in; (void)out_size; (void)ws_size;
    const float* x      = (const float*)d_in[0];
    const float* w_attn = (const float*)d_in[1];
    const float* w_proj = (const float*)d_in[2];
    const float* qcw    = (const float*)d_in[3];
    const float* kcw    = (const float*)d_in[4];
    const float* vcw    = (const float*)d_in[5];
    const float* cosb   = (const float*)d_in[6];
    const float* sinb   = (const float*)d_in[7];
    const float* beta   = (const float*)d_in[8];
    const float* g      = (const float*)d_in[9];
    float* out = (float*)d_out;
    float* ws  = (float*)d_ws;

    const size_t TE = (size_t)TT * EE;
    float* buf0 = ws + 0 * TE;          // qkv -> Bt
    float* buf1 = ws + 1 * TE;          // qkv -> Ct -> ybf
    float* buf2 = ws + 2 * TE;          // qkv -> Ft -> wpT
    float* qb   = ws + 3 * TE;          // xbf -> q
    float* kb   = ws + 4 * TE;          // waT -> k
    float* vb   = ws + 5 * TE;          // v -> E -> O
    float* qkv  = buf0;
    ushort* xbf = (ushort*)qb;
    ushort* waT = (ushort*)kb;
    ushort* ybf = (ushort*)buf1;
    ushort* wpT = (ushort*)buf2;
    float* Sbuf = out;                  // d_out as S-tile scratch

    cvt_bf16_kernel<<<TT * EE / 2048, 256, 0, stream>>>(x, xbf);
    cvt_transpose_kernel<<<dim3(NN / 64, EE / 64), 256, 0, stream>>>(w_attn, waT, EE, NN);
    gemm_bf16<128, 128><<<dim3(NN / 128, TT / 128), 256, 0, stream>>>(
        xbf, waT, qkv, TT, NN, EE);
    conv_rope_kernel<<<dim3(TT / 4, HH, 3), dim3(64, 4), 0, stream>>>(
        qkv, qcw, kcw, vcw, cosb, sinb, qb, kb, vb);
    chunk_prep_kernel<<<dim3(NCH, HH), 256, 0, stream>>>(qb, kb, vb, beta, g, buf0, buf1, buf2);
    delta_scan4_kernel<<<dim3(CPH, HH), 256, 0, stream>>>(buf0, buf1, g, Sbuf);
    delta_apply_kernel<<<dim3(NCH, HH), 256, 0, stream>>>(Sbuf, buf2, vb);
    cvt_transpose_kernel<<<dim3(EE / 64, EE / 64), 256, 0, stream>>>(w_proj, wpT, EE, EE);
    attn_mfma_kernel<<<dim3(512), 256, 0, stream>>>(qb, kb, vb, ybf);
    gemm_bf16<64, 64><<<dim3(EE / 64, TT / 64), 256, 0, stream>>>(
        ybf, wpT, out, TT, EE, EE);
}

// Round 13
// 239.831 us; speedup vs baseline: 9.6475x; 1.0094x over previous
//
#include <hip/hip_runtime.h>
#include <math.h>

#define TT 2048
#define HH 16
#define DD 64
#define EE 1024
#define NN 3072
#define CHUNK 64
#define NCH (TT / CHUNK)
#define SCALE 0.125f
#define KS 72   // attn LDS row stride (bf16): conflict-free b128
#define CPH 8   // column-split blocks per head in delta scan

typedef short bf16x8 __attribute__((ext_vector_type(8)));
typedef short bf16x4 __attribute__((ext_vector_type(4)));
typedef float f32x4 __attribute__((ext_vector_type(4)));
typedef unsigned short ushort;
typedef const __attribute__((address_space(1))) unsigned int* gptr_t;
typedef __attribute__((address_space(3))) unsigned int* lptr_t;

__device__ __forceinline__ unsigned short f2bf(float x) {
    union { float f; unsigned u; } un; un.f = x;
    unsigned r = un.u + 0x7FFFu + ((un.u >> 16) & 1u);
    return (unsigned short)(r >> 16);
}

// XOR slot swizzle for 64-float rows (4-float slots, key = row bits 2..4)
__device__ __forceinline__ int swz(int r, int c) {
    return (r << 6) + ((((c >> 2) ^ ((r >> 2) & 7)) << 2) | (c & 3));
}
__device__ __forceinline__ int swz4(int r, int c4) {
    return (r << 6) + (((c4 >> 2) ^ ((r >> 2) & 7)) << 2);
}
// XOR slot swizzle for 64-bf16 rows (8-elem 16B slots, key = row bits 0..2)
__device__ __forceinline__ int bswz(int r, int c) {
    return (r << 6) + ((((c >> 3) ^ (r & 7)) << 3) | (c & 7));
}

// ---------------------------------------------------------------------------
// fp32 -> bf16 elementwise convert (x)
// ---------------------------------------------------------------------------
__global__ __launch_bounds__(256) void cvt_bf16_kernel(
    const float* __restrict__ in, ushort* __restrict__ out)
{
    int i = ((int)blockIdx.x * 256 + (int)threadIdx.x) << 3;
    float4 a = *(const float4*)&in[i];
    float4 b = *(const float4*)&in[i + 4];
    bf16x8 o;
    o[0] = (short)f2bf(a.x); o[1] = (short)f2bf(a.y);
    o[2] = (short)f2bf(a.z); o[3] = (short)f2bf(a.w);
    o[4] = (short)f2bf(b.x); o[5] = (short)f2bf(b.y);
    o[6] = (short)f2bf(b.z); o[7] = (short)f2bf(b.w);
    *(bf16x8*)&out[i] = o;
}

// ---------------------------------------------------------------------------
// fp32 [K][N] -> bf16 [N][K] convert + transpose (weights)
// ---------------------------------------------------------------------------
__global__ __launch_bounds__(256) void cvt_transpose_kernel(
    const float* __restrict__ W, ushort* __restrict__ WT, int K, int N)
{
    __shared__ float Ls[64][65];
    int n0 = blockIdx.x * 64, k0 = blockIdx.y * 64;
    int tid = threadIdx.x;
    int lr = tid >> 4, lc4 = (tid & 15) << 2;
    #pragma unroll
    for (int m = 0; m < 4; ++m) {
        int r = lr + m * 16;
        float4 v = *(const float4*)&W[(size_t)(k0 + r) * N + n0 + lc4];
        Ls[r][lc4 + 0] = v.x; Ls[r][lc4 + 1] = v.y;
        Ls[r][lc4 + 2] = v.z; Ls[r][lc4 + 3] = v.w;
    }
    __syncthreads();
    int n = tid >> 2, kb = (tid & 3) << 4;
    bf16x8 o0, o1;
    #pragma unroll
    for (int j = 0; j < 8; ++j) o0[j] = (short)f2bf(Ls[kb + j][n]);
    #pragma unroll
    for (int j = 0; j < 8; ++j) o1[j] = (short)f2bf(Ls[kb + 8 + j][n]);
    *(bf16x8*)&WT[(size_t)(n0 + n) * K + k0 + kb] = o0;
    *(bf16x8*)&WT[(size_t)(n0 + n) * K + k0 + kb + 8] = o1;
}

// ---------------------------------------------------------------------------
// bf16 MFMA GEMM: C(fp32)[M][N] = A(bf16)[M][K] * BT(bf16)[N][K]^T
// ---------------------------------------------------------------------------
template<int BM, int BN>
__global__ __launch_bounds__(256) void gemm_bf16(
    const ushort* __restrict__ A, const ushort* __restrict__ BT,
    float* __restrict__ C, int M, int N, int K)
{
    constexpr int MT = BM / 32;
    constexpr int NT = BN / 32;
    constexpr int AIT = BM * 64 / 2048;
    constexpr int BIT = BN * 64 / 2048;
    __shared__ __align__(16) ushort Asl[2][BM * 64];
    __shared__ __align__(16) ushort Bsl[2][BN * 64];
    const int tid = threadIdx.x;
    const int lane = tid & 63, w = tid >> 6;
    const int wm = w >> 1, wn = w & 1;
    const int l16 = lane & 15, lq = lane >> 4;
    const int row0 = blockIdx.y * BM, col0 = blockIdx.x * BN;
    const int wvb = w << 9;

    f32x4 acc[MT][NT];
    #pragma unroll
    for (int i = 0; i < MT; ++i)
        #pragma unroll
        for (int j = 0; j < NT; ++j)
            acc[i][j] = (f32x4){0.f, 0.f, 0.f, 0.f};

#define STAGE_TILE(buf, k0)                                                    \
    {                                                                          \
        _Pragma("unroll")                                                      \
        for (int u = 0; u < AIT; ++u) {                                        \
            int idx = u * 256 + tid;                                           \
            int r = idx >> 3, s = idx & 7;                                     \
            const ushort* srcp =                                               \
                &A[(size_t)(row0 + r) * K + (k0) + ((s ^ (r & 7)) << 3)];      \
            __builtin_amdgcn_global_load_lds((gptr_t)srcp,                     \
                (lptr_t)&Asl[buf][(u << 11) + wvb], 16, 0, 0);                 \
        }                                                                      \
        _Pragma("unroll")                                                      \
        for (int u = 0; u < BIT; ++u) {                                        \
            int idx = u * 256 + tid;                                           \
            int r = idx >> 3, s = idx & 7;                                     \
            const ushort* srcp =                                               \
                &BT[(size_t)(col0 + r) * K + (k0) + ((s ^ (r & 7)) << 3)];     \
            __builtin_amdgcn_global_load_lds((gptr_t)srcp,                     \
                (lptr_t)&Bsl[buf][(u << 11) + wvb], 16, 0, 0);                 \
        }                                                                      \
    }

    const int nK = K >> 6;
    STAGE_TILE(0, 0)
    for (int kt = 0; kt < nK; ++kt) {
        __syncthreads();                       // stage(kt) drained + visible
        if (kt + 1 < nK) STAGE_TILE((kt + 1) & 1, (kt + 1) << 6)
        const int cb = kt & 1;
        #pragma unroll
        for (int kk = 0; kk < 2; ++kk) {
            bf16x8 afr[MT], bfr[NT];
            #pragma unroll
            for (int mt = 0; mt < MT; ++mt) {
                int rr = wm * (BM / 2) + mt * 16 + l16;
                afr[mt] = *(bf16x8*)&Asl[cb][rr * 64 +
                           (((kk * 4 + lq) ^ (rr & 7)) << 3)];
            }
            #pragma unroll
            for (int nt = 0; nt < NT; ++nt) {
                int cc = wn * (BN / 2) + nt * 16 + l16;
                bfr[nt] = *(bf16x8*)&Bsl[cb][cc * 64 +
                           (((kk * 4 + lq) ^ (cc & 7)) << 3)];
            }
            #pragma unroll
            for (int mt = 0; mt < MT; ++mt)
                #pragma unroll
                for (int nt = 0; nt < NT; ++nt)
                    acc[mt][nt] = __builtin_amdgcn_mfma_f32_16x16x32_bf16(
                        afr[mt], bfr[nt], acc[mt][nt], 0, 0, 0);
        }
    }
#undef STAGE_TILE

    #pragma unroll
    for (int mt = 0; mt < MT; ++mt) {
        #pragma unroll
        for (int nt = 0; nt < NT; ++nt) {
            int col = col0 + wn * (BN / 2) + nt * 16 + l16;
            #pragma unroll
            for (int r = 0; r < 4; ++r) {
                int row = row0 + wm * (BM / 2) + mt * 16 + lq * 4 + r;
                C[(size_t)row * N + col] = acc[mt][nt][r];
            }
        }
    }
}

// ---------------------------------------------------------------------------
// Causal depthwise conv1d (DC=4) + SiLU, then RoPE for q,k; v plain.
// ---------------------------------------------------------------------------
__global__ __launch_bounds__(256) void conv_rope_kernel(
    const float* __restrict__ qkv,
    const float* __restrict__ qw, const float* __restrict__ kw, const float* __restrict__ vw,
    const float* __restrict__ cosb, const float* __restrict__ sinb,
    float* __restrict__ qo, float* __restrict__ ko, float* __restrict__ vo)
{
    int j = blockIdx.z;
    const float* w = (j == 0) ? qw : (j == 1) ? kw : vw;
    float* dst     = (j == 0) ? qo : (j == 1) ? ko : vo;
    int d  = threadIdx.x;
    int tl = threadIdx.y;
    int t  = blockIdx.x * 4 + tl;
    int h  = blockIdx.y;
    int c  = h * DD + d;
    int n  = h * 192 + j * 64 + d;
    float acc = 0.f;
    #pragma unroll
    for (int i = 0; i < 4; ++i) {
        int tt = t - 3 + i;
        if (tt >= 0) acc = fmaf(qkv[(size_t)tt * NN + n], w[c * 4 + i], acc);
    }
    float yv = acc / (1.f + __expf(-acc));
    if (j == 2) { dst[t * EE + c] = yv; return; }
    __shared__ float sh[4][64];
    sh[tl][d] = yv;
    __syncthreads();
    int dh = d & 31;
    float cc = cosb[t * 32 + dh];
    float ss = sinb[t * 32 + dh];
    float outv;
    if (d < 32) outv = yv * cc - sh[tl][d + 32] * ss;
    else        outv = yv * cc + sh[tl][d - 32] * ss;
    dst[t * EE + c] = outv;
}

// ---------------------------------------------------------------------------
// Chunked gated delta rule, phase 1 — v3 (MFMA phase B + fold, fp32 subst).
// ---------------------------------------------------------------------------
__global__ __launch_bounds__(256) void chunk_prep_kernel(
    const float* __restrict__ qb, const float* __restrict__ kb, float* __restrict__ vb,
    const float* __restrict__ beta, const float* __restrict__ g,
    float* __restrict__ Bt, float* __restrict__ Ct, float* __restrict__ Ft)
{
    __shared__ __align__(16) float Kc[4096];     // K fp32 swz -> Xk in place
    __shared__ __align__(16) float Vx[4096];     // V fp32 swz -> Xv in place
    __shared__ __align__(16) float Mpool[4096];  // Kbf+Qbf bf16 -> M fp32 swz
    __shared__ __align__(16) ushort Abf[4096];   // A~ bf16 [t][s] bswz (0 for s>t)
    __shared__ __align__(16) ushort KTb[4096];   // K~^T bf16 [b][s] bswz
    __shared__ __align__(16) ushort XkT[4096];   // Xk^T bf16 [a][s] bswz
    __shared__ __align__(16) ushort XvT[4096];   // Xv^T bf16 [a][s] bswz
    ushort* Kbf = (ushort*)Mpool;
    ushort* Qbf = (ushort*)Mpool + 4096;
    float*  Mm  = Mpool;

    int c = blockIdx.x, h = blockIdx.y;
    int tid = threadIdx.x;
    int lane = tid & 63;
    int w = tid >> 6;
    int l16 = lane & 15, lq = lane >> 4;
    int t0 = c * CHUNK;

    float gsreg, bsreg;
    {
        float x = g[(t0 + lane) * HH + h];
        #pragma unroll
        for (int off = 1; off < 64; off <<= 1) {
            float y = __shfl_up(x, off);
            if (lane >= off) x *= y;
        }
        gsreg = x;
        bsreg = beta[(t0 + lane) * HH + h];
    }

    {
        int row = tid >> 4, c4 = (tid & 15) << 2;
        #pragma unroll
        for (int m = 0; m < 4; ++m) {
            int r = row + m * 16;
            size_t gidx = (size_t)(t0 + r) * EE + h * DD + c4;
            float4 kv = *(const float4*)&kb[gidx];
            float4 qv = *(const float4*)&qb[gidx];
            float4 vv = *(const float4*)&vb[gidx];
            *(float4*)&Kc[swz4(r, c4)] = kv;
            *(float4*)&Vx[swz4(r, c4)] = vv;
            int ba = bswz(r, c4);
            bf16x4 kb4 = { (short)f2bf(kv.x), (short)f2bf(kv.y),
                           (short)f2bf(kv.z), (short)f2bf(kv.w) };
            bf16x4 qb4 = { (short)f2bf(qv.x), (short)f2bf(qv.y),
                           (short)f2bf(qv.z), (short)f2bf(qv.w) };
            *(bf16x4*)&Kbf[ba] = kb4;
            *(bf16x4*)&Qbf[ba] = qb4;
        }
    }
    __syncthreads();

    f32x4 akk[4], aqk[4];
    {
        bf16x8 kaf[2];
        int rr = w * 16 + l16;
        #pragma unroll
        for (int kk = 0; kk < 2; ++kk)
            kaf[kk] = *(bf16x8*)&Kbf[rr * 64 + (((kk * 4 + lq) ^ (rr & 7)) << 3)];
        #pragma unroll
        for (int ct = 0; ct < 4; ++ct) {
            int tt = ct * 16 + l16;
            f32x4 a1 = {0.f, 0.f, 0.f, 0.f}, a2 = {0.f, 0.f, 0.f, 0.f};
            #pragma unroll
            for (int kk = 0; kk < 2; ++kk) {
                int sl = ((kk * 4 + lq) ^ (tt & 7)) << 3;
                bf16x8 kbfr = *(bf16x8*)&Kbf[tt * 64 + sl];
                bf16x8 qbfr = *(bf16x8*)&Qbf[tt * 64 + sl];
                a1 = __builtin_amdgcn_mfma_f32_16x16x32_bf16(kaf[kk], kbfr, a1, 0, 0, 0);
                a2 = __builtin_amdgcn_mfma_f32_16x16x32_bf16(kaf[kk], qbfr, a2, 0, 0, 0);
            }
            akk[ct] = a1; aqk[ct] = a2;
        }
    }
    __syncthreads();

    {
        int s0 = w * 16 + lq * 4;
        float gS[4];
        #pragma unroll
        for (int r = 0; r < 4; ++r) gS[r] = __shfl(gsreg, s0 + r);
        #pragma unroll
        for (int ct = 0; ct < 4; ++ct) {
            int t = ct * 16 + l16;
            float gT = __shfl(gsreg, t);
            float bT = __shfl(bsreg, t);
            float mw[4];
            bf16x4 ab4;
            #pragma unroll
            for (int r = 0; r < 4; ++r) {
                int s = s0 + r;
                float gr = gT / gS[r];
                mw[r] = bT * gr * akk[ct][r];
                float av = (s <= t) ? SCALE * gr * aqk[ct][r] : 0.f;
                ab4[r] = (short)f2bf(av);
            }
            float4 mw4 = {mw[0], mw[1], mw[2], mw[3]};
            *(float4*)&Mm[swz4(t, s0)] = mw4;
            *(bf16x4*)&Abf[bswz(t, s0)] = ab4;
        }
    }

    {
        float g63 = __shfl(gsreg, 63);
        int s = tid >> 2;
        int cb = (tid & 3) << 4;
        float ratio = g63 / __shfl(gsreg, s);
        #pragma unroll
        for (int u = 0; u < 4; ++u) {
            int b4 = cb + u * 4;
            float4 kv = *(const float4*)&Kc[swz4(s, b4)];
            float kvr[4] = {kv.x, kv.y, kv.z, kv.w};
            #pragma unroll
            for (int j = 0; j < 4; ++j)
                KTb[bswz(b4 + j, s)] = f2bf(ratio * kvr[j]);
        }
    }
    __syncthreads();

    if (tid < 128) {
        int col = tid & 63;
        int wK = tid >> 6;
        float* Xp = wK ? Kc : Vx;
        ushort* XT = wK ? XkT : XvT;
        #pragma unroll 1
        for (int tb = 0; tb < 64; tb += 8) {
            unsigned pk0 = 0, pk1 = 0, pk2 = 0, pk3 = 0;
            #pragma unroll
            for (int u = 0; u < 8; ++u) {
                int t = tb + u;
                float bsv = __shfl(bsreg, t);
                float acc = wK ? (bsv * __shfl(gsreg, t) * Kc[swz(t, col)])
                               : (bsv * Vx[swz(t, col)]);
                int t4 = t & ~3;
                for (int s4 = 0; s4 < t4; s4 += 4) {
                    float4 mp = *(const float4*)&Mm[swz4(t, s4)];
                    acc = fmaf(-mp.x, Xp[swz(s4 + 0, col)], acc);
                    acc = fmaf(-mp.y, Xp[swz(s4 + 1, col)], acc);
                    acc = fmaf(-mp.z, Xp[swz(s4 + 2, col)], acc);
                    acc = fmaf(-mp.w, Xp[swz(s4 + 3, col)], acc);
                }
                for (int s = t4; s < t; ++s)
                    acc = fmaf(-Mm[swz(t, s)], Xp[swz(s, col)], acc);
                Xp[swz(t, col)] = acc;
                unsigned hb = (unsigned)f2bf(acc) << ((u & 1) * 16);
                if (u == 0) pk0 = hb; else if (u == 1) pk0 |= hb;
                else if (u == 2) pk1 = hb; else if (u == 3) pk1 |= hb;
                else if (u == 4) pk2 = hb; else if (u == 5) pk2 |= hb;
                else if (u == 6) pk3 = hb; else pk3 |= hb;
            }
            int slot = (((tb >> 3) ^ (col & 7)) << 3);
            uint4 pkv = {pk0, pk1, pk2, pk3};
            *(uint4*)&XT[col * 64 + slot] = pkv;
        }
    }
    __syncthreads();

    {
        int a_r = w * 16 + l16;
        bf16x8 xkA[2], ktA[2], abA[2];
        #pragma unroll
        for (int kk = 0; kk < 2; ++kk) {
            int sl = ((kk * 4 + lq) ^ (a_r & 7)) << 3;
            xkA[kk] = *(bf16x8*)&XkT[a_r * 64 + sl];
            ktA[kk] = *(bf16x8*)&KTb[a_r * 64 + sl];
            abA[kk] = *(bf16x8*)&Abf[a_r * 64 + sl];
        }
        size_t tile = ((size_t)(c * HH + h)) << 12;
        int a0f = w * 16 + lq * 4;
        #pragma unroll
        for (int ct = 0; ct < 4; ++ct) {
            int b_r = ct * 16 + l16;
            f32x4 accB = {0.f,0.f,0.f,0.f}, accC = {0.f,0.f,0.f,0.f};
            f32x4 accF = {0.f,0.f,0.f,0.f}, accE = {0.f,0.f,0.f,0.f};
            #pragma unroll
            for (int kk = 0; kk < 2; ++kk) {
                int sl = ((kk * 4 + lq) ^ (b_r & 7)) << 3;
                bf16x8 ktB = *(bf16x8*)&KTb[b_r * 64 + sl];
                bf16x8 xvB = *(bf16x8*)&XvT[b_r * 64 + sl];
                bf16x8 abB = *(bf16x8*)&Abf[b_r * 64 + sl];
                accB = __builtin_amdgcn_mfma_f32_16x16x32_bf16(xkA[kk], ktB, accB, 0, 0, 0);
                accC = __builtin_amdgcn_mfma_f32_16x16x32_bf16(ktA[kk], xvB, accC, 0, 0, 0);
                accF = __builtin_amdgcn_mfma_f32_16x16x32_bf16(xkA[kk], abB, accF, 0, 0, 0);
                accE = __builtin_amdgcn_mfma_f32_16x16x32_bf16(abA[kk], xvB, accE, 0, 0, 0);
            }
            float gB = __shfl(gsreg, b_r);
            float4 qv = *(const float4*)&qb[(size_t)(t0 + b_r) * EE + h * DD + a0f];
            float qvr[4] = {qv.x, qv.y, qv.z, qv.w};
            #pragma unroll
            for (int i = 0; i < 4; ++i) {
                int a = a0f + i;
                Bt[tile + (size_t)a * 64 + b_r] = accB[i];
                Ct[tile + (size_t)a * 64 + b_r] = accC[i];
                Ft[tile + (size_t)a * 64 + b_r] = SCALE * gB * qvr[i] - accF[i];
                vb[(size_t)(t0 + a) * EE + h * DD + b_r] = accE[i];
            }
        }
    }
}

// ---------------------------------------------------------------------------
// Delta rule serial S-chain, column-split v2: flat grid 128, XCD-pinned
// (all 8 col-blocks of head h on XCD h%8 -> Bt L2-resident), Ss double-
// buffered -> ONE barrier per chunk (prefetch latency overlaps compute).
// FMA chains identical to v1.
// ---------------------------------------------------------------------------
__global__ __launch_bounds__(256) void delta_scan4_kernel(
    const float* __restrict__ Bt, const float* __restrict__ Ct,
    const float* __restrict__ g, float* __restrict__ Sout)
{
    __shared__ __align__(16) float Bsb[2][4096];
    __shared__ __align__(16) float Csb[2][512];
    __shared__ float Ss[2][64][10];
    __shared__ float GCs[NCH];
    int bid = (int)blockIdx.x;
    int xcd = bid & 7;
    int idx = bid >> 3;                 // 0..15
    int h = xcd + ((idx & 1) << 3);
    int p = idx >> 1;                   // 0..7
    int bo = p * 8;
    int tid = threadIdx.x;
    int a = tid & 63;
    int w = tid >> 6;
    int j0 = w * 2;

    {
        float pr = 1.f;
        int t0 = tid * 8;
        #pragma unroll
        for (int j = 0; j < 8; ++j) pr *= g[(t0 + j) * HH + h];
        pr *= __shfl_xor(pr, 1);
        pr *= __shfl_xor(pr, 2);
        pr *= __shfl_xor(pr, 4);
        GCs[tid >> 3] = pr;
        Ss[0][a][j0] = 0.f;
        Ss[0][a][j0 + 1] = 0.f;
    }

#define STG4(buf, cc)                                                          \
    {                                                                          \
        size_t tb = ((size_t)((cc) * HH + h)) << 12;                           \
        _Pragma("unroll")                                                      \
        for (int u = 0; u < 4; ++u) {                                          \
            int fi = ((u << 8) + tid) << 2;                                    \
            int fb = ((u << 8) + (tid & 192)) << 2;                            \
            __builtin_amdgcn_global_load_lds((gptr_t)&Bt[tb + fi],             \
                (lptr_t)&Bsb[buf][fb], 16, 0, 0);                              \
        }                                                                      \
        if (tid < 128) {                                                       \
            size_t cfi = tb + ((size_t)(tid >> 1) << 6) + bo + ((tid & 1) << 2); \
            __builtin_amdgcn_global_load_lds((gptr_t)&Ct[cfi],                 \
                (lptr_t)&Csb[buf][(tid & 64) << 2], 16, 0, 0);                 \
        }                                                                      \
    }

    STG4(0, 0)
    for (int c = 0; c < NCH; ++c) {
        __syncthreads();            // stage(c) drained; Ss[c&1] writes visible
        if (c + 1 < NCH) STG4((c + 1) & 1, c + 1)
        const int cb = c & 1;
        const float* Bsp = Bsb[cb];
        const float* Csp = Csb[cb];
        float gc = GCs[c];
        size_t tile = ((size_t)(c * HH + h)) << 12;
        float s0 = Ss[cb][a][j0], s1 = Ss[cb][a][j0 + 1];
        Sout[tile + (size_t)(bo + j0) * 64 + a] = s0;
        Sout[tile + (size_t)(bo + j0 + 1) * 64 + a] = s1;
        float p0 = 0.f, p1 = 0.f;
        #pragma unroll 4
        for (int k = 0; k < 64; ++k) {
            float bk = Bsp[k * 64 + a];
            float2 sv = *(const float2*)&Ss[cb][k][j0];
            p0 = fmaf(bk, sv.x, p0);
            p1 = fmaf(bk, sv.y, p1);
        }
        float c0v = Csp[a * 8 + j0], c1v = Csp[a * 8 + j0 + 1];
        Ss[cb ^ 1][a][j0]     = fmaf(gc, s0, c0v - p0);
        Ss[cb ^ 1][a][j0 + 1] = fmaf(gc, s1, c1v - p1);
    }
#undef STG4
}

// ---------------------------------------------------------------------------
// Delta rule parallel output map: O_c = F_c.S_c + E_c. grid (NCH, HH).
// ---------------------------------------------------------------------------
__global__ __launch_bounds__(256) void delta_apply_kernel(
    const float* __restrict__ Sb, const float* __restrict__ Ft,
    float* __restrict__ vb)
{
    __shared__ float Fs[64][64];
    __shared__ float S2[64][68];
    int c = blockIdx.x, h = blockIdx.y;
    int tid = threadIdx.x;
    int tx = tid & 15, ty = tid >> 4;
    int a0 = ty << 2, b0 = tx << 2;
    size_t tile = ((size_t)(c * HH + h)) << 12;
    {
        int row = tid >> 4, c4 = (tid & 15) << 2;
        #pragma unroll
        for (int m = 0; m < 4; ++m) {
            int r = row + m * 16;
            *(float4*)&Fs[r][c4] = *(const float4*)&Ft[tile + r * 64 + c4];
            float4 sv = *(const float4*)&Sb[tile + r * 64 + c4];
            S2[c4 + 0][r] = sv.x;
            S2[c4 + 1][r] = sv.y;
            S2[c4 + 2][r] = sv.z;
            S2[c4 + 3][r] = sv.w;
        }
    }
    __syncthreads();
    float accO[4][4] = {};
    #pragma unroll 4
    for (int k = 0; k < 64; ++k) {
        float4 fv = *(const float4*)&Fs[k][a0];
        float4 sv = *(const float4*)&S2[k][b0];
        float fa[4] = {fv.x, fv.y, fv.z, fv.w};
        float sa[4] = {sv.x, sv.y, sv.z, sv.w};
        #pragma unroll
        for (int i = 0; i < 4; ++i)
            #pragma unroll
            for (int j = 0; j < 4; ++j)
                accO[i][j] = fmaf(fa[i], sa[j], accO[i][j]);
    }
    #pragma unroll
    for (int i = 0; i < 4; ++i) {
        size_t gi = (size_t)((c << 6) + a0 + i) * EE + h * DD + b0;
        float4 ev = *(const float4*)&vb[gi];
        float4 ov = {accO[i][0] + ev.x, accO[i][1] + ev.y,
                     accO[i][2] + ev.z, accO[i][3] + ev.w};
        *(float4*)&vb[gi] = ov;
    }
}

// ---------------------------------------------------------------------------
// Causal flash attention, bf16 MFMA, swapped-operand QK^T (S^T layout),
// XCD-pinned head swizzle, reg-staged prefetch.
// ---------------------------------------------------------------------------
__global__ __launch_bounds__(256) void attn_mfma_kernel(
    const float* __restrict__ q, const float* __restrict__ k, const float* __restrict__ v,
    ushort* __restrict__ y)
{
    __shared__ __align__(16) unsigned short KsL[64 * KS];
    __shared__ __align__(16) unsigned short VtL[64 * KS];
    __shared__ __align__(16) unsigned int PL[4][16 * 36];  // packed P, stride 36 u32

    int bid = (int)blockIdx.x;
    int xcd = bid & 7;
    int idx = bid >> 3;                 // 0..63 within XCD
    int h = xcd + ((idx & 1) << 3);
    int rb = (31 - (idx >> 1)) * 64;

    int tid = threadIdx.x;
    int w = tid >> 6;
    int lane = tid & 63;
    int l16 = lane & 15;
    int lq = lane >> 4;
    int qr0 = rb + w * 16;
    unsigned* PLw = PL[w];

    bf16x8 qf[2];
    {
        const float* qrow = &q[(size_t)(qr0 + l16) * EE + h * DD];
        #pragma unroll
        for (int kk = 0; kk < 2; ++kk) {
            float4 v0 = *(const float4*)&qrow[kk * 32 + lq * 8];
            float4 v1 = *(const float4*)&qrow[kk * 32 + lq * 8 + 4];
            qf[kk][0] = (short)f2bf(v0.x); qf[kk][1] = (short)f2bf(v0.y);
            qf[kk][2] = (short)f2bf(v0.z); qf[kk][3] = (short)f2bf(v0.w);
            qf[kk][4] = (short)f2bf(v1.x); qf[kk][5] = (short)f2bf(v1.y);
            qf[kk][6] = (short)f2bf(v1.z); qf[kk][7] = (short)f2bf(v1.w);
        }
    }

    f32x4 oacc[4];
    #pragma unroll
    for (int dt = 0; dt < 4; ++dt) oacc[dt] = (f32x4){0.f, 0.f, 0.f, 0.f};
    float mrow = -3e38f, lrow = 0.f;
    const int qrow_i = qr0 + l16;

    int ks_s = tid >> 2, ks_d0 = (tid & 3) << 4;
    int vt_s0 = (tid & 15) << 2;        // s-quad
    int vt_d0 = (tid >> 4) << 2;        // d-quad

    float4 kreg[4];
    f32x4 vreg0, vreg1, vreg2, vreg3;

#define ATT_ISSUE(c0)                                                          \
    {                                                                          \
        const float* krow = &k[(size_t)((c0) + ks_s) * EE + h * DD + ks_d0];   \
        kreg[0] = *(const float4*)&krow[0];                                    \
        kreg[1] = *(const float4*)&krow[4];                                    \
        kreg[2] = *(const float4*)&krow[8];                                    \
        kreg[3] = *(const float4*)&krow[12];                                   \
        const float* vrow = &v[(size_t)((c0) + vt_s0) * EE + h * DD + vt_d0];  \
        vreg0 = *(const f32x4*)&vrow[0];                                       \
        vreg1 = *(const f32x4*)&vrow[EE];                                      \
        vreg2 = *(const f32x4*)&vrow[2 * EE];                                  \
        vreg3 = *(const f32x4*)&vrow[3 * EE];                                  \
    }

    ATT_ISSUE(0)
    for (int c0 = 0; c0 <= rb; c0 += 64) {
        __syncthreads();          // prior tile's LDS reads complete
        {
            #pragma unroll
            for (int u = 0; u < 4; ++u) {
                bf16x4 pk4 = { (short)f2bf(kreg[u].x), (short)f2bf(kreg[u].y),
                               (short)f2bf(kreg[u].z), (short)f2bf(kreg[u].w) };
                *(bf16x4*)&KsL[ks_s * KS + ks_d0 + u * 4] = pk4;
            }
            #pragma unroll
            for (int dd = 0; dd < 4; ++dd) {
                uint2 pv;
                pv.x = (unsigned)f2bf(vreg0[dd]) | ((unsigned)f2bf(vreg1[dd]) << 16);
                pv.y = (unsigned)f2bf(vreg2[dd]) | ((unsigned)f2bf(vreg3[dd]) << 16);
                *(uint2*)&VtL[(vt_d0 + dd) * KS + vt_s0] = pv;   // ds_write_b64
            }
        }
        __syncthreads();          // tile visible to all waves
        if (c0 + 64 <= rb) ATT_ISSUE(c0 + 64)

        f32x4 sacc[4];
        #pragma unroll
        for (int ct = 0; ct < 4; ++ct) {
            bf16x8 ka0 = *(bf16x8*)&KsL[(ct * 16 + l16) * KS + lq * 8];
            bf16x8 ka1 = *(bf16x8*)&KsL[(ct * 16 + l16) * KS + 32 + lq * 8];
            f32x4 acc = {0.f, 0.f, 0.f, 0.f};
            acc = __builtin_amdgcn_mfma_f32_16x16x32_bf16(ka0, qf[0], acc, 0, 0, 0);
            acc = __builtin_amdgcn_mfma_f32_16x16x32_bf16(ka1, qf[1], acc, 0, 0, 0);
            sacc[ct] = acc;
        }

        float sv[4][4];
        float tm = -3e38f;
        #pragma unroll
        for (int ct = 0; ct < 4; ++ct) {
            int sbase = c0 + ct * 16 + lq * 4;
            #pragma unroll
            for (int r = 0; r < 4; ++r) {
                float s = sacc[ct][r] * SCALE;
                if (sbase + r > qrow_i) s = -3e38f;
                sv[ct][r] = s;
                tm = fmaxf(tm, s);
            }
        }
        tm = fmaxf(tm, __shfl_xor(tm, 16));
        tm = fmaxf(tm, __shfl_xor(tm, 32));
        float mn = fmaxf(mrow, tm);
        float corr = __expf(mrow - mn);
        mrow = mn;

        float ps = 0.f;
        #pragma unroll
        for (int ct = 0; ct < 4; ++ct) {
            float p0 = __expf(sv[ct][0] - mn);
            float p1 = __expf(sv[ct][1] - mn);
            float p2 = __expf(sv[ct][2] - mn);
            float p3 = __expf(sv[ct][3] - mn);
            ps += (p0 + p1) + (p2 + p3);
            uint2 wv;
            wv.x = (unsigned)f2bf(p0) | ((unsigned)f2bf(p1) << 16);
            wv.y = (unsigned)f2bf(p2) | ((unsigned)f2bf(p3) << 16);
            *(uint2*)&PLw[l16 * 36 + ct * 8 + lq * 2] = wv;
        }
        ps += __shfl_xor(ps, 16);
        ps += __shfl_xor(ps, 32);
        lrow = lrow * corr + ps;

        float corr_o[4];
        #pragma unroll
        for (int r = 0; r < 4; ++r)
            corr_o[r] = __shfl(corr, (lane & 48) + lq * 4 + r);
        #pragma unroll
        for (int dt = 0; dt < 4; ++dt) {
            #pragma unroll
            for (int r = 0; r < 4; ++r)
                oacc[dt][r] *= corr_o[r];
        }

        bf16x8 pa0 = *(bf16x8*)&PLw[l16 * 36 + lq * 4];
        bf16x8 pa1 = *(bf16x8*)&PLw[l16 * 36 + 16 + lq * 4];
        #pragma unroll
        for (int dt = 0; dt < 4; ++dt) {
            bf16x8 vv0 = *(bf16x8*)&VtL[(dt * 16 + l16) * KS + lq * 8];
            bf16x8 vv1 = *(bf16x8*)&VtL[(dt * 16 + l16) * KS + 32 + lq * 8];
            oacc[dt] = __builtin_amdgcn_mfma_f32_16x16x32_bf16(pa0, vv0, oacc[dt], 0, 0, 0);
            oacc[dt] = __builtin_amdgcn_mfma_f32_16x16x32_bf16(pa1, vv1, oacc[dt], 0, 0, 0);
        }
    }
#undef ATT_ISSUE

    float li = 1.f / lrow;
    float linv_o[4];
    #pragma unroll
    for (int r = 0; r < 4; ++r)
        linv_o[r] = __shfl(li, (lane & 48) + lq * 4 + r);
    #pragma unroll
    for (int dt = 0; dt < 4; ++dt) {
        #pragma unroll
        for (int r = 0; r < 4; ++r) {
            int row = qr0 + lq * 4 + r;
            y[(size_t)row * EE + h * DD + dt * 16 + l16] = f2bf(oacc[dt][r] * linv_o[r]);
        }
    }
}

// ---------------------------------------------------------------------------
extern "C" void kernel_launch(void* const* d_in, const int* in_sizes, int n_in,
                              void* d_out, int out_size, void* d_ws, size_t ws_size,
                              hipStream_t stream)
{
    (void)in_sizes; (void)n_in; (void)out_size; (void)ws_size;
    const float* x      = (const float*)d_in[0];
    const float* w_attn = (const float*)d_in[1];
    const float* w_proj = (const float*)d_in[2];
    const float* qcw    = (const float*)d_in[3];
    const float* kcw    = (const float*)d_in[4];
    const float* vcw    = (const float*)d_in[5];
    const float* cosb   = (const float*)d_in[6];
    const float* sinb   = (const float*)d_in[7];
    const float* beta   = (const float*)d_in[8];
    const float* g      = (const float*)d_in[9];
    float* out = (float*)d_out;
    float* ws  = (float*)d_ws;

    const size_t TE = (size_t)TT * EE;
    float* buf0 = ws + 0 * TE;          // qkv -> Bt
    float* buf1 = ws + 1 * TE;          // qkv -> Ct -> ybf
    float* buf2 = ws + 2 * TE;          // qkv -> Ft -> wpT
    float* qb   = ws + 3 * TE;          // xbf -> q
    float* kb   = ws + 4 * TE;          // waT -> k
    float* vb   = ws + 5 * TE;          // v -> E -> O
    float* qkv  = buf0;
    ushort* xbf = (ushort*)qb;
    ushort* waT = (ushort*)kb;
    ushort* ybf = (ushort*)buf1;
    ushort* wpT = (ushort*)buf2;
    float* Sbuf = out;                  // d_out as S-tile scratch

    cvt_bf16_kernel<<<TT * EE / 2048, 256, 0, stream>>>(x, xbf);
    cvt_transpose_kernel<<<dim3(NN / 64, EE / 64), 256, 0, stream>>>(w_attn, waT, EE, NN);
    gemm_bf16<128, 128><<<dim3(NN / 128, TT / 128), 256, 0, stream>>>(
        xbf, waT, qkv, TT, NN, EE);
    conv_rope_kernel<<<dim3(TT / 4, HH, 3), dim3(64, 4), 0, stream>>>(
        qkv, qcw, kcw, vcw, cosb, sinb, qb, kb, vb);
    chunk_prep_kernel<<<dim3(NCH, HH), 256, 0, stream>>>(qb, kb, vb, beta, g, buf0, buf1, buf2);
    delta_scan4_kernel<<<dim3(CPH * HH), 256, 0, stream>>>(buf0, buf1, g, Sbuf);
    delta_apply_kernel<<<dim3(NCH, HH), 256, 0, stream>>>(Sbuf, buf2, vb);
    cvt_transpose_kernel<<<dim3(EE / 64, EE / 64), 256, 0, stream>>>(w_proj, wpT, EE, EE);
    attn_mfma_kernel<<<dim3(512), 256, 0, stream>>>(qb, kb, vb, ybf);
    gemm_bf16<64, 64><<<dim3(EE / 64, TT / 64), 256, 0, stream>>>(
        ybf, wpT, out, TT, EE, EE);
}

// Round 14
// 216.587 us; speedup vs baseline: 10.6829x; 1.1073x over previous
//
#include <hip/hip_runtime.h>
#include <math.h>

#define TT 2048
#define HH 16
#define DD 64
#define EE 1024
#define NN 3072
#define CHUNK 64
#define NCH (TT / CHUNK)
#define SCALE 0.125f
#define KS 72   // attn LDS row stride (bf16): conflict-free b128
#define SCPH 4  // column-split blocks per head in delta scan (16 cols each)

typedef short bf16x8 __attribute__((ext_vector_type(8)));
typedef short bf16x4 __attribute__((ext_vector_type(4)));
typedef float f32x4 __attribute__((ext_vector_type(4)));
typedef unsigned short ushort;
typedef const __attribute__((address_space(1))) unsigned int* gptr_t;
typedef __attribute__((address_space(3))) unsigned int* lptr_t;

__device__ __forceinline__ unsigned short f2bf(float x) {
    union { float f; unsigned u; } un; un.f = x;
    unsigned r = un.u + 0x7FFFu + ((un.u >> 16) & 1u);
    return (unsigned short)(r >> 16);
}
__device__ __forceinline__ float bf2f(unsigned short h) {
    union { unsigned u; float f; } un; un.u = ((unsigned)h) << 16;
    return un.f;
}

// XOR slot swizzle for 64-float rows (4-float slots, key = row bits 2..4)
__device__ __forceinline__ int swz(int r, int c) {
    return (r << 6) + ((((c >> 2) ^ ((r >> 2) & 7)) << 2) | (c & 3));
}
__device__ __forceinline__ int swz4(int r, int c4) {
    return (r << 6) + (((c4 >> 2) ^ ((r >> 2) & 7)) << 2);
}
// XOR slot swizzle for 64-bf16 rows (8-elem 16B slots, key = row bits 0..2)
__device__ __forceinline__ int bswz(int r, int c) {
    return (r << 6) + ((((c >> 3) ^ (r & 7)) << 3) | (c & 7));
}

// ---------------------------------------------------------------------------
// fp32 -> bf16 elementwise convert (x)
// ---------------------------------------------------------------------------
__global__ __launch_bounds__(256) void cvt_bf16_kernel(
    const float* __restrict__ in, ushort* __restrict__ out)
{
    int i = ((int)blockIdx.x * 256 + (int)threadIdx.x) << 3;
    float4 a = *(const float4*)&in[i];
    float4 b = *(const float4*)&in[i + 4];
    bf16x8 o;
    o[0] = (short)f2bf(a.x); o[1] = (short)f2bf(a.y);
    o[2] = (short)f2bf(a.z); o[3] = (short)f2bf(a.w);
    o[4] = (short)f2bf(b.x); o[5] = (short)f2bf(b.y);
    o[6] = (short)f2bf(b.z); o[7] = (short)f2bf(b.w);
    *(bf16x8*)&out[i] = o;
}

// ---------------------------------------------------------------------------
// fp32 [K][N] -> bf16 [N][K] convert + transpose (weights)
// ---------------------------------------------------------------------------
__global__ __launch_bounds__(256) void cvt_transpose_kernel(
    const float* __restrict__ W, ushort* __restrict__ WT, int K, int N)
{
    __shared__ float Ls[64][65];
    int n0 = blockIdx.x * 64, k0 = blockIdx.y * 64;
    int tid = threadIdx.x;
    int lr = tid >> 4, lc4 = (tid & 15) << 2;
    #pragma unroll
    for (int m = 0; m < 4; ++m) {
        int r = lr + m * 16;
        float4 v = *(const float4*)&W[(size_t)(k0 + r) * N + n0 + lc4];
        Ls[r][lc4 + 0] = v.x; Ls[r][lc4 + 1] = v.y;
        Ls[r][lc4 + 2] = v.z; Ls[r][lc4 + 3] = v.w;
    }
    __syncthreads();
    int n = tid >> 2, kb = (tid & 3) << 4;
    bf16x8 o0, o1;
    #pragma unroll
    for (int j = 0; j < 8; ++j) o0[j] = (short)f2bf(Ls[kb + j][n]);
    #pragma unroll
    for (int j = 0; j < 8; ++j) o1[j] = (short)f2bf(Ls[kb + 8 + j][n]);
    *(bf16x8*)&WT[(size_t)(n0 + n) * K + k0 + kb] = o0;
    *(bf16x8*)&WT[(size_t)(n0 + n) * K + k0 + kb + 8] = o1;
}

// ---------------------------------------------------------------------------
// bf16 MFMA GEMM: C(fp32)[M][N] = A(bf16)[M][K] * BT(bf16)[N][K]^T
// ---------------------------------------------------------------------------
template<int BM, int BN>
__global__ __launch_bounds__(256) void gemm_bf16(
    const ushort* __restrict__ A, const ushort* __restrict__ BT,
    float* __restrict__ C, int M, int N, int K)
{
    constexpr int MT = BM / 32;
    constexpr int NT = BN / 32;
    constexpr int AIT = BM * 64 / 2048;
    constexpr int BIT = BN * 64 / 2048;
    __shared__ __align__(16) ushort Asl[2][BM * 64];
    __shared__ __align__(16) ushort Bsl[2][BN * 64];
    const int tid = threadIdx.x;
    const int lane = tid & 63, w = tid >> 6;
    const int wm = w >> 1, wn = w & 1;
    const int l16 = lane & 15, lq = lane >> 4;
    const int row0 = blockIdx.y * BM, col0 = blockIdx.x * BN;
    const int wvb = w << 9;

    f32x4 acc[MT][NT];
    #pragma unroll
    for (int i = 0; i < MT; ++i)
        #pragma unroll
        for (int j = 0; j < NT; ++j)
            acc[i][j] = (f32x4){0.f, 0.f, 0.f, 0.f};

#define STAGE_TILE(buf, k0)                                                    \
    {                                                                          \
        _Pragma("unroll")                                                      \
        for (int u = 0; u < AIT; ++u) {                                        \
            int idx = u * 256 + tid;                                           \
            int r = idx >> 3, s = idx & 7;                                     \
            const ushort* srcp =                                               \
                &A[(size_t)(row0 + r) * K + (k0) + ((s ^ (r & 7)) << 3)];      \
            __builtin_amdgcn_global_load_lds((gptr_t)srcp,                     \
                (lptr_t)&Asl[buf][(u << 11) + wvb], 16, 0, 0);                 \
        }                                                                      \
        _Pragma("unroll")                                                      \
        for (int u = 0; u < BIT; ++u) {                                        \
            int idx = u * 256 + tid;                                           \
            int r = idx >> 3, s = idx & 7;                                     \
            const ushort* srcp =                                               \
                &BT[(size_t)(col0 + r) * K + (k0) + ((s ^ (r & 7)) << 3)];     \
            __builtin_amdgcn_global_load_lds((gptr_t)srcp,                     \
                (lptr_t)&Bsl[buf][(u << 11) + wvb], 16, 0, 0);                 \
        }                                                                      \
    }

    const int nK = K >> 6;
    STAGE_TILE(0, 0)
    for (int kt = 0; kt < nK; ++kt) {
        __syncthreads();                       // stage(kt) drained + visible
        if (kt + 1 < nK) STAGE_TILE((kt + 1) & 1, (kt + 1) << 6)
        const int cb = kt & 1;
        #pragma unroll
        for (int kk = 0; kk < 2; ++kk) {
            bf16x8 afr[MT], bfr[NT];
            #pragma unroll
            for (int mt = 0; mt < MT; ++mt) {
                int rr = wm * (BM / 2) + mt * 16 + l16;
                afr[mt] = *(bf16x8*)&Asl[cb][rr * 64 +
                           (((kk * 4 + lq) ^ (rr & 7)) << 3)];
            }
            #pragma unroll
            for (int nt = 0; nt < NT; ++nt) {
                int cc = wn * (BN / 2) + nt * 16 + l16;
                bfr[nt] = *(bf16x8*)&Bsl[cb][cc * 64 +
                           (((kk * 4 + lq) ^ (cc & 7)) << 3)];
            }
            #pragma unroll
            for (int mt = 0; mt < MT; ++mt)
                #pragma unroll
                for (int nt = 0; nt < NT; ++nt)
                    acc[mt][nt] = __builtin_amdgcn_mfma_f32_16x16x32_bf16(
                        afr[mt], bfr[nt], acc[mt][nt], 0, 0, 0);
        }
    }
#undef STAGE_TILE

    #pragma unroll
    for (int mt = 0; mt < MT; ++mt) {
        #pragma unroll
        for (int nt = 0; nt < NT; ++nt) {
            int col = col0 + wn * (BN / 2) + nt * 16 + l16;
            #pragma unroll
            for (int r = 0; r < 4; ++r) {
                int row = row0 + wm * (BM / 2) + mt * 16 + lq * 4 + r;
                C[(size_t)row * N + col] = acc[mt][nt][r];
            }
        }
    }
}

// ---------------------------------------------------------------------------
// Causal depthwise conv1d (DC=4) + SiLU, then RoPE for q,k; v plain.
// ---------------------------------------------------------------------------
__global__ __launch_bounds__(256) void conv_rope_kernel(
    const float* __restrict__ qkv,
    const float* __restrict__ qw, const float* __restrict__ kw, const float* __restrict__ vw,
    const float* __restrict__ cosb, const float* __restrict__ sinb,
    float* __restrict__ qo, float* __restrict__ ko, float* __restrict__ vo)
{
    int j = blockIdx.z;
    const float* w = (j == 0) ? qw : (j == 1) ? kw : vw;
    float* dst     = (j == 0) ? qo : (j == 1) ? ko : vo;
    int d  = threadIdx.x;
    int tl = threadIdx.y;
    int t  = blockIdx.x * 4 + tl;
    int h  = blockIdx.y;
    int c  = h * DD + d;
    int n  = h * 192 + j * 64 + d;
    float acc = 0.f;
    #pragma unroll
    for (int i = 0; i < 4; ++i) {
        int tt = t - 3 + i;
        if (tt >= 0) acc = fmaf(qkv[(size_t)tt * NN + n], w[c * 4 + i], acc);
    }
    float yv = acc / (1.f + __expf(-acc));
    if (j == 2) { dst[t * EE + c] = yv; return; }
    __shared__ float sh[4][64];
    sh[tl][d] = yv;
    __syncthreads();
    int dh = d & 31;
    float cc = cosb[t * 32 + dh];
    float ss = sinb[t * 32 + dh];
    float outv;
    if (d < 32) outv = yv * cc - sh[tl][d + 32] * ss;
    else        outv = yv * cc + sh[tl][d - 32] * ss;
    dst[t * EE + c] = outv;
}

// ---------------------------------------------------------------------------
// Chunked gated delta rule, phase 1 — v4: as v3, but the B output is stored
// TRANSPOSED ([a-col][k] layout, k-slot swizzled) as bf16 hi/lo planes for
// the MFMA scan. C/F/E outputs unchanged.
// ---------------------------------------------------------------------------
__global__ __launch_bounds__(256) void chunk_prep_kernel(
    const float* __restrict__ qb, const float* __restrict__ kb, float* __restrict__ vb,
    const float* __restrict__ beta, const float* __restrict__ g,
    ushort* __restrict__ BtTh, ushort* __restrict__ BtTl,
    float* __restrict__ Ct, float* __restrict__ Ft)
{
    __shared__ __align__(16) float Kc[4096];     // K fp32 swz -> Xk in place
    __shared__ __align__(16) float Vx[4096];     // V fp32 swz -> Xv in place
    __shared__ __align__(16) float Mpool[4096];  // Kbf+Qbf bf16 -> M fp32 swz
    __shared__ __align__(16) ushort Abf[4096];   // A~ bf16 [t][s] bswz (0 for s>t)
    __shared__ __align__(16) ushort KTb[4096];   // K~^T bf16 [b][s] bswz
    __shared__ __align__(16) ushort XkT[4096];   // Xk^T bf16 [a][s] bswz
    __shared__ __align__(16) ushort XvT[4096];   // Xv^T bf16 [a][s] bswz
    ushort* Kbf = (ushort*)Mpool;
    ushort* Qbf = (ushort*)Mpool + 4096;
    float*  Mm  = Mpool;

    int c = blockIdx.x, h = blockIdx.y;
    int tid = threadIdx.x;
    int lane = tid & 63;
    int w = tid >> 6;
    int l16 = lane & 15, lq = lane >> 4;
    int t0 = c * CHUNK;

    float gsreg, bsreg;
    {
        float x = g[(t0 + lane) * HH + h];
        #pragma unroll
        for (int off = 1; off < 64; off <<= 1) {
            float y = __shfl_up(x, off);
            if (lane >= off) x *= y;
        }
        gsreg = x;
        bsreg = beta[(t0 + lane) * HH + h];
    }

    {
        int row = tid >> 4, c4 = (tid & 15) << 2;
        #pragma unroll
        for (int m = 0; m < 4; ++m) {
            int r = row + m * 16;
            size_t gidx = (size_t)(t0 + r) * EE + h * DD + c4;
            float4 kv = *(const float4*)&kb[gidx];
            float4 qv = *(const float4*)&qb[gidx];
            float4 vv = *(const float4*)&vb[gidx];
            *(float4*)&Kc[swz4(r, c4)] = kv;
            *(float4*)&Vx[swz4(r, c4)] = vv;
            int ba = bswz(r, c4);
            bf16x4 kb4 = { (short)f2bf(kv.x), (short)f2bf(kv.y),
                           (short)f2bf(kv.z), (short)f2bf(kv.w) };
            bf16x4 qb4 = { (short)f2bf(qv.x), (short)f2bf(qv.y),
                           (short)f2bf(qv.z), (short)f2bf(qv.w) };
            *(bf16x4*)&Kbf[ba] = kb4;
            *(bf16x4*)&Qbf[ba] = qb4;
        }
    }
    __syncthreads();

    f32x4 akk[4], aqk[4];
    {
        bf16x8 kaf[2];
        int rr = w * 16 + l16;
        #pragma unroll
        for (int kk = 0; kk < 2; ++kk)
            kaf[kk] = *(bf16x8*)&Kbf[rr * 64 + (((kk * 4 + lq) ^ (rr & 7)) << 3)];
        #pragma unroll
        for (int ct = 0; ct < 4; ++ct) {
            int tt = ct * 16 + l16;
            f32x4 a1 = {0.f, 0.f, 0.f, 0.f}, a2 = {0.f, 0.f, 0.f, 0.f};
            #pragma unroll
            for (int kk = 0; kk < 2; ++kk) {
                int sl = ((kk * 4 + lq) ^ (tt & 7)) << 3;
                bf16x8 kbfr = *(bf16x8*)&Kbf[tt * 64 + sl];
                bf16x8 qbfr = *(bf16x8*)&Qbf[tt * 64 + sl];
                a1 = __builtin_amdgcn_mfma_f32_16x16x32_bf16(kaf[kk], kbfr, a1, 0, 0, 0);
                a2 = __builtin_amdgcn_mfma_f32_16x16x32_bf16(kaf[kk], qbfr, a2, 0, 0, 0);
            }
            akk[ct] = a1; aqk[ct] = a2;
        }
    }
    __syncthreads();

    {
        int s0 = w * 16 + lq * 4;
        float gS[4];
        #pragma unroll
        for (int r = 0; r < 4; ++r) gS[r] = __shfl(gsreg, s0 + r);
        #pragma unroll
        for (int ct = 0; ct < 4; ++ct) {
            int t = ct * 16 + l16;
            float gT = __shfl(gsreg, t);
            float bT = __shfl(bsreg, t);
            float mw[4];
            bf16x4 ab4;
            #pragma unroll
            for (int r = 0; r < 4; ++r) {
                int s = s0 + r;
                float gr = gT / gS[r];
                mw[r] = bT * gr * akk[ct][r];
                float av = (s <= t) ? SCALE * gr * aqk[ct][r] : 0.f;
                ab4[r] = (short)f2bf(av);
            }
            float4 mw4 = {mw[0], mw[1], mw[2], mw[3]};
            *(float4*)&Mm[swz4(t, s0)] = mw4;
            *(bf16x4*)&Abf[bswz(t, s0)] = ab4;
        }
    }

    {
        float g63 = __shfl(gsreg, 63);
        int s = tid >> 2;
        int cb = (tid & 3) << 4;
        float ratio = g63 / __shfl(gsreg, s);
        #pragma unroll
        for (int u = 0; u < 4; ++u) {
            int b4 = cb + u * 4;
            float4 kv = *(const float4*)&Kc[swz4(s, b4)];
            float kvr[4] = {kv.x, kv.y, kv.z, kv.w};
            #pragma unroll
            for (int j = 0; j < 4; ++j)
                KTb[bswz(b4 + j, s)] = f2bf(ratio * kvr[j]);
        }
    }
    __syncthreads();

    if (tid < 128) {
        int col = tid & 63;
        int wK = tid >> 6;
        float* Xp = wK ? Kc : Vx;
        ushort* XT = wK ? XkT : XvT;
        #pragma unroll 1
        for (int tb = 0; tb < 64; tb += 8) {
            unsigned pk0 = 0, pk1 = 0, pk2 = 0, pk3 = 0;
            #pragma unroll
            for (int u = 0; u < 8; ++u) {
                int t = tb + u;
                float bsv = __shfl(bsreg, t);
                float acc = wK ? (bsv * __shfl(gsreg, t) * Kc[swz(t, col)])
                               : (bsv * Vx[swz(t, col)]);
                int t4 = t & ~3;
                for (int s4 = 0; s4 < t4; s4 += 4) {
                    float4 mp = *(const float4*)&Mm[swz4(t, s4)];
                    acc = fmaf(-mp.x, Xp[swz(s4 + 0, col)], acc);
                    acc = fmaf(-mp.y, Xp[swz(s4 + 1, col)], acc);
                    acc = fmaf(-mp.z, Xp[swz(s4 + 2, col)], acc);
                    acc = fmaf(-mp.w, Xp[swz(s4 + 3, col)], acc);
                }
                for (int s = t4; s < t; ++s)
                    acc = fmaf(-Mm[swz(t, s)], Xp[swz(s, col)], acc);
                Xp[swz(t, col)] = acc;
                unsigned hb = (unsigned)f2bf(acc) << ((u & 1) * 16);
                if (u == 0) pk0 = hb; else if (u == 1) pk0 |= hb;
                else if (u == 2) pk1 = hb; else if (u == 3) pk1 |= hb;
                else if (u == 4) pk2 = hb; else if (u == 5) pk2 |= hb;
                else if (u == 6) pk3 = hb; else pk3 |= hb;
            }
            int slot = (((tb >> 3) ^ (col & 7)) << 3);
            uint4 pkv = {pk0, pk1, pk2, pk3};
            *(uint4*)&XT[col * 64 + slot] = pkv;
        }
    }
    __syncthreads();

    {
        int a_r = w * 16 + l16;
        bf16x8 xkA[2], ktA[2], abA[2];
        #pragma unroll
        for (int kk = 0; kk < 2; ++kk) {
            int sl = ((kk * 4 + lq) ^ (a_r & 7)) << 3;
            xkA[kk] = *(bf16x8*)&XkT[a_r * 64 + sl];
            ktA[kk] = *(bf16x8*)&KTb[a_r * 64 + sl];
            abA[kk] = *(bf16x8*)&Abf[a_r * 64 + sl];
        }
        size_t tile = ((size_t)(c * HH + h)) << 12;
        int a0f = w * 16 + lq * 4;
        // transposed-store swizzle slot base for the B planes (k-quad = a0f..a0f+3)
        #pragma unroll
        for (int ct = 0; ct < 4; ++ct) {
            int b_r = ct * 16 + l16;
            f32x4 accB = {0.f,0.f,0.f,0.f}, accC = {0.f,0.f,0.f,0.f};
            f32x4 accF = {0.f,0.f,0.f,0.f}, accE = {0.f,0.f,0.f,0.f};
            #pragma unroll
            for (int kk = 0; kk < 2; ++kk) {
                int sl = ((kk * 4 + lq) ^ (b_r & 7)) << 3;
                bf16x8 ktB = *(bf16x8*)&KTb[b_r * 64 + sl];
                bf16x8 xvB = *(bf16x8*)&XvT[b_r * 64 + sl];
                bf16x8 abB = *(bf16x8*)&Abf[b_r * 64 + sl];
                accB = __builtin_amdgcn_mfma_f32_16x16x32_bf16(xkA[kk], ktB, accB, 0, 0, 0);
                accC = __builtin_amdgcn_mfma_f32_16x16x32_bf16(ktA[kk], xvB, accC, 0, 0, 0);
                accF = __builtin_amdgcn_mfma_f32_16x16x32_bf16(xkA[kk], abB, accF, 0, 0, 0);
                accE = __builtin_amdgcn_mfma_f32_16x16x32_bf16(abA[kk], xvB, accE, 0, 0, 0);
            }
            float gB = __shfl(gsreg, b_r);
            float4 qv = *(const float4*)&qb[(size_t)(t0 + b_r) * EE + h * DD + a0f];
            float qvr[4] = {qv.x, qv.y, qv.z, qv.w};
            // B transposed hi/lo store: BtT[b_r][k = a0f..a0f+3], slot-swizzled
            {
                bf16x4 hv, lv;
                #pragma unroll
                for (int i = 0; i < 4; ++i) {
                    ushort hb = f2bf(accB[i]);
                    hv[i] = (short)hb;
                    lv[i] = (short)f2bf(accB[i] - bf2f(hb));
                }
                int sl2 = b_r * 64 + ((((a0f >> 3) ^ (b_r & 7)) << 3) | (a0f & 7));
                *(bf16x4*)&BtTh[tile + sl2] = hv;
                *(bf16x4*)&BtTl[tile + sl2] = lv;
            }
            #pragma unroll
            for (int i = 0; i < 4; ++i) {
                int a = a0f + i;
                Ct[tile + (size_t)a * 64 + b_r] = accC[i];
                Ft[tile + (size_t)a * 64 + b_r] = SCALE * gB * qvr[i] - accF[i];
                vb[(size_t)(t0 + a) * EE + h * DD + b_r] = accE[i];
            }
        }
    }
}

// ---------------------------------------------------------------------------
// Delta rule serial S-chain v5 (MFMA): 64 blocks XCD-pinned; block owns 16
// state-columns. S fp32 master in registers (D-frag layout); per chunk
// P^T = mfma(S^T_hi/lo, B_hi/lo) 3-term split; single barrier per chunk.
// ---------------------------------------------------------------------------
__global__ __launch_bounds__(256) void delta_scan5_kernel(
    const ushort* __restrict__ Bh, const ushort* __restrict__ Bl,
    const float* __restrict__ Ct, const float* __restrict__ g,
    float* __restrict__ Sout)
{
    __shared__ __align__(16) ushort Bhs[2][4096];
    __shared__ __align__(16) ushort Bls[2][4096];
    __shared__ __align__(16) float  Cs[2][1024];
    __shared__ __align__(16) ushort STh[2][16 * 72];
    __shared__ __align__(16) ushort STl[2][16 * 72];
    __shared__ float GCs[NCH];

    int bid = (int)blockIdx.x;          // 64 blocks
    int xcd = bid & 7;
    int idx = bid >> 3;                 // 0..7
    int h = xcd + ((idx & 1) << 3);
    int p = idx >> 1;                   // 0..3
    int bo = p * 16;
    int tid = threadIdx.x;
    int lane = tid & 63, w = tid >> 6;
    int l16 = lane & 15, lq = lane >> 4;

    // per-chunk gate products
    {
        float pr = 1.f;
        int t0 = tid * 8;
        #pragma unroll
        for (int j = 0; j < 8; ++j) pr *= g[(t0 + j) * HH + h];
        pr *= __shfl_xor(pr, 1);
        pr *= __shfl_xor(pr, 2);
        pr *= __shfl_xor(pr, 4);
        GCs[tid >> 3] = pr;
    }
    // zero S^T buf 0 (both planes): 1152 ushorts = 576 u32 each
    for (int i = tid; i < 576; i += 256) {
        ((unsigned*)&STh[0][0])[i] = 0;
        ((unsigned*)&STl[0][0])[i] = 0;
    }

#define STG5(buf, cc)                                                          \
    {                                                                          \
        size_t tb = ((size_t)((cc) * HH + h)) << 12;                           \
        _Pragma("unroll")                                                      \
        for (int u = 0; u < 2; ++u) {                                          \
            int ei = ((u << 8) + tid) << 3;                                    \
            int eb = ((u << 8) + (tid & 192)) << 3;                            \
            __builtin_amdgcn_global_load_lds((gptr_t)&Bh[tb + ei],             \
                (lptr_t)&Bhs[buf][eb], 16, 0, 0);                              \
            __builtin_amdgcn_global_load_lds((gptr_t)&Bl[tb + ei],             \
                (lptr_t)&Bls[buf][eb], 16, 0, 0);                              \
        }                                                                      \
        {                                                                      \
            int jq = tid >> 6, aa = tid & 63;                                  \
            __builtin_amdgcn_global_load_lds(                                  \
                (gptr_t)&Ct[tb + (size_t)aa * 64 + bo + jq * 4],               \
                (lptr_t)&Cs[buf][(tid & 192) << 2], 16, 0, 0);                 \
        }                                                                      \
    }

    f32x4 sreg = {0.f, 0.f, 0.f, 0.f};   // S[a = w*16+l16][bo + lq*4 + i]
    const int ar = w * 16 + l16;

    STG5(0, 0)
    for (int c = 0; c < NCH; ++c) {
        __syncthreads();            // stage(c) drained; S^T(c) writes visible
        if (c + 1 < NCH) STG5((c + 1) & 1, c + 1)
        const int cb = c & 1;
        float gc = GCs[c];
        size_t tile = ((size_t)(c * HH + h)) << 12;
        // pre-update state out (column-major [col][row])
        #pragma unroll
        for (int i = 0; i < 4; ++i)
            Sout[tile + (size_t)(bo + lq * 4 + i) * 64 + ar] = sreg[i];
        // P^T[j][a] via split MFMA
        f32x4 acc = {0.f, 0.f, 0.f, 0.f};
        #pragma unroll
        for (int m = 0; m < 2; ++m) {
            int koff = m * 32 + lq * 8;
            bf16x8 aHi = *(bf16x8*)&STh[cb][l16 * 72 + koff];
            bf16x8 aLo = *(bf16x8*)&STl[cb][l16 * 72 + koff];
            int saddr = ar * 64 + ((((koff >> 3) ^ (ar & 7)) << 3));
            bf16x8 bHi = *(bf16x8*)&Bhs[cb][saddr];
            bf16x8 bLo = *(bf16x8*)&Bls[cb][saddr];
            acc = __builtin_amdgcn_mfma_f32_16x16x32_bf16(aHi, bHi, acc, 0, 0, 0);
            acc = __builtin_amdgcn_mfma_f32_16x16x32_bf16(aLo, bHi, acc, 0, 0, 0);
            acc = __builtin_amdgcn_mfma_f32_16x16x32_bf16(aHi, bLo, acc, 0, 0, 0);
        }
        // S update (fp32 master) + write S^T hi/lo for next chunk
        f32x4 cvv = *(const f32x4*)&Cs[cb][lq * 256 + ar * 4];
        #pragma unroll
        for (int i = 0; i < 4; ++i) {
            float sn = fmaf(gc, sreg[i], cvv[i] - acc[i]);
            sreg[i] = sn;
            ushort hb = f2bf(sn);
            int j = lq * 4 + i;
            STh[cb ^ 1][j * 72 + ar] = hb;
            STl[cb ^ 1][j * 72 + ar] = f2bf(sn - bf2f(hb));
        }
    }
#undef STG5
}

// ---------------------------------------------------------------------------
// Delta rule parallel output map: O_c = F_c.S_c + E_c. grid (NCH, HH).
// ---------------------------------------------------------------------------
__global__ __launch_bounds__(256) void delta_apply_kernel(
    const float* __restrict__ Sb, const float* __restrict__ Ft,
    float* __restrict__ vb)
{
    __shared__ float Fs[64][64];
    __shared__ float S2[64][68];
    int c = blockIdx.x, h = blockIdx.y;
    int tid = threadIdx.x;
    int tx = tid & 15, ty = tid >> 4;
    int a0 = ty << 2, b0 = tx << 2;
    size_t tile = ((size_t)(c * HH + h)) << 12;
    {
        int row = tid >> 4, c4 = (tid & 15) << 2;
        #pragma unroll
        for (int m = 0; m < 4; ++m) {
            int r = row + m * 16;
            *(float4*)&Fs[r][c4] = *(const float4*)&Ft[tile + r * 64 + c4];
            float4 sv = *(const float4*)&Sb[tile + r * 64 + c4];
            S2[c4 + 0][r] = sv.x;
            S2[c4 + 1][r] = sv.y;
            S2[c4 + 2][r] = sv.z;
            S2[c4 + 3][r] = sv.w;
        }
    }
    __syncthreads();
    float accO[4][4] = {};
    #pragma unroll 4
    for (int k = 0; k < 64; ++k) {
        float4 fv = *(const float4*)&Fs[k][a0];
        float4 sv = *(const float4*)&S2[k][b0];
        float fa[4] = {fv.x, fv.y, fv.z, fv.w};
        float sa[4] = {sv.x, sv.y, sv.z, sv.w};
        #pragma unroll
        for (int i = 0; i < 4; ++i)
            #pragma unroll
            for (int j = 0; j < 4; ++j)
                accO[i][j] = fmaf(fa[i], sa[j], accO[i][j]);
    }
    #pragma unroll
    for (int i = 0; i < 4; ++i) {
        size_t gi = (size_t)((c << 6) + a0 + i) * EE + h * DD + b0;
        float4 ev = *(const float4*)&vb[gi];
        float4 ov = {accO[i][0] + ev.x, accO[i][1] + ev.y,
                     accO[i][2] + ev.z, accO[i][3] + ev.w};
        *(float4*)&vb[gi] = ov;
    }
}

// ---------------------------------------------------------------------------
// Causal flash attention, bf16 MFMA, swapped-operand QK^T (S^T layout),
// XCD-pinned head swizzle, reg-staged prefetch.
// ---------------------------------------------------------------------------
__global__ __launch_bounds__(256) void attn_mfma_kernel(
    const float* __restrict__ q, const float* __restrict__ k, const float* __restrict__ v,
    ushort* __restrict__ y)
{
    __shared__ __align__(16) unsigned short KsL[64 * KS];
    __shared__ __align__(16) unsigned short VtL[64 * KS];
    __shared__ __align__(16) unsigned int PL[4][16 * 36];  // packed P, stride 36 u32

    int bid = (int)blockIdx.x;
    int xcd = bid & 7;
    int idx = bid >> 3;                 // 0..63 within XCD
    int h = xcd + ((idx & 1) << 3);
    int rb = (31 - (idx >> 1)) * 64;

    int tid = threadIdx.x;
    int w = tid >> 6;
    int lane = tid & 63;
    int l16 = lane & 15;
    int lq = lane >> 4;
    int qr0 = rb + w * 16;
    unsigned* PLw = PL[w];

    bf16x8 qf[2];
    {
        const float* qrow = &q[(size_t)(qr0 + l16) * EE + h * DD];
        #pragma unroll
        for (int kk = 0; kk < 2; ++kk) {
            float4 v0 = *(const float4*)&qrow[kk * 32 + lq * 8];
            float4 v1 = *(const float4*)&qrow[kk * 32 + lq * 8 + 4];
            qf[kk][0] = (short)f2bf(v0.x); qf[kk][1] = (short)f2bf(v0.y);
            qf[kk][2] = (short)f2bf(v0.z); qf[kk][3] = (short)f2bf(v0.w);
            qf[kk][4] = (short)f2bf(v1.x); qf[kk][5] = (short)f2bf(v1.y);
            qf[kk][6] = (short)f2bf(v1.z); qf[kk][7] = (short)f2bf(v1.w);
        }
    }

    f32x4 oacc[4];
    #pragma unroll
    for (int dt = 0; dt < 4; ++dt) oacc[dt] = (f32x4){0.f, 0.f, 0.f, 0.f};
    float mrow = -3e38f, lrow = 0.f;
    const int qrow_i = qr0 + l16;

    int ks_s = tid >> 2, ks_d0 = (tid & 3) << 4;
    int vt_s0 = (tid & 15) << 2;        // s-quad
    int vt_d0 = (tid >> 4) << 2;        // d-quad

    float4 kreg[4];
    f32x4 vreg0, vreg1, vreg2, vreg3;

#define ATT_ISSUE(c0)                                                          \
    {                                                                          \
        const float* krow = &k[(size_t)((c0) + ks_s) * EE + h * DD + ks_d0];   \
        kreg[0] = *(const float4*)&krow[0];                                    \
        kreg[1] = *(const float4*)&krow[4];                                    \
        kreg[2] = *(const float4*)&krow[8];                                    \
        kreg[3] = *(const float4*)&krow[12];                                   \
        const float* vrow = &v[(size_t)((c0) + vt_s0) * EE + h * DD + vt_d0];  \
        vreg0 = *(const f32x4*)&vrow[0];                                       \
        vreg1 = *(const f32x4*)&vrow[EE];                                      \
        vreg2 = *(const f32x4*)&vrow[2 * EE];                                  \
        vreg3 = *(const f32x4*)&vrow[3 * EE];                                  \
    }

    ATT_ISSUE(0)
    for (int c0 = 0; c0 <= rb; c0 += 64) {
        __syncthreads();          // prior tile's LDS reads complete
        {
            #pragma unroll
            for (int u = 0; u < 4; ++u) {
                bf16x4 pk4 = { (short)f2bf(kreg[u].x), (short)f2bf(kreg[u].y),
                               (short)f2bf(kreg[u].z), (short)f2bf(kreg[u].w) };
                *(bf16x4*)&KsL[ks_s * KS + ks_d0 + u * 4] = pk4;
            }
            #pragma unroll
            for (int dd = 0; dd < 4; ++dd) {
                uint2 pv;
                pv.x = (unsigned)f2bf(vreg0[dd]) | ((unsigned)f2bf(vreg1[dd]) << 16);
                pv.y = (unsigned)f2bf(vreg2[dd]) | ((unsigned)f2bf(vreg3[dd]) << 16);
                *(uint2*)&VtL[(vt_d0 + dd) * KS + vt_s0] = pv;   // ds_write_b64
            }
        }
        __syncthreads();          // tile visible to all waves
        if (c0 + 64 <= rb) ATT_ISSUE(c0 + 64)

        f32x4 sacc[4];
        #pragma unroll
        for (int ct = 0; ct < 4; ++ct) {
            bf16x8 ka0 = *(bf16x8*)&KsL[(ct * 16 + l16) * KS + lq * 8];
            bf16x8 ka1 = *(bf16x8*)&KsL[(ct * 16 + l16) * KS + 32 + lq * 8];
            f32x4 acc = {0.f, 0.f, 0.f, 0.f};
            acc = __builtin_amdgcn_mfma_f32_16x16x32_bf16(ka0, qf[0], acc, 0, 0, 0);
            acc = __builtin_amdgcn_mfma_f32_16x16x32_bf16(ka1, qf[1], acc, 0, 0, 0);
            sacc[ct] = acc;
        }

        float sv[4][4];
        float tm = -3e38f;
        #pragma unroll
        for (int ct = 0; ct < 4; ++ct) {
            int sbase = c0 + ct * 16 + lq * 4;
            #pragma unroll
            for (int r = 0; r < 4; ++r) {
                float s = sacc[ct][r] * SCALE;
                if (sbase + r > qrow_i) s = -3e38f;
                sv[ct][r] = s;
                tm = fmaxf(tm, s);
            }
        }
        tm = fmaxf(tm, __shfl_xor(tm, 16));
        tm = fmaxf(tm, __shfl_xor(tm, 32));
        float mn = fmaxf(mrow, tm);
        float corr = __expf(mrow - mn);
        mrow = mn;

        float ps = 0.f;
        #pragma unroll
        for (int ct = 0; ct < 4; ++ct) {
            float p0 = __expf(sv[ct][0] - mn);
            float p1 = __expf(sv[ct][1] - mn);
            float p2 = __expf(sv[ct][2] - mn);
            float p3 = __expf(sv[ct][3] - mn);
            ps += (p0 + p1) + (p2 + p3);
            uint2 wv;
            wv.x = (unsigned)f2bf(p0) | ((unsigned)f2bf(p1) << 16);
            wv.y = (unsigned)f2bf(p2) | ((unsigned)f2bf(p3) << 16);
            *(uint2*)&PLw[l16 * 36 + ct * 8 + lq * 2] = wv;
        }
        ps += __shfl_xor(ps, 16);
        ps += __shfl_xor(ps, 32);
        lrow = lrow * corr + ps;

        float corr_o[4];
        #pragma unroll
        for (int r = 0; r < 4; ++r)
            corr_o[r] = __shfl(corr, (lane & 48) + lq * 4 + r);
        #pragma unroll
        for (int dt = 0; dt < 4; ++dt) {
            #pragma unroll
            for (int r = 0; r < 4; ++r)
                oacc[dt][r] *= corr_o[r];
        }

        bf16x8 pa0 = *(bf16x8*)&PLw[l16 * 36 + lq * 4];
        bf16x8 pa1 = *(bf16x8*)&PLw[l16 * 36 + 16 + lq * 4];
        #pragma unroll
        for (int dt = 0; dt < 4; ++dt) {
            bf16x8 vv0 = *(bf16x8*)&VtL[(dt * 16 + l16) * KS + lq * 8];
            bf16x8 vv1 = *(bf16x8*)&VtL[(dt * 16 + l16) * KS + 32 + lq * 8];
            oacc[dt] = __builtin_amdgcn_mfma_f32_16x16x32_bf16(pa0, vv0, oacc[dt], 0, 0, 0);
            oacc[dt] = __builtin_amdgcn_mfma_f32_16x16x32_bf16(pa1, vv1, oacc[dt], 0, 0, 0);
        }
    }
#undef ATT_ISSUE

    float li = 1.f / lrow;
    float linv_o[4];
    #pragma unroll
    for (int r = 0; r < 4; ++r)
        linv_o[r] = __shfl(li, (lane & 48) + lq * 4 + r);
    #pragma unroll
    for (int dt = 0; dt < 4; ++dt) {
        #pragma unroll
        for (int r = 0; r < 4; ++r) {
            int row = qr0 + lq * 4 + r;
            y[(size_t)row * EE + h * DD + dt * 16 + l16] = f2bf(oacc[dt][r] * linv_o[r]);
        }
    }
}

// ---------------------------------------------------------------------------
extern "C" void kernel_launch(void* const* d_in, const int* in_sizes, int n_in,
                              void* d_out, int out_size, void* d_ws, size_t ws_size,
                              hipStream_t stream)
{
    (void)in_sizes; (void)n_in; (void)out_size; (void)ws_size;
    const float* x      = (const float*)d_in[0];
    const float* w_attn = (const float*)d_in[1];
    const float* w_proj = (const float*)d_in[2];
    const float* qcw    = (const float*)d_in[3];
    const float* kcw    = (const float*)d_in[4];
    const float* vcw    = (const float*)d_in[5];
    const float* cosb   = (const float*)d_in[6];
    const float* sinb   = (const float*)d_in[7];
    const float* beta   = (const float*)d_in[8];
    const float* g      = (const float*)d_in[9];
    float* out = (float*)d_out;
    float* ws  = (float*)d_ws;

    const size_t TE = (size_t)TT * EE;
    float* buf0 = ws + 0 * TE;          // qkv -> BtT hi/lo bf16 planes
    float* buf1 = ws + 1 * TE;          // qkv -> Ct -> ybf
    float* buf2 = ws + 2 * TE;          // qkv -> Ft -> wpT
    float* qb   = ws + 3 * TE;          // xbf -> q
    float* kb   = ws + 4 * TE;          // waT -> k
    float* vb   = ws + 5 * TE;          // v -> E -> O
    float* qkv  = buf0;
    ushort* xbf = (ushort*)qb;
    ushort* waT = (ushort*)kb;
    ushort* ybf = (ushort*)buf1;
    ushort* wpT = (ushort*)buf2;
    ushort* BtTh = (ushort*)buf0;               // 4MB hi plane
    ushort* BtTl = (ushort*)buf0 + 2097152;     // 4MB lo plane
    float* Sbuf = out;                  // d_out as S-tile scratch

    cvt_bf16_kernel<<<TT * EE / 2048, 256, 0, stream>>>(x, xbf);
    cvt_transpose_kernel<<<dim3(NN / 64, EE / 64), 256, 0, stream>>>(w_attn, waT, EE, NN);
    gemm_bf16<128, 128><<<dim3(NN / 128, TT / 128), 256, 0, stream>>>(
        xbf, waT, qkv, TT, NN, EE);
    conv_rope_kernel<<<dim3(TT / 4, HH, 3), dim3(64, 4), 0, stream>>>(
        qkv, qcw, kcw, vcw, cosb, sinb, qb, kb, vb);
    chunk_prep_kernel<<<dim3(NCH, HH), 256, 0, stream>>>(
        qb, kb, vb, beta, g, BtTh, BtTl, buf1, buf2);
    delta_scan5_kernel<<<dim3(SCPH * HH), 256, 0, stream>>>(BtTh, BtTl, buf1, g, Sbuf);
    delta_apply_kernel<<<dim3(NCH, HH), 256, 0, stream>>>(Sbuf, buf2, vb);
    cvt_transpose_kernel<<<dim3(EE / 64, EE / 64), 256, 0, stream>>>(w_proj, wpT, EE, EE);
    attn_mfma_kernel<<<dim3(512), 256, 0, stream>>>(qb, kb, vb, ybf);
    gemm_bf16<64, 64><<<dim3(EE / 64, TT / 64), 256, 0, stream>>>(
        ybf, wpT, out, TT, EE, EE);
}